// Round 7
// baseline (2534.959 us; speedup 1.0000x reference)
//
#include <hip/hip_runtime.h>
#include <cstdint>
#include <cstddef>

typedef __attribute__((ext_vector_type(8))) short bf16x8;
typedef __attribute__((ext_vector_type(4))) float f32x4;

#define S_LEN 2048
#define DMODEL 4096
#define NHQ 32
#define NHKV 8
#define HDIM 128
#define KVDIM 1024
#define NKEEP 640
#define SEL_N 1536

__device__ __forceinline__ short f2bf(float f) {
  unsigned u = __float_as_uint(f);
  u += 0x7fffu + ((u >> 16) & 1u);
  return (short)(u >> 16);
}
__device__ __forceinline__ float bf2f(short s) {
  return __uint_as_float(((unsigned)(unsigned short)s) << 16);
}
// EXACT 3-way split: x == h + m + l for normal-range f32 (8+8+8 mantissa bits)
__device__ __forceinline__ void split3(float x, short& h, short& m, short& l) {
  unsigned u = __float_as_uint(x) & 0xffff0000u;
  h = (short)(u >> 16);
  float r1 = x - __uint_as_float(u);
  unsigned v = __float_as_uint(r1) & 0xffff0000u;
  m = (short)(v >> 16);
  float r2 = r1 - __uint_as_float(v);
  l = (short)(__float_as_uint(r2) >> 16);
}
__device__ __forceinline__ f32x4 mfma16(bf16x8 a, bf16x8 b, f32x4 c) {
  return __builtin_amdgcn_mfma_f32_16x16x32_bf16(a, b, c, 0, 0, 0);
}
__device__ __forceinline__ size_t climp(size_t i, size_t sz, size_t w) {
  size_t hi = sz - w;
  return i <= hi ? i : hi;
}

// ---------------- gemm_hp3: C(f32)[M,N] = A(f32)[M,Kd] * B(f32)[Kd,N]
// exact 3-split, 6 terms (>=2^-24), per-chunk f32 MFMA -> f64 fold.
// Block tile 128(M) x 64(N), 4 waves (2Mx2N), wave = 64x32 = 4x2 frags.
__global__ __launch_bounds__(256, 2) void gemm_hp3(const float* __restrict__ A,
                                                   const float* __restrict__ B,
                                                   float* __restrict__ C,
                                                   int M, int N, int Kd) {
  __shared__ alignas(16) short Ah[128 * 40];
  __shared__ alignas(16) short Am[128 * 40];
  __shared__ alignas(16) short Al[128 * 40];
  __shared__ alignas(16) short Bh[64 * 40];
  __shared__ alignas(16) short Bm[64 * 40];
  __shared__ alignas(16) short Bl[64 * 40];
  int tid = threadIdx.x;
  int lane = tid & 63, wave = tid >> 6;
  int l15 = lane & 15, l4 = lane >> 4;
  int m0 = blockIdx.x * 128, n0 = blockIdx.y * 64;
  int wm = (wave >> 1) * 64, wn = (wave & 1) * 32;
  const size_t aSz = (size_t)M * Kd, bSz = (size_t)Kd * N, cSz = (size_t)M * N;
  double accd[4][2][4];
#pragma unroll
  for (int i = 0; i < 4; i++)
#pragma unroll
    for (int j = 0; j < 2; j++)
#pragma unroll
      for (int r = 0; r < 4; r++) accd[i][j][r] = 0.0;
  f32x4 zf = {0.f, 0.f, 0.f, 0.f};

  for (int k0 = 0; k0 < Kd; k0 += 32) {
    // A tile 128x32
#pragma unroll
    for (int c = 0; c < 2; c++) {
      int idx = tid + c * 256;
      int r = idx >> 2, c8 = (idx & 3) * 8;
      size_t ai = climp((size_t)(m0 + r) * Kd + k0 + c8, aSz, 8);
      const float* Ap = A + ai;
      float4 v0 = *reinterpret_cast<const float4*>(Ap);
      float4 v1 = *reinterpret_cast<const float4*>(Ap + 4);
      float vv[8] = {v0.x, v0.y, v0.z, v0.w, v1.x, v1.y, v1.z, v1.w};
      bf16x8 sh, sm, sl;
#pragma unroll
      for (int t = 0; t < 8; t++) { short a, b, cc; split3(vv[t], a, b, cc); sh[t] = a; sm[t] = b; sl[t] = cc; }
      *reinterpret_cast<bf16x8*>(&Ah[r * 40 + c8]) = sh;
      *reinterpret_cast<bf16x8*>(&Am[r * 40 + c8]) = sm;
      *reinterpret_cast<bf16x8*>(&Al[r * 40 + c8]) = sl;
    }
    // B tile 32x64 -> [n][k]
    {
      int n = tid & 63, kg = (tid >> 6) * 8;
      bf16x8 sh, sm, sl;
#pragma unroll
      for (int t = 0; t < 8; t++) {
        size_t bi = climp((size_t)(k0 + kg + t) * N + n0 + n, bSz, 1);
        short a, b, cc;
        split3(B[bi], a, b, cc);
        sh[t] = a; sm[t] = b; sl[t] = cc;
      }
      *reinterpret_cast<bf16x8*>(&Bh[n * 40 + kg]) = sh;
      *reinterpret_cast<bf16x8*>(&Bm[n * 40 + kg]) = sm;
      *reinterpret_cast<bf16x8*>(&Bl[n * 40 + kg]) = sl;
    }
    __syncthreads();
    bf16x8 bh[2], bm[2], bl[2];
#pragma unroll
    for (int nf = 0; nf < 2; nf++) {
      int br = (wn + nf * 16 + l15) * 40 + l4 * 8;
      bh[nf] = *reinterpret_cast<const bf16x8*>(&Bh[br]);
      bm[nf] = *reinterpret_cast<const bf16x8*>(&Bm[br]);
      bl[nf] = *reinterpret_cast<const bf16x8*>(&Bl[br]);
    }
#pragma unroll
    for (int mf = 0; mf < 4; mf++) {
      int ar = (wm + mf * 16 + l15) * 40 + l4 * 8;
      bf16x8 ah = *reinterpret_cast<const bf16x8*>(&Ah[ar]);
      bf16x8 am = *reinterpret_cast<const bf16x8*>(&Am[ar]);
      bf16x8 al = *reinterpret_cast<const bf16x8*>(&Al[ar]);
#pragma unroll
      for (int nf = 0; nf < 2; nf++) {
        // ascending-magnitude 6-term chain: am*bm, ah*bl, al*bh, ah*bm, am*bh, ah*bh
        f32x4 cc = mfma16(am, bm[nf], zf);
        cc = mfma16(ah, bl[nf], cc);
        cc = mfma16(al, bh[nf], cc);
        cc = mfma16(ah, bm[nf], cc);
        cc = mfma16(am, bh[nf], cc);
        cc = mfma16(ah, bh[nf], cc);
#pragma unroll
        for (int r = 0; r < 4; r++) accd[mf][nf][r] += (double)cc[r];
      }
    }
    __syncthreads();
  }
  int rbase = m0 + wm + (l4 << 2);
  int cbase = n0 + wn + l15;
#pragma unroll
  for (int mf = 0; mf < 4; mf++)
#pragma unroll
    for (int nf = 0; nf < 2; nf++)
#pragma unroll
      for (int r = 0; r < 4; r++) {
        int row = rbase + mf * 16 + r;
        int col = cbase + nf * 16;
        size_t ci = (size_t)row * N + col;
        if (row < M && col < N && ci < cSz) C[ci] = (float)accd[mf][nf][r];
      }
}

// ---------------- plain bf16 GEMM (V projection, O projection)
template <int A_F32, int STORE_BF16>
__global__ __launch_bounds__(256, 2) void gemm128(const void* __restrict__ Av,
                                                  const float* __restrict__ B,
                                                  void* __restrict__ Cv,
                                                  int M, int N, int Kd) {
  __shared__ alignas(16) short Al[128 * 72];
  __shared__ alignas(16) short Bl[128 * 72];
  int tid = threadIdx.x;
  int lane = tid & 63, wave = tid >> 6;
  int l15 = lane & 15, l4 = lane >> 4;
  int m0 = blockIdx.x * 128, n0 = blockIdx.y * 128;
  int wm = (wave >> 1) * 64, wn = (wave & 1) * 64;
  const size_t aSz = (size_t)M * Kd, bSz = (size_t)Kd * N, cSz = (size_t)M * N;
  f32x4 zf = {0.f, 0.f, 0.f, 0.f};
  f32x4 acc[4][4];
#pragma unroll
  for (int i = 0; i < 4; i++)
#pragma unroll
    for (int j = 0; j < 4; j++) acc[i][j] = zf;

  for (int k0 = 0; k0 < Kd; k0 += 64) {
#pragma unroll
    for (int c = 0; c < 4; c++) {
      int idx = tid + c * 256;
      int r = idx >> 3, k8 = (idx & 7) * 8;
      size_t ai = climp((size_t)(m0 + r) * Kd + k0 + k8, aSz, 8);
      bf16x8 a;
      if constexpr (A_F32 != 0) {
        const float* Ap = (const float*)Av + ai;
        float4 v0 = *reinterpret_cast<const float4*>(Ap);
        float4 v1 = *reinterpret_cast<const float4*>(Ap + 4);
        a[0] = f2bf(v0.x); a[1] = f2bf(v0.y); a[2] = f2bf(v0.z); a[3] = f2bf(v0.w);
        a[4] = f2bf(v1.x); a[5] = f2bf(v1.y); a[6] = f2bf(v1.z); a[7] = f2bf(v1.w);
      } else {
        a = *reinterpret_cast<const bf16x8*>((const short*)Av + ai);
      }
      *reinterpret_cast<bf16x8*>(&Al[r * 72 + k8]) = a;
    }
#pragma unroll
    for (int c = 0; c < 4; c++) {
      int idx = tid + c * 256;
      int n = idx & 127, kg = (idx >> 7) * 8;
      bf16x8 b;
#pragma unroll
      for (int t = 0; t < 8; t++) {
        size_t bi = climp((size_t)(k0 + kg + t) * N + n0 + n, bSz, 1);
        b[t] = f2bf(B[bi]);
      }
      *reinterpret_cast<bf16x8*>(&Bl[n * 72 + kg]) = b;
    }
    __syncthreads();
    bf16x8 af[4][2], bfr[4][2];
#pragma unroll
    for (int mf = 0; mf < 4; mf++)
#pragma unroll
      for (int ks = 0; ks < 2; ks++)
        af[mf][ks] = *reinterpret_cast<const bf16x8*>(
            &Al[(wm + mf * 16 + l15) * 72 + ks * 32 + l4 * 8]);
#pragma unroll
    for (int nf = 0; nf < 4; nf++)
#pragma unroll
      for (int ks = 0; ks < 2; ks++)
        bfr[nf][ks] = *reinterpret_cast<const bf16x8*>(
            &Bl[(wn + nf * 16 + l15) * 72 + ks * 32 + l4 * 8]);
#pragma unroll
    for (int ks = 0; ks < 2; ks++)
#pragma unroll
      for (int mf = 0; mf < 4; mf++)
#pragma unroll
        for (int nf = 0; nf < 4; nf++)
          acc[mf][nf] = mfma16(af[mf][ks], bfr[nf][ks], acc[mf][nf]);
    __syncthreads();
  }
  int rbase = m0 + wm + (l4 << 2);
  int cbase = n0 + wn + l15;
#pragma unroll
  for (int mf = 0; mf < 4; mf++)
#pragma unroll
    for (int nf = 0; nf < 4; nf++)
#pragma unroll
      for (int r = 0; r < 4; r++) {
        int row = rbase + mf * 16 + r;
        int col = cbase + nf * 16;
        size_t ci = (size_t)row * N + col;
        if (row < M && col < N && ci < cSz) {
          float v = acc[mf][nf][r];
          if constexpr (STORE_BF16 != 0)
            ((short*)Cv)[ci] = f2bf(v);
          else
            ((float*)Cv)[ci] = v;
        }
      }
}

// ---------------- RoPE in-place on f32 buffer (s, NH*128)
template <int NH>
__global__ __launch_bounds__(256) void rope_f32(float* __restrict__ buf,
                                                const float* __restrict__ cosb,
                                                const float* __restrict__ sinb,
                                                const int* __restrict__ pos) {
  int idx = blockIdx.x * 256 + threadIdx.x;
  if (idx >= S_LEN * NH * 64) return;
  int d = idx & 63;
  int h = (idx >> 6) % NH;
  int s = idx / (64 * NH);
  int p = pos[s];
  if (p < 0) p = 0;
  if (p >= S_LEN) p = S_LEN - 1;
  size_t base = ((size_t)s * NH + h) * 128 + d;
  float lo = buf[base], hi = buf[base + 64];
  float c0 = cosb[p * 128 + d], s0 = sinb[p * 128 + d];
  float c1 = cosb[p * 128 + d + 64], s1 = sinb[p * 128 + d + 64];
  buf[base] = lo * c0 - hi * s0;
  buf[base + 64] = hi * c1 + lo * s1;
}

// ---------------- V transpose: (s, g, d) -> (g, d, s) bf16
__global__ __launch_bounds__(128) void vtrans_k(const short* __restrict__ v,
                                                short* __restrict__ vT) {
  int g = blockIdx.y;
  int s0 = blockIdx.x * 8;
  int d = threadIdx.x;
  if (s0 + 7 >= S_LEN || g >= NHKV || d >= HDIM) return;
  const size_t vSz = (size_t)S_LEN * KVDIM;
  bf16x8 vals;
#pragma unroll
  for (int i = 0; i < 8; i++)
    vals[i] = v[climp((size_t)(s0 + i) * KVDIM + g * HDIM + d, vSz, 1)];
  *reinterpret_cast<bf16x8*>(vT + climp(((size_t)g * HDIM + d) * S_LEN + s0,
                                        (size_t)NHKV * HDIM * S_LEN, 8)) = vals;
}

// ---------------- attn_ml3: hp m, l per (head, q-row)
__global__ __launch_bounds__(256, 2) void attn_ml3(const float* __restrict__ qf,
                                                   const float* __restrict__ kf,
                                                   float* __restrict__ mbuf,
                                                   float* __restrict__ lbuf) {
  int h = blockIdx.x, qt = blockIdx.y;
  int g = h >> 2;
  int q0 = qt * 128;
  int tid = threadIdx.x, lane = tid & 63, wave = tid >> 6;
  int l15 = lane & 15, l4 = lane >> 4;
  __shared__ alignas(16) short Kh[32 * 136];
  __shared__ alignas(16) short Km[32 * 136];
  __shared__ alignas(16) short Kl[32 * 136];
  const size_t qSz = (size_t)S_LEN * DMODEL;
  const size_t kSz = (size_t)S_LEN * KVDIM;

  int qrow_base = q0 + wave * 32;
  bf16x8 qh[2][4], qm[2][4], ql[2][4];
#pragma unroll
  for (int mf = 0; mf < 2; mf++)
#pragma unroll
    for (int ks = 0; ks < 4; ks++) {
      size_t qi = climp((size_t)(qrow_base + mf * 16 + l15) * DMODEL + h * HDIM + ks * 32 + l4 * 8,
                        qSz, 8);
      const float* Qp = qf + qi;
      float4 v0 = *reinterpret_cast<const float4*>(Qp);
      float4 v1 = *reinterpret_cast<const float4*>(Qp + 4);
      float vv[8] = {v0.x, v0.y, v0.z, v0.w, v1.x, v1.y, v1.z, v1.w};
      bf16x8 sh, sm, sl;
#pragma unroll
      for (int t = 0; t < 8; t++) { short a, b, cc; split3(vv[t], a, b, cc); sh[t] = a; sm[t] = b; sl[t] = cc; }
      qh[mf][ks] = sh; qm[mf][ks] = sm; ql[mf][ks] = sl;
    }

  float mrow[2][4], lrow[2][4];
#pragma unroll
  for (int mf = 0; mf < 2; mf++)
#pragma unroll
    for (int r = 0; r < 4; r++) { mrow[mf][r] = -1e30f; lrow[mf][r] = 0.f; }
  int wqmax = qrow_base + 31;
  int nkt = qt * 4 + 4;
  const float scale = 0.08838834764831845f;
  f32x4 zf = {0.f, 0.f, 0.f, 0.f};

  for (int kt = 0; kt < nkt; kt++) {
    int k0 = kt * 32;
#pragma unroll
    for (int c = 0; c < 2; c++) {
      int idx = tid + c * 256;
      int r = idx >> 4, c8 = (idx & 15) * 8;
      size_t ki = climp((size_t)(k0 + r) * KVDIM + g * HDIM + c8, kSz, 8);
      const float* Kp = kf + ki;
      float4 v0 = *reinterpret_cast<const float4*>(Kp);
      float4 v1 = *reinterpret_cast<const float4*>(Kp + 4);
      float vv[8] = {v0.x, v0.y, v0.z, v0.w, v1.x, v1.y, v1.z, v1.w};
      bf16x8 sh, sm, sl;
#pragma unroll
      for (int t = 0; t < 8; t++) { short a, b, cc; split3(vv[t], a, b, cc); sh[t] = a; sm[t] = b; sl[t] = cc; }
      *reinterpret_cast<bf16x8*>(&Kh[r * 136 + c8]) = sh;
      *reinterpret_cast<bf16x8*>(&Km[r * 136 + c8]) = sm;
      *reinterpret_cast<bf16x8*>(&Kl[r * 136 + c8]) = sl;
    }
    __syncthreads();
    if (k0 <= wqmax) {
      double sd[2][2][4];
#pragma unroll
      for (int mf = 0; mf < 2; mf++)
#pragma unroll
        for (int nf = 0; nf < 2; nf++)
#pragma unroll
          for (int r = 0; r < 4; r++) sd[mf][nf][r] = 0.0;
#pragma unroll
      for (int ks = 0; ks < 4; ks++) {
#pragma unroll
        for (int nf = 0; nf < 2; nf++) {
          int kr = (nf * 16 + l15) * 136 + ks * 32 + l4 * 8;
          bf16x8 bh = *reinterpret_cast<const bf16x8*>(&Kh[kr]);
          bf16x8 bm = *reinterpret_cast<const bf16x8*>(&Km[kr]);
          bf16x8 bl = *reinterpret_cast<const bf16x8*>(&Kl[kr]);
#pragma unroll
          for (int mf = 0; mf < 2; mf++) {
            // products in order: QmKm, QhKl, QlKh, QhKm, QmKh, QhKh
            f32x4 cc = mfma16(qm[mf][ks], bm, zf);
            cc = mfma16(qh[mf][ks], bl, cc);
            cc = mfma16(ql[mf][ks], bh, cc);
            cc = mfma16(qh[mf][ks], bm, cc);
            cc = mfma16(qm[mf][ks], bh, cc);
            cc = mfma16(qh[mf][ks], bh, cc);
#pragma unroll
            for (int r = 0; r < 4; r++) sd[mf][nf][r] += (double)cc[r];
          }
        }
      }
#pragma unroll
      for (int mf = 0; mf < 2; mf++) {
#pragma unroll
        for (int r = 0; r < 4; r++) {
          int qg = qrow_base + mf * 16 + (l4 << 2) + r;
          float v0 = (float)sd[mf][0][r] * scale;
          float v1 = (float)sd[mf][1][r] * scale;
          if (k0 + l15 > qg) v0 = -1e9f;
          if (k0 + 16 + l15 > qg) v1 = -1e9f;
          float mx = fmaxf(v0, v1);
          mx = fmaxf(mx, __shfl_xor(mx, 1));
          mx = fmaxf(mx, __shfl_xor(mx, 2));
          mx = fmaxf(mx, __shfl_xor(mx, 4));
          mx = fmaxf(mx, __shfl_xor(mx, 8));
          float mnew = fmaxf(mrow[mf][r], mx);
          float alpha = expf(mrow[mf][r] - mnew);
          float rs = expf(v0 - mnew) + expf(v1 - mnew);
          rs += __shfl_xor(rs, 1);
          rs += __shfl_xor(rs, 2);
          rs += __shfl_xor(rs, 4);
          rs += __shfl_xor(rs, 8);
          lrow[mf][r] = lrow[mf][r] * alpha + rs;
          mrow[mf][r] = mnew;
        }
      }
    }
    __syncthreads();
  }
  if (l15 == 0) {
#pragma unroll
    for (int mf = 0; mf < 2; mf++)
#pragma unroll
      for (int r = 0; r < 4; r++) {
        int row = qrow_base + mf * 16 + (l4 << 2) + r;
        if (row < S_LEN) {
          mbuf[(size_t)h * S_LEN + row] = mrow[mf][r];
          lbuf[(size_t)h * S_LEN + row] = lrow[mf][r];
        }
      }
  }
}

// ---------------- attn_fwd: O from bf16 scores + precomputed hp m,l
__global__ __launch_bounds__(256, 2) void attn_fwd(const float* __restrict__ qf,
                                                   const float* __restrict__ kf,
                                                   const short* __restrict__ vT,
                                                   short* __restrict__ ob,
                                                   const float* __restrict__ mbuf,
                                                   const float* __restrict__ lbuf) {
  int h = blockIdx.x, qt = blockIdx.y;
  int g = h >> 2;
  int q0 = qt * 128;
  int tid = threadIdx.x, lane = tid & 63, wave = tid >> 6;
  int l15 = lane & 15, l4 = lane >> 4;
  __shared__ alignas(16) short Kl[32 * 136];
  __shared__ alignas(16) short Vl[128 * 40];
  __shared__ alignas(16) short Pl[4][32 * 40];
  const size_t qSz = (size_t)S_LEN * DMODEL;
  const size_t kSz = (size_t)S_LEN * KVDIM;
  const size_t vtSz = (size_t)NHKV * HDIM * S_LEN;

  int qrow_base = q0 + wave * 32;
  bf16x8 qfr[2][4];
#pragma unroll
  for (int mf = 0; mf < 2; mf++)
#pragma unroll
    for (int ks = 0; ks < 4; ks++) {
      size_t qi = climp((size_t)(qrow_base + mf * 16 + l15) * DMODEL + h * HDIM + ks * 32 + l4 * 8,
                        qSz, 8);
      const float* Qp = qf + qi;
      float4 v0 = *reinterpret_cast<const float4*>(Qp);
      float4 v1 = *reinterpret_cast<const float4*>(Qp + 4);
      bf16x8 a;
      a[0] = f2bf(v0.x); a[1] = f2bf(v0.y); a[2] = f2bf(v0.z); a[3] = f2bf(v0.w);
      a[4] = f2bf(v1.x); a[5] = f2bf(v1.y); a[6] = f2bf(v1.z); a[7] = f2bf(v1.w);
      qfr[mf][ks] = a;
    }

  float mrow[2][4], rlrow[2][4];
#pragma unroll
  for (int mf = 0; mf < 2; mf++)
#pragma unroll
    for (int r = 0; r < 4; r++) {
      int row = qrow_base + mf * 16 + (l4 << 2) + r;
      size_t mi = climp((size_t)h * S_LEN + row, (size_t)NHQ * S_LEN, 1);
      mrow[mf][r] = mbuf[mi];
      rlrow[mf][r] = 1.0f / lbuf[mi];
    }

  f32x4 zf = {0.f, 0.f, 0.f, 0.f};
  f32x4 accO[2][8];
#pragma unroll
  for (int mf = 0; mf < 2; mf++)
#pragma unroll
    for (int nfo = 0; nfo < 8; nfo++) accO[mf][nfo] = zf;
  int wqmax = qrow_base + 31;
  int nkt = qt * 4 + 4;
  const float scale = 0.08838834764831845f;

  for (int kt = 0; kt < nkt; kt++) {
    int k0 = kt * 32;
#pragma unroll
    for (int c = 0; c < 2; c++) {
      int idx = tid + c * 256;
      int r = idx >> 4, c8 = (idx & 15) * 8;
      size_t ki = climp((size_t)(k0 + r) * KVDIM + g * HDIM + c8, kSz, 8);
      const float* Kp = kf + ki;
      float4 v0 = *reinterpret_cast<const float4*>(Kp);
      float4 v1 = *reinterpret_cast<const float4*>(Kp + 4);
      bf16x8 a;
      a[0] = f2bf(v0.x); a[1] = f2bf(v0.y); a[2] = f2bf(v0.z); a[3] = f2bf(v0.w);
      a[4] = f2bf(v1.x); a[5] = f2bf(v1.y); a[6] = f2bf(v1.z); a[7] = f2bf(v1.w);
      *reinterpret_cast<bf16x8*>(&Kl[r * 136 + c8]) = a;
    }
#pragma unroll
    for (int c = 0; c < 2; c++) {
      int idx = tid + c * 256;
      int r = idx >> 2, c8 = idx & 3;
      *reinterpret_cast<bf16x8*>(&Vl[r * 40 + c8 * 8]) =
          *reinterpret_cast<const bf16x8*>(
              vT + climp(((size_t)g * HDIM + r) * S_LEN + k0 + c8 * 8, vtSz, 8));
    }
    __syncthreads();
    if (k0 <= wqmax) {
      f32x4 sf[2][2] = {{zf, zf}, {zf, zf}};
#pragma unroll
      for (int nf = 0; nf < 2; nf++)
#pragma unroll
        for (int ks = 0; ks < 4; ks++) {
          bf16x8 bk = *reinterpret_cast<const bf16x8*>(
              &Kl[(nf * 16 + l15) * 136 + ks * 32 + l4 * 8]);
          sf[0][nf] = mfma16(qfr[0][ks], bk, sf[0][nf]);
          sf[1][nf] = mfma16(qfr[1][ks], bk, sf[1][nf]);
        }
#pragma unroll
      for (int mf = 0; mf < 2; mf++)
#pragma unroll
        for (int r = 0; r < 4; r++) {
          int qg = qrow_base + mf * 16 + (l4 << 2) + r;
          float v0 = sf[mf][0][r] * scale;
          float v1 = sf[mf][1][r] * scale;
          if (k0 + l15 > qg) v0 = -1e9f;
          if (k0 + 16 + l15 > qg) v1 = -1e9f;
          float p0 = __expf(v0 - mrow[mf][r]);
          float p1 = __expf(v1 - mrow[mf][r]);
          Pl[wave][(mf * 16 + (l4 << 2) + r) * 40 + l15] = f2bf(p0);
          Pl[wave][(mf * 16 + (l4 << 2) + r) * 40 + 16 + l15] = f2bf(p1);
        }
      bf16x8 pa[2];
      pa[0] = *reinterpret_cast<const bf16x8*>(&Pl[wave][(0 + l15) * 40 + l4 * 8]);
      pa[1] = *reinterpret_cast<const bf16x8*>(&Pl[wave][(16 + l15) * 40 + l4 * 8]);
#pragma unroll
      for (int nfo = 0; nfo < 8; nfo++) {
        bf16x8 bv = *reinterpret_cast<const bf16x8*>(&Vl[(nfo * 16 + l15) * 40 + l4 * 8]);
        accO[0][nfo] = mfma16(pa[0], bv, accO[0][nfo]);
        accO[1][nfo] = mfma16(pa[1], bv, accO[1][nfo]);
      }
    }
    __syncthreads();
  }
#pragma unroll
  for (int mf = 0; mf < 2; mf++)
#pragma unroll
    for (int nfo = 0; nfo < 8; nfo++)
#pragma unroll
      for (int r = 0; r < 4; r++) {
        int row = qrow_base + mf * 16 + (l4 << 2) + r;
        int col = h * HDIM + nfo * 16 + l15;
        if (row < S_LEN && col < DMODEL)
          ob[(size_t)row * DMODEL + col] = f2bf(accO[mf][nfo][r] * rlrow[mf][r]);
      }
}

// ---------------- attn_hh3: hp column sums (order-matched to attn_ml3)
__global__ __launch_bounds__(256, 2) void attn_hh3(const float* __restrict__ qf,
                                                   const float* __restrict__ kf,
                                                   const float* __restrict__ mbuf,
                                                   const float* __restrict__ lbuf,
                                                   float* __restrict__ hh_h) {
  int h = blockIdx.x, kt = blockIdx.y;
  int g = h >> 2;
  int key0 = kt * 128;
  int tid = threadIdx.x, lane = tid & 63, wave = tid >> 6;
  int l15 = lane & 15, l4 = lane >> 4;
  __shared__ alignas(16) short Qh[32 * 136];
  __shared__ alignas(16) short Qm[32 * 136];
  __shared__ alignas(16) short Ql[32 * 136];
  const size_t qSz = (size_t)S_LEN * DMODEL;
  const size_t kSz = (size_t)S_LEN * KVDIM;
  const size_t mlSz = (size_t)NHQ * S_LEN;
  const float scale = 0.08838834764831845f;
  f32x4 zf = {0.f, 0.f, 0.f, 0.f};

  int keymin = key0 + wave * 32;
  bf16x8 akh[2][4], akm[2][4], akl[2][4];
#pragma unroll
  for (int mf = 0; mf < 2; mf++)
#pragma unroll
    for (int ks = 0; ks < 4; ks++) {
      size_t ki = climp((size_t)(keymin + mf * 16 + l15) * KVDIM + g * HDIM + ks * 32 + l4 * 8,
                        kSz, 8);
      const float* Kp = kf + ki;
      float4 v0 = *reinterpret_cast<const float4*>(Kp);
      float4 v1 = *reinterpret_cast<const float4*>(Kp + 4);
      float vv[8] = {v0.x, v0.y, v0.z, v0.w, v1.x, v1.y, v1.z, v1.w};
      bf16x8 sh, sm, sl;
#pragma unroll
      for (int t = 0; t < 8; t++) { short a, b, cc; split3(vv[t], a, b, cc); sh[t] = a; sm[t] = b; sl[t] = cc; }
      akh[mf][ks] = sh; akm[mf][ks] = sm; akl[mf][ks] = sl;
    }

  double acc[2][4];
#pragma unroll
  for (int mf = 0; mf < 2; mf++)
#pragma unroll
    for (int r = 0; r < 4; r++) acc[mf][r] = 0.0;

  for (int q0 = key0; q0 < S_LEN; q0 += 32) {
#pragma unroll
    for (int c = 0; c < 2; c++) {
      int idx = tid + c * 256;
      int r = idx >> 4, c8 = (idx & 15) * 8;
      size_t qi = climp((size_t)(q0 + r) * DMODEL + h * HDIM + c8, qSz, 8);
      const float* Qp = qf + qi;
      float4 v0 = *reinterpret_cast<const float4*>(Qp);
      float4 v1 = *reinterpret_cast<const float4*>(Qp + 4);
      float vv[8] = {v0.x, v0.y, v0.z, v0.w, v1.x, v1.y, v1.z, v1.w};
      bf16x8 sh, sm, sl;
#pragma unroll
      for (int t = 0; t < 8; t++) { short a, b, cc; split3(vv[t], a, b, cc); sh[t] = a; sm[t] = b; sl[t] = cc; }
      *reinterpret_cast<bf16x8*>(&Qh[r * 136 + c8]) = sh;
      *reinterpret_cast<bf16x8*>(&Qm[r * 136 + c8]) = sm;
      *reinterpret_cast<bf16x8*>(&Ql[r * 136 + c8]) = sl;
    }
    __syncthreads();
    if (q0 + 31 >= keymin) {
      double sd[2][2][4];
#pragma unroll
      for (int mf = 0; mf < 2; mf++)
#pragma unroll
        for (int nf = 0; nf < 2; nf++)
#pragma unroll
          for (int r = 0; r < 4; r++) sd[mf][nf][r] = 0.0;
#pragma unroll
      for (int ks = 0; ks < 4; ks++) {
#pragma unroll
        for (int nf = 0; nf < 2; nf++) {
          int qr = (nf * 16 + l15) * 136 + ks * 32 + l4 * 8;
          bf16x8 bqh = *reinterpret_cast<const bf16x8*>(&Qh[qr]);
          bf16x8 bqm = *reinterpret_cast<const bf16x8*>(&Qm[qr]);
          bf16x8 bql = *reinterpret_cast<const bf16x8*>(&Ql[qr]);
#pragma unroll
          for (int mf = 0; mf < 2; mf++) {
            // same products, same order as ml3: KmQm, KlQh, KhQl, KmQh, KhQm, KhQh
            f32x4 cc = mfma16(akm[mf][ks], bqm, zf);
            cc = mfma16(akl[mf][ks], bqh, cc);
            cc = mfma16(akh[mf][ks], bql, cc);
            cc = mfma16(akm[mf][ks], bqh, cc);
            cc = mfma16(akh[mf][ks], bqm, cc);
            cc = mfma16(akh[mf][ks], bqh, cc);
#pragma unroll
            for (int r = 0; r < 4; r++) sd[mf][nf][r] += (double)cc[r];
          }
        }
      }
#pragma unroll
      for (int nf = 0; nf < 2; nf++) {
        int q = q0 + nf * 16 + l15;
        float mq = mbuf[climp((size_t)h * S_LEN + q, mlSz, 1)];
        float rl = 1.0f / lbuf[climp((size_t)h * S_LEN + q, mlSz, 1)];
#pragma unroll
        for (int mf = 0; mf < 2; mf++)
#pragma unroll
          for (int r = 0; r < 4; r++) {
            int key = keymin + mf * 16 + (l4 << 2) + r;
            if (q >= key && q < S_LEN)
              acc[mf][r] += (double)(expf((float)sd[mf][nf][r] * scale - mq) * rl);
          }
      }
    }
    __syncthreads();
  }
#pragma unroll
  for (int mf = 0; mf < 2; mf++)
#pragma unroll
    for (int r = 0; r < 4; r++) {
      double v = acc[mf][r];
      v += __shfl_xor(v, 1);
      v += __shfl_xor(v, 2);
      v += __shfl_xor(v, 4);
      v += __shfl_xor(v, 8);
      int key = keymin + mf * 16 + (l4 << 2) + r;
      if (l15 == 0 && key < S_LEN)
        hh_h[(size_t)h * S_LEN + key] = (float)v;
    }
}

// ---------------- top-k + gather
__global__ __launch_bounds__(512) void topk_gather(const float* __restrict__ hh_h,
                                                   const float* __restrict__ kfp,
                                                   const short* __restrict__ vb,
                                                   float* __restrict__ out_k,
                                                   float* __restrict__ out_v,
                                                   float* __restrict__ out_hh) {
  int g = blockIdx.x, t = threadIdx.x;
  __shared__ float hhg[2048];
  __shared__ float sv[2048];
  __shared__ int si[2048];
  __shared__ int st[128];
  __shared__ int keep[NKEEP];
  const size_t hhSz = (size_t)NHQ * S_LEN;
  const size_t kvSz = (size_t)S_LEN * KVDIM;
#pragma unroll
  for (int i = 0; i < 4; i++) {
    int idx = t + i * 512;
    float s = 0.25f * (hh_h[climp((size_t)(4 * g + 0) * 2048 + idx, hhSz, 1)] +
                       hh_h[climp((size_t)(4 * g + 1) * 2048 + idx, hhSz, 1)] +
                       hh_h[climp((size_t)(4 * g + 2) * 2048 + idx, hhSz, 1)] +
                       hh_h[climp((size_t)(4 * g + 3) * 2048 + idx, hhSz, 1)]);
    hhg[idx] = s;
    sv[idx] = (idx < SEL_N) ? s : -1e30f;
    si[idx] = idx;
  }
  __syncthreads();
  for (int k = 2; k <= 2048; k <<= 1) {
    for (int j = k >> 1; j > 0; j >>= 1) {
#pragma unroll
      for (int pass = 0; pass < 4; pass++) {
        int i = t + pass * 512;
        int ixj = i ^ j;
        if (ixj > i) {
          bool up = ((i & k) == 0);
          float a = sv[i], b = sv[ixj];
          int ia = si[i], ib = si[ixj];
          bool before = (a > b) || (a == b && ia < ib);
          bool doswap = up ? !before : before;
          if (doswap) { sv[i] = b; sv[ixj] = a; si[i] = ib; si[ixj] = ia; }
        }
      }
      __syncthreads();
    }
  }
  if (t < 128) st[t] = si[t];
  __syncthreads();
  for (int k = 2; k <= 128; k <<= 1) {
    for (int j = k >> 1; j > 0; j >>= 1) {
      if (t < 128) {
        int i = t, ixj = i ^ j;
        if (ixj > i) {
          bool up = ((i & k) == 0);
          int a = st[i], b = st[ixj];
          bool doswap = up ? (a > b) : (a < b);
          if (doswap) { st[i] = b; st[ixj] = a; }
        }
      }
      __syncthreads();
    }
  }
  // FIX (R1-R6 bug): 512 threads must initialize ALL 640 keep[] entries.
  // Old code: `if (t<128) ... else if (t<NKEEP) ...` left keep[512..639]
  // as stale LDS garbage -> OOB gathers (R1/R2 aborts) / wrong rows (R3-R6).
  for (int i = t; i < NKEEP; i += 512)
    keep[i] = (i < 128) ? st[i] : (SEL_N + (i - 128));
  __syncthreads();
  for (int i = 0; i < 160; i++) {
    int idx = t + i * 512;
    int jj = idx >> 7, d = idx & 127;
    int src = (jj < NKEEP) ? keep[jj] : 0;
    if (src < 0) src = 0;
    if (src >= S_LEN) src = S_LEN - 1;
    size_t oi = ((size_t)g * NKEEP + jj) * HDIM + d;
    if (jj < NKEEP) {
      out_k[oi] = kfp[climp((size_t)src * KVDIM + g * HDIM + d, kvSz, 1)];
      out_v[oi] = bf2f(vb[climp((size_t)src * KVDIM + g * HDIM + d, kvSz, 1)]);
    }
  }
  for (int i = t; i < NKEEP; i += 512) {
    int src = keep[i];
    if (src < 0) src = 0;
    if (src >= 2048) src = 2047;
    out_hh[(size_t)g * NKEEP + i] = hhg[src];
  }
}

extern "C" void kernel_launch(void* const* d_in, const int* in_sizes, int n_in,
                              void* d_out, int out_size, void* d_ws, size_t ws_size,
                              hipStream_t stream) {
  const float* x = (const float*)d_in[0];
  const float* Wq = (const float*)d_in[1];
  const float* Wk = (const float*)d_in[2];
  const float* Wv = (const float*)d_in[3];
  const float* Wo = (const float*)d_in[4];
  const float* cosb = (const float*)d_in[5];
  const float* sinb = (const float*)d_in[6];
  const int* pos = (const int*)d_in[7];

  char* ws = (char*)d_ws;
  size_t off = 0;
  auto alloc = [&](size_t bytes) {
    void* p = ws + off;
    off += (bytes + 255) & ~(size_t)255;
    return p;
  };
  float* qf32 = (float*)alloc((size_t)S_LEN * DMODEL * 4);   // 32 MB
  float* kf32 = (float*)alloc((size_t)S_LEN * KVDIM * 4);    // 8 MB
  short* vbuf = (short*)alloc((size_t)S_LEN * KVDIM * 2);    // 4 MB
  short* vT   = (short*)alloc((size_t)NHKV * HDIM * S_LEN * 2); // 4 MB
  short* obuf = (short*)alloc((size_t)S_LEN * DMODEL * 2);   // 16 MB
  float* mbuf = (float*)alloc((size_t)NHQ * S_LEN * 4);
  float* lbuf = (float*)alloc((size_t)NHQ * S_LEN * 4);
  float* hh_h = (float*)alloc((size_t)NHQ * S_LEN * 4);
  if (off > ws_size) return;

  float* out = (float*)d_out;
  float* out_k = out + (size_t)S_LEN * DMODEL;
  float* out_v = out_k + (size_t)NHKV * NKEEP * HDIM;
  float* out_hh = out_v + (size_t)NHKV * NKEEP * HDIM;

  // q,k projections: exact-3-split 6-term hp GEMM (f32 out); v plain bf16
  gemm_hp3<<<dim3(16, 64), 256, 0, stream>>>(x, Wq, qf32, S_LEN, DMODEL, DMODEL);
  gemm_hp3<<<dim3(16, 16), 256, 0, stream>>>(x, Wk, kf32, S_LEN, KVDIM, DMODEL);
  gemm128<1, 1><<<dim3(16, 8), 256, 0, stream>>>(x, Wv, vbuf, S_LEN, KVDIM, DMODEL);
  // f32 RoPE in place
  rope_f32<32><<<(S_LEN * 32 * 64) / 256, 256, 0, stream>>>(qf32, cosb, sinb, pos);
  rope_f32<8><<<(S_LEN * 8 * 64) / 256, 256, 0, stream>>>(kf32, cosb, sinb, pos);
  vtrans_k<<<dim3(S_LEN / 8, NHKV), 128, 0, stream>>>(vbuf, vT);
  // hp softmax stats, attention output, hp column sums
  attn_ml3<<<dim3(NHQ, S_LEN / 128), 256, 0, stream>>>(qf32, kf32, mbuf, lbuf);
  attn_fwd<<<dim3(NHQ, S_LEN / 128), 256, 0, stream>>>(qf32, kf32, vT, obuf, mbuf, lbuf);
  attn_hh3<<<dim3(NHQ, S_LEN / 128), 256, 0, stream>>>(qf32, kf32, mbuf, lbuf, hh_h);
  // output projection
  gemm128<0, 0><<<dim3(16, 32), 256, 0, stream>>>(obuf, Wo, out, S_LEN, DMODEL, DMODEL);
  // H2O top-k + gathers
  topk_gather<<<NHKV, 512, 0, stream>>>(hh_h, kf32, vbuf, out_k, out_v, out_hh);
}

// Round 8
// 1807.740 us; speedup vs baseline: 1.4023x; 1.4023x over previous
//
#include <hip/hip_runtime.h>
#include <cstdint>
#include <cstddef>

typedef __attribute__((ext_vector_type(8))) short bf16x8;
typedef __attribute__((ext_vector_type(4))) float f32x4;

#define S_LEN 2048
#define DMODEL 4096
#define NHQ 32
#define NHKV 8
#define HDIM 128
#define KVDIM 1024
#define NKEEP 640
#define SEL_N 1536

__device__ __forceinline__ short f2bf(float f) {
  unsigned u = __float_as_uint(f);
  u += 0x7fffu + ((u >> 16) & 1u);
  return (short)(u >> 16);
}
__device__ __forceinline__ float bf2f(short s) {
  return __uint_as_float(((unsigned)(unsigned short)s) << 16);
}
// split-2, round-to-nearest hi plane: h = rne16(x) (== f2bf(x)), l = rne16(x - h).
// |x - h - l| <= 2^-17 |x|. h-plane equals the bf16 value the R7 fwd path used.
__device__ __forceinline__ void split2r(float x, short& h, short& l) {
  short hh = f2bf(x);
  float r = x - bf2f(hh);
  h = hh;
  l = f2bf(r);
}
__device__ __forceinline__ f32x4 mfma16(bf16x8 a, bf16x8 b, f32x4 c) {
  return __builtin_amdgcn_mfma_f32_16x16x32_bf16(a, b, c, 0, 0, 0);
}
__device__ __forceinline__ size_t climp(size_t i, size_t sz, size_t w) {
  size_t hi = sz - w;
  return i <= hi ? i : hi;
}

// ---------------- gemm_hp2: C = A(f32)[M,Kd] * B(f32)[Kd,N] -> hi/lo bf16 planes
// 3-term split-2 chain (ah*bl + al*bh + ah*bh), f32 MFMA acc. 128x128 tile, BK=32.
__global__ __launch_bounds__(256, 2) void gemm_hp2(const float* __restrict__ A,
                                                   const float* __restrict__ B,
                                                   short* __restrict__ Ch,
                                                   short* __restrict__ Cl,
                                                   int M, int N, int Kd) {
  __shared__ alignas(16) short Ah[128 * 40];
  __shared__ alignas(16) short Al[128 * 40];
  __shared__ alignas(16) short Bh[128 * 40];
  __shared__ alignas(16) short Bl[128 * 40];
  int tid = threadIdx.x;
  int lane = tid & 63, wave = tid >> 6;
  int l15 = lane & 15, l4 = lane >> 4;
  int m0 = blockIdx.x * 128, n0 = blockIdx.y * 128;
  int wm = (wave >> 1) * 64, wn = (wave & 1) * 64;
  const size_t aSz = (size_t)M * Kd, bSz = (size_t)Kd * N, cSz = (size_t)M * N;
  f32x4 zf = {0.f, 0.f, 0.f, 0.f};
  f32x4 acc[4][4];
#pragma unroll
  for (int i = 0; i < 4; i++)
#pragma unroll
    for (int j = 0; j < 4; j++) acc[i][j] = zf;

  for (int k0 = 0; k0 < Kd; k0 += 32) {
    // A tile 128x32 -> split planes
#pragma unroll
    for (int c = 0; c < 2; c++) {
      int idx = tid + c * 256;
      int r = idx >> 2, c8 = (idx & 3) * 8;
      size_t ai = climp((size_t)(m0 + r) * Kd + k0 + c8, aSz, 8);
      const float* Ap = A + ai;
      float4 v0 = *reinterpret_cast<const float4*>(Ap);
      float4 v1 = *reinterpret_cast<const float4*>(Ap + 4);
      float vv[8] = {v0.x, v0.y, v0.z, v0.w, v1.x, v1.y, v1.z, v1.w};
      bf16x8 sh, sl;
#pragma unroll
      for (int t = 0; t < 8; t++) { short a, b; split2r(vv[t], a, b); sh[t] = a; sl[t] = b; }
      *reinterpret_cast<bf16x8*>(&Ah[r * 40 + c8]) = sh;
      *reinterpret_cast<bf16x8*>(&Al[r * 40 + c8]) = sl;
    }
    // B tile 32x128 -> transposed [n][k] split planes
#pragma unroll
    for (int c = 0; c < 2; c++) {
      int idx = tid + c * 256;
      int n = idx & 127, kg = (idx >> 7) * 8;
      bf16x8 sh, sl;
#pragma unroll
      for (int t = 0; t < 8; t++) {
        size_t bi = climp((size_t)(k0 + kg + t) * N + n0 + n, bSz, 1);
        short a, b;
        split2r(B[bi], a, b);
        sh[t] = a; sl[t] = b;
      }
      *reinterpret_cast<bf16x8*>(&Bh[n * 40 + kg]) = sh;
      *reinterpret_cast<bf16x8*>(&Bl[n * 40 + kg]) = sl;
    }
    __syncthreads();
    bf16x8 ah[4], al[4], bh4[4], bl4[4];
#pragma unroll
    for (int mf = 0; mf < 4; mf++) {
      int ar = (wm + mf * 16 + l15) * 40 + l4 * 8;
      ah[mf] = *reinterpret_cast<const bf16x8*>(&Ah[ar]);
      al[mf] = *reinterpret_cast<const bf16x8*>(&Al[ar]);
    }
#pragma unroll
    for (int nf = 0; nf < 4; nf++) {
      int br = (wn + nf * 16 + l15) * 40 + l4 * 8;
      bh4[nf] = *reinterpret_cast<const bf16x8*>(&Bh[br]);
      bl4[nf] = *reinterpret_cast<const bf16x8*>(&Bl[br]);
    }
#pragma unroll
    for (int mf = 0; mf < 4; mf++)
#pragma unroll
      for (int nf = 0; nf < 4; nf++)
        acc[mf][nf] = mfma16(ah[mf], bh4[nf],
                      mfma16(al[mf], bh4[nf],
                      mfma16(ah[mf], bl4[nf], acc[mf][nf])));
    __syncthreads();
  }
  int rbase = m0 + wm + (l4 << 2);
  int cbase = n0 + wn + l15;
#pragma unroll
  for (int mf = 0; mf < 4; mf++)
#pragma unroll
    for (int nf = 0; nf < 4; nf++)
#pragma unroll
      for (int r = 0; r < 4; r++) {
        int row = rbase + mf * 16 + r;
        int col = cbase + nf * 16;
        size_t ci = (size_t)row * N + col;
        if (row < M && col < N && ci < cSz) {
          short h, l;
          split2r(acc[mf][nf][r], h, l);
          Ch[ci] = h;
          Cl[ci] = l;
        }
      }
}

// ---------------- plain bf16 GEMM (V projection, O projection)
template <int A_F32, int STORE_BF16>
__global__ __launch_bounds__(256, 2) void gemm128(const void* __restrict__ Av,
                                                  const float* __restrict__ B,
                                                  void* __restrict__ Cv,
                                                  int M, int N, int Kd) {
  __shared__ alignas(16) short Al[128 * 72];
  __shared__ alignas(16) short Bl[128 * 72];
  int tid = threadIdx.x;
  int lane = tid & 63, wave = tid >> 6;
  int l15 = lane & 15, l4 = lane >> 4;
  int m0 = blockIdx.x * 128, n0 = blockIdx.y * 128;
  int wm = (wave >> 1) * 64, wn = (wave & 1) * 64;
  const size_t aSz = (size_t)M * Kd, bSz = (size_t)Kd * N, cSz = (size_t)M * N;
  f32x4 zf = {0.f, 0.f, 0.f, 0.f};
  f32x4 acc[4][4];
#pragma unroll
  for (int i = 0; i < 4; i++)
#pragma unroll
    for (int j = 0; j < 4; j++) acc[i][j] = zf;

  for (int k0 = 0; k0 < Kd; k0 += 64) {
#pragma unroll
    for (int c = 0; c < 4; c++) {
      int idx = tid + c * 256;
      int r = idx >> 3, k8 = (idx & 7) * 8;
      size_t ai = climp((size_t)(m0 + r) * Kd + k0 + k8, aSz, 8);
      bf16x8 a;
      if constexpr (A_F32 != 0) {
        const float* Ap = (const float*)Av + ai;
        float4 v0 = *reinterpret_cast<const float4*>(Ap);
        float4 v1 = *reinterpret_cast<const float4*>(Ap + 4);
        a[0] = f2bf(v0.x); a[1] = f2bf(v0.y); a[2] = f2bf(v0.z); a[3] = f2bf(v0.w);
        a[4] = f2bf(v1.x); a[5] = f2bf(v1.y); a[6] = f2bf(v1.z); a[7] = f2bf(v1.w);
      } else {
        a = *reinterpret_cast<const bf16x8*>((const short*)Av + ai);
      }
      *reinterpret_cast<bf16x8*>(&Al[r * 72 + k8]) = a;
    }
#pragma unroll
    for (int c = 0; c < 4; c++) {
      int idx = tid + c * 256;
      int n = idx & 127, kg = (idx >> 7) * 8;
      bf16x8 b;
#pragma unroll
      for (int t = 0; t < 8; t++) {
        size_t bi = climp((size_t)(k0 + kg + t) * N + n0 + n, bSz, 1);
        b[t] = f2bf(B[bi]);
      }
      *reinterpret_cast<bf16x8*>(&Bl[n * 72 + kg]) = b;
    }
    __syncthreads();
    bf16x8 af[4][2], bfr[4][2];
#pragma unroll
    for (int mf = 0; mf < 4; mf++)
#pragma unroll
      for (int ks = 0; ks < 2; ks++)
        af[mf][ks] = *reinterpret_cast<const bf16x8*>(
            &Al[(wm + mf * 16 + l15) * 72 + ks * 32 + l4 * 8]);
#pragma unroll
    for (int nf = 0; nf < 4; nf++)
#pragma unroll
      for (int ks = 0; ks < 2; ks++)
        bfr[nf][ks] = *reinterpret_cast<const bf16x8*>(
            &Bl[(wn + nf * 16 + l15) * 72 + ks * 32 + l4 * 8]);
#pragma unroll
    for (int ks = 0; ks < 2; ks++)
#pragma unroll
      for (int mf = 0; mf < 4; mf++)
#pragma unroll
        for (int nf = 0; nf < 4; nf++)
          acc[mf][nf] = mfma16(af[mf][ks], bfr[nf][ks], acc[mf][nf]);
    __syncthreads();
  }
  int rbase = m0 + wm + (l4 << 2);
  int cbase = n0 + wn + l15;
#pragma unroll
  for (int mf = 0; mf < 4; mf++)
#pragma unroll
    for (int nf = 0; nf < 4; nf++)
#pragma unroll
      for (int r = 0; r < 4; r++) {
        int row = rbase + mf * 16 + r;
        int col = cbase + nf * 16;
        size_t ci = (size_t)row * N + col;
        if (row < M && col < N && ci < cSz) {
          float v = acc[mf][nf][r];
          if constexpr (STORE_BF16 != 0)
            ((short*)Cv)[ci] = f2bf(v);
          else
            ((float*)Cv)[ci] = v;
        }
      }
}

// ---------------- RoPE in-place on split planes (s, NH*128)
template <int NH>
__global__ __launch_bounds__(256) void rope_planes(short* __restrict__ bh,
                                                   short* __restrict__ bl,
                                                   const float* __restrict__ cosb,
                                                   const float* __restrict__ sinb,
                                                   const int* __restrict__ pos) {
  int idx = blockIdx.x * 256 + threadIdx.x;
  if (idx >= S_LEN * NH * 64) return;
  int d = idx & 63;
  int h = (idx >> 6) % NH;
  int s = idx / (64 * NH);
  int p = pos[s];
  if (p < 0) p = 0;
  if (p >= S_LEN) p = S_LEN - 1;
  size_t base = ((size_t)s * NH + h) * 128 + d;
  float lo = bf2f(bh[base]) + bf2f(bl[base]);
  float hi = bf2f(bh[base + 64]) + bf2f(bl[base + 64]);
  float c0 = cosb[p * 128 + d], s0 = sinb[p * 128 + d];
  float c1 = cosb[p * 128 + d + 64], s1 = sinb[p * 128 + d + 64];
  float o0 = lo * c0 - hi * s0;
  float o1 = hi * c1 + lo * s1;
  short a, b;
  split2r(o0, a, b);
  bh[base] = a; bl[base] = b;
  split2r(o1, a, b);
  bh[base + 64] = a; bl[base + 64] = b;
}

// ---------------- V transpose: (s, g, d) -> (g, d, s) bf16
__global__ __launch_bounds__(128) void vtrans_k(const short* __restrict__ v,
                                                short* __restrict__ vT) {
  int g = blockIdx.y;
  int s0 = blockIdx.x * 8;
  int d = threadIdx.x;
  if (s0 + 7 >= S_LEN || g >= NHKV || d >= HDIM) return;
  const size_t vSz = (size_t)S_LEN * KVDIM;
  bf16x8 vals;
#pragma unroll
  for (int i = 0; i < 8; i++)
    vals[i] = v[climp((size_t)(s0 + i) * KVDIM + g * HDIM + d, vSz, 1)];
  *reinterpret_cast<bf16x8*>(vT + climp(((size_t)g * HDIM + d) * S_LEN + s0,
                                        (size_t)NHKV * HDIM * S_LEN, 8)) = vals;
}

// ---------------- attn_ml2: hp m,l from split planes, 3-term chain, f32 score acc
__global__ __launch_bounds__(256, 2) void attn_ml2(const short* __restrict__ qhp,
                                                   const short* __restrict__ qlp,
                                                   const short* __restrict__ khp,
                                                   const short* __restrict__ klp,
                                                   float* __restrict__ mbuf,
                                                   float* __restrict__ lbuf) {
  int h = blockIdx.x, qt = blockIdx.y;
  int g = h >> 2;
  int q0 = qt * 128;
  int tid = threadIdx.x, lane = tid & 63, wave = tid >> 6;
  int l15 = lane & 15, l4 = lane >> 4;
  __shared__ alignas(16) short Kh[32 * 136];
  __shared__ alignas(16) short Kl[32 * 136];
  const size_t qSz = (size_t)S_LEN * DMODEL;
  const size_t kSz = (size_t)S_LEN * KVDIM;

  int qrow_base = q0 + wave * 32;
  bf16x8 qh[2][4], ql[2][4];
#pragma unroll
  for (int mf = 0; mf < 2; mf++)
#pragma unroll
    for (int ks = 0; ks < 4; ks++) {
      size_t qi = climp((size_t)(qrow_base + mf * 16 + l15) * DMODEL + h * HDIM + ks * 32 + l4 * 8,
                        qSz, 8);
      qh[mf][ks] = *reinterpret_cast<const bf16x8*>(qhp + qi);
      ql[mf][ks] = *reinterpret_cast<const bf16x8*>(qlp + qi);
    }

  float mrow[2][4], lrow[2][4];
#pragma unroll
  for (int mf = 0; mf < 2; mf++)
#pragma unroll
    for (int r = 0; r < 4; r++) { mrow[mf][r] = -1e30f; lrow[mf][r] = 0.f; }
  int wqmax = qrow_base + 31;
  int nkt = qt * 4 + 4;
  const float scale = 0.08838834764831845f;
  f32x4 zf = {0.f, 0.f, 0.f, 0.f};

  for (int kt = 0; kt < nkt; kt++) {
    int k0 = kt * 32;
#pragma unroll
    for (int c = 0; c < 2; c++) {
      int idx = tid + c * 256;
      int r = idx >> 4, c8 = (idx & 15) * 8;
      size_t ki = climp((size_t)(k0 + r) * KVDIM + g * HDIM + c8, kSz, 8);
      *reinterpret_cast<bf16x8*>(&Kh[r * 136 + c8]) =
          *reinterpret_cast<const bf16x8*>(khp + ki);
      *reinterpret_cast<bf16x8*>(&Kl[r * 136 + c8]) =
          *reinterpret_cast<const bf16x8*>(klp + ki);
    }
    __syncthreads();
    if (k0 <= wqmax) {
      f32x4 sf[2][2] = {{zf, zf}, {zf, zf}};
#pragma unroll
      for (int ks = 0; ks < 4; ks++)
#pragma unroll
        for (int nf = 0; nf < 2; nf++) {
          int kr = (nf * 16 + l15) * 136 + ks * 32 + l4 * 8;
          bf16x8 bh = *reinterpret_cast<const bf16x8*>(&Kh[kr]);
          bf16x8 bl = *reinterpret_cast<const bf16x8*>(&Kl[kr]);
#pragma unroll
          for (int mf = 0; mf < 2; mf++)
            sf[mf][nf] = mfma16(qh[mf][ks], bh,
                         mfma16(ql[mf][ks], bh,
                         mfma16(qh[mf][ks], bl, sf[mf][nf])));
        }
#pragma unroll
      for (int mf = 0; mf < 2; mf++) {
#pragma unroll
        for (int r = 0; r < 4; r++) {
          int qg = qrow_base + mf * 16 + (l4 << 2) + r;
          float v0 = sf[mf][0][r] * scale;
          float v1 = sf[mf][1][r] * scale;
          if (k0 + l15 > qg) v0 = -1e9f;
          if (k0 + 16 + l15 > qg) v1 = -1e9f;
          float mx = fmaxf(v0, v1);
          mx = fmaxf(mx, __shfl_xor(mx, 1));
          mx = fmaxf(mx, __shfl_xor(mx, 2));
          mx = fmaxf(mx, __shfl_xor(mx, 4));
          mx = fmaxf(mx, __shfl_xor(mx, 8));
          float mnew = fmaxf(mrow[mf][r], mx);
          float alpha = expf(mrow[mf][r] - mnew);
          float rs = expf(v0 - mnew) + expf(v1 - mnew);
          rs += __shfl_xor(rs, 1);
          rs += __shfl_xor(rs, 2);
          rs += __shfl_xor(rs, 4);
          rs += __shfl_xor(rs, 8);
          lrow[mf][r] = lrow[mf][r] * alpha + rs;
          mrow[mf][r] = mnew;
        }
      }
    }
    __syncthreads();
  }
  if (l15 == 0) {
#pragma unroll
    for (int mf = 0; mf < 2; mf++)
#pragma unroll
      for (int r = 0; r < 4; r++) {
        int row = qrow_base + mf * 16 + (l4 << 2) + r;
        if (row < S_LEN) {
          mbuf[(size_t)h * S_LEN + row] = mrow[mf][r];
          lbuf[(size_t)h * S_LEN + row] = lrow[mf][r];
        }
      }
  }
}

// ---------------- attn_fwd: O from h-plane bf16 scores + precomputed hp m,l
__global__ __launch_bounds__(256, 2) void attn_fwd(const short* __restrict__ qhp,
                                                   const short* __restrict__ khp,
                                                   const short* __restrict__ vT,
                                                   short* __restrict__ ob,
                                                   const float* __restrict__ mbuf,
                                                   const float* __restrict__ lbuf) {
  int h = blockIdx.x, qt = blockIdx.y;
  int g = h >> 2;
  int q0 = qt * 128;
  int tid = threadIdx.x, lane = tid & 63, wave = tid >> 6;
  int l15 = lane & 15, l4 = lane >> 4;
  __shared__ alignas(16) short Kl[32 * 136];
  __shared__ alignas(16) short Vl[128 * 40];
  __shared__ alignas(16) short Pl[4][32 * 40];
  const size_t qSz = (size_t)S_LEN * DMODEL;
  const size_t kSz = (size_t)S_LEN * KVDIM;
  const size_t vtSz = (size_t)NHKV * HDIM * S_LEN;

  int qrow_base = q0 + wave * 32;
  bf16x8 qfr[2][4];
#pragma unroll
  for (int mf = 0; mf < 2; mf++)
#pragma unroll
    for (int ks = 0; ks < 4; ks++) {
      size_t qi = climp((size_t)(qrow_base + mf * 16 + l15) * DMODEL + h * HDIM + ks * 32 + l4 * 8,
                        qSz, 8);
      qfr[mf][ks] = *reinterpret_cast<const bf16x8*>(qhp + qi);
    }

  float mrow[2][4], rlrow[2][4];
#pragma unroll
  for (int mf = 0; mf < 2; mf++)
#pragma unroll
    for (int r = 0; r < 4; r++) {
      int row = qrow_base + mf * 16 + (l4 << 2) + r;
      size_t mi = climp((size_t)h * S_LEN + row, (size_t)NHQ * S_LEN, 1);
      mrow[mf][r] = mbuf[mi];
      rlrow[mf][r] = 1.0f / lbuf[mi];
    }

  f32x4 zf = {0.f, 0.f, 0.f, 0.f};
  f32x4 accO[2][8];
#pragma unroll
  for (int mf = 0; mf < 2; mf++)
#pragma unroll
    for (int nfo = 0; nfo < 8; nfo++) accO[mf][nfo] = zf;
  int wqmax = qrow_base + 31;
  int nkt = qt * 4 + 4;
  const float scale = 0.08838834764831845f;

  for (int kt = 0; kt < nkt; kt++) {
    int k0 = kt * 32;
#pragma unroll
    for (int c = 0; c < 2; c++) {
      int idx = tid + c * 256;
      int r = idx >> 4, c8 = (idx & 15) * 8;
      size_t ki = climp((size_t)(k0 + r) * KVDIM + g * HDIM + c8, kSz, 8);
      *reinterpret_cast<bf16x8*>(&Kl[r * 136 + c8]) =
          *reinterpret_cast<const bf16x8*>(khp + ki);
    }
#pragma unroll
    for (int c = 0; c < 2; c++) {
      int idx = tid + c * 256;
      int r = idx >> 2, c8 = idx & 3;
      *reinterpret_cast<bf16x8*>(&Vl[r * 40 + c8 * 8]) =
          *reinterpret_cast<const bf16x8*>(
              vT + climp(((size_t)g * HDIM + r) * S_LEN + k0 + c8 * 8, vtSz, 8));
    }
    __syncthreads();
    if (k0 <= wqmax) {
      f32x4 sf[2][2] = {{zf, zf}, {zf, zf}};
#pragma unroll
      for (int nf = 0; nf < 2; nf++)
#pragma unroll
        for (int ks = 0; ks < 4; ks++) {
          bf16x8 bk = *reinterpret_cast<const bf16x8*>(
              &Kl[(nf * 16 + l15) * 136 + ks * 32 + l4 * 8]);
          sf[0][nf] = mfma16(qfr[0][ks], bk, sf[0][nf]);
          sf[1][nf] = mfma16(qfr[1][ks], bk, sf[1][nf]);
        }
#pragma unroll
      for (int mf = 0; mf < 2; mf++)
#pragma unroll
        for (int r = 0; r < 4; r++) {
          int qg = qrow_base + mf * 16 + (l4 << 2) + r;
          float v0 = sf[mf][0][r] * scale;
          float v1 = sf[mf][1][r] * scale;
          if (k0 + l15 > qg) v0 = -1e9f;
          if (k0 + 16 + l15 > qg) v1 = -1e9f;
          float p0 = __expf(v0 - mrow[mf][r]);
          float p1 = __expf(v1 - mrow[mf][r]);
          Pl[wave][(mf * 16 + (l4 << 2) + r) * 40 + l15] = f2bf(p0);
          Pl[wave][(mf * 16 + (l4 << 2) + r) * 40 + 16 + l15] = f2bf(p1);
        }
      bf16x8 pa[2];
      pa[0] = *reinterpret_cast<const bf16x8*>(&Pl[wave][(0 + l15) * 40 + l4 * 8]);
      pa[1] = *reinterpret_cast<const bf16x8*>(&Pl[wave][(16 + l15) * 40 + l4 * 8]);
#pragma unroll
      for (int nfo = 0; nfo < 8; nfo++) {
        bf16x8 bv = *reinterpret_cast<const bf16x8*>(&Vl[(nfo * 16 + l15) * 40 + l4 * 8]);
        accO[0][nfo] = mfma16(pa[0], bv, accO[0][nfo]);
        accO[1][nfo] = mfma16(pa[1], bv, accO[1][nfo]);
      }
    }
    __syncthreads();
  }
#pragma unroll
  for (int mf = 0; mf < 2; mf++)
#pragma unroll
    for (int nfo = 0; nfo < 8; nfo++)
#pragma unroll
      for (int r = 0; r < 4; r++) {
        int row = qrow_base + mf * 16 + (l4 << 2) + r;
        int col = h * HDIM + nfo * 16 + l15;
        if (row < S_LEN && col < DMODEL)
          ob[(size_t)row * DMODEL + col] = f2bf(accO[mf][nfo][r] * rlrow[mf][r]);
      }
}

// ---------------- attn_hh2: column sums from split planes, 3-term chain, f64 col-acc
__global__ __launch_bounds__(256, 2) void attn_hh2(const short* __restrict__ qhp,
                                                   const short* __restrict__ qlp,
                                                   const short* __restrict__ khp,
                                                   const short* __restrict__ klp,
                                                   const float* __restrict__ mbuf,
                                                   const float* __restrict__ lbuf,
                                                   float* __restrict__ hh_h) {
  int h = blockIdx.x, kt = blockIdx.y;
  int g = h >> 2;
  int key0 = kt * 128;
  int tid = threadIdx.x, lane = tid & 63, wave = tid >> 6;
  int l15 = lane & 15, l4 = lane >> 4;
  __shared__ alignas(16) short Qh[32 * 136];
  __shared__ alignas(16) short Ql[32 * 136];
  const size_t qSz = (size_t)S_LEN * DMODEL;
  const size_t kSz = (size_t)S_LEN * KVDIM;
  const size_t mlSz = (size_t)NHQ * S_LEN;
  const float scale = 0.08838834764831845f;
  f32x4 zf = {0.f, 0.f, 0.f, 0.f};

  int keymin = key0 + wave * 32;
  bf16x8 akh[2][4], akl[2][4];
#pragma unroll
  for (int mf = 0; mf < 2; mf++)
#pragma unroll
    for (int ks = 0; ks < 4; ks++) {
      size_t ki = climp((size_t)(keymin + mf * 16 + l15) * KVDIM + g * HDIM + ks * 32 + l4 * 8,
                        kSz, 8);
      akh[mf][ks] = *reinterpret_cast<const bf16x8*>(khp + ki);
      akl[mf][ks] = *reinterpret_cast<const bf16x8*>(klp + ki);
    }

  double acc[2][4];
#pragma unroll
  for (int mf = 0; mf < 2; mf++)
#pragma unroll
    for (int r = 0; r < 4; r++) acc[mf][r] = 0.0;

  for (int q0 = key0; q0 < S_LEN; q0 += 32) {
#pragma unroll
    for (int c = 0; c < 2; c++) {
      int idx = tid + c * 256;
      int r = idx >> 4, c8 = (idx & 15) * 8;
      size_t qi = climp((size_t)(q0 + r) * DMODEL + h * HDIM + c8, qSz, 8);
      *reinterpret_cast<bf16x8*>(&Qh[r * 136 + c8]) =
          *reinterpret_cast<const bf16x8*>(qhp + qi);
      *reinterpret_cast<bf16x8*>(&Ql[r * 136 + c8]) =
          *reinterpret_cast<const bf16x8*>(qlp + qi);
    }
    __syncthreads();
    if (q0 + 31 >= keymin) {
      f32x4 sf[2][2] = {{zf, zf}, {zf, zf}};
#pragma unroll
      for (int ks = 0; ks < 4; ks++)
#pragma unroll
        for (int nf = 0; nf < 2; nf++) {
          int qr = (nf * 16 + l15) * 136 + ks * 32 + l4 * 8;
          bf16x8 bqh = *reinterpret_cast<const bf16x8*>(&Qh[qr]);
          bf16x8 bql = *reinterpret_cast<const bf16x8*>(&Ql[qr]);
#pragma unroll
          for (int mf = 0; mf < 2; mf++)
            sf[mf][nf] = mfma16(akh[mf][ks], bqh,
                         mfma16(akh[mf][ks], bql,
                         mfma16(akl[mf][ks], bqh, sf[mf][nf])));
        }
#pragma unroll
      for (int nf = 0; nf < 2; nf++) {
        int q = q0 + nf * 16 + l15;
        float mq = mbuf[climp((size_t)h * S_LEN + q, mlSz, 1)];
        float rl = 1.0f / lbuf[climp((size_t)h * S_LEN + q, mlSz, 1)];
#pragma unroll
        for (int mf = 0; mf < 2; mf++)
#pragma unroll
          for (int r = 0; r < 4; r++) {
            int key = keymin + mf * 16 + (l4 << 2) + r;
            if (q >= key && q < S_LEN)
              acc[mf][r] += (double)(expf(sf[mf][nf][r] * scale - mq) * rl);
          }
      }
    }
    __syncthreads();
  }
#pragma unroll
  for (int mf = 0; mf < 2; mf++)
#pragma unroll
    for (int r = 0; r < 4; r++) {
      double v = acc[mf][r];
      v += __shfl_xor(v, 1);
      v += __shfl_xor(v, 2);
      v += __shfl_xor(v, 4);
      v += __shfl_xor(v, 8);
      int key = keymin + mf * 16 + (l4 << 2) + r;
      if (l15 == 0 && key < S_LEN)
        hh_h[(size_t)h * S_LEN + key] = (float)v;
    }
}

// ---------------- top-k + gather (k reconstructed from planes)
__global__ __launch_bounds__(512) void topk_gather(const float* __restrict__ hh_h,
                                                   const short* __restrict__ khp,
                                                   const short* __restrict__ klp,
                                                   const short* __restrict__ vb,
                                                   float* __restrict__ out_k,
                                                   float* __restrict__ out_v,
                                                   float* __restrict__ out_hh) {
  int g = blockIdx.x, t = threadIdx.x;
  __shared__ float hhg[2048];
  __shared__ float sv[2048];
  __shared__ int si[2048];
  __shared__ int st[128];
  __shared__ int keep[NKEEP];
  const size_t hhSz = (size_t)NHQ * S_LEN;
  const size_t kvSz = (size_t)S_LEN * KVDIM;
#pragma unroll
  for (int i = 0; i < 4; i++) {
    int idx = t + i * 512;
    float s = 0.25f * (hh_h[climp((size_t)(4 * g + 0) * 2048 + idx, hhSz, 1)] +
                       hh_h[climp((size_t)(4 * g + 1) * 2048 + idx, hhSz, 1)] +
                       hh_h[climp((size_t)(4 * g + 2) * 2048 + idx, hhSz, 1)] +
                       hh_h[climp((size_t)(4 * g + 3) * 2048 + idx, hhSz, 1)]);
    hhg[idx] = s;
    sv[idx] = (idx < SEL_N) ? s : -1e30f;
    si[idx] = idx;
  }
  __syncthreads();
  for (int k = 2; k <= 2048; k <<= 1) {
    for (int j = k >> 1; j > 0; j >>= 1) {
#pragma unroll
      for (int pass = 0; pass < 4; pass++) {
        int i = t + pass * 512;
        int ixj = i ^ j;
        if (ixj > i) {
          bool up = ((i & k) == 0);
          float a = sv[i], b = sv[ixj];
          int ia = si[i], ib = si[ixj];
          bool before = (a > b) || (a == b && ia < ib);
          bool doswap = up ? !before : before;
          if (doswap) { sv[i] = b; sv[ixj] = a; si[i] = ib; si[ixj] = ia; }
        }
      }
      __syncthreads();
    }
  }
  if (t < 128) st[t] = si[t];
  __syncthreads();
  for (int k = 2; k <= 128; k <<= 1) {
    for (int j = k >> 1; j > 0; j >>= 1) {
      if (t < 128) {
        int i = t, ixj = i ^ j;
        if (ixj > i) {
          bool up = ((i & k) == 0);
          int a = st[i], b = st[ixj];
          bool doswap = up ? (a > b) : (a < b);
          if (doswap) { st[i] = b; st[ixj] = a; }
        }
      }
      __syncthreads();
    }
  }
  // All 640 keep[] entries initialized by all 512 threads (R1-R6 bug fix).
  for (int i = t; i < NKEEP; i += 512)
    keep[i] = (i < 128) ? st[i] : (SEL_N + (i - 128));
  __syncthreads();
  for (int i = 0; i < 160; i++) {
    int idx = t + i * 512;
    int jj = idx >> 7, d = idx & 127;
    int src = (jj < NKEEP) ? keep[jj] : 0;
    if (src < 0) src = 0;
    if (src >= S_LEN) src = S_LEN - 1;
    size_t oi = ((size_t)g * NKEEP + jj) * HDIM + d;
    if (jj < NKEEP) {
      size_t ki = climp((size_t)src * KVDIM + g * HDIM + d, kvSz, 1);
      out_k[oi] = bf2f(khp[ki]) + bf2f(klp[ki]);
      out_v[oi] = bf2f(vb[ki]);
    }
  }
  for (int i = t; i < NKEEP; i += 512) {
    int src = keep[i];
    if (src < 0) src = 0;
    if (src >= 2048) src = 2047;
    out_hh[(size_t)g * NKEEP + i] = hhg[src];
  }
}

extern "C" void kernel_launch(void* const* d_in, const int* in_sizes, int n_in,
                              void* d_out, int out_size, void* d_ws, size_t ws_size,
                              hipStream_t stream) {
  const float* x = (const float*)d_in[0];
  const float* Wq = (const float*)d_in[1];
  const float* Wk = (const float*)d_in[2];
  const float* Wv = (const float*)d_in[3];
  const float* Wo = (const float*)d_in[4];
  const float* cosb = (const float*)d_in[5];
  const float* sinb = (const float*)d_in[6];
  const int* pos = (const int*)d_in[7];

  char* ws = (char*)d_ws;
  size_t off = 0;
  auto alloc = [&](size_t bytes) {
    void* p = ws + off;
    off += (bytes + 255) & ~(size_t)255;
    return p;
  };
  short* qh = (short*)alloc((size_t)S_LEN * DMODEL * 2);   // 16 MB
  short* ql = (short*)alloc((size_t)S_LEN * DMODEL * 2);   // 16 MB
  short* kh = (short*)alloc((size_t)S_LEN * KVDIM * 2);    // 4 MB
  short* kl = (short*)alloc((size_t)S_LEN * KVDIM * 2);    // 4 MB
  short* vbuf = (short*)alloc((size_t)S_LEN * KVDIM * 2);  // 4 MB
  short* vT   = (short*)alloc((size_t)NHKV * HDIM * S_LEN * 2); // 4 MB
  short* obuf = (short*)alloc((size_t)S_LEN * DMODEL * 2); // 16 MB
  float* mbuf = (float*)alloc((size_t)NHQ * S_LEN * 4);
  float* lbuf = (float*)alloc((size_t)NHQ * S_LEN * 4);
  float* hh_h = (float*)alloc((size_t)NHQ * S_LEN * 4);
  if (off > ws_size) return;

  float* out = (float*)d_out;
  float* out_k = out + (size_t)S_LEN * DMODEL;
  float* out_v = out_k + (size_t)NHKV * NKEEP * HDIM;
  float* out_hh = out_v + (size_t)NHKV * NKEEP * HDIM;

  // q,k projections -> split bf16 planes (3-term hp); v plain bf16
  gemm_hp2<<<dim3(16, 32), 256, 0, stream>>>(x, Wq, qh, ql, S_LEN, DMODEL, DMODEL);
  gemm_hp2<<<dim3(16, 8), 256, 0, stream>>>(x, Wk, kh, kl, S_LEN, KVDIM, DMODEL);
  gemm128<1, 1><<<dim3(16, 8), 256, 0, stream>>>(x, Wv, vbuf, S_LEN, KVDIM, DMODEL);
  // RoPE on planes
  rope_planes<32><<<(S_LEN * 32 * 64) / 256, 256, 0, stream>>>(qh, ql, cosb, sinb, pos);
  rope_planes<8><<<(S_LEN * 8 * 64) / 256, 256, 0, stream>>>(kh, kl, cosb, sinb, pos);
  vtrans_k<<<dim3(S_LEN / 8, NHKV), 128, 0, stream>>>(vbuf, vT);
  // softmax stats, attention output, column sums
  attn_ml2<<<dim3(NHQ, S_LEN / 128), 256, 0, stream>>>(qh, ql, kh, kl, mbuf, lbuf);
  attn_fwd<<<dim3(NHQ, S_LEN / 128), 256, 0, stream>>>(qh, kh, vT, obuf, mbuf, lbuf);
  attn_hh2<<<dim3(NHQ, S_LEN / 128), 256, 0, stream>>>(qh, ql, kh, kl, mbuf, lbuf, hh_h);
  // output projection
  gemm128<0, 0><<<dim3(16, 32), 256, 0, stream>>>(obuf, Wo, out, S_LEN, DMODEL, DMODEL);
  // H2O top-k + gathers
  topk_gather<<<NHKV, 512, 0, stream>>>(hh_h, kh, kl, vbuf, out_k, out_v, out_hh);
}

// Round 9
// 1307.626 us; speedup vs baseline: 1.9386x; 1.3825x over previous
//
#include <hip/hip_runtime.h>
#include <cstdint>
#include <cstddef>

typedef __attribute__((ext_vector_type(8))) short bf16x8;
typedef __attribute__((ext_vector_type(4))) short short4v;
typedef __attribute__((ext_vector_type(4))) float f32x4;

#define S_LEN 2048
#define DMODEL 4096
#define NHQ 32
#define NHKV 8
#define HDIM 128
#define KVDIM 1024
#define NKEEP 640
#define SEL_N 1536

__device__ __forceinline__ short f2bf(float f) {
  unsigned u = __float_as_uint(f);
  u += 0x7fffu + ((u >> 16) & 1u);
  return (short)(u >> 16);
}
__device__ __forceinline__ float bf2f(short s) {
  return __uint_as_float(((unsigned)(unsigned short)s) << 16);
}
// split-2, round-to-nearest hi plane: h = rne16(x), l = rne16(x - h). err <= 2^-17|x|
__device__ __forceinline__ void split2r(float x, short& h, short& l) {
  short hh = f2bf(x);
  float r = x - bf2f(hh);
  h = hh;
  l = f2bf(r);
}
__device__ __forceinline__ f32x4 mfma16(bf16x8 a, bf16x8 b, f32x4 c) {
  return __builtin_amdgcn_mfma_f32_16x16x32_bf16(a, b, c, 0, 0, 0);
}
__device__ __forceinline__ size_t climp(size_t i, size_t sz, size_t w) {
  size_t hi = sz - w;
  return i <= hi ? i : hi;
}

// ---------------- transpose+convert: W (Kd,N) f32 -> Wt (N,Kd) bf16
__global__ __launch_bounds__(256) void transpose_cvt(const float* __restrict__ W,
                                                     short* __restrict__ Wt,
                                                     int Kd, int N) {
  __shared__ float tile[64][65];
  int tx = threadIdx.x;
  int n0 = blockIdx.x * 64;
  int k0 = blockIdx.y * 64;
#pragma unroll
  for (int i = 0; i < 4; i++) {
    int idx = tx + i * 256;
    int r = idx >> 4, c4 = (idx & 15) * 4;
    float4 v = *reinterpret_cast<const float4*>(W + (size_t)(k0 + r) * N + n0 + c4);
    tile[r][c4 + 0] = v.x;
    tile[r][c4 + 1] = v.y;
    tile[r][c4 + 2] = v.z;
    tile[r][c4 + 3] = v.w;
  }
  __syncthreads();
#pragma unroll
  for (int i = 0; i < 4; i++) {
    int idx = tx + i * 256;
    int rn = idx >> 4, c4 = (idx & 15) * 4;
    short4v o;
#pragma unroll
    for (int j = 0; j < 4; j++) o[j] = f2bf(tile[c4 + j][rn]);
    *reinterpret_cast<short4v*>(Wt + (size_t)(n0 + rn) * Kd + k0 + c4) = o;
  }
}

// ---------------- transpose+split: W (Kd,N) f32 -> hi/lo bf16 planes (N,Kd)
__global__ __launch_bounds__(256) void transpose_split(const float* __restrict__ W,
                                                       short* __restrict__ Wth,
                                                       short* __restrict__ Wtl,
                                                       int Kd, int N) {
  __shared__ float tile[64][65];
  int tx = threadIdx.x;
  int n0 = blockIdx.x * 64;
  int k0 = blockIdx.y * 64;
#pragma unroll
  for (int i = 0; i < 4; i++) {
    int idx = tx + i * 256;
    int r = idx >> 4, c4 = (idx & 15) * 4;
    float4 v = *reinterpret_cast<const float4*>(W + (size_t)(k0 + r) * N + n0 + c4);
    tile[r][c4 + 0] = v.x;
    tile[r][c4 + 1] = v.y;
    tile[r][c4 + 2] = v.z;
    tile[r][c4 + 3] = v.w;
  }
  __syncthreads();
#pragma unroll
  for (int i = 0; i < 4; i++) {
    int idx = tx + i * 256;
    int rn = idx >> 4, c4 = (idx & 15) * 4;
    short4v oh, ol;
#pragma unroll
    for (int j = 0; j < 4; j++) {
      short a, b;
      split2r(tile[c4 + j][rn], a, b);
      oh[j] = a; ol[j] = b;
    }
    size_t wi = (size_t)(n0 + rn) * Kd + k0 + c4;
    *reinterpret_cast<short4v*>(Wth + wi) = oh;
    *reinterpret_cast<short4v*>(Wtl + wi) = ol;
  }
}

// ---------------- gemm_hp2bt: C planes = A(f32)[M,Kd] * B^T planes[N,Kd]
// 3-term split-2 chain, BK=32, 128x128 tile. Same math/order as R8 hp2.
__global__ __launch_bounds__(256, 3) void gemm_hp2bt(const float* __restrict__ A,
                                                     const short* __restrict__ Bth,
                                                     const short* __restrict__ Btl,
                                                     short* __restrict__ Ch,
                                                     short* __restrict__ Cl,
                                                     int M, int N, int Kd) {
  __shared__ alignas(16) short Ah[128 * 40];
  __shared__ alignas(16) short Alo[128 * 40];
  __shared__ alignas(16) short Bh[128 * 40];
  __shared__ alignas(16) short Bl[128 * 40];
  int tid = threadIdx.x;
  int lane = tid & 63, wave = tid >> 6;
  int l15 = lane & 15, l4 = lane >> 4;
  int m0 = blockIdx.x * 128, n0 = blockIdx.y * 128;
  int wm = (wave >> 1) * 64, wn = (wave & 1) * 64;
  f32x4 zf = {0.f, 0.f, 0.f, 0.f};
  f32x4 acc[4][4];
#pragma unroll
  for (int i = 0; i < 4; i++)
#pragma unroll
    for (int j = 0; j < 4; j++) acc[i][j] = zf;

  for (int k0 = 0; k0 < Kd; k0 += 32) {
    // A tile 128x32 f32 -> split planes (vector loads, b128 LDS writes)
#pragma unroll
    for (int c = 0; c < 2; c++) {
      int idx = tid + c * 256;          // 0..511
      int r = idx >> 2, c8 = (idx & 3) * 8;
      const float* Ap = A + (size_t)(m0 + r) * Kd + k0 + c8;
      float4 v0 = *reinterpret_cast<const float4*>(Ap);
      float4 v1 = *reinterpret_cast<const float4*>(Ap + 4);
      float vv[8] = {v0.x, v0.y, v0.z, v0.w, v1.x, v1.y, v1.z, v1.w};
      bf16x8 sh, sl;
#pragma unroll
      for (int t = 0; t < 8; t++) { short a, b; split2r(vv[t], a, b); sh[t] = a; sl[t] = b; }
      *reinterpret_cast<bf16x8*>(&Ah[r * 40 + c8]) = sh;
      *reinterpret_cast<bf16x8*>(&Alo[r * 40 + c8]) = sl;
    }
    // B^T planes 128x32 bf16 -> LDS (pure vector copies)
#pragma unroll
    for (int c = 0; c < 2; c++) {
      int idx = tid + c * 256;          // 0..511
      int r = idx >> 2, c8 = (idx & 3) * 8;
      size_t bi = (size_t)(n0 + r) * Kd + k0 + c8;
      *reinterpret_cast<bf16x8*>(&Bh[r * 40 + c8]) =
          *reinterpret_cast<const bf16x8*>(Bth + bi);
      *reinterpret_cast<bf16x8*>(&Bl[r * 40 + c8]) =
          *reinterpret_cast<const bf16x8*>(Btl + bi);
    }
    __syncthreads();
    bf16x8 ah[4], al[4], bh4[4], bl4[4];
#pragma unroll
    for (int mf = 0; mf < 4; mf++) {
      int ar = (wm + mf * 16 + l15) * 40 + l4 * 8;
      ah[mf] = *reinterpret_cast<const bf16x8*>(&Ah[ar]);
      al[mf] = *reinterpret_cast<const bf16x8*>(&Alo[ar]);
    }
#pragma unroll
    for (int nf = 0; nf < 4; nf++) {
      int br = (wn + nf * 16 + l15) * 40 + l4 * 8;
      bh4[nf] = *reinterpret_cast<const bf16x8*>(&Bh[br]);
      bl4[nf] = *reinterpret_cast<const bf16x8*>(&Bl[br]);
    }
#pragma unroll
    for (int mf = 0; mf < 4; mf++)
#pragma unroll
      for (int nf = 0; nf < 4; nf++)
        acc[mf][nf] = mfma16(ah[mf], bh4[nf],
                      mfma16(al[mf], bh4[nf],
                      mfma16(ah[mf], bl4[nf], acc[mf][nf])));
    __syncthreads();
  }
  int rbase = m0 + wm + (l4 << 2);
  int cbase = n0 + wn + l15;
#pragma unroll
  for (int mf = 0; mf < 4; mf++)
#pragma unroll
    for (int nf = 0; nf < 4; nf++)
#pragma unroll
      for (int r = 0; r < 4; r++) {
        int row = rbase + mf * 16 + r;
        int col = cbase + nf * 16;
        if (row < M && col < N) {
          size_t ci = (size_t)row * N + col;
          short h, l;
          split2r(acc[mf][nf][r], h, l);
          Ch[ci] = h;
          Cl[ci] = l;
        }
      }
}

// ---------------- gemm_bt: plain bf16 GEMM with B^T (N,Kd) bf16 input
template <int A_F32, int STORE_BF16>
__global__ __launch_bounds__(256, 3) void gemm_bt(const void* __restrict__ Av,
                                                  const short* __restrict__ Bt,
                                                  void* __restrict__ Cv,
                                                  int M, int N, int Kd) {
  __shared__ alignas(16) short Al[128 * 72];
  __shared__ alignas(16) short Bl[128 * 72];
  int tid = threadIdx.x;
  int lane = tid & 63, wave = tid >> 6;
  int l15 = lane & 15, l4 = lane >> 4;
  int m0 = blockIdx.x * 128, n0 = blockIdx.y * 128;
  int wm = (wave >> 1) * 64, wn = (wave & 1) * 64;
  f32x4 zf = {0.f, 0.f, 0.f, 0.f};
  f32x4 acc[4][4];
#pragma unroll
  for (int i = 0; i < 4; i++)
#pragma unroll
    for (int j = 0; j < 4; j++) acc[i][j] = zf;

  for (int k0 = 0; k0 < Kd; k0 += 64) {
#pragma unroll
    for (int c = 0; c < 4; c++) {
      int idx = tid + c * 256;
      int r = idx >> 3, k8 = (idx & 7) * 8;
      bf16x8 a;
      if constexpr (A_F32 != 0) {
        const float* Ap = (const float*)Av + (size_t)(m0 + r) * Kd + k0 + k8;
        float4 v0 = *reinterpret_cast<const float4*>(Ap);
        float4 v1 = *reinterpret_cast<const float4*>(Ap + 4);
        a[0] = f2bf(v0.x); a[1] = f2bf(v0.y); a[2] = f2bf(v0.z); a[3] = f2bf(v0.w);
        a[4] = f2bf(v1.x); a[5] = f2bf(v1.y); a[6] = f2bf(v1.z); a[7] = f2bf(v1.w);
      } else {
        a = *reinterpret_cast<const bf16x8*>((const short*)Av + (size_t)(m0 + r) * Kd + k0 + k8);
      }
      *reinterpret_cast<bf16x8*>(&Al[r * 72 + k8]) = a;
      *reinterpret_cast<bf16x8*>(&Bl[r * 72 + k8]) =
          *reinterpret_cast<const bf16x8*>(Bt + (size_t)(n0 + r) * Kd + k0 + k8);
    }
    __syncthreads();
    bf16x8 af[4][2], bfr[4][2];
#pragma unroll
    for (int mf = 0; mf < 4; mf++)
#pragma unroll
      for (int ks = 0; ks < 2; ks++)
        af[mf][ks] = *reinterpret_cast<const bf16x8*>(
            &Al[(wm + mf * 16 + l15) * 72 + ks * 32 + l4 * 8]);
#pragma unroll
    for (int nf = 0; nf < 4; nf++)
#pragma unroll
      for (int ks = 0; ks < 2; ks++)
        bfr[nf][ks] = *reinterpret_cast<const bf16x8*>(
            &Bl[(wn + nf * 16 + l15) * 72 + ks * 32 + l4 * 8]);
#pragma unroll
    for (int ks = 0; ks < 2; ks++)
#pragma unroll
      for (int mf = 0; mf < 4; mf++)
#pragma unroll
        for (int nf = 0; nf < 4; nf++)
          acc[mf][nf] = mfma16(af[mf][ks], bfr[nf][ks], acc[mf][nf]);
    __syncthreads();
  }
  int rbase = m0 + wm + (l4 << 2);
  int cbase = n0 + wn + l15;
#pragma unroll
  for (int mf = 0; mf < 4; mf++)
#pragma unroll
    for (int nf = 0; nf < 4; nf++)
#pragma unroll
      for (int r = 0; r < 4; r++) {
        int row = rbase + mf * 16 + r;
        int col = cbase + nf * 16;
        if (row < M && col < N) {
          size_t ci = (size_t)row * N + col;
          float v = acc[mf][nf][r];
          if constexpr (STORE_BF16 != 0)
            ((short*)Cv)[ci] = f2bf(v);
          else
            ((float*)Cv)[ci] = v;
        }
      }
}

// ---------------- RoPE in-place on split planes (s, NH*128)
template <int NH>
__global__ __launch_bounds__(256) void rope_planes(short* __restrict__ bh,
                                                   short* __restrict__ bl,
                                                   const float* __restrict__ cosb,
                                                   const float* __restrict__ sinb,
                                                   const int* __restrict__ pos) {
  int idx = blockIdx.x * 256 + threadIdx.x;
  if (idx >= S_LEN * NH * 64) return;
  int d = idx & 63;
  int h = (idx >> 6) % NH;
  int s = idx / (64 * NH);
  int p = pos[s];
  if (p < 0) p = 0;
  if (p >= S_LEN) p = S_LEN - 1;
  size_t base = ((size_t)s * NH + h) * 128 + d;
  float lo = bf2f(bh[base]) + bf2f(bl[base]);
  float hi = bf2f(bh[base + 64]) + bf2f(bl[base + 64]);
  float c0 = cosb[p * 128 + d], s0 = sinb[p * 128 + d];
  float c1 = cosb[p * 128 + d + 64], s1 = sinb[p * 128 + d + 64];
  float o0 = lo * c0 - hi * s0;
  float o1 = hi * c1 + lo * s1;
  short a, b;
  split2r(o0, a, b);
  bh[base] = a; bl[base] = b;
  split2r(o1, a, b);
  bh[base + 64] = a; bl[base + 64] = b;
}

// ---------------- V transpose: (s, g, d) -> (g, d, s) bf16
__global__ __launch_bounds__(128) void vtrans_k(const short* __restrict__ v,
                                                short* __restrict__ vT) {
  int g = blockIdx.y;
  int s0 = blockIdx.x * 8;
  int d = threadIdx.x;
  if (s0 + 7 >= S_LEN || g >= NHKV || d >= HDIM) return;
  const size_t vSz = (size_t)S_LEN * KVDIM;
  bf16x8 vals;
#pragma unroll
  for (int i = 0; i < 8; i++)
    vals[i] = v[climp((size_t)(s0 + i) * KVDIM + g * HDIM + d, vSz, 1)];
  *reinterpret_cast<bf16x8*>(vT + climp(((size_t)g * HDIM + d) * S_LEN + s0,
                                        (size_t)NHKV * HDIM * S_LEN, 8)) = vals;
}

// ---------------- attn_ml2: hp m,l from split planes, 3-term chain
__global__ __launch_bounds__(256, 2) void attn_ml2(const short* __restrict__ qhp,
                                                   const short* __restrict__ qlp,
                                                   const short* __restrict__ khp,
                                                   const short* __restrict__ klp,
                                                   float* __restrict__ mbuf,
                                                   float* __restrict__ lbuf) {
  int h = blockIdx.x, qt = blockIdx.y;
  int g = h >> 2;
  int q0 = qt * 128;
  int tid = threadIdx.x, lane = tid & 63, wave = tid >> 6;
  int l15 = lane & 15, l4 = lane >> 4;
  __shared__ alignas(16) short Kh[32 * 136];
  __shared__ alignas(16) short Kl[32 * 136];
  const size_t qSz = (size_t)S_LEN * DMODEL;
  const size_t kSz = (size_t)S_LEN * KVDIM;

  int qrow_base = q0 + wave * 32;
  bf16x8 qh[2][4], ql[2][4];
#pragma unroll
  for (int mf = 0; mf < 2; mf++)
#pragma unroll
    for (int ks = 0; ks < 4; ks++) {
      size_t qi = climp((size_t)(qrow_base + mf * 16 + l15) * DMODEL + h * HDIM + ks * 32 + l4 * 8,
                        qSz, 8);
      qh[mf][ks] = *reinterpret_cast<const bf16x8*>(qhp + qi);
      ql[mf][ks] = *reinterpret_cast<const bf16x8*>(qlp + qi);
    }

  float mrow[2][4], lrow[2][4];
#pragma unroll
  for (int mf = 0; mf < 2; mf++)
#pragma unroll
    for (int r = 0; r < 4; r++) { mrow[mf][r] = -1e30f; lrow[mf][r] = 0.f; }
  int wqmax = qrow_base + 31;
  int nkt = qt * 4 + 4;
  const float scale = 0.08838834764831845f;
  f32x4 zf = {0.f, 0.f, 0.f, 0.f};

  for (int kt = 0; kt < nkt; kt++) {
    int k0 = kt * 32;
#pragma unroll
    for (int c = 0; c < 2; c++) {
      int idx = tid + c * 256;
      int r = idx >> 4, c8 = (idx & 15) * 8;
      size_t ki = climp((size_t)(k0 + r) * KVDIM + g * HDIM + c8, kSz, 8);
      *reinterpret_cast<bf16x8*>(&Kh[r * 136 + c8]) =
          *reinterpret_cast<const bf16x8*>(khp + ki);
      *reinterpret_cast<bf16x8*>(&Kl[r * 136 + c8]) =
          *reinterpret_cast<const bf16x8*>(klp + ki);
    }
    __syncthreads();
    if (k0 <= wqmax) {
      f32x4 sf[2][2] = {{zf, zf}, {zf, zf}};
#pragma unroll
      for (int ks = 0; ks < 4; ks++)
#pragma unroll
        for (int nf = 0; nf < 2; nf++) {
          int kr = (nf * 16 + l15) * 136 + ks * 32 + l4 * 8;
          bf16x8 bh = *reinterpret_cast<const bf16x8*>(&Kh[kr]);
          bf16x8 bl = *reinterpret_cast<const bf16x8*>(&Kl[kr]);
#pragma unroll
          for (int mf = 0; mf < 2; mf++)
            sf[mf][nf] = mfma16(qh[mf][ks], bh,
                         mfma16(ql[mf][ks], bh,
                         mfma16(qh[mf][ks], bl, sf[mf][nf])));
        }
#pragma unroll
      for (int mf = 0; mf < 2; mf++) {
#pragma unroll
        for (int r = 0; r < 4; r++) {
          int qg = qrow_base + mf * 16 + (l4 << 2) + r;
          float v0 = sf[mf][0][r] * scale;
          float v1 = sf[mf][1][r] * scale;
          if (k0 + l15 > qg) v0 = -1e9f;
          if (k0 + 16 + l15 > qg) v1 = -1e9f;
          float mx = fmaxf(v0, v1);
          mx = fmaxf(mx, __shfl_xor(mx, 1));
          mx = fmaxf(mx, __shfl_xor(mx, 2));
          mx = fmaxf(mx, __shfl_xor(mx, 4));
          mx = fmaxf(mx, __shfl_xor(mx, 8));
          float mnew = fmaxf(mrow[mf][r], mx);
          float alpha = expf(mrow[mf][r] - mnew);
          float rs = expf(v0 - mnew) + expf(v1 - mnew);
          rs += __shfl_xor(rs, 1);
          rs += __shfl_xor(rs, 2);
          rs += __shfl_xor(rs, 4);
          rs += __shfl_xor(rs, 8);
          lrow[mf][r] = lrow[mf][r] * alpha + rs;
          mrow[mf][r] = mnew;
        }
      }
    }
    __syncthreads();
  }
  if (l15 == 0) {
#pragma unroll
    for (int mf = 0; mf < 2; mf++)
#pragma unroll
      for (int r = 0; r < 4; r++) {
        int row = qrow_base + mf * 16 + (l4 << 2) + r;
        if (row < S_LEN) {
          mbuf[(size_t)h * S_LEN + row] = mrow[mf][r];
          lbuf[(size_t)h * S_LEN + row] = lrow[mf][r];
        }
      }
  }
}

// ---------------- attn_fwd: O from h-plane bf16 scores + precomputed hp m,l
__global__ __launch_bounds__(256, 2) void attn_fwd(const short* __restrict__ qhp,
                                                   const short* __restrict__ khp,
                                                   const short* __restrict__ vT,
                                                   short* __restrict__ ob,
                                                   const float* __restrict__ mbuf,
                                                   const float* __restrict__ lbuf) {
  int h = blockIdx.x, qt = blockIdx.y;
  int g = h >> 2;
  int q0 = qt * 128;
  int tid = threadIdx.x, lane = tid & 63, wave = tid >> 6;
  int l15 = lane & 15, l4 = lane >> 4;
  __shared__ alignas(16) short Kl[32 * 136];
  __shared__ alignas(16) short Vl[128 * 40];
  __shared__ alignas(16) short Pl[4][32 * 40];
  const size_t qSz = (size_t)S_LEN * DMODEL;
  const size_t kSz = (size_t)S_LEN * KVDIM;
  const size_t vtSz = (size_t)NHKV * HDIM * S_LEN;

  int qrow_base = q0 + wave * 32;
  bf16x8 qfr[2][4];
#pragma unroll
  for (int mf = 0; mf < 2; mf++)
#pragma unroll
    for (int ks = 0; ks < 4; ks++) {
      size_t qi = climp((size_t)(qrow_base + mf * 16 + l15) * DMODEL + h * HDIM + ks * 32 + l4 * 8,
                        qSz, 8);
      qfr[mf][ks] = *reinterpret_cast<const bf16x8*>(qhp + qi);
    }

  float mrow[2][4], rlrow[2][4];
#pragma unroll
  for (int mf = 0; mf < 2; mf++)
#pragma unroll
    for (int r = 0; r < 4; r++) {
      int row = qrow_base + mf * 16 + (l4 << 2) + r;
      size_t mi = climp((size_t)h * S_LEN + row, (size_t)NHQ * S_LEN, 1);
      mrow[mf][r] = mbuf[mi];
      rlrow[mf][r] = 1.0f / lbuf[mi];
    }

  f32x4 zf = {0.f, 0.f, 0.f, 0.f};
  f32x4 accO[2][8];
#pragma unroll
  for (int mf = 0; mf < 2; mf++)
#pragma unroll
    for (int nfo = 0; nfo < 8; nfo++) accO[mf][nfo] = zf;
  int wqmax = qrow_base + 31;
  int nkt = qt * 4 + 4;
  const float scale = 0.08838834764831845f;

  for (int kt = 0; kt < nkt; kt++) {
    int k0 = kt * 32;
#pragma unroll
    for (int c = 0; c < 2; c++) {
      int idx = tid + c * 256;
      int r = idx >> 4, c8 = (idx & 15) * 8;
      size_t ki = climp((size_t)(k0 + r) * KVDIM + g * HDIM + c8, kSz, 8);
      *reinterpret_cast<bf16x8*>(&Kl[r * 136 + c8]) =
          *reinterpret_cast<const bf16x8*>(khp + ki);
    }
#pragma unroll
    for (int c = 0; c < 2; c++) {
      int idx = tid + c * 256;
      int r = idx >> 2, c8 = idx & 3;
      *reinterpret_cast<bf16x8*>(&Vl[r * 40 + c8 * 8]) =
          *reinterpret_cast<const bf16x8*>(
              vT + climp(((size_t)g * HDIM + r) * S_LEN + k0 + c8 * 8, vtSz, 8));
    }
    __syncthreads();
    if (k0 <= wqmax) {
      f32x4 sf[2][2] = {{zf, zf}, {zf, zf}};
#pragma unroll
      for (int nf = 0; nf < 2; nf++)
#pragma unroll
        for (int ks = 0; ks < 4; ks++) {
          bf16x8 bk = *reinterpret_cast<const bf16x8*>(
              &Kl[(nf * 16 + l15) * 136 + ks * 32 + l4 * 8]);
          sf[0][nf] = mfma16(qfr[0][ks], bk, sf[0][nf]);
          sf[1][nf] = mfma16(qfr[1][ks], bk, sf[1][nf]);
        }
#pragma unroll
      for (int mf = 0; mf < 2; mf++)
#pragma unroll
        for (int r = 0; r < 4; r++) {
          int qg = qrow_base + mf * 16 + (l4 << 2) + r;
          float v0 = sf[mf][0][r] * scale;
          float v1 = sf[mf][1][r] * scale;
          if (k0 + l15 > qg) v0 = -1e9f;
          if (k0 + 16 + l15 > qg) v1 = -1e9f;
          float p0 = __expf(v0 - mrow[mf][r]);
          float p1 = __expf(v1 - mrow[mf][r]);
          Pl[wave][(mf * 16 + (l4 << 2) + r) * 40 + l15] = f2bf(p0);
          Pl[wave][(mf * 16 + (l4 << 2) + r) * 40 + 16 + l15] = f2bf(p1);
        }
      bf16x8 pa[2];
      pa[0] = *reinterpret_cast<const bf16x8*>(&Pl[wave][(0 + l15) * 40 + l4 * 8]);
      pa[1] = *reinterpret_cast<const bf16x8*>(&Pl[wave][(16 + l15) * 40 + l4 * 8]);
#pragma unroll
      for (int nfo = 0; nfo < 8; nfo++) {
        bf16x8 bv = *reinterpret_cast<const bf16x8*>(&Vl[(nfo * 16 + l15) * 40 + l4 * 8]);
        accO[0][nfo] = mfma16(pa[0], bv, accO[0][nfo]);
        accO[1][nfo] = mfma16(pa[1], bv, accO[1][nfo]);
      }
    }
    __syncthreads();
  }
#pragma unroll
  for (int mf = 0; mf < 2; mf++)
#pragma unroll
    for (int nfo = 0; nfo < 8; nfo++)
#pragma unroll
      for (int r = 0; r < 4; r++) {
        int row = qrow_base + mf * 16 + (l4 << 2) + r;
        int col = h * HDIM + nfo * 16 + l15;
        if (row < S_LEN && col < DMODEL)
          ob[(size_t)row * DMODEL + col] = f2bf(accO[mf][nfo][r] * rlrow[mf][r]);
      }
}

// ---------------- attn_hh2: column sums from split planes, 3-term chain, f64 col-acc
__global__ __launch_bounds__(256, 2) void attn_hh2(const short* __restrict__ qhp,
                                                   const short* __restrict__ qlp,
                                                   const short* __restrict__ khp,
                                                   const short* __restrict__ klp,
                                                   const float* __restrict__ mbuf,
                                                   const float* __restrict__ lbuf,
                                                   float* __restrict__ hh_h) {
  int h = blockIdx.x, kt = blockIdx.y;
  int g = h >> 2;
  int key0 = kt * 128;
  int tid = threadIdx.x, lane = tid & 63, wave = tid >> 6;
  int l15 = lane & 15, l4 = lane >> 4;
  __shared__ alignas(16) short Qh[32 * 136];
  __shared__ alignas(16) short Ql[32 * 136];
  const size_t qSz = (size_t)S_LEN * DMODEL;
  const size_t kSz = (size_t)S_LEN * KVDIM;
  const size_t mlSz = (size_t)NHQ * S_LEN;
  const float scale = 0.08838834764831845f;
  f32x4 zf = {0.f, 0.f, 0.f, 0.f};

  int keymin = key0 + wave * 32;
  bf16x8 akh[2][4], akl[2][4];
#pragma unroll
  for (int mf = 0; mf < 2; mf++)
#pragma unroll
    for (int ks = 0; ks < 4; ks++) {
      size_t ki = climp((size_t)(keymin + mf * 16 + l15) * KVDIM + g * HDIM + ks * 32 + l4 * 8,
                        kSz, 8);
      akh[mf][ks] = *reinterpret_cast<const bf16x8*>(khp + ki);
      akl[mf][ks] = *reinterpret_cast<const bf16x8*>(klp + ki);
    }

  double acc[2][4];
#pragma unroll
  for (int mf = 0; mf < 2; mf++)
#pragma unroll
    for (int r = 0; r < 4; r++) acc[mf][r] = 0.0;

  for (int q0 = key0; q0 < S_LEN; q0 += 32) {
#pragma unroll
    for (int c = 0; c < 2; c++) {
      int idx = tid + c * 256;
      int r = idx >> 4, c8 = (idx & 15) * 8;
      size_t qi = climp((size_t)(q0 + r) * DMODEL + h * HDIM + c8, qSz, 8);
      *reinterpret_cast<bf16x8*>(&Qh[r * 136 + c8]) =
          *reinterpret_cast<const bf16x8*>(qhp + qi);
      *reinterpret_cast<bf16x8*>(&Ql[r * 136 + c8]) =
          *reinterpret_cast<const bf16x8*>(qlp + qi);
    }
    __syncthreads();
    if (q0 + 31 >= keymin) {
      f32x4 sf[2][2] = {{zf, zf}, {zf, zf}};
#pragma unroll
      for (int ks = 0; ks < 4; ks++)
#pragma unroll
        for (int nf = 0; nf < 2; nf++) {
          int qr = (nf * 16 + l15) * 136 + ks * 32 + l4 * 8;
          bf16x8 bqh = *reinterpret_cast<const bf16x8*>(&Qh[qr]);
          bf16x8 bql = *reinterpret_cast<const bf16x8*>(&Ql[qr]);
#pragma unroll
          for (int mf = 0; mf < 2; mf++)
            sf[mf][nf] = mfma16(akh[mf][ks], bqh,
                         mfma16(akh[mf][ks], bql,
                         mfma16(akl[mf][ks], bqh, sf[mf][nf])));
        }
#pragma unroll
      for (int nf = 0; nf < 2; nf++) {
        int q = q0 + nf * 16 + l15;
        float mq = mbuf[climp((size_t)h * S_LEN + q, mlSz, 1)];
        float rl = 1.0f / lbuf[climp((size_t)h * S_LEN + q, mlSz, 1)];
#pragma unroll
        for (int mf = 0; mf < 2; mf++)
#pragma unroll
          for (int r = 0; r < 4; r++) {
            int key = keymin + mf * 16 + (l4 << 2) + r;
            if (q >= key && q < S_LEN)
              acc[mf][r] += (double)(expf(sf[mf][nf][r] * scale - mq) * rl);
          }
      }
    }
    __syncthreads();
  }
#pragma unroll
  for (int mf = 0; mf < 2; mf++)
#pragma unroll
    for (int r = 0; r < 4; r++) {
      double v = acc[mf][r];
      v += __shfl_xor(v, 1);
      v += __shfl_xor(v, 2);
      v += __shfl_xor(v, 4);
      v += __shfl_xor(v, 8);
      int key = keymin + mf * 16 + (l4 << 2) + r;
      if (l15 == 0 && key < S_LEN)
        hh_h[(size_t)h * S_LEN + key] = (float)v;
    }
}

// ---------------- top-k + gather (k reconstructed from planes)
__global__ __launch_bounds__(512) void topk_gather(const float* __restrict__ hh_h,
                                                   const short* __restrict__ khp,
                                                   const short* __restrict__ klp,
                                                   const short* __restrict__ vb,
                                                   float* __restrict__ out_k,
                                                   float* __restrict__ out_v,
                                                   float* __restrict__ out_hh) {
  int g = blockIdx.x, t = threadIdx.x;
  __shared__ float hhg[2048];
  __shared__ float sv[2048];
  __shared__ int si[2048];
  __shared__ int st[128];
  __shared__ int keep[NKEEP];
  const size_t hhSz = (size_t)NHQ * S_LEN;
  const size_t kvSz = (size_t)S_LEN * KVDIM;
#pragma unroll
  for (int i = 0; i < 4; i++) {
    int idx = t + i * 512;
    float s = 0.25f * (hh_h[climp((size_t)(4 * g + 0) * 2048 + idx, hhSz, 1)] +
                       hh_h[climp((size_t)(4 * g + 1) * 2048 + idx, hhSz, 1)] +
                       hh_h[climp((size_t)(4 * g + 2) * 2048 + idx, hhSz, 1)] +
                       hh_h[climp((size_t)(4 * g + 3) * 2048 + idx, hhSz, 1)]);
    hhg[idx] = s;
    sv[idx] = (idx < SEL_N) ? s : -1e30f;
    si[idx] = idx;
  }
  __syncthreads();
  for (int k = 2; k <= 2048; k <<= 1) {
    for (int j = k >> 1; j > 0; j >>= 1) {
#pragma unroll
      for (int pass = 0; pass < 4; pass++) {
        int i = t + pass * 512;
        int ixj = i ^ j;
        if (ixj > i) {
          bool up = ((i & k) == 0);
          float a = sv[i], b = sv[ixj];
          int ia = si[i], ib = si[ixj];
          bool before = (a > b) || (a == b && ia < ib);
          bool doswap = up ? !before : before;
          if (doswap) { sv[i] = b; sv[ixj] = a; si[i] = ib; si[ixj] = ia; }
        }
      }
      __syncthreads();
    }
  }
  if (t < 128) st[t] = si[t];
  __syncthreads();
  for (int k = 2; k <= 128; k <<= 1) {
    for (int j = k >> 1; j > 0; j >>= 1) {
      if (t < 128) {
        int i = t, ixj = i ^ j;
        if (ixj > i) {
          bool up = ((i & k) == 0);
          int a = st[i], b = st[ixj];
          bool doswap = up ? (a > b) : (a < b);
          if (doswap) { st[i] = b; st[ixj] = a; }
        }
      }
      __syncthreads();
    }
  }
  // All 640 keep[] entries initialized by all 512 threads (R1-R6 bug fix).
  for (int i = t; i < NKEEP; i += 512)
    keep[i] = (i < 128) ? st[i] : (SEL_N + (i - 128));
  __syncthreads();
  for (int i = 0; i < 160; i++) {
    int idx = t + i * 512;
    int jj = idx >> 7, d = idx & 127;
    int src = (jj < NKEEP) ? keep[jj] : 0;
    if (src < 0) src = 0;
    if (src >= S_LEN) src = S_LEN - 1;
    size_t oi = ((size_t)g * NKEEP + jj) * HDIM + d;
    if (jj < NKEEP) {
      size_t ki = climp((size_t)src * KVDIM + g * HDIM + d, kvSz, 1);
      out_k[oi] = bf2f(khp[ki]) + bf2f(klp[ki]);
      out_v[oi] = bf2f(vb[ki]);
    }
  }
  for (int i = t; i < NKEEP; i += 512) {
    int src = keep[i];
    if (src < 0) src = 0;
    if (src >= 2048) src = 2047;
    out_hh[(size_t)g * NKEEP + i] = hhg[src];
  }
}

extern "C" void kernel_launch(void* const* d_in, const int* in_sizes, int n_in,
                              void* d_out, int out_size, void* d_ws, size_t ws_size,
                              hipStream_t stream) {
  const float* x = (const float*)d_in[0];
  const float* Wq = (const float*)d_in[1];
  const float* Wk = (const float*)d_in[2];
  const float* Wv = (const float*)d_in[3];
  const float* Wo = (const float*)d_in[4];
  const float* cosb = (const float*)d_in[5];
  const float* sinb = (const float*)d_in[6];
  const int* pos = (const int*)d_in[7];

  char* ws = (char*)d_ws;
  size_t off = 0;
  auto alloc = [&](size_t bytes) {
    void* p = ws + off;
    off += (bytes + 255) & ~(size_t)255;
    return p;
  };
  // weight-transpose region, reused across stages (stream-ordered):
  //   stage 1: WqT hi (32MB) + WqT lo (32MB)
  //   stage 2: WkT hi (8MB) | WkT lo (8MB) | WvT (8MB) | WoT (32MB)  = 56MB
  short* Rg = (short*)alloc((size_t)64 * 1024 * 1024);          // 64 MB
  short* qh = (short*)alloc((size_t)S_LEN * DMODEL * 2);        // 16 MB
  short* ql = (short*)alloc((size_t)S_LEN * DMODEL * 2);        // 16 MB
  short* kh = (short*)alloc((size_t)S_LEN * KVDIM * 2);         // 4 MB
  short* kl = (short*)alloc((size_t)S_LEN * KVDIM * 2);         // 4 MB
  short* vbuf = (short*)alloc((size_t)S_LEN * KVDIM * 2);       // 4 MB
  short* vT = (short*)alloc((size_t)NHKV * HDIM * S_LEN * 2);   // 4 MB
  short* obuf = (short*)alloc((size_t)S_LEN * DMODEL * 2);      // 16 MB
  float* mbuf = (float*)alloc((size_t)NHQ * S_LEN * 4);
  float* lbuf = (float*)alloc((size_t)NHQ * S_LEN * 4);
  float* hh_h = (float*)alloc((size_t)NHQ * S_LEN * 4);
  if (off > ws_size) return;  // diagnostic: clean poison-fail if ws too small

  short* WqTh = Rg;
  short* WqTl = Rg + (size_t)16777216;   // +32 MB
  short* WkTh = Rg;
  short* WkTl = Rg + (size_t)4194304;    // +8 MB
  short* WvT  = Rg + (size_t)8388608;    // +16 MB
  short* WoT  = Rg + (size_t)12582912;   // +24 MB

  float* out = (float*)d_out;
  float* out_k = out + (size_t)S_LEN * DMODEL;
  float* out_v = out_k + (size_t)NHKV * NKEEP * HDIM;
  float* out_hh = out_v + (size_t)NHKV * NKEEP * HDIM;

  // ---- Q projection (hp planes), weights transposed first
  transpose_split<<<dim3(64, 64), 256, 0, stream>>>(Wq, WqTh, WqTl, DMODEL, DMODEL);
  gemm_hp2bt<<<dim3(16, 32), 256, 0, stream>>>(x, WqTh, WqTl, qh, ql, S_LEN, DMODEL, DMODEL);
  // ---- K projection (hp planes); WkT overwrites WqT region (stream-ordered)
  transpose_split<<<dim3(16, 64), 256, 0, stream>>>(Wk, WkTh, WkTl, DMODEL, KVDIM);
  gemm_hp2bt<<<dim3(16, 8), 256, 0, stream>>>(x, WkTh, WkTl, kh, kl, S_LEN, KVDIM, DMODEL);
  // ---- V projection (plain bf16)
  transpose_cvt<<<dim3(16, 64), 256, 0, stream>>>(Wv, WvT, DMODEL, KVDIM);
  gemm_bt<1, 1><<<dim3(16, 8), 256, 0, stream>>>(x, WvT, vbuf, S_LEN, KVDIM, DMODEL);
  // ---- Wo transpose (used later by O projection)
  transpose_cvt<<<dim3(64, 64), 256, 0, stream>>>(Wo, WoT, DMODEL, DMODEL);
  // ---- RoPE on planes, V transpose
  rope_planes<32><<<(S_LEN * 32 * 64) / 256, 256, 0, stream>>>(qh, ql, cosb, sinb, pos);
  rope_planes<8><<<(S_LEN * 8 * 64) / 256, 256, 0, stream>>>(kh, kl, cosb, sinb, pos);
  vtrans_k<<<dim3(S_LEN / 8, NHKV), 128, 0, stream>>>(vbuf, vT);
  // ---- softmax stats, attention output, column sums
  attn_ml2<<<dim3(NHQ, S_LEN / 128), 256, 0, stream>>>(qh, ql, kh, kl, mbuf, lbuf);
  attn_fwd<<<dim3(NHQ, S_LEN / 128), 256, 0, stream>>>(qh, kh, vT, obuf, mbuf, lbuf);
  attn_hh2<<<dim3(NHQ, S_LEN / 128), 256, 0, stream>>>(qh, ql, kh, kl, mbuf, lbuf, hh_h);
  // ---- output projection
  gemm_bt<0, 0><<<dim3(16, 32), 256, 0, stream>>>(obuf, WoT, out, S_LEN, DMODEL, DMODEL);
  // ---- H2O top-k + gathers
  topk_gather<<<NHKV, 512, 0, stream>>>(hh_h, kh, kl, vbuf, out_k, out_v, out_hh);
}

// Round 11
// 1102.907 us; speedup vs baseline: 2.2984x; 1.1856x over previous
//
#include <hip/hip_runtime.h>
#include <cstdint>
#include <cstddef>

typedef __attribute__((ext_vector_type(8))) short bf16x8;
typedef __attribute__((ext_vector_type(4))) short short4v;
typedef __attribute__((ext_vector_type(4))) float f32x4;

#define S_LEN 2048
#define DMODEL 4096
#define NHQ 32
#define NHKV 8
#define HDIM 128
#define KVDIM 1024
#define NKEEP 640
#define SEL_N 1536

__device__ __forceinline__ short f2bf(float f) {
  unsigned u = __float_as_uint(f);
  u += 0x7fffu + ((u >> 16) & 1u);
  return (short)(u >> 16);
}
__device__ __forceinline__ float bf2f(short s) {
  return __uint_as_float(((unsigned)(unsigned short)s) << 16);
}
// split-2, round-to-nearest hi plane: h = rne16(x), l = rne16(x - h). err <= 2^-17|x|
__device__ __forceinline__ void split2r(float x, short& h, short& l) {
  short hh = f2bf(x);
  float r = x - bf2f(hh);
  h = hh;
  l = f2bf(r);
}
__device__ __forceinline__ f32x4 mfma16(bf16x8 a, bf16x8 b, f32x4 c) {
  return __builtin_amdgcn_mfma_f32_16x16x32_bf16(a, b, c, 0, 0, 0);
}
__device__ __forceinline__ size_t climp(size_t i, size_t sz, size_t w) {
  size_t hi = sz - w;
  return i <= hi ? i : hi;
}

// ---------------- transpose+convert: W (Kd,N) f32 -> Wt (N,Kd) bf16
__global__ __launch_bounds__(256) void transpose_cvt(const float* __restrict__ W,
                                                     short* __restrict__ Wt,
                                                     int Kd, int N) {
  __shared__ float tile[64][65];
  int tx = threadIdx.x;
  int n0 = blockIdx.x * 64;
  int k0 = blockIdx.y * 64;
#pragma unroll
  for (int i = 0; i < 4; i++) {
    int idx = tx + i * 256;
    int r = idx >> 4, c4 = (idx & 15) * 4;
    float4 v = *reinterpret_cast<const float4*>(W + (size_t)(k0 + r) * N + n0 + c4);
    tile[r][c4 + 0] = v.x;
    tile[r][c4 + 1] = v.y;
    tile[r][c4 + 2] = v.z;
    tile[r][c4 + 3] = v.w;
  }
  __syncthreads();
#pragma unroll
  for (int i = 0; i < 4; i++) {
    int idx = tx + i * 256;
    int rn = idx >> 4, c4 = (idx & 15) * 4;
    short4v o;
#pragma unroll
    for (int j = 0; j < 4; j++) o[j] = f2bf(tile[c4 + j][rn]);
    *reinterpret_cast<short4v*>(Wt + (size_t)(n0 + rn) * Kd + k0 + c4) = o;
  }
}

// ---------------- transpose+split: W (Kd,N) f32 -> hi/lo bf16 planes (N,Kd)
__global__ __launch_bounds__(256) void transpose_split(const float* __restrict__ W,
                                                       short* __restrict__ Wth,
                                                       short* __restrict__ Wtl,
                                                       int Kd, int N) {
  __shared__ float tile[64][65];
  int tx = threadIdx.x;
  int n0 = blockIdx.x * 64;
  int k0 = blockIdx.y * 64;
#pragma unroll
  for (int i = 0; i < 4; i++) {
    int idx = tx + i * 256;
    int r = idx >> 4, c4 = (idx & 15) * 4;
    float4 v = *reinterpret_cast<const float4*>(W + (size_t)(k0 + r) * N + n0 + c4);
    tile[r][c4 + 0] = v.x;
    tile[r][c4 + 1] = v.y;
    tile[r][c4 + 2] = v.z;
    tile[r][c4 + 3] = v.w;
  }
  __syncthreads();
#pragma unroll
  for (int i = 0; i < 4; i++) {
    int idx = tx + i * 256;
    int rn = idx >> 4, c4 = (idx & 15) * 4;
    short4v oh, ol;
#pragma unroll
    for (int j = 0; j < 4; j++) {
      short a, b;
      split2r(tile[c4 + j][rn], a, b);
      oh[j] = a; ol[j] = b;
    }
    size_t wi = (size_t)(n0 + rn) * Kd + k0 + c4;
    *reinterpret_cast<short4v*>(Wth + wi) = oh;
    *reinterpret_cast<short4v*>(Wtl + wi) = ol;
  }
}

// ---------------- gemm_hp2bt: C planes = A(f32)[M,Kd] * B^T planes[N,Kd]
// 3-term split-2 chain, BK=32, 128x128 tile. (R8/R9-verified numerics.)
__global__ __launch_bounds__(256, 3) void gemm_hp2bt(const float* __restrict__ A,
                                                     const short* __restrict__ Bth,
                                                     const short* __restrict__ Btl,
                                                     short* __restrict__ Ch,
                                                     short* __restrict__ Cl,
                                                     int M, int N, int Kd) {
  __shared__ alignas(16) short Ah[128 * 40];
  __shared__ alignas(16) short Alo[128 * 40];
  __shared__ alignas(16) short Bh[128 * 40];
  __shared__ alignas(16) short Bl[128 * 40];
  int tid = threadIdx.x;
  int lane = tid & 63, wave = tid >> 6;
  int l15 = lane & 15, l4 = lane >> 4;
  int m0 = blockIdx.x * 128, n0 = blockIdx.y * 128;
  int wm = (wave >> 1) * 64, wn = (wave & 1) * 64;
  f32x4 zf = {0.f, 0.f, 0.f, 0.f};
  f32x4 acc[4][4];
#pragma unroll
  for (int i = 0; i < 4; i++)
#pragma unroll
    for (int j = 0; j < 4; j++) acc[i][j] = zf;

  for (int k0 = 0; k0 < Kd; k0 += 32) {
#pragma unroll
    for (int c = 0; c < 2; c++) {
      int idx = tid + c * 256;
      int r = idx >> 2, c8 = (idx & 3) * 8;
      const float* Ap = A + (size_t)(m0 + r) * Kd + k0 + c8;
      float4 v0 = *reinterpret_cast<const float4*>(Ap);
      float4 v1 = *reinterpret_cast<const float4*>(Ap + 4);
      float vv[8] = {v0.x, v0.y, v0.z, v0.w, v1.x, v1.y, v1.z, v1.w};
      bf16x8 sh, sl;
#pragma unroll
      for (int t = 0; t < 8; t++) { short a, b; split2r(vv[t], a, b); sh[t] = a; sl[t] = b; }
      *reinterpret_cast<bf16x8*>(&Ah[r * 40 + c8]) = sh;
      *reinterpret_cast<bf16x8*>(&Alo[r * 40 + c8]) = sl;
    }
#pragma unroll
    for (int c = 0; c < 2; c++) {
      int idx = tid + c * 256;
      int r = idx >> 2, c8 = (idx & 3) * 8;
      size_t bi = (size_t)(n0 + r) * Kd + k0 + c8;
      *reinterpret_cast<bf16x8*>(&Bh[r * 40 + c8]) =
          *reinterpret_cast<const bf16x8*>(Bth + bi);
      *reinterpret_cast<bf16x8*>(&Bl[r * 40 + c8]) =
          *reinterpret_cast<const bf16x8*>(Btl + bi);
    }
    __syncthreads();
    bf16x8 ah[4], al[4], bh4[4], bl4[4];
#pragma unroll
    for (int mf = 0; mf < 4; mf++) {
      int ar = (wm + mf * 16 + l15) * 40 + l4 * 8;
      ah[mf] = *reinterpret_cast<const bf16x8*>(&Ah[ar]);
      al[mf] = *reinterpret_cast<const bf16x8*>(&Alo[ar]);
    }
#pragma unroll
    for (int nf = 0; nf < 4; nf++) {
      int br = (wn + nf * 16 + l15) * 40 + l4 * 8;
      bh4[nf] = *reinterpret_cast<const bf16x8*>(&Bh[br]);
      bl4[nf] = *reinterpret_cast<const bf16x8*>(&Bl[br]);
    }
#pragma unroll
    for (int mf = 0; mf < 4; mf++)
#pragma unroll
      for (int nf = 0; nf < 4; nf++)
        acc[mf][nf] = mfma16(ah[mf], bh4[nf],
                      mfma16(al[mf], bh4[nf],
                      mfma16(ah[mf], bl4[nf], acc[mf][nf])));
    __syncthreads();
  }
  int rbase = m0 + wm + (l4 << 2);
  int cbase = n0 + wn + l15;
#pragma unroll
  for (int mf = 0; mf < 4; mf++)
#pragma unroll
    for (int nf = 0; nf < 4; nf++)
#pragma unroll
      for (int r = 0; r < 4; r++) {
        int row = rbase + mf * 16 + r;
        int col = cbase + nf * 16;
        if (row < M && col < N) {
          size_t ci = (size_t)row * N + col;
          short h, l;
          split2r(acc[mf][nf][r], h, l);
          Ch[ci] = h;
          Cl[ci] = l;
        }
      }
}

// ---------------- gemm_bt: plain bf16 GEMM with B^T (N,Kd) bf16 input
template <int A_F32, int STORE_BF16>
__global__ __launch_bounds__(256, 3) void gemm_bt(const void* __restrict__ Av,
                                                  const short* __restrict__ Bt,
                                                  void* __restrict__ Cv,
                                                  int M, int N, int Kd) {
  __shared__ alignas(16) short Al[128 * 72];
  __shared__ alignas(16) short Bl[128 * 72];
  int tid = threadIdx.x;
  int lane = tid & 63, wave = tid >> 6;
  int l15 = lane & 15, l4 = lane >> 4;
  int m0 = blockIdx.x * 128, n0 = blockIdx.y * 128;
  int wm = (wave >> 1) * 64, wn = (wave & 1) * 64;
  f32x4 zf = {0.f, 0.f, 0.f, 0.f};
  f32x4 acc[4][4];
#pragma unroll
  for (int i = 0; i < 4; i++)
#pragma unroll
    for (int j = 0; j < 4; j++) acc[i][j] = zf;

  for (int k0 = 0; k0 < Kd; k0 += 64) {
#pragma unroll
    for (int c = 0; c < 4; c++) {
      int idx = tid + c * 256;
      int r = idx >> 3, k8 = (idx & 7) * 8;
      bf16x8 a;
      if constexpr (A_F32 != 0) {
        const float* Ap = (const float*)Av + (size_t)(m0 + r) * Kd + k0 + k8;
        float4 v0 = *reinterpret_cast<const float4*>(Ap);
        float4 v1 = *reinterpret_cast<const float4*>(Ap + 4);
        a[0] = f2bf(v0.x); a[1] = f2bf(v0.y); a[2] = f2bf(v0.z); a[3] = f2bf(v0.w);
        a[4] = f2bf(v1.x); a[5] = f2bf(v1.y); a[6] = f2bf(v1.z); a[7] = f2bf(v1.w);
      } else {
        a = *reinterpret_cast<const bf16x8*>((const short*)Av + (size_t)(m0 + r) * Kd + k0 + k8);
      }
      *reinterpret_cast<bf16x8*>(&Al[r * 72 + k8]) = a;
      *reinterpret_cast<bf16x8*>(&Bl[r * 72 + k8]) =
          *reinterpret_cast<const bf16x8*>(Bt + (size_t)(n0 + r) * Kd + k0 + k8);
    }
    __syncthreads();
    bf16x8 af[4][2], bfr[4][2];
#pragma unroll
    for (int mf = 0; mf < 4; mf++)
#pragma unroll
      for (int ks = 0; ks < 2; ks++)
        af[mf][ks] = *reinterpret_cast<const bf16x8*>(
            &Al[(wm + mf * 16 + l15) * 72 + ks * 32 + l4 * 8]);
#pragma unroll
    for (int nf = 0; nf < 4; nf++)
#pragma unroll
      for (int ks = 0; ks < 2; ks++)
        bfr[nf][ks] = *reinterpret_cast<const bf16x8*>(
            &Bl[(wn + nf * 16 + l15) * 72 + ks * 32 + l4 * 8]);
#pragma unroll
    for (int ks = 0; ks < 2; ks++)
#pragma unroll
      for (int mf = 0; mf < 4; mf++)
#pragma unroll
        for (int nf = 0; nf < 4; nf++)
          acc[mf][nf] = mfma16(af[mf][ks], bfr[nf][ks], acc[mf][nf]);
    __syncthreads();
  }
  int rbase = m0 + wm + (l4 << 2);
  int cbase = n0 + wn + l15;
#pragma unroll
  for (int mf = 0; mf < 4; mf++)
#pragma unroll
    for (int nf = 0; nf < 4; nf++)
#pragma unroll
      for (int r = 0; r < 4; r++) {
        int row = rbase + mf * 16 + r;
        int col = cbase + nf * 16;
        if (row < M && col < N) {
          size_t ci = (size_t)row * N + col;
          float v = acc[mf][nf][r];
          if constexpr (STORE_BF16 != 0)
            ((short*)Cv)[ci] = f2bf(v);
          else
            ((float*)Cv)[ci] = v;
        }
      }
}

// ---------------- RoPE in-place on split planes (s, NH*128)
template <int NH>
__global__ __launch_bounds__(256) void rope_planes(short* __restrict__ bh,
                                                   short* __restrict__ bl,
                                                   const float* __restrict__ cosb,
                                                   const float* __restrict__ sinb,
                                                   const int* __restrict__ pos) {
  int idx = blockIdx.x * 256 + threadIdx.x;
  if (idx >= S_LEN * NH * 64) return;
  int d = idx & 63;
  int h = (idx >> 6) % NH;
  int s = idx / (64 * NH);
  int p = pos[s];
  if (p < 0) p = 0;
  if (p >= S_LEN) p = S_LEN - 1;
  size_t base = ((size_t)s * NH + h) * 128 + d;
  float lo = bf2f(bh[base]) + bf2f(bl[base]);
  float hi = bf2f(bh[base + 64]) + bf2f(bl[base + 64]);
  float c0 = cosb[p * 128 + d], s0 = sinb[p * 128 + d];
  float c1 = cosb[p * 128 + d + 64], s1 = sinb[p * 128 + d + 64];
  float o0 = lo * c0 - hi * s0;
  float o1 = hi * c1 + lo * s1;
  short a, b;
  split2r(o0, a, b);
  bh[base] = a; bl[base] = b;
  split2r(o1, a, b);
  bh[base + 64] = a; bl[base + 64] = b;
}

// ---------------- V transpose: (s, g, d) -> (g, d, s) bf16
__global__ __launch_bounds__(128) void vtrans_k(const short* __restrict__ v,
                                                short* __restrict__ vT) {
  int g = blockIdx.y;
  int s0 = blockIdx.x * 8;
  int d = threadIdx.x;
  if (s0 + 7 >= S_LEN || g >= NHKV || d >= HDIM) return;
  const size_t vSz = (size_t)S_LEN * KVDIM;
  bf16x8 vals;
#pragma unroll
  for (int i = 0; i < 8; i++)
    vals[i] = v[climp((size_t)(s0 + i) * KVDIM + g * HDIM + d, vSz, 1)];
  *reinterpret_cast<bf16x8*>(vT + climp(((size_t)g * HDIM + d) * S_LEN + s0,
                                        (size_t)NHKV * HDIM * S_LEN, 8)) = vals;
}

// ---------------- attn_fwd3: FUSED ml2+fwd — 3-term hp scores, online softmax,
// bf16 P, PV. Writes O, m, l. (Same score chain/order as R9's attn_ml2.)
__global__ __launch_bounds__(256, 2) void attn_fwd3(const short* __restrict__ qhp,
                                                    const short* __restrict__ qlp,
                                                    const short* __restrict__ khp,
                                                    const short* __restrict__ klp,
                                                    const short* __restrict__ vT,
                                                    short* __restrict__ ob,
                                                    float* __restrict__ mbuf,
                                                    float* __restrict__ lbuf) {
  int h = blockIdx.x, qt = blockIdx.y;
  int g = h >> 2;
  int q0 = qt * 128;
  int tid = threadIdx.x, lane = tid & 63, wave = tid >> 6;
  int l15 = lane & 15, l4 = lane >> 4;
  __shared__ alignas(16) short Kh[32 * 136];
  __shared__ alignas(16) short Kl2[32 * 136];
  __shared__ alignas(16) short Vl[128 * 40];
  __shared__ alignas(16) short Pl[4][32 * 40];
  const size_t qSz = (size_t)S_LEN * DMODEL;
  const size_t kSz = (size_t)S_LEN * KVDIM;
  const size_t vtSz = (size_t)NHKV * HDIM * S_LEN;

  int qrow_base = q0 + wave * 32;
  bf16x8 qh[2][4], ql[2][4];
#pragma unroll
  for (int mf = 0; mf < 2; mf++)
#pragma unroll
    for (int ks = 0; ks < 4; ks++) {
      size_t qi = climp((size_t)(qrow_base + mf * 16 + l15) * DMODEL + h * HDIM + ks * 32 + l4 * 8,
                        qSz, 8);
      qh[mf][ks] = *reinterpret_cast<const bf16x8*>(qhp + qi);
      ql[mf][ks] = *reinterpret_cast<const bf16x8*>(qlp + qi);
    }

  f32x4 zf = {0.f, 0.f, 0.f, 0.f};
  f32x4 accO[2][8];
  float mrow[2][4], lrow[2][4];
#pragma unroll
  for (int mf = 0; mf < 2; mf++) {
#pragma unroll
    for (int nfo = 0; nfo < 8; nfo++) accO[mf][nfo] = zf;
#pragma unroll
    for (int r = 0; r < 4; r++) { mrow[mf][r] = -1e30f; lrow[mf][r] = 0.f; }
  }
  int wqmax = qrow_base + 31;
  int nkt = qt * 4 + 4;
  const float scale = 0.08838834764831845f;

  for (int kt = 0; kt < nkt; kt++) {
    int k0 = kt * 32;
#pragma unroll
    for (int c = 0; c < 2; c++) {
      int idx = tid + c * 256;
      int r = idx >> 4, c8 = (idx & 15) * 8;
      size_t ki = climp((size_t)(k0 + r) * KVDIM + g * HDIM + c8, kSz, 8);
      *reinterpret_cast<bf16x8*>(&Kh[r * 136 + c8]) =
          *reinterpret_cast<const bf16x8*>(khp + ki);
      *reinterpret_cast<bf16x8*>(&Kl2[r * 136 + c8]) =
          *reinterpret_cast<const bf16x8*>(klp + ki);
    }
#pragma unroll
    for (int c = 0; c < 2; c++) {
      int idx = tid + c * 256;
      int r = idx >> 2, c8 = idx & 3;
      *reinterpret_cast<bf16x8*>(&Vl[r * 40 + c8 * 8]) =
          *reinterpret_cast<const bf16x8*>(
              vT + climp(((size_t)g * HDIM + r) * S_LEN + k0 + c8 * 8, vtSz, 8));
    }
    __syncthreads();
    if (k0 <= wqmax) {
      // 3-term hp scores (same chain/order as R9 attn_ml2)
      f32x4 sf[2][2] = {{zf, zf}, {zf, zf}};
#pragma unroll
      for (int ks = 0; ks < 4; ks++)
#pragma unroll
        for (int nf = 0; nf < 2; nf++) {
          int kr = (nf * 16 + l15) * 136 + ks * 32 + l4 * 8;
          bf16x8 bh = *reinterpret_cast<const bf16x8*>(&Kh[kr]);
          bf16x8 bl = *reinterpret_cast<const bf16x8*>(&Kl2[kr]);
#pragma unroll
          for (int mf = 0; mf < 2; mf++)
            sf[mf][nf] = mfma16(qh[mf][ks], bh,
                         mfma16(ql[mf][ks], bh,
                         mfma16(qh[mf][ks], bl, sf[mf][nf])));
        }
      // online softmax update + P
      float p[2][2][4];
#pragma unroll
      for (int mf = 0; mf < 2; mf++) {
#pragma unroll
        for (int r = 0; r < 4; r++) {
          int qg = qrow_base + mf * 16 + (l4 << 2) + r;
          float v0 = sf[mf][0][r] * scale;
          float v1 = sf[mf][1][r] * scale;
          if (k0 + l15 > qg) v0 = -1e9f;
          if (k0 + 16 + l15 > qg) v1 = -1e9f;
          float mx = fmaxf(v0, v1);
          mx = fmaxf(mx, __shfl_xor(mx, 1));
          mx = fmaxf(mx, __shfl_xor(mx, 2));
          mx = fmaxf(mx, __shfl_xor(mx, 4));
          mx = fmaxf(mx, __shfl_xor(mx, 8));
          float mnew = fmaxf(mrow[mf][r], mx);
          float alpha = __expf(mrow[mf][r] - mnew);
          float p0 = __expf(v0 - mnew);
          float p1 = __expf(v1 - mnew);
          float rs = p0 + p1;
          rs += __shfl_xor(rs, 1);
          rs += __shfl_xor(rs, 2);
          rs += __shfl_xor(rs, 4);
          rs += __shfl_xor(rs, 8);
          lrow[mf][r] = lrow[mf][r] * alpha + rs;
          mrow[mf][r] = mnew;
#pragma unroll
          for (int nfo = 0; nfo < 8; nfo++) accO[mf][nfo][r] *= alpha;
          p[mf][0][r] = p0;
          p[mf][1][r] = p1;
        }
      }
#pragma unroll
      for (int mf = 0; mf < 2; mf++)
#pragma unroll
        for (int nf = 0; nf < 2; nf++)
#pragma unroll
          for (int r = 0; r < 4; r++)
            Pl[wave][(mf * 16 + (l4 << 2) + r) * 40 + nf * 16 + l15] = f2bf(p[mf][nf][r]);
      bf16x8 pa[2];
      pa[0] = *reinterpret_cast<const bf16x8*>(&Pl[wave][(0 + l15) * 40 + l4 * 8]);
      pa[1] = *reinterpret_cast<const bf16x8*>(&Pl[wave][(16 + l15) * 40 + l4 * 8]);
#pragma unroll
      for (int nfo = 0; nfo < 8; nfo++) {
        bf16x8 bv = *reinterpret_cast<const bf16x8*>(&Vl[(nfo * 16 + l15) * 40 + l4 * 8]);
        accO[0][nfo] = mfma16(pa[0], bv, accO[0][nfo]);
        accO[1][nfo] = mfma16(pa[1], bv, accO[1][nfo]);
      }
    }
    __syncthreads();
  }
#pragma unroll
  for (int mf = 0; mf < 2; mf++) {
    float inv[4];
#pragma unroll
    for (int r = 0; r < 4; r++) inv[r] = 1.0f / lrow[mf][r];
#pragma unroll
    for (int nfo = 0; nfo < 8; nfo++)
#pragma unroll
      for (int r = 0; r < 4; r++) {
        int row = qrow_base + mf * 16 + (l4 << 2) + r;
        int col = h * HDIM + nfo * 16 + l15;
        if (row < S_LEN && col < DMODEL)
          ob[(size_t)row * DMODEL + col] = f2bf(accO[mf][nfo][r] * inv[r]);
      }
  }
  if (l15 == 0) {
#pragma unroll
    for (int mf = 0; mf < 2; mf++)
#pragma unroll
      for (int r = 0; r < 4; r++) {
        int row = qrow_base + mf * 16 + (l4 << 2) + r;
        if (row < S_LEN) {
          mbuf[(size_t)h * S_LEN + row] = mrow[mf][r];
          lbuf[(size_t)h * S_LEN + row] = lrow[mf][r];
        }
      }
  }
}

// ---------------- attn_hh2: column sums from split planes, 3-term chain, f64 col-acc
__global__ __launch_bounds__(256, 2) void attn_hh2(const short* __restrict__ qhp,
                                                   const short* __restrict__ qlp,
                                                   const short* __restrict__ khp,
                                                   const short* __restrict__ klp,
                                                   const float* __restrict__ mbuf,
                                                   const float* __restrict__ lbuf,
                                                   float* __restrict__ hh_h) {
  int h = blockIdx.x, kt = blockIdx.y;
  int g = h >> 2;
  int key0 = kt * 128;
  int tid = threadIdx.x, lane = tid & 63, wave = tid >> 6;
  int l15 = lane & 15, l4 = lane >> 4;
  __shared__ alignas(16) short Qh[32 * 136];
  __shared__ alignas(16) short Ql[32 * 136];
  const size_t qSz = (size_t)S_LEN * DMODEL;
  const size_t kSz = (size_t)S_LEN * KVDIM;
  const size_t mlSz = (size_t)NHQ * S_LEN;
  const float scale = 0.08838834764831845f;
  f32x4 zf = {0.f, 0.f, 0.f, 0.f};

  int keymin = key0 + wave * 32;
  bf16x8 akh[2][4], akl[2][4];
#pragma unroll
  for (int mf = 0; mf < 2; mf++)
#pragma unroll
    for (int ks = 0; ks < 4; ks++) {
      size_t ki = climp((size_t)(keymin + mf * 16 + l15) * KVDIM + g * HDIM + ks * 32 + l4 * 8,
                        kSz, 8);
      akh[mf][ks] = *reinterpret_cast<const bf16x8*>(khp + ki);
      akl[mf][ks] = *reinterpret_cast<const bf16x8*>(klp + ki);
    }

  double acc[2][4];
#pragma unroll
  for (int mf = 0; mf < 2; mf++)
#pragma unroll
    for (int r = 0; r < 4; r++) acc[mf][r] = 0.0;

  for (int q0 = key0; q0 < S_LEN; q0 += 32) {
#pragma unroll
    for (int c = 0; c < 2; c++) {
      int idx = tid + c * 256;
      int r = idx >> 4, c8 = (idx & 15) * 8;
      size_t qi = climp((size_t)(q0 + r) * DMODEL + h * HDIM + c8, qSz, 8);
      *reinterpret_cast<bf16x8*>(&Qh[r * 136 + c8]) =
          *reinterpret_cast<const bf16x8*>(qhp + qi);
      *reinterpret_cast<bf16x8*>(&Ql[r * 136 + c8]) =
          *reinterpret_cast<const bf16x8*>(qlp + qi);
    }
    __syncthreads();
    if (q0 + 31 >= keymin) {
      f32x4 sf[2][2] = {{zf, zf}, {zf, zf}};
#pragma unroll
      for (int ks = 0; ks < 4; ks++)
#pragma unroll
        for (int nf = 0; nf < 2; nf++) {
          int qr = (nf * 16 + l15) * 136 + ks * 32 + l4 * 8;
          bf16x8 bqh = *reinterpret_cast<const bf16x8*>(&Qh[qr]);
          bf16x8 bql = *reinterpret_cast<const bf16x8*>(&Ql[qr]);
#pragma unroll
          for (int mf = 0; mf < 2; mf++)
            sf[mf][nf] = mfma16(akh[mf][ks], bqh,
                         mfma16(akh[mf][ks], bql,
                         mfma16(akl[mf][ks], bqh, sf[mf][nf])));
        }
#pragma unroll
      for (int nf = 0; nf < 2; nf++) {
        int q = q0 + nf * 16 + l15;
        float mq = mbuf[climp((size_t)h * S_LEN + q, mlSz, 1)];
        float rl = 1.0f / lbuf[climp((size_t)h * S_LEN + q, mlSz, 1)];
#pragma unroll
        for (int mf = 0; mf < 2; mf++)
#pragma unroll
          for (int r = 0; r < 4; r++) {
            int key = keymin + mf * 16 + (l4 << 2) + r;
            if (q >= key && q < S_LEN)
              acc[mf][r] += (double)(__expf(sf[mf][nf][r] * scale - mq) * rl);
          }
      }
    }
    __syncthreads();
  }
#pragma unroll
  for (int mf = 0; mf < 2; mf++)
#pragma unroll
    for (int r = 0; r < 4; r++) {
      double v = acc[mf][r];
      v += __shfl_xor(v, 1);
      v += __shfl_xor(v, 2);
      v += __shfl_xor(v, 4);
      v += __shfl_xor(v, 8);
      int key = keymin + mf * 16 + (l4 << 2) + r;
      if (l15 == 0 && key < S_LEN)
        hh_h[(size_t)h * S_LEN + key] = (float)v;
    }
}

// ---------------- top-k + gather (k reconstructed from planes)
__global__ __launch_bounds__(512) void topk_gather(const float* __restrict__ hh_h,
                                                   const short* __restrict__ khp,
                                                   const short* __restrict__ klp,
                                                   const short* __restrict__ vb,
                                                   float* __restrict__ out_k,
                                                   float* __restrict__ out_v,
                                                   float* __restrict__ out_hh) {
  int g = blockIdx.x, t = threadIdx.x;
  __shared__ float hhg[2048];
  __shared__ float sv[2048];
  __shared__ int si[2048];
  __shared__ int st[128];
  __shared__ int keep[NKEEP];
  const size_t hhSz = (size_t)NHQ * S_LEN;
  const size_t kvSz = (size_t)S_LEN * KVDIM;
#pragma unroll
  for (int i = 0; i < 4; i++) {
    int idx = t + i * 512;
    float s = 0.25f * (hh_h[climp((size_t)(4 * g + 0) * 2048 + idx, hhSz, 1)] +
                       hh_h[climp((size_t)(4 * g + 1) * 2048 + idx, hhSz, 1)] +
                       hh_h[climp((size_t)(4 * g + 2) * 2048 + idx, hhSz, 1)] +
                       hh_h[climp((size_t)(4 * g + 3) * 2048 + idx, hhSz, 1)]);
    hhg[idx] = s;
    sv[idx] = (idx < SEL_N) ? s : -1e30f;
    si[idx] = idx;
  }
  __syncthreads();
  for (int k = 2; k <= 2048; k <<= 1) {
    for (int j = k >> 1; j > 0; j >>= 1) {
#pragma unroll
      for (int pass = 0; pass < 4; pass++) {
        int i = t + pass * 512;
        int ixj = i ^ j;
        if (ixj > i) {
          bool up = ((i & k) == 0);
          float a = sv[i], b = sv[ixj];
          int ia = si[i], ib = si[ixj];
          bool before = (a > b) || (a == b && ia < ib);
          bool doswap = up ? !before : before;
          if (doswap) { sv[i] = b; sv[ixj] = a; si[i] = ib; si[ixj] = ia; }
        }
      }
      __syncthreads();
    }
  }
  if (t < 128) st[t] = si[t];
  __syncthreads();
  for (int k = 2; k <= 128; k <<= 1) {
    for (int j = k >> 1; j > 0; j >>= 1) {
      if (t < 128) {
        int i = t, ixj = i ^ j;
        if (ixj > i) {
          bool up = ((i & k) == 0);
          int a = st[i], b = st[ixj];
          bool doswap = up ? (a > b) : (a < b);
          if (doswap) { st[i] = b; st[ixj] = a; }
        }
      }
      __syncthreads();
    }
  }
  // All 640 keep[] entries initialized by all 512 threads (R1-R6 bug fix).
  for (int i = t; i < NKEEP; i += 512)
    keep[i] = (i < 128) ? st[i] : (SEL_N + (i - 128));
  __syncthreads();
  for (int i = 0; i < 160; i++) {
    int idx = t + i * 512;
    int jj = idx >> 7, d = idx & 127;
    int src = (jj < NKEEP) ? keep[jj] : 0;
    if (src < 0) src = 0;
    if (src >= S_LEN) src = S_LEN - 1;
    size_t oi = ((size_t)g * NKEEP + jj) * HDIM + d;
    if (jj < NKEEP) {
      size_t ki = climp((size_t)src * KVDIM + g * HDIM + d, kvSz, 1);
      out_k[oi] = bf2f(khp[ki]) + bf2f(klp[ki]);
      out_v[oi] = bf2f(vb[ki]);
    }
  }
  for (int i = t; i < NKEEP; i += 512) {
    int src = keep[i];
    if (src < 0) src = 0;
    if (src >= 2048) src = 2047;
    out_hh[(size_t)g * NKEEP + i] = hhg[src];
  }
}

extern "C" void kernel_launch(void* const* d_in, const int* in_sizes, int n_in,
                              void* d_out, int out_size, void* d_ws, size_t ws_size,
                              hipStream_t stream) {
  const float* x = (const float*)d_in[0];
  const float* Wq = (const float*)d_in[1];
  const float* Wk = (const float*)d_in[2];
  const float* Wv = (const float*)d_in[3];
  const float* Wo = (const float*)d_in[4];
  const float* cosb = (const float*)d_in[5];
  const float* sinb = (const float*)d_in[6];
  const int* pos = (const int*)d_in[7];

  char* ws = (char*)d_ws;
  size_t off = 0;
  auto alloc = [&](size_t bytes) {
    void* p = ws + off;
    off += (bytes + 255) & ~(size_t)255;
    return p;
  };
  // weight-transpose region, reused across stages (stream-ordered):
  //   stage 1: WqT hi (32MB) + WqT lo (32MB)
  //   stage 2: WkT hi (8MB) | WkT lo (8MB) | WvT (8MB) | WoT (32MB)  = 56MB
  short* Rg = (short*)alloc((size_t)64 * 1024 * 1024);          // 64 MB
  short* qh = (short*)alloc((size_t)S_LEN * DMODEL * 2);        // 16 MB
  short* ql = (short*)alloc((size_t)S_LEN * DMODEL * 2);        // 16 MB
  short* kh = (short*)alloc((size_t)S_LEN * KVDIM * 2);         // 4 MB
  short* kl = (short*)alloc((size_t)S_LEN * KVDIM * 2);         // 4 MB
  short* vbuf = (short*)alloc((size_t)S_LEN * KVDIM * 2);       // 4 MB
  short* vT = (short*)alloc((size_t)NHKV * HDIM * S_LEN * 2);   // 4 MB
  short* obuf = (short*)alloc((size_t)S_LEN * DMODEL * 2);      // 16 MB
  float* mbuf = (float*)alloc((size_t)NHQ * S_LEN * 4);
  float* lbuf = (float*)alloc((size_t)NHQ * S_LEN * 4);
  float* hh_h = (float*)alloc((size_t)NHQ * S_LEN * 4);
  if (off > ws_size) return;  // diagnostic: clean poison-fail if ws too small

  short* WqTh = Rg;
  short* WqTl = Rg + (size_t)16777216;   // +32 MB
  short* WkTh = Rg;
  short* WkTl = Rg + (size_t)4194304;    // +8 MB
  short* WvT  = Rg + (size_t)8388608;    // +16 MB
  short* WoT  = Rg + (size_t)12582912;   // +24 MB

  float* out = (float*)d_out;
  float* out_k = out + (size_t)S_LEN * DMODEL;
  float* out_v = out_k + (size_t)NHKV * NKEEP * HDIM;
  float* out_hh = out_v + (size_t)NHKV * NKEEP * HDIM;

  // ---- Q projection (hp planes)
  transpose_split<<<dim3(64, 64), 256, 0, stream>>>(Wq, WqTh, WqTl, DMODEL, DMODEL);
  gemm_hp2bt<<<dim3(16, 32), 256, 0, stream>>>(x, WqTh, WqTl, qh, ql, S_LEN, DMODEL, DMODEL);
  // ---- K projection (hp planes); WkT overwrites WqT region (stream-ordered)
  transpose_split<<<dim3(16, 64), 256, 0, stream>>>(Wk, WkTh, WkTl, DMODEL, KVDIM);
  gemm_hp2bt<<<dim3(16, 8), 256, 0, stream>>>(x, WkTh, WkTl, kh, kl, S_LEN, KVDIM, DMODEL);
  // ---- V projection (plain bf16)
  transpose_cvt<<<dim3(16, 64), 256, 0, stream>>>(Wv, WvT, DMODEL, KVDIM);
  gemm_bt<1, 1><<<dim3(16, 8), 256, 0, stream>>>(x, WvT, vbuf, S_LEN, KVDIM, DMODEL);
  // ---- Wo transpose (used later by O projection)
  transpose_cvt<<<dim3(64, 64), 256, 0, stream>>>(Wo, WoT, DMODEL, DMODEL);
  // ---- RoPE on planes, V transpose
  rope_planes<32><<<(S_LEN * 32 * 64) / 256, 256, 0, stream>>>(qh, ql, cosb, sinb, pos);
  rope_planes<8><<<(S_LEN * 8 * 64) / 256, 256, 0, stream>>>(kh, kl, cosb, sinb, pos);
  vtrans_k<<<dim3(S_LEN / 8, NHKV), 128, 0, stream>>>(vbuf, vT);
  // ---- fused attention fwd (3-term scores, online softmax, writes m,l), then column sums
  attn_fwd3<<<dim3(NHQ, S_LEN / 128), 256, 0, stream>>>(qh, ql, kh, kl, vT, obuf, mbuf, lbuf);
  attn_hh2<<<dim3(NHQ, S_LEN / 128), 256, 0, stream>>>(qh, ql, kh, kl, mbuf, lbuf, hh_h);
  // ---- output projection
  gemm_bt<0, 0><<<dim3(16, 32), 256, 0, stream>>>(obuf, WoT, out, S_LEN, DMODEL, DMODEL);
  // ---- H2O top-k + gathers
  topk_gather<<<NHKV, 512, 0, stream>>>(hh_h, kh, kl, vbuf, out_k, out_v, out_hh);
}

// Round 12
// 1062.600 us; speedup vs baseline: 2.3856x; 1.0379x over previous
//
#include <hip/hip_runtime.h>
#include <cstdint>
#include <cstddef>

typedef __attribute__((ext_vector_type(8))) short bf16x8;
typedef __attribute__((ext_vector_type(4))) short short4v;
typedef __attribute__((ext_vector_type(4))) float f32x4;

#define S_LEN 2048
#define DMODEL 4096
#define NHQ 32
#define NHKV 8
#define HDIM 128
#define KVDIM 1024
#define NKEEP 640
#define SEL_N 1536

__device__ __forceinline__ short f2bf(float f) {
  unsigned u = __float_as_uint(f);
  u += 0x7fffu + ((u >> 16) & 1u);
  return (short)(u >> 16);
}
__device__ __forceinline__ float bf2f(short s) {
  return __uint_as_float(((unsigned)(unsigned short)s) << 16);
}
// split-2, round-to-nearest hi plane: h = rne16(x), l = rne16(x - h). err <= 2^-17|x|
__device__ __forceinline__ void split2r(float x, short& h, short& l) {
  short hh = f2bf(x);
  float r = x - bf2f(hh);
  h = hh;
  l = f2bf(r);
}
__device__ __forceinline__ f32x4 mfma16(bf16x8 a, bf16x8 b, f32x4 c) {
  return __builtin_amdgcn_mfma_f32_16x16x32_bf16(a, b, c, 0, 0, 0);
}
__device__ __forceinline__ size_t climp(size_t i, size_t sz, size_t w) {
  size_t hi = sz - w;
  return i <= hi ? i : hi;
}

// ---------------- split_x: x f32 -> hi/lo bf16 planes (same values as inline split)
__global__ __launch_bounds__(256) void split_x(const float* __restrict__ x,
                                               short* __restrict__ xh,
                                               short* __restrict__ xl) {
  size_t i = ((size_t)blockIdx.x * 256 + threadIdx.x) * 8;
  if (i + 8 > (size_t)S_LEN * DMODEL) return;
  const float* p = x + i;
  float4 v0 = *reinterpret_cast<const float4*>(p);
  float4 v1 = *reinterpret_cast<const float4*>(p + 4);
  float vv[8] = {v0.x, v0.y, v0.z, v0.w, v1.x, v1.y, v1.z, v1.w};
  bf16x8 sh, sl;
#pragma unroll
  for (int t = 0; t < 8; t++) { short a, b; split2r(vv[t], a, b); sh[t] = a; sl[t] = b; }
  *reinterpret_cast<bf16x8*>(xh + i) = sh;
  *reinterpret_cast<bf16x8*>(xl + i) = sl;
}

// ---------------- transpose+convert: W (Kd,N) f32 -> Wt (N,Kd) bf16
__global__ __launch_bounds__(256) void transpose_cvt(const float* __restrict__ W,
                                                     short* __restrict__ Wt,
                                                     int Kd, int N) {
  __shared__ float tile[64][65];
  int tx = threadIdx.x;
  int n0 = blockIdx.x * 64;
  int k0 = blockIdx.y * 64;
#pragma unroll
  for (int i = 0; i < 4; i++) {
    int idx = tx + i * 256;
    int r = idx >> 4, c4 = (idx & 15) * 4;
    float4 v = *reinterpret_cast<const float4*>(W + (size_t)(k0 + r) * N + n0 + c4);
    tile[r][c4 + 0] = v.x;
    tile[r][c4 + 1] = v.y;
    tile[r][c4 + 2] = v.z;
    tile[r][c4 + 3] = v.w;
  }
  __syncthreads();
#pragma unroll
  for (int i = 0; i < 4; i++) {
    int idx = tx + i * 256;
    int rn = idx >> 4, c4 = (idx & 15) * 4;
    short4v o;
#pragma unroll
    for (int j = 0; j < 4; j++) o[j] = f2bf(tile[c4 + j][rn]);
    *reinterpret_cast<short4v*>(Wt + (size_t)(n0 + rn) * Kd + k0 + c4) = o;
  }
}

// ---------------- transpose+split: W (Kd,N) f32 -> hi/lo bf16 planes (N,Kd)
__global__ __launch_bounds__(256) void transpose_split(const float* __restrict__ W,
                                                       short* __restrict__ Wth,
                                                       short* __restrict__ Wtl,
                                                       int Kd, int N) {
  __shared__ float tile[64][65];
  int tx = threadIdx.x;
  int n0 = blockIdx.x * 64;
  int k0 = blockIdx.y * 64;
#pragma unroll
  for (int i = 0; i < 4; i++) {
    int idx = tx + i * 256;
    int r = idx >> 4, c4 = (idx & 15) * 4;
    float4 v = *reinterpret_cast<const float4*>(W + (size_t)(k0 + r) * N + n0 + c4);
    tile[r][c4 + 0] = v.x;
    tile[r][c4 + 1] = v.y;
    tile[r][c4 + 2] = v.z;
    tile[r][c4 + 3] = v.w;
  }
  __syncthreads();
#pragma unroll
  for (int i = 0; i < 4; i++) {
    int idx = tx + i * 256;
    int rn = idx >> 4, c4 = (idx & 15) * 4;
    short4v oh, ol;
#pragma unroll
    for (int j = 0; j < 4; j++) {
      short a, b;
      split2r(tile[c4 + j][rn], a, b);
      oh[j] = a; ol[j] = b;
    }
    size_t wi = (size_t)(n0 + rn) * Kd + k0 + c4;
    *reinterpret_cast<short4v*>(Wth + wi) = oh;
    *reinterpret_cast<short4v*>(Wtl + wi) = ol;
  }
}

// ---------------- gemm_hp2bt: C planes = A planes[M,Kd] * B^T planes[N,Kd]
// 3-term split-2 chain, BK=32, 128x128 tile. A pre-split (bitwise = R11 inline).
__global__ __launch_bounds__(256, 3) void gemm_hp2bt(const short* __restrict__ Ath,
                                                     const short* __restrict__ Atl,
                                                     const short* __restrict__ Bth,
                                                     const short* __restrict__ Btl,
                                                     short* __restrict__ Ch,
                                                     short* __restrict__ Cl,
                                                     int M, int N, int Kd) {
  __shared__ alignas(16) short Ah[128 * 40];
  __shared__ alignas(16) short Alo[128 * 40];
  __shared__ alignas(16) short Bh[128 * 40];
  __shared__ alignas(16) short Bl[128 * 40];
  int tid = threadIdx.x;
  int lane = tid & 63, wave = tid >> 6;
  int l15 = lane & 15, l4 = lane >> 4;
  int m0 = blockIdx.x * 128, n0 = blockIdx.y * 128;
  int wm = (wave >> 1) * 64, wn = (wave & 1) * 64;
  f32x4 zf = {0.f, 0.f, 0.f, 0.f};
  f32x4 acc[4][4];
#pragma unroll
  for (int i = 0; i < 4; i++)
#pragma unroll
    for (int j = 0; j < 4; j++) acc[i][j] = zf;

  for (int k0 = 0; k0 < Kd; k0 += 32) {
#pragma unroll
    for (int c = 0; c < 2; c++) {
      int idx = tid + c * 256;
      int r = idx >> 2, c8 = (idx & 3) * 8;
      size_t ai = (size_t)(m0 + r) * Kd + k0 + c8;
      *reinterpret_cast<bf16x8*>(&Ah[r * 40 + c8]) =
          *reinterpret_cast<const bf16x8*>(Ath + ai);
      *reinterpret_cast<bf16x8*>(&Alo[r * 40 + c8]) =
          *reinterpret_cast<const bf16x8*>(Atl + ai);
    }
#pragma unroll
    for (int c = 0; c < 2; c++) {
      int idx = tid + c * 256;
      int r = idx >> 2, c8 = (idx & 3) * 8;
      size_t bi = (size_t)(n0 + r) * Kd + k0 + c8;
      *reinterpret_cast<bf16x8*>(&Bh[r * 40 + c8]) =
          *reinterpret_cast<const bf16x8*>(Bth + bi);
      *reinterpret_cast<bf16x8*>(&Bl[r * 40 + c8]) =
          *reinterpret_cast<const bf16x8*>(Btl + bi);
    }
    __syncthreads();
    bf16x8 ah[4], al[4], bh4[4], bl4[4];
#pragma unroll
    for (int mf = 0; mf < 4; mf++) {
      int ar = (wm + mf * 16 + l15) * 40 + l4 * 8;
      ah[mf] = *reinterpret_cast<const bf16x8*>(&Ah[ar]);
      al[mf] = *reinterpret_cast<const bf16x8*>(&Alo[ar]);
    }
#pragma unroll
    for (int nf = 0; nf < 4; nf++) {
      int br = (wn + nf * 16 + l15) * 40 + l4 * 8;
      bh4[nf] = *reinterpret_cast<const bf16x8*>(&Bh[br]);
      bl4[nf] = *reinterpret_cast<const bf16x8*>(&Bl[br]);
    }
#pragma unroll
    for (int mf = 0; mf < 4; mf++)
#pragma unroll
      for (int nf = 0; nf < 4; nf++)
        acc[mf][nf] = mfma16(ah[mf], bh4[nf],
                      mfma16(al[mf], bh4[nf],
                      mfma16(ah[mf], bl4[nf], acc[mf][nf])));
    __syncthreads();
  }
  int rbase = m0 + wm + (l4 << 2);
  int cbase = n0 + wn + l15;
#pragma unroll
  for (int mf = 0; mf < 4; mf++)
#pragma unroll
    for (int nf = 0; nf < 4; nf++)
#pragma unroll
      for (int r = 0; r < 4; r++) {
        int row = rbase + mf * 16 + r;
        int col = cbase + nf * 16;
        if (row < M && col < N) {
          size_t ci = (size_t)row * N + col;
          short h, l;
          split2r(acc[mf][nf][r], h, l);
          Ch[ci] = h;
          Cl[ci] = l;
        }
      }
}

// ---------------- gemm_bt: plain bf16 GEMM with B^T (N,Kd) bf16 input
template <int A_F32, int STORE_BF16>
__global__ __launch_bounds__(256, 3) void gemm_bt(const void* __restrict__ Av,
                                                  const short* __restrict__ Bt,
                                                  void* __restrict__ Cv,
                                                  int M, int N, int Kd) {
  __shared__ alignas(16) short Al[128 * 72];
  __shared__ alignas(16) short Bl[128 * 72];
  int tid = threadIdx.x;
  int lane = tid & 63, wave = tid >> 6;
  int l15 = lane & 15, l4 = lane >> 4;
  int m0 = blockIdx.x * 128, n0 = blockIdx.y * 128;
  int wm = (wave >> 1) * 64, wn = (wave & 1) * 64;
  f32x4 zf = {0.f, 0.f, 0.f, 0.f};
  f32x4 acc[4][4];
#pragma unroll
  for (int i = 0; i < 4; i++)
#pragma unroll
    for (int j = 0; j < 4; j++) acc[i][j] = zf;

  for (int k0 = 0; k0 < Kd; k0 += 64) {
#pragma unroll
    for (int c = 0; c < 4; c++) {
      int idx = tid + c * 256;
      int r = idx >> 3, k8 = (idx & 7) * 8;
      bf16x8 a;
      if constexpr (A_F32 != 0) {
        const float* Ap = (const float*)Av + (size_t)(m0 + r) * Kd + k0 + k8;
        float4 v0 = *reinterpret_cast<const float4*>(Ap);
        float4 v1 = *reinterpret_cast<const float4*>(Ap + 4);
        a[0] = f2bf(v0.x); a[1] = f2bf(v0.y); a[2] = f2bf(v0.z); a[3] = f2bf(v0.w);
        a[4] = f2bf(v1.x); a[5] = f2bf(v1.y); a[6] = f2bf(v1.z); a[7] = f2bf(v1.w);
      } else {
        a = *reinterpret_cast<const bf16x8*>((const short*)Av + (size_t)(m0 + r) * Kd + k0 + k8);
      }
      *reinterpret_cast<bf16x8*>(&Al[r * 72 + k8]) = a;
      *reinterpret_cast<bf16x8*>(&Bl[r * 72 + k8]) =
          *reinterpret_cast<const bf16x8*>(Bt + (size_t)(n0 + r) * Kd + k0 + k8);
    }
    __syncthreads();
    bf16x8 af[4][2], bfr[4][2];
#pragma unroll
    for (int mf = 0; mf < 4; mf++)
#pragma unroll
      for (int ks = 0; ks < 2; ks++)
        af[mf][ks] = *reinterpret_cast<const bf16x8*>(
            &Al[(wm + mf * 16 + l15) * 72 + ks * 32 + l4 * 8]);
#pragma unroll
    for (int nf = 0; nf < 4; nf++)
#pragma unroll
      for (int ks = 0; ks < 2; ks++)
        bfr[nf][ks] = *reinterpret_cast<const bf16x8*>(
            &Bl[(wn + nf * 16 + l15) * 72 + ks * 32 + l4 * 8]);
#pragma unroll
    for (int ks = 0; ks < 2; ks++)
#pragma unroll
      for (int mf = 0; mf < 4; mf++)
#pragma unroll
        for (int nf = 0; nf < 4; nf++)
          acc[mf][nf] = mfma16(af[mf][ks], bfr[nf][ks], acc[mf][nf]);
    __syncthreads();
  }
  int rbase = m0 + wm + (l4 << 2);
  int cbase = n0 + wn + l15;
#pragma unroll
  for (int mf = 0; mf < 4; mf++)
#pragma unroll
    for (int nf = 0; nf < 4; nf++)
#pragma unroll
      for (int r = 0; r < 4; r++) {
        int row = rbase + mf * 16 + r;
        int col = cbase + nf * 16;
        if (row < M && col < N) {
          size_t ci = (size_t)row * N + col;
          float v = acc[mf][nf][r];
          if constexpr (STORE_BF16 != 0)
            ((short*)Cv)[ci] = f2bf(v);
          else
            ((float*)Cv)[ci] = v;
        }
      }
}

// ---------------- RoPE in-place on split planes (s, NH*128)
template <int NH>
__global__ __launch_bounds__(256) void rope_planes(short* __restrict__ bh,
                                                   short* __restrict__ bl,
                                                   const float* __restrict__ cosb,
                                                   const float* __restrict__ sinb,
                                                   const int* __restrict__ pos) {
  int idx = blockIdx.x * 256 + threadIdx.x;
  if (idx >= S_LEN * NH * 64) return;
  int d = idx & 63;
  int h = (idx >> 6) % NH;
  int s = idx / (64 * NH);
  int p = pos[s];
  if (p < 0) p = 0;
  if (p >= S_LEN) p = S_LEN - 1;
  size_t base = ((size_t)s * NH + h) * 128 + d;
  float lo = bf2f(bh[base]) + bf2f(bl[base]);
  float hi = bf2f(bh[base + 64]) + bf2f(bl[base + 64]);
  float c0 = cosb[p * 128 + d], s0 = sinb[p * 128 + d];
  float c1 = cosb[p * 128 + d + 64], s1 = sinb[p * 128 + d + 64];
  float o0 = lo * c0 - hi * s0;
  float o1 = hi * c1 + lo * s1;
  short a, b;
  split2r(o0, a, b);
  bh[base] = a; bl[base] = b;
  split2r(o1, a, b);
  bh[base + 64] = a; bl[base + 64] = b;
}

// ---------------- V transpose: (s, g, d) -> (g, d, s) bf16
__global__ __launch_bounds__(128) void vtrans_k(const short* __restrict__ v,
                                                short* __restrict__ vT) {
  int g = blockIdx.y;
  int s0 = blockIdx.x * 8;
  int d = threadIdx.x;
  if (s0 + 7 >= S_LEN || g >= NHKV || d >= HDIM) return;
  const size_t vSz = (size_t)S_LEN * KVDIM;
  bf16x8 vals;
#pragma unroll
  for (int i = 0; i < 8; i++)
    vals[i] = v[climp((size_t)(s0 + i) * KVDIM + g * HDIM + d, vSz, 1)];
  *reinterpret_cast<bf16x8*>(vT + climp(((size_t)g * HDIM + d) * S_LEN + s0,
                                        (size_t)NHKV * HDIM * S_LEN, 8)) = vals;
}

// ---------------- attn_fwd3: FUSED — 3-term hp scores, online softmax, bf16 P, PV.
__global__ __launch_bounds__(256, 2) void attn_fwd3(const short* __restrict__ qhp,
                                                    const short* __restrict__ qlp,
                                                    const short* __restrict__ khp,
                                                    const short* __restrict__ klp,
                                                    const short* __restrict__ vT,
                                                    short* __restrict__ ob,
                                                    float* __restrict__ mbuf,
                                                    float* __restrict__ lbuf) {
  int h = blockIdx.x, qt = blockIdx.y;
  int g = h >> 2;
  int q0 = qt * 128;
  int tid = threadIdx.x, lane = tid & 63, wave = tid >> 6;
  int l15 = lane & 15, l4 = lane >> 4;
  __shared__ alignas(16) short Kh[32 * 136];
  __shared__ alignas(16) short Kl2[32 * 136];
  __shared__ alignas(16) short Vl[128 * 40];
  __shared__ alignas(16) short Pl[4][32 * 40];
  const size_t qSz = (size_t)S_LEN * DMODEL;
  const size_t kSz = (size_t)S_LEN * KVDIM;
  const size_t vtSz = (size_t)NHKV * HDIM * S_LEN;

  int qrow_base = q0 + wave * 32;
  bf16x8 qh[2][4], ql[2][4];
#pragma unroll
  for (int mf = 0; mf < 2; mf++)
#pragma unroll
    for (int ks = 0; ks < 4; ks++) {
      size_t qi = climp((size_t)(qrow_base + mf * 16 + l15) * DMODEL + h * HDIM + ks * 32 + l4 * 8,
                        qSz, 8);
      qh[mf][ks] = *reinterpret_cast<const bf16x8*>(qhp + qi);
      ql[mf][ks] = *reinterpret_cast<const bf16x8*>(qlp + qi);
    }

  f32x4 zf = {0.f, 0.f, 0.f, 0.f};
  f32x4 accO[2][8];
  float mrow[2][4], lrow[2][4];
#pragma unroll
  for (int mf = 0; mf < 2; mf++) {
#pragma unroll
    for (int nfo = 0; nfo < 8; nfo++) accO[mf][nfo] = zf;
#pragma unroll
    for (int r = 0; r < 4; r++) { mrow[mf][r] = -1e30f; lrow[mf][r] = 0.f; }
  }
  int wqmax = qrow_base + 31;
  int nkt = qt * 4 + 4;
  const float scale = 0.08838834764831845f;

  for (int kt = 0; kt < nkt; kt++) {
    int k0 = kt * 32;
#pragma unroll
    for (int c = 0; c < 2; c++) {
      int idx = tid + c * 256;
      int r = idx >> 4, c8 = (idx & 15) * 8;
      size_t ki = climp((size_t)(k0 + r) * KVDIM + g * HDIM + c8, kSz, 8);
      *reinterpret_cast<bf16x8*>(&Kh[r * 136 + c8]) =
          *reinterpret_cast<const bf16x8*>(khp + ki);
      *reinterpret_cast<bf16x8*>(&Kl2[r * 136 + c8]) =
          *reinterpret_cast<const bf16x8*>(klp + ki);
    }
#pragma unroll
    for (int c = 0; c < 2; c++) {
      int idx = tid + c * 256;
      int r = idx >> 2, c8 = idx & 3;
      *reinterpret_cast<bf16x8*>(&Vl[r * 40 + c8 * 8]) =
          *reinterpret_cast<const bf16x8*>(
              vT + climp(((size_t)g * HDIM + r) * S_LEN + k0 + c8 * 8, vtSz, 8));
    }
    __syncthreads();
    if (k0 <= wqmax) {
      f32x4 sf[2][2] = {{zf, zf}, {zf, zf}};
#pragma unroll
      for (int ks = 0; ks < 4; ks++)
#pragma unroll
        for (int nf = 0; nf < 2; nf++) {
          int kr = (nf * 16 + l15) * 136 + ks * 32 + l4 * 8;
          bf16x8 bh = *reinterpret_cast<const bf16x8*>(&Kh[kr]);
          bf16x8 bl = *reinterpret_cast<const bf16x8*>(&Kl2[kr]);
#pragma unroll
          for (int mf = 0; mf < 2; mf++)
            sf[mf][nf] = mfma16(qh[mf][ks], bh,
                         mfma16(ql[mf][ks], bh,
                         mfma16(qh[mf][ks], bl, sf[mf][nf])));
        }
      float p[2][2][4];
#pragma unroll
      for (int mf = 0; mf < 2; mf++) {
#pragma unroll
        for (int r = 0; r < 4; r++) {
          int qg = qrow_base + mf * 16 + (l4 << 2) + r;
          float v0 = sf[mf][0][r] * scale;
          float v1 = sf[mf][1][r] * scale;
          if (k0 + l15 > qg) v0 = -1e9f;
          if (k0 + 16 + l15 > qg) v1 = -1e9f;
          float mx = fmaxf(v0, v1);
          mx = fmaxf(mx, __shfl_xor(mx, 1));
          mx = fmaxf(mx, __shfl_xor(mx, 2));
          mx = fmaxf(mx, __shfl_xor(mx, 4));
          mx = fmaxf(mx, __shfl_xor(mx, 8));
          float mnew = fmaxf(mrow[mf][r], mx);
          float alpha = __expf(mrow[mf][r] - mnew);
          float p0 = __expf(v0 - mnew);
          float p1 = __expf(v1 - mnew);
          float rs = p0 + p1;
          rs += __shfl_xor(rs, 1);
          rs += __shfl_xor(rs, 2);
          rs += __shfl_xor(rs, 4);
          rs += __shfl_xor(rs, 8);
          lrow[mf][r] = lrow[mf][r] * alpha + rs;
          mrow[mf][r] = mnew;
#pragma unroll
          for (int nfo = 0; nfo < 8; nfo++) accO[mf][nfo][r] *= alpha;
          p[mf][0][r] = p0;
          p[mf][1][r] = p1;
        }
      }
#pragma unroll
      for (int mf = 0; mf < 2; mf++)
#pragma unroll
        for (int nf = 0; nf < 2; nf++)
#pragma unroll
          for (int r = 0; r < 4; r++)
            Pl[wave][(mf * 16 + (l4 << 2) + r) * 40 + nf * 16 + l15] = f2bf(p[mf][nf][r]);
      bf16x8 pa[2];
      pa[0] = *reinterpret_cast<const bf16x8*>(&Pl[wave][(0 + l15) * 40 + l4 * 8]);
      pa[1] = *reinterpret_cast<const bf16x8*>(&Pl[wave][(16 + l15) * 40 + l4 * 8]);
#pragma unroll
      for (int nfo = 0; nfo < 8; nfo++) {
        bf16x8 bv = *reinterpret_cast<const bf16x8*>(&Vl[(nfo * 16 + l15) * 40 + l4 * 8]);
        accO[0][nfo] = mfma16(pa[0], bv, accO[0][nfo]);
        accO[1][nfo] = mfma16(pa[1], bv, accO[1][nfo]);
      }
    }
    __syncthreads();
  }
#pragma unroll
  for (int mf = 0; mf < 2; mf++) {
    float inv[4];
#pragma unroll
    for (int r = 0; r < 4; r++) inv[r] = 1.0f / lrow[mf][r];
#pragma unroll
    for (int nfo = 0; nfo < 8; nfo++)
#pragma unroll
      for (int r = 0; r < 4; r++) {
        int row = qrow_base + mf * 16 + (l4 << 2) + r;
        int col = h * HDIM + nfo * 16 + l15;
        if (row < S_LEN && col < DMODEL)
          ob[(size_t)row * DMODEL + col] = f2bf(accO[mf][nfo][r] * inv[r]);
      }
  }
  if (l15 == 0) {
#pragma unroll
    for (int mf = 0; mf < 2; mf++)
#pragma unroll
      for (int r = 0; r < 4; r++) {
        int row = qrow_base + mf * 16 + (l4 << 2) + r;
        if (row < S_LEN) {
          mbuf[(size_t)h * S_LEN + row] = mrow[mf][r];
          lbuf[(size_t)h * S_LEN + row] = lrow[mf][r];
        }
      }
  }
}

// ---------------- attn_hh2: column sums from split planes, 3-term chain, f64 col-acc
__global__ __launch_bounds__(256, 2) void attn_hh2(const short* __restrict__ qhp,
                                                   const short* __restrict__ qlp,
                                                   const short* __restrict__ khp,
                                                   const short* __restrict__ klp,
                                                   const float* __restrict__ mbuf,
                                                   const float* __restrict__ lbuf,
                                                   float* __restrict__ hh_h) {
  int h = blockIdx.x, kt = blockIdx.y;
  int g = h >> 2;
  int key0 = kt * 128;
  int tid = threadIdx.x, lane = tid & 63, wave = tid >> 6;
  int l15 = lane & 15, l4 = lane >> 4;
  __shared__ alignas(16) short Qh[32 * 136];
  __shared__ alignas(16) short Ql[32 * 136];
  const size_t qSz = (size_t)S_LEN * DMODEL;
  const size_t kSz = (size_t)S_LEN * KVDIM;
  const size_t mlSz = (size_t)NHQ * S_LEN;
  const float scale = 0.08838834764831845f;
  f32x4 zf = {0.f, 0.f, 0.f, 0.f};

  int keymin = key0 + wave * 32;
  bf16x8 akh[2][4], akl[2][4];
#pragma unroll
  for (int mf = 0; mf < 2; mf++)
#pragma unroll
    for (int ks = 0; ks < 4; ks++) {
      size_t ki = climp((size_t)(keymin + mf * 16 + l15) * KVDIM + g * HDIM + ks * 32 + l4 * 8,
                        kSz, 8);
      akh[mf][ks] = *reinterpret_cast<const bf16x8*>(khp + ki);
      akl[mf][ks] = *reinterpret_cast<const bf16x8*>(klp + ki);
    }

  double acc[2][4];
#pragma unroll
  for (int mf = 0; mf < 2; mf++)
#pragma unroll
    for (int r = 0; r < 4; r++) acc[mf][r] = 0.0;

  for (int q0 = key0; q0 < S_LEN; q0 += 32) {
#pragma unroll
    for (int c = 0; c < 2; c++) {
      int idx = tid + c * 256;
      int r = idx >> 4, c8 = (idx & 15) * 8;
      size_t qi = climp((size_t)(q0 + r) * DMODEL + h * HDIM + c8, qSz, 8);
      *reinterpret_cast<bf16x8*>(&Qh[r * 136 + c8]) =
          *reinterpret_cast<const bf16x8*>(qhp + qi);
      *reinterpret_cast<bf16x8*>(&Ql[r * 136 + c8]) =
          *reinterpret_cast<const bf16x8*>(qlp + qi);
    }
    __syncthreads();
    if (q0 + 31 >= keymin) {
      f32x4 sf[2][2] = {{zf, zf}, {zf, zf}};
#pragma unroll
      for (int ks = 0; ks < 4; ks++)
#pragma unroll
        for (int nf = 0; nf < 2; nf++) {
          int qr = (nf * 16 + l15) * 136 + ks * 32 + l4 * 8;
          bf16x8 bqh = *reinterpret_cast<const bf16x8*>(&Qh[qr]);
          bf16x8 bql = *reinterpret_cast<const bf16x8*>(&Ql[qr]);
#pragma unroll
          for (int mf = 0; mf < 2; mf++)
            sf[mf][nf] = mfma16(akh[mf][ks], bqh,
                         mfma16(akh[mf][ks], bql,
                         mfma16(akl[mf][ks], bqh, sf[mf][nf])));
        }
#pragma unroll
      for (int nf = 0; nf < 2; nf++) {
        int q = q0 + nf * 16 + l15;
        float mq = mbuf[climp((size_t)h * S_LEN + q, mlSz, 1)];
        float rl = 1.0f / lbuf[climp((size_t)h * S_LEN + q, mlSz, 1)];
#pragma unroll
        for (int mf = 0; mf < 2; mf++)
#pragma unroll
          for (int r = 0; r < 4; r++) {
            int key = keymin + mf * 16 + (l4 << 2) + r;
            if (q >= key && q < S_LEN)
              acc[mf][r] += (double)(__expf(sf[mf][nf][r] * scale - mq) * rl);
          }
      }
    }
    __syncthreads();
  }
#pragma unroll
  for (int mf = 0; mf < 2; mf++)
#pragma unroll
    for (int r = 0; r < 4; r++) {
      double v = acc[mf][r];
      v += __shfl_xor(v, 1);
      v += __shfl_xor(v, 2);
      v += __shfl_xor(v, 4);
      v += __shfl_xor(v, 8);
      int key = keymin + mf * 16 + (l4 << 2) + r;
      if (l15 == 0 && key < S_LEN)
        hh_h[(size_t)h * S_LEN + key] = (float)v;
    }
}

// ---------------- top-k + gather (k reconstructed from planes)
__global__ __launch_bounds__(512) void topk_gather(const float* __restrict__ hh_h,
                                                   const short* __restrict__ khp,
                                                   const short* __restrict__ klp,
                                                   const short* __restrict__ vb,
                                                   float* __restrict__ out_k,
                                                   float* __restrict__ out_v,
                                                   float* __restrict__ out_hh) {
  int g = blockIdx.x, t = threadIdx.x;
  __shared__ float hhg[2048];
  __shared__ float sv[2048];
  __shared__ int si[2048];
  __shared__ int st[128];
  __shared__ int keep[NKEEP];
  const size_t hhSz = (size_t)NHQ * S_LEN;
  const size_t kvSz = (size_t)S_LEN * KVDIM;
#pragma unroll
  for (int i = 0; i < 4; i++) {
    int idx = t + i * 512;
    float s = 0.25f * (hh_h[climp((size_t)(4 * g + 0) * 2048 + idx, hhSz, 1)] +
                       hh_h[climp((size_t)(4 * g + 1) * 2048 + idx, hhSz, 1)] +
                       hh_h[climp((size_t)(4 * g + 2) * 2048 + idx, hhSz, 1)] +
                       hh_h[climp((size_t)(4 * g + 3) * 2048 + idx, hhSz, 1)]);
    hhg[idx] = s;
    sv[idx] = (idx < SEL_N) ? s : -1e30f;
    si[idx] = idx;
  }
  __syncthreads();
  for (int k = 2; k <= 2048; k <<= 1) {
    for (int j = k >> 1; j > 0; j >>= 1) {
#pragma unroll
      for (int pass = 0; pass < 4; pass++) {
        int i = t + pass * 512;
        int ixj = i ^ j;
        if (ixj > i) {
          bool up = ((i & k) == 0);
          float a = sv[i], b = sv[ixj];
          int ia = si[i], ib = si[ixj];
          bool before = (a > b) || (a == b && ia < ib);
          bool doswap = up ? !before : before;
          if (doswap) { sv[i] = b; sv[ixj] = a; si[i] = ib; si[ixj] = ia; }
        }
      }
      __syncthreads();
    }
  }
  if (t < 128) st[t] = si[t];
  __syncthreads();
  for (int k = 2; k <= 128; k <<= 1) {
    for (int j = k >> 1; j > 0; j >>= 1) {
      if (t < 128) {
        int i = t, ixj = i ^ j;
        if (ixj > i) {
          bool up = ((i & k) == 0);
          int a = st[i], b = st[ixj];
          bool doswap = up ? (a > b) : (a < b);
          if (doswap) { st[i] = b; st[ixj] = a; }
        }
      }
      __syncthreads();
    }
  }
  // All 640 keep[] entries initialized by all 512 threads (R1-R6 bug fix).
  for (int i = t; i < NKEEP; i += 512)
    keep[i] = (i < 128) ? st[i] : (SEL_N + (i - 128));
  __syncthreads();
  for (int i = 0; i < 160; i++) {
    int idx = t + i * 512;
    int jj = idx >> 7, d = idx & 127;
    int src = (jj < NKEEP) ? keep[jj] : 0;
    if (src < 0) src = 0;
    if (src >= S_LEN) src = S_LEN - 1;
    size_t oi = ((size_t)g * NKEEP + jj) * HDIM + d;
    if (jj < NKEEP) {
      size_t ki = climp((size_t)src * KVDIM + g * HDIM + d, kvSz, 1);
      out_k[oi] = bf2f(khp[ki]) + bf2f(klp[ki]);
      out_v[oi] = bf2f(vb[ki]);
    }
  }
  for (int i = t; i < NKEEP; i += 512) {
    int src = keep[i];
    if (src < 0) src = 0;
    if (src >= 2048) src = 2047;
    out_hh[(size_t)g * NKEEP + i] = hhg[src];
  }
}

extern "C" void kernel_launch(void* const* d_in, const int* in_sizes, int n_in,
                              void* d_out, int out_size, void* d_ws, size_t ws_size,
                              hipStream_t stream) {
  const float* x = (const float*)d_in[0];
  const float* Wq = (const float*)d_in[1];
  const float* Wk = (const float*)d_in[2];
  const float* Wv = (const float*)d_in[3];
  const float* Wo = (const float*)d_in[4];
  const float* cosb = (const float*)d_in[5];
  const float* sinb = (const float*)d_in[6];
  const int* pos = (const int*)d_in[7];

  char* ws = (char*)d_ws;
  size_t off = 0;
  auto alloc = [&](size_t bytes) {
    void* p = ws + off;
    off += (bytes + 255) & ~(size_t)255;
    return p;
  };
  // weight-transpose region, reused across stages (stream-ordered):
  //   stage 1: WqT hi (32MB) + WqT lo (32MB)
  //   stage 2: WkT hi (8MB) | WkT lo (8MB) | WvT (8MB) | WoT (32MB)  = 56MB
  short* Rg = (short*)alloc((size_t)64 * 1024 * 1024);          // 64 MB
  short* qh = (short*)alloc((size_t)S_LEN * DMODEL * 2);        // 16 MB
  short* ql = (short*)alloc((size_t)S_LEN * DMODEL * 2);        // 16 MB
  short* kh = (short*)alloc((size_t)S_LEN * KVDIM * 2);         // 4 MB
  short* kl = (short*)alloc((size_t)S_LEN * KVDIM * 2);         // 4 MB
  short* vbuf = (short*)alloc((size_t)S_LEN * KVDIM * 2);       // 4 MB
  short* vT = (short*)alloc((size_t)NHKV * HDIM * S_LEN * 2);   // 4 MB
  short* obuf = (short*)alloc((size_t)S_LEN * DMODEL * 2);      // 16 MB
  float* mbuf = (float*)alloc((size_t)NHQ * S_LEN * 4);
  float* lbuf = (float*)alloc((size_t)NHQ * S_LEN * 4);
  float* hh_h = (float*)alloc((size_t)NHQ * S_LEN * 4);
  if (off > ws_size) return;  // diagnostic: clean poison-fail if ws too small

  short* WqTh = Rg;
  short* WqTl = Rg + (size_t)16777216;   // +32 MB
  short* WkTh = Rg;
  short* WkTl = Rg + (size_t)4194304;    // +8 MB
  short* WvT  = Rg + (size_t)8388608;    // +16 MB
  short* WoT  = Rg + (size_t)12582912;   // +24 MB

  float* out = (float*)d_out;
  float* out_k = out + (size_t)S_LEN * DMODEL;
  float* out_v = out_k + (size_t)NHKV * NKEEP * HDIM;
  float* out_hh = out_v + (size_t)NHKV * NKEEP * HDIM;

  // x planes live in the `out` chunk of d_out (32 MiB, dead until the final
  // O-projection overwrites it; xh/xl last used by the V projection).
  short* xh = (short*)out;
  short* xl = xh + (size_t)S_LEN * DMODEL;

  // ---- pre-split x (same values as the former inline splits -> bitwise identical)
  split_x<<<(S_LEN * DMODEL / 8) / 256, 256, 0, stream>>>(x, xh, xl);
  // ---- Q projection (hp planes)
  transpose_split<<<dim3(64, 64), 256, 0, stream>>>(Wq, WqTh, WqTl, DMODEL, DMODEL);
  gemm_hp2bt<<<dim3(16, 32), 256, 0, stream>>>(xh, xl, WqTh, WqTl, qh, ql, S_LEN, DMODEL, DMODEL);
  // ---- K projection (hp planes); WkT overwrites WqT region (stream-ordered)
  transpose_split<<<dim3(16, 64), 256, 0, stream>>>(Wk, WkTh, WkTl, DMODEL, KVDIM);
  gemm_hp2bt<<<dim3(16, 8), 256, 0, stream>>>(xh, xl, WkTh, WkTl, kh, kl, S_LEN, KVDIM, DMODEL);
  // ---- V projection (plain bf16; A = xh, identical to inline f2bf(x))
  transpose_cvt<<<dim3(16, 64), 256, 0, stream>>>(Wv, WvT, DMODEL, KVDIM);
  gemm_bt<0, 1><<<dim3(16, 8), 256, 0, stream>>>(xh, WvT, vbuf, S_LEN, KVDIM, DMODEL);
  // ---- Wo transpose (used later by O projection)
  transpose_cvt<<<dim3(64, 64), 256, 0, stream>>>(Wo, WoT, DMODEL, DMODEL);
  // ---- RoPE on planes, V transpose
  rope_planes<32><<<(S_LEN * 32 * 64) / 256, 256, 0, stream>>>(qh, ql, cosb, sinb, pos);
  rope_planes<8><<<(S_LEN * 8 * 64) / 256, 256, 0, stream>>>(kh, kl, cosb, sinb, pos);
  vtrans_k<<<dim3(S_LEN / 8, NHKV), 128, 0, stream>>>(vbuf, vT);
  // ---- fused attention fwd (3-term scores, online softmax, writes m,l), then column sums
  attn_fwd3<<<dim3(NHQ, S_LEN / 128), 256, 0, stream>>>(qh, ql, kh, kl, vT, obuf, mbuf, lbuf);
  attn_hh2<<<dim3(NHQ, S_LEN / 128), 256, 0, stream>>>(qh, ql, kh, kl, mbuf, lbuf, hh_h);
  // ---- output projection (overwrites the xh/xl scratch region with the real `out`)
  gemm_bt<0, 0><<<dim3(16, 32), 256, 0, stream>>>(obuf, WoT, out, S_LEN, DMODEL, DMODEL);
  // ---- H2O top-k + gathers
  topk_gather<<<NHKV, 512, 0, stream>>>(hh_h, kh, kl, vbuf, out_k, out_v, out_hh);
}

// Round 13
// 1048.682 us; speedup vs baseline: 2.4173x; 1.0133x over previous
//
#include <hip/hip_runtime.h>
#include <cstdint>
#include <cstddef>

typedef __attribute__((ext_vector_type(8))) short bf16x8;
typedef __attribute__((ext_vector_type(4))) short short4v;
typedef __attribute__((ext_vector_type(4))) float f32x4;

#define S_LEN 2048
#define DMODEL 4096
#define NHQ 32
#define NHKV 8
#define HDIM 128
#define KVDIM 1024
#define NKEEP 640
#define SEL_N 1536

__device__ __forceinline__ short f2bf(float f) {
  unsigned u = __float_as_uint(f);
  u += 0x7fffu + ((u >> 16) & 1u);
  return (short)(u >> 16);
}
__device__ __forceinline__ float bf2f(short s) {
  return __uint_as_float(((unsigned)(unsigned short)s) << 16);
}
// split-2, round-to-nearest hi plane: h = rne16(x), l = rne16(x - h). err <= 2^-17|x|
__device__ __forceinline__ void split2r(float x, short& h, short& l) {
  short hh = f2bf(x);
  float r = x - bf2f(hh);
  h = hh;
  l = f2bf(r);
}
__device__ __forceinline__ f32x4 mfma16(bf16x8 a, bf16x8 b, f32x4 c) {
  return __builtin_amdgcn_mfma_f32_16x16x32_bf16(a, b, c, 0, 0, 0);
}
__device__ __forceinline__ size_t climp(size_t i, size_t sz, size_t w) {
  size_t hi = sz - w;
  return i <= hi ? i : hi;
}

// ---------------- split_x: x f32 -> hi/lo bf16 planes
__global__ __launch_bounds__(256) void split_x(const float* __restrict__ x,
                                               short* __restrict__ xh,
                                               short* __restrict__ xl) {
  size_t i = ((size_t)blockIdx.x * 256 + threadIdx.x) * 8;
  if (i + 8 > (size_t)S_LEN * DMODEL) return;
  const float* p = x + i;
  float4 v0 = *reinterpret_cast<const float4*>(p);
  float4 v1 = *reinterpret_cast<const float4*>(p + 4);
  float vv[8] = {v0.x, v0.y, v0.z, v0.w, v1.x, v1.y, v1.z, v1.w};
  bf16x8 sh, sl;
#pragma unroll
  for (int t = 0; t < 8; t++) { short a, b; split2r(vv[t], a, b); sh[t] = a; sl[t] = b; }
  *reinterpret_cast<bf16x8*>(xh + i) = sh;
  *reinterpret_cast<bf16x8*>(xl + i) = sl;
}

// ---------------- transpose+convert: W (Kd,N) f32 -> Wt (N,Kd) bf16
__global__ __launch_bounds__(256) void transpose_cvt(const float* __restrict__ W,
                                                     short* __restrict__ Wt,
                                                     int Kd, int N) {
  __shared__ float tile[64][65];
  int tx = threadIdx.x;
  int n0 = blockIdx.x * 64;
  int k0 = blockIdx.y * 64;
#pragma unroll
  for (int i = 0; i < 4; i++) {
    int idx = tx + i * 256;
    int r = idx >> 4, c4 = (idx & 15) * 4;
    float4 v = *reinterpret_cast<const float4*>(W + (size_t)(k0 + r) * N + n0 + c4);
    tile[r][c4 + 0] = v.x;
    tile[r][c4 + 1] = v.y;
    tile[r][c4 + 2] = v.z;
    tile[r][c4 + 3] = v.w;
  }
  __syncthreads();
#pragma unroll
  for (int i = 0; i < 4; i++) {
    int idx = tx + i * 256;
    int rn = idx >> 4, c4 = (idx & 15) * 4;
    short4v o;
#pragma unroll
    for (int j = 0; j < 4; j++) o[j] = f2bf(tile[c4 + j][rn]);
    *reinterpret_cast<short4v*>(Wt + (size_t)(n0 + rn) * Kd + k0 + c4) = o;
  }
}

// ---------------- transpose+split: W (Kd,N) f32 -> hi/lo bf16 planes (N,Kd)
__global__ __launch_bounds__(256) void transpose_split(const float* __restrict__ W,
                                                       short* __restrict__ Wth,
                                                       short* __restrict__ Wtl,
                                                       int Kd, int N) {
  __shared__ float tile[64][65];
  int tx = threadIdx.x;
  int n0 = blockIdx.x * 64;
  int k0 = blockIdx.y * 64;
#pragma unroll
  for (int i = 0; i < 4; i++) {
    int idx = tx + i * 256;
    int r = idx >> 4, c4 = (idx & 15) * 4;
    float4 v = *reinterpret_cast<const float4*>(W + (size_t)(k0 + r) * N + n0 + c4);
    tile[r][c4 + 0] = v.x;
    tile[r][c4 + 1] = v.y;
    tile[r][c4 + 2] = v.z;
    tile[r][c4 + 3] = v.w;
  }
  __syncthreads();
#pragma unroll
  for (int i = 0; i < 4; i++) {
    int idx = tx + i * 256;
    int rn = idx >> 4, c4 = (idx & 15) * 4;
    short4v oh, ol;
#pragma unroll
    for (int j = 0; j < 4; j++) {
      short a, b;
      split2r(tile[c4 + j][rn], a, b);
      oh[j] = a; ol[j] = b;
    }
    size_t wi = (size_t)(n0 + rn) * Kd + k0 + c4;
    *reinterpret_cast<short4v*>(Wth + wi) = oh;
    *reinterpret_cast<short4v*>(Wtl + wi) = ol;
  }
}

// ---------------- gemm_hp2bt: C planes = A planes[M,Kd] * B^T planes[N,Kd]
__global__ __launch_bounds__(256, 3) void gemm_hp2bt(const short* __restrict__ Ath,
                                                     const short* __restrict__ Atl,
                                                     const short* __restrict__ Bth,
                                                     const short* __restrict__ Btl,
                                                     short* __restrict__ Ch,
                                                     short* __restrict__ Cl,
                                                     int M, int N, int Kd) {
  __shared__ alignas(16) short Ah[128 * 40];
  __shared__ alignas(16) short Alo[128 * 40];
  __shared__ alignas(16) short Bh[128 * 40];
  __shared__ alignas(16) short Bl[128 * 40];
  int tid = threadIdx.x;
  int lane = tid & 63, wave = tid >> 6;
  int l15 = lane & 15, l4 = lane >> 4;
  int m0 = blockIdx.x * 128, n0 = blockIdx.y * 128;
  int wm = (wave >> 1) * 64, wn = (wave & 1) * 64;
  f32x4 zf = {0.f, 0.f, 0.f, 0.f};
  f32x4 acc[4][4];
#pragma unroll
  for (int i = 0; i < 4; i++)
#pragma unroll
    for (int j = 0; j < 4; j++) acc[i][j] = zf;

  for (int k0 = 0; k0 < Kd; k0 += 32) {
#pragma unroll
    for (int c = 0; c < 2; c++) {
      int idx = tid + c * 256;
      int r = idx >> 2, c8 = (idx & 3) * 8;
      size_t ai = (size_t)(m0 + r) * Kd + k0 + c8;
      *reinterpret_cast<bf16x8*>(&Ah[r * 40 + c8]) =
          *reinterpret_cast<const bf16x8*>(Ath + ai);
      *reinterpret_cast<bf16x8*>(&Alo[r * 40 + c8]) =
          *reinterpret_cast<const bf16x8*>(Atl + ai);
    }
#pragma unroll
    for (int c = 0; c < 2; c++) {
      int idx = tid + c * 256;
      int r = idx >> 2, c8 = (idx & 3) * 8;
      size_t bi = (size_t)(n0 + r) * Kd + k0 + c8;
      *reinterpret_cast<bf16x8*>(&Bh[r * 40 + c8]) =
          *reinterpret_cast<const bf16x8*>(Bth + bi);
      *reinterpret_cast<bf16x8*>(&Bl[r * 40 + c8]) =
          *reinterpret_cast<const bf16x8*>(Btl + bi);
    }
    __syncthreads();
    bf16x8 ah[4], al[4], bh4[4], bl4[4];
#pragma unroll
    for (int mf = 0; mf < 4; mf++) {
      int ar = (wm + mf * 16 + l15) * 40 + l4 * 8;
      ah[mf] = *reinterpret_cast<const bf16x8*>(&Ah[ar]);
      al[mf] = *reinterpret_cast<const bf16x8*>(&Alo[ar]);
    }
#pragma unroll
    for (int nf = 0; nf < 4; nf++) {
      int br = (wn + nf * 16 + l15) * 40 + l4 * 8;
      bh4[nf] = *reinterpret_cast<const bf16x8*>(&Bh[br]);
      bl4[nf] = *reinterpret_cast<const bf16x8*>(&Bl[br]);
    }
#pragma unroll
    for (int mf = 0; mf < 4; mf++)
#pragma unroll
      for (int nf = 0; nf < 4; nf++)
        acc[mf][nf] = mfma16(ah[mf], bh4[nf],
                      mfma16(al[mf], bh4[nf],
                      mfma16(ah[mf], bl4[nf], acc[mf][nf])));
    __syncthreads();
  }
  int rbase = m0 + wm + (l4 << 2);
  int cbase = n0 + wn + l15;
#pragma unroll
  for (int mf = 0; mf < 4; mf++)
#pragma unroll
    for (int nf = 0; nf < 4; nf++)
#pragma unroll
      for (int r = 0; r < 4; r++) {
        int row = rbase + mf * 16 + r;
        int col = cbase + nf * 16;
        if (row < M && col < N) {
          size_t ci = (size_t)row * N + col;
          short h, l;
          split2r(acc[mf][nf][r], h, l);
          Ch[ci] = h;
          Cl[ci] = l;
        }
      }
}

// ---------------- gemm_bt: plain bf16 GEMM with B^T (N,Kd) bf16 input
template <int A_F32, int STORE_BF16>
__global__ __launch_bounds__(256, 3) void gemm_bt(const void* __restrict__ Av,
                                                  const short* __restrict__ Bt,
                                                  void* __restrict__ Cv,
                                                  int M, int N, int Kd) {
  __shared__ alignas(16) short Al[128 * 72];
  __shared__ alignas(16) short Bl[128 * 72];
  int tid = threadIdx.x;
  int lane = tid & 63, wave = tid >> 6;
  int l15 = lane & 15, l4 = lane >> 4;
  int m0 = blockIdx.x * 128, n0 = blockIdx.y * 128;
  int wm = (wave >> 1) * 64, wn = (wave & 1) * 64;
  f32x4 zf = {0.f, 0.f, 0.f, 0.f};
  f32x4 acc[4][4];
#pragma unroll
  for (int i = 0; i < 4; i++)
#pragma unroll
    for (int j = 0; j < 4; j++) acc[i][j] = zf;

  for (int k0 = 0; k0 < Kd; k0 += 64) {
#pragma unroll
    for (int c = 0; c < 4; c++) {
      int idx = tid + c * 256;
      int r = idx >> 3, k8 = (idx & 7) * 8;
      bf16x8 a;
      if constexpr (A_F32 != 0) {
        const float* Ap = (const float*)Av + (size_t)(m0 + r) * Kd + k0 + k8;
        float4 v0 = *reinterpret_cast<const float4*>(Ap);
        float4 v1 = *reinterpret_cast<const float4*>(Ap + 4);
        a[0] = f2bf(v0.x); a[1] = f2bf(v0.y); a[2] = f2bf(v0.z); a[3] = f2bf(v0.w);
        a[4] = f2bf(v1.x); a[5] = f2bf(v1.y); a[6] = f2bf(v1.z); a[7] = f2bf(v1.w);
      } else {
        a = *reinterpret_cast<const bf16x8*>((const short*)Av + (size_t)(m0 + r) * Kd + k0 + k8);
      }
      *reinterpret_cast<bf16x8*>(&Al[r * 72 + k8]) = a;
      *reinterpret_cast<bf16x8*>(&Bl[r * 72 + k8]) =
          *reinterpret_cast<const bf16x8*>(Bt + (size_t)(n0 + r) * Kd + k0 + k8);
    }
    __syncthreads();
    bf16x8 af[4][2], bfr[4][2];
#pragma unroll
    for (int mf = 0; mf < 4; mf++)
#pragma unroll
      for (int ks = 0; ks < 2; ks++)
        af[mf][ks] = *reinterpret_cast<const bf16x8*>(
            &Al[(wm + mf * 16 + l15) * 72 + ks * 32 + l4 * 8]);
#pragma unroll
    for (int nf = 0; nf < 4; nf++)
#pragma unroll
      for (int ks = 0; ks < 2; ks++)
        bfr[nf][ks] = *reinterpret_cast<const bf16x8*>(
            &Bl[(wn + nf * 16 + l15) * 72 + ks * 32 + l4 * 8]);
#pragma unroll
    for (int ks = 0; ks < 2; ks++)
#pragma unroll
      for (int mf = 0; mf < 4; mf++)
#pragma unroll
        for (int nf = 0; nf < 4; nf++)
          acc[mf][nf] = mfma16(af[mf][ks], bfr[nf][ks], acc[mf][nf]);
    __syncthreads();
  }
  int rbase = m0 + wm + (l4 << 2);
  int cbase = n0 + wn + l15;
#pragma unroll
  for (int mf = 0; mf < 4; mf++)
#pragma unroll
    for (int nf = 0; nf < 4; nf++)
#pragma unroll
      for (int r = 0; r < 4; r++) {
        int row = rbase + mf * 16 + r;
        int col = cbase + nf * 16;
        if (row < M && col < N) {
          size_t ci = (size_t)row * N + col;
          float v = acc[mf][nf][r];
          if constexpr (STORE_BF16 != 0)
            ((short*)Cv)[ci] = f2bf(v);
          else
            ((float*)Cv)[ci] = v;
        }
      }
}

// ---------------- RoPE in-place on split planes (s, NH*128)
template <int NH>
__global__ __launch_bounds__(256) void rope_planes(short* __restrict__ bh,
                                                   short* __restrict__ bl,
                                                   const float* __restrict__ cosb,
                                                   const float* __restrict__ sinb,
                                                   const int* __restrict__ pos) {
  int idx = blockIdx.x * 256 + threadIdx.x;
  if (idx >= S_LEN * NH * 64) return;
  int d = idx & 63;
  int h = (idx >> 6) % NH;
  int s = idx / (64 * NH);
  int p = pos[s];
  if (p < 0) p = 0;
  if (p >= S_LEN) p = S_LEN - 1;
  size_t base = ((size_t)s * NH + h) * 128 + d;
  float lo = bf2f(bh[base]) + bf2f(bl[base]);
  float hi = bf2f(bh[base + 64]) + bf2f(bl[base + 64]);
  float c0 = cosb[p * 128 + d], s0 = sinb[p * 128 + d];
  float c1 = cosb[p * 128 + d + 64], s1 = sinb[p * 128 + d + 64];
  float o0 = lo * c0 - hi * s0;
  float o1 = hi * c1 + lo * s1;
  short a, b;
  split2r(o0, a, b);
  bh[base] = a; bl[base] = b;
  split2r(o1, a, b);
  bh[base + 64] = a; bl[base + 64] = b;
}

// ---------------- V transpose: (s, g, d) -> (g, d, s) bf16
__global__ __launch_bounds__(128) void vtrans_k(const short* __restrict__ v,
                                                short* __restrict__ vT) {
  int g = blockIdx.y;
  int s0 = blockIdx.x * 8;
  int d = threadIdx.x;
  if (s0 + 7 >= S_LEN || g >= NHKV || d >= HDIM) return;
  const size_t vSz = (size_t)S_LEN * KVDIM;
  bf16x8 vals;
#pragma unroll
  for (int i = 0; i < 8; i++)
    vals[i] = v[climp((size_t)(s0 + i) * KVDIM + g * HDIM + d, vSz, 1)];
  *reinterpret_cast<bf16x8*>(vT + climp(((size_t)g * HDIM + d) * S_LEN + s0,
                                        (size_t)NHKV * HDIM * S_LEN, 8)) = vals;
}

// ---------------- attn_fwd3: FUSED — 3-term hp scores, online softmax, bf16 P, PV.
// blockIdx.y remapped so co-resident CU pairs (z, z+8) -> q-tiles (z, 15-z),
// equalizing per-CU causal work at 68 K-tile iterations (was 40..96).
__global__ __launch_bounds__(256, 2) void attn_fwd3(const short* __restrict__ qhp,
                                                    const short* __restrict__ qlp,
                                                    const short* __restrict__ khp,
                                                    const short* __restrict__ klp,
                                                    const short* __restrict__ vT,
                                                    short* __restrict__ ob,
                                                    float* __restrict__ mbuf,
                                                    float* __restrict__ lbuf) {
  int h = blockIdx.x;
  int z = blockIdx.y;
  int qt = (z < 8) ? z : (23 - z);   // pairs (z, z+8) -> (qt, 15-qt): constant work
  int g = h >> 2;
  int q0 = qt * 128;
  int tid = threadIdx.x, lane = tid & 63, wave = tid >> 6;
  int l15 = lane & 15, l4 = lane >> 4;
  __shared__ alignas(16) short Kh[32 * 136];
  __shared__ alignas(16) short Kl2[32 * 136];
  __shared__ alignas(16) short Vl[128 * 40];
  __shared__ alignas(16) short Pl[4][32 * 40];
  const size_t qSz = (size_t)S_LEN * DMODEL;
  const size_t kSz = (size_t)S_LEN * KVDIM;
  const size_t vtSz = (size_t)NHKV * HDIM * S_LEN;

  int qrow_base = q0 + wave * 32;
  bf16x8 qh[2][4], ql[2][4];
#pragma unroll
  for (int mf = 0; mf < 2; mf++)
#pragma unroll
    for (int ks = 0; ks < 4; ks++) {
      size_t qi = climp((size_t)(qrow_base + mf * 16 + l15) * DMODEL + h * HDIM + ks * 32 + l4 * 8,
                        qSz, 8);
      qh[mf][ks] = *reinterpret_cast<const bf16x8*>(qhp + qi);
      ql[mf][ks] = *reinterpret_cast<const bf16x8*>(qlp + qi);
    }

  f32x4 zf = {0.f, 0.f, 0.f, 0.f};
  f32x4 accO[2][8];
  float mrow[2][4], lrow[2][4];
#pragma unroll
  for (int mf = 0; mf < 2; mf++) {
#pragma unroll
    for (int nfo = 0; nfo < 8; nfo++) accO[mf][nfo] = zf;
#pragma unroll
    for (int r = 0; r < 4; r++) { mrow[mf][r] = -1e30f; lrow[mf][r] = 0.f; }
  }
  int wqmax = qrow_base + 31;
  int nkt = qt * 4 + 4;
  const float scale = 0.08838834764831845f;

  for (int kt = 0; kt < nkt; kt++) {
    int k0 = kt * 32;
#pragma unroll
    for (int c = 0; c < 2; c++) {
      int idx = tid + c * 256;
      int r = idx >> 4, c8 = (idx & 15) * 8;
      size_t ki = climp((size_t)(k0 + r) * KVDIM + g * HDIM + c8, kSz, 8);
      *reinterpret_cast<bf16x8*>(&Kh[r * 136 + c8]) =
          *reinterpret_cast<const bf16x8*>(khp + ki);
      *reinterpret_cast<bf16x8*>(&Kl2[r * 136 + c8]) =
          *reinterpret_cast<const bf16x8*>(klp + ki);
    }
#pragma unroll
    for (int c = 0; c < 2; c++) {
      int idx = tid + c * 256;
      int r = idx >> 2, c8 = idx & 3;
      *reinterpret_cast<bf16x8*>(&Vl[r * 40 + c8 * 8]) =
          *reinterpret_cast<const bf16x8*>(
              vT + climp(((size_t)g * HDIM + r) * S_LEN + k0 + c8 * 8, vtSz, 8));
    }
    __syncthreads();
    if (k0 <= wqmax) {
      f32x4 sf[2][2] = {{zf, zf}, {zf, zf}};
#pragma unroll
      for (int ks = 0; ks < 4; ks++)
#pragma unroll
        for (int nf = 0; nf < 2; nf++) {
          int kr = (nf * 16 + l15) * 136 + ks * 32 + l4 * 8;
          bf16x8 bh = *reinterpret_cast<const bf16x8*>(&Kh[kr]);
          bf16x8 bl = *reinterpret_cast<const bf16x8*>(&Kl2[kr]);
#pragma unroll
          for (int mf = 0; mf < 2; mf++)
            sf[mf][nf] = mfma16(qh[mf][ks], bh,
                         mfma16(ql[mf][ks], bh,
                         mfma16(qh[mf][ks], bl, sf[mf][nf])));
        }
      float p[2][2][4];
#pragma unroll
      for (int mf = 0; mf < 2; mf++) {
#pragma unroll
        for (int r = 0; r < 4; r++) {
          int qg = qrow_base + mf * 16 + (l4 << 2) + r;
          float v0 = sf[mf][0][r] * scale;
          float v1 = sf[mf][1][r] * scale;
          if (k0 + l15 > qg) v0 = -1e9f;
          if (k0 + 16 + l15 > qg) v1 = -1e9f;
          float mx = fmaxf(v0, v1);
          mx = fmaxf(mx, __shfl_xor(mx, 1));
          mx = fmaxf(mx, __shfl_xor(mx, 2));
          mx = fmaxf(mx, __shfl_xor(mx, 4));
          mx = fmaxf(mx, __shfl_xor(mx, 8));
          float mnew = fmaxf(mrow[mf][r], mx);
          float alpha = __expf(mrow[mf][r] - mnew);
          float p0 = __expf(v0 - mnew);
          float p1 = __expf(v1 - mnew);
          float rs = p0 + p1;
          rs += __shfl_xor(rs, 1);
          rs += __shfl_xor(rs, 2);
          rs += __shfl_xor(rs, 4);
          rs += __shfl_xor(rs, 8);
          lrow[mf][r] = lrow[mf][r] * alpha + rs;
          mrow[mf][r] = mnew;
#pragma unroll
          for (int nfo = 0; nfo < 8; nfo++) accO[mf][nfo][r] *= alpha;
          p[mf][0][r] = p0;
          p[mf][1][r] = p1;
        }
      }
#pragma unroll
      for (int mf = 0; mf < 2; mf++)
#pragma unroll
        for (int nf = 0; nf < 2; nf++)
#pragma unroll
          for (int r = 0; r < 4; r++)
            Pl[wave][(mf * 16 + (l4 << 2) + r) * 40 + nf * 16 + l15] = f2bf(p[mf][nf][r]);
      bf16x8 pa[2];
      pa[0] = *reinterpret_cast<const bf16x8*>(&Pl[wave][(0 + l15) * 40 + l4 * 8]);
      pa[1] = *reinterpret_cast<const bf16x8*>(&Pl[wave][(16 + l15) * 40 + l4 * 8]);
#pragma unroll
      for (int nfo = 0; nfo < 8; nfo++) {
        bf16x8 bv = *reinterpret_cast<const bf16x8*>(&Vl[(nfo * 16 + l15) * 40 + l4 * 8]);
        accO[0][nfo] = mfma16(pa[0], bv, accO[0][nfo]);
        accO[1][nfo] = mfma16(pa[1], bv, accO[1][nfo]);
      }
    }
    __syncthreads();
  }
#pragma unroll
  for (int mf = 0; mf < 2; mf++) {
    float inv[4];
#pragma unroll
    for (int r = 0; r < 4; r++) inv[r] = 1.0f / lrow[mf][r];
#pragma unroll
    for (int nfo = 0; nfo < 8; nfo++)
#pragma unroll
      for (int r = 0; r < 4; r++) {
        int row = qrow_base + mf * 16 + (l4 << 2) + r;
        int col = h * HDIM + nfo * 16 + l15;
        if (row < S_LEN && col < DMODEL)
          ob[(size_t)row * DMODEL + col] = f2bf(accO[mf][nfo][r] * inv[r]);
      }
  }
  if (l15 == 0) {
#pragma unroll
    for (int mf = 0; mf < 2; mf++)
#pragma unroll
      for (int r = 0; r < 4; r++) {
        int row = qrow_base + mf * 16 + (l4 << 2) + r;
        if (row < S_LEN) {
          mbuf[(size_t)h * S_LEN + row] = mrow[mf][r];
          lbuf[(size_t)h * S_LEN + row] = lrow[mf][r];
        }
      }
  }
}

// ---------------- attn_hh2: column sums, 3-term chain, f64 col-acc.
// Same complementary-pair remap: work(kt) = 64-4kt, pairs (z, 15-z) -> 68 const.
__global__ __launch_bounds__(256, 2) void attn_hh2(const short* __restrict__ qhp,
                                                   const short* __restrict__ qlp,
                                                   const short* __restrict__ khp,
                                                   const short* __restrict__ klp,
                                                   const float* __restrict__ mbuf,
                                                   const float* __restrict__ lbuf,
                                                   float* __restrict__ hh_h) {
  int h = blockIdx.x;
  int z = blockIdx.y;
  int kt = (z < 8) ? z : (23 - z);
  int g = h >> 2;
  int key0 = kt * 128;
  int tid = threadIdx.x, lane = tid & 63, wave = tid >> 6;
  int l15 = lane & 15, l4 = lane >> 4;
  __shared__ alignas(16) short Qh[32 * 136];
  __shared__ alignas(16) short Ql[32 * 136];
  const size_t qSz = (size_t)S_LEN * DMODEL;
  const size_t kSz = (size_t)S_LEN * KVDIM;
  const size_t mlSz = (size_t)NHQ * S_LEN;
  const float scale = 0.08838834764831845f;
  f32x4 zf = {0.f, 0.f, 0.f, 0.f};

  int keymin = key0 + wave * 32;
  bf16x8 akh[2][4], akl[2][4];
#pragma unroll
  for (int mf = 0; mf < 2; mf++)
#pragma unroll
    for (int ks = 0; ks < 4; ks++) {
      size_t ki = climp((size_t)(keymin + mf * 16 + l15) * KVDIM + g * HDIM + ks * 32 + l4 * 8,
                        kSz, 8);
      akh[mf][ks] = *reinterpret_cast<const bf16x8*>(khp + ki);
      akl[mf][ks] = *reinterpret_cast<const bf16x8*>(klp + ki);
    }

  double acc[2][4];
#pragma unroll
  for (int mf = 0; mf < 2; mf++)
#pragma unroll
    for (int r = 0; r < 4; r++) acc[mf][r] = 0.0;

  for (int q0 = key0; q0 < S_LEN; q0 += 32) {
#pragma unroll
    for (int c = 0; c < 2; c++) {
      int idx = tid + c * 256;
      int r = idx >> 4, c8 = (idx & 15) * 8;
      size_t qi = climp((size_t)(q0 + r) * DMODEL + h * HDIM + c8, qSz, 8);
      *reinterpret_cast<bf16x8*>(&Qh[r * 136 + c8]) =
          *reinterpret_cast<const bf16x8*>(qhp + qi);
      *reinterpret_cast<bf16x8*>(&Ql[r * 136 + c8]) =
          *reinterpret_cast<const bf16x8*>(qlp + qi);
    }
    __syncthreads();
    if (q0 + 31 >= keymin) {
      f32x4 sf[2][2] = {{zf, zf}, {zf, zf}};
#pragma unroll
      for (int ks = 0; ks < 4; ks++)
#pragma unroll
        for (int nf = 0; nf < 2; nf++) {
          int qr = (nf * 16 + l15) * 136 + ks * 32 + l4 * 8;
          bf16x8 bqh = *reinterpret_cast<const bf16x8*>(&Qh[qr]);
          bf16x8 bql = *reinterpret_cast<const bf16x8*>(&Ql[qr]);
#pragma unroll
          for (int mf = 0; mf < 2; mf++)
            sf[mf][nf] = mfma16(akh[mf][ks], bqh,
                         mfma16(akh[mf][ks], bql,
                         mfma16(akl[mf][ks], bqh, sf[mf][nf])));
        }
#pragma unroll
      for (int nf = 0; nf < 2; nf++) {
        int q = q0 + nf * 16 + l15;
        float mq = mbuf[climp((size_t)h * S_LEN + q, mlSz, 1)];
        float rl = 1.0f / lbuf[climp((size_t)h * S_LEN + q, mlSz, 1)];
#pragma unroll
        for (int mf = 0; mf < 2; mf++)
#pragma unroll
          for (int r = 0; r < 4; r++) {
            int key = keymin + mf * 16 + (l4 << 2) + r;
            if (q >= key && q < S_LEN)
              acc[mf][r] += (double)(__expf(sf[mf][nf][r] * scale - mq) * rl);
          }
      }
    }
    __syncthreads();
  }
#pragma unroll
  for (int mf = 0; mf < 2; mf++)
#pragma unroll
    for (int r = 0; r < 4; r++) {
      double v = acc[mf][r];
      v += __shfl_xor(v, 1);
      v += __shfl_xor(v, 2);
      v += __shfl_xor(v, 4);
      v += __shfl_xor(v, 8);
      int key = keymin + mf * 16 + (l4 << 2) + r;
      if (l15 == 0 && key < S_LEN)
        hh_h[(size_t)h * S_LEN + key] = (float)v;
    }
}

// ---------------- top-k + gather (k reconstructed from planes)
__global__ __launch_bounds__(512) void topk_gather(const float* __restrict__ hh_h,
                                                   const short* __restrict__ khp,
                                                   const short* __restrict__ klp,
                                                   const short* __restrict__ vb,
                                                   float* __restrict__ out_k,
                                                   float* __restrict__ out_v,
                                                   float* __restrict__ out_hh) {
  int g = blockIdx.x, t = threadIdx.x;
  __shared__ float hhg[2048];
  __shared__ float sv[2048];
  __shared__ int si[2048];
  __shared__ int st[128];
  __shared__ int keep[NKEEP];
  const size_t hhSz = (size_t)NHQ * S_LEN;
  const size_t kvSz = (size_t)S_LEN * KVDIM;
#pragma unroll
  for (int i = 0; i < 4; i++) {
    int idx = t + i * 512;
    float s = 0.25f * (hh_h[climp((size_t)(4 * g + 0) * 2048 + idx, hhSz, 1)] +
                       hh_h[climp((size_t)(4 * g + 1) * 2048 + idx, hhSz, 1)] +
                       hh_h[climp((size_t)(4 * g + 2) * 2048 + idx, hhSz, 1)] +
                       hh_h[climp((size_t)(4 * g + 3) * 2048 + idx, hhSz, 1)]);
    hhg[idx] = s;
    sv[idx] = (idx < SEL_N) ? s : -1e30f;
    si[idx] = idx;
  }
  __syncthreads();
  for (int k = 2; k <= 2048; k <<= 1) {
    for (int j = k >> 1; j > 0; j >>= 1) {
#pragma unroll
      for (int pass = 0; pass < 4; pass++) {
        int i = t + pass * 512;
        int ixj = i ^ j;
        if (ixj > i) {
          bool up = ((i & k) == 0);
          float a = sv[i], b = sv[ixj];
          int ia = si[i], ib = si[ixj];
          bool before = (a > b) || (a == b && ia < ib);
          bool doswap = up ? !before : before;
          if (doswap) { sv[i] = b; sv[ixj] = a; si[i] = ib; si[ixj] = ia; }
        }
      }
      __syncthreads();
    }
  }
  if (t < 128) st[t] = si[t];
  __syncthreads();
  for (int k = 2; k <= 128; k <<= 1) {
    for (int j = k >> 1; j > 0; j >>= 1) {
      if (t < 128) {
        int i = t, ixj = i ^ j;
        if (ixj > i) {
          bool up = ((i & k) == 0);
          int a = st[i], b = st[ixj];
          bool doswap = up ? (a > b) : (a < b);
          if (doswap) { st[i] = b; st[ixj] = a; }
        }
      }
      __syncthreads();
    }
  }
  // All 640 keep[] entries initialized by all 512 threads (R1-R6 bug fix).
  for (int i = t; i < NKEEP; i += 512)
    keep[i] = (i < 128) ? st[i] : (SEL_N + (i - 128));
  __syncthreads();
  for (int i = 0; i < 160; i++) {
    int idx = t + i * 512;
    int jj = idx >> 7, d = idx & 127;
    int src = (jj < NKEEP) ? keep[jj] : 0;
    if (src < 0) src = 0;
    if (src >= S_LEN) src = S_LEN - 1;
    size_t oi = ((size_t)g * NKEEP + jj) * HDIM + d;
    if (jj < NKEEP) {
      size_t ki = climp((size_t)src * KVDIM + g * HDIM + d, kvSz, 1);
      out_k[oi] = bf2f(khp[ki]) + bf2f(klp[ki]);
      out_v[oi] = bf2f(vb[ki]);
    }
  }
  for (int i = t; i < NKEEP; i += 512) {
    int src = keep[i];
    if (src < 0) src = 0;
    if (src >= 2048) src = 2047;
    out_hh[(size_t)g * NKEEP + i] = hhg[src];
  }
}

extern "C" void kernel_launch(void* const* d_in, const int* in_sizes, int n_in,
                              void* d_out, int out_size, void* d_ws, size_t ws_size,
                              hipStream_t stream) {
  const float* x = (const float*)d_in[0];
  const float* Wq = (const float*)d_in[1];
  const float* Wk = (const float*)d_in[2];
  const float* Wv = (const float*)d_in[3];
  const float* Wo = (const float*)d_in[4];
  const float* cosb = (const float*)d_in[5];
  const float* sinb = (const float*)d_in[6];
  const int* pos = (const int*)d_in[7];

  char* ws = (char*)d_ws;
  size_t off = 0;
  auto alloc = [&](size_t bytes) {
    void* p = ws + off;
    off += (bytes + 255) & ~(size_t)255;
    return p;
  };
  short* Rg = (short*)alloc((size_t)64 * 1024 * 1024);          // 64 MB
  short* qh = (short*)alloc((size_t)S_LEN * DMODEL * 2);        // 16 MB
  short* ql = (short*)alloc((size_t)S_LEN * DMODEL * 2);        // 16 MB
  short* kh = (short*)alloc((size_t)S_LEN * KVDIM * 2);         // 4 MB
  short* kl = (short*)alloc((size_t)S_LEN * KVDIM * 2);         // 4 MB
  short* vbuf = (short*)alloc((size_t)S_LEN * KVDIM * 2);       // 4 MB
  short* vT = (short*)alloc((size_t)NHKV * HDIM * S_LEN * 2);   // 4 MB
  short* obuf = (short*)alloc((size_t)S_LEN * DMODEL * 2);      // 16 MB
  float* mbuf = (float*)alloc((size_t)NHQ * S_LEN * 4);
  float* lbuf = (float*)alloc((size_t)NHQ * S_LEN * 4);
  float* hh_h = (float*)alloc((size_t)NHQ * S_LEN * 4);
  if (off > ws_size) return;

  short* WqTh = Rg;
  short* WqTl = Rg + (size_t)16777216;   // +32 MB
  short* WkTh = Rg;
  short* WkTl = Rg + (size_t)4194304;    // +8 MB
  short* WvT  = Rg + (size_t)8388608;    // +16 MB
  short* WoT  = Rg + (size_t)12582912;   // +24 MB

  float* out = (float*)d_out;
  float* out_k = out + (size_t)S_LEN * DMODEL;
  float* out_v = out_k + (size_t)NHKV * NKEEP * HDIM;
  float* out_hh = out_v + (size_t)NHKV * NKEEP * HDIM;

  // x planes live in the `out` chunk of d_out (dead until O-projection writes it)
  short* xh = (short*)out;
  short* xl = xh + (size_t)S_LEN * DMODEL;

  split_x<<<(S_LEN * DMODEL / 8) / 256, 256, 0, stream>>>(x, xh, xl);
  transpose_split<<<dim3(64, 64), 256, 0, stream>>>(Wq, WqTh, WqTl, DMODEL, DMODEL);
  gemm_hp2bt<<<dim3(16, 32), 256, 0, stream>>>(xh, xl, WqTh, WqTl, qh, ql, S_LEN, DMODEL, DMODEL);
  transpose_split<<<dim3(16, 64), 256, 0, stream>>>(Wk, WkTh, WkTl, DMODEL, KVDIM);
  gemm_hp2bt<<<dim3(16, 8), 256, 0, stream>>>(xh, xl, WkTh, WkTl, kh, kl, S_LEN, KVDIM, DMODEL);
  transpose_cvt<<<dim3(16, 64), 256, 0, stream>>>(Wv, WvT, DMODEL, KVDIM);
  gemm_bt<0, 1><<<dim3(16, 8), 256, 0, stream>>>(xh, WvT, vbuf, S_LEN, KVDIM, DMODEL);
  transpose_cvt<<<dim3(64, 64), 256, 0, stream>>>(Wo, WoT, DMODEL, DMODEL);
  rope_planes<32><<<(S_LEN * 32 * 64) / 256, 256, 0, stream>>>(qh, ql, cosb, sinb, pos);
  rope_planes<8><<<(S_LEN * 8 * 64) / 256, 256, 0, stream>>>(kh, kl, cosb, sinb, pos);
  vtrans_k<<<dim3(S_LEN / 8, NHKV), 128, 0, stream>>>(vbuf, vT);
  attn_fwd3<<<dim3(NHQ, S_LEN / 128), 256, 0, stream>>>(qh, ql, kh, kl, vT, obuf, mbuf, lbuf);
  attn_hh2<<<dim3(NHQ, S_LEN / 128), 256, 0, stream>>>(qh, ql, kh, kl, mbuf, lbuf, hh_h);
  gemm_bt<0, 0><<<dim3(16, 32), 256, 0, stream>>>(obuf, WoT, out, S_LEN, DMODEL, DMODEL);
  topk_gather<<<NHKV, 512, 0, stream>>>(hh_h, kh, kl, vbuf, out_k, out_v, out_hh);
}

// Round 14
// 1045.763 us; speedup vs baseline: 2.4240x; 1.0028x over previous
//
#include <hip/hip_runtime.h>
#include <cstdint>
#include <cstddef>

typedef __attribute__((ext_vector_type(8))) short bf16x8;
typedef __attribute__((ext_vector_type(4))) short short4v;
typedef __attribute__((ext_vector_type(4))) float f32x4;

#define S_LEN 2048
#define DMODEL 4096
#define NHQ 32
#define NHKV 8
#define HDIM 128
#define KVDIM 1024
#define NKEEP 640
#define SEL_N 1536

__device__ __forceinline__ short f2bf(float f) {
  unsigned u = __float_as_uint(f);
  u += 0x7fffu + ((u >> 16) & 1u);
  return (short)(u >> 16);
}
__device__ __forceinline__ float bf2f(short s) {
  return __uint_as_float(((unsigned)(unsigned short)s) << 16);
}
// split-2, round-to-nearest hi plane: h = rne16(x), l = rne16(x - h). err <= 2^-17|x|
__device__ __forceinline__ void split2r(float x, short& h, short& l) {
  short hh = f2bf(x);
  float r = x - bf2f(hh);
  h = hh;
  l = f2bf(r);
}
__device__ __forceinline__ f32x4 mfma16(bf16x8 a, bf16x8 b, f32x4 c) {
  return __builtin_amdgcn_mfma_f32_16x16x32_bf16(a, b, c, 0, 0, 0);
}
__device__ __forceinline__ size_t climp(size_t i, size_t sz, size_t w) {
  size_t hi = sz - w;
  return i <= hi ? i : hi;
}

// ---------------- split_x: x f32 -> hi/lo bf16 planes
__global__ __launch_bounds__(256) void split_x(const float* __restrict__ x,
                                               short* __restrict__ xh,
                                               short* __restrict__ xl) {
  size_t i = ((size_t)blockIdx.x * 256 + threadIdx.x) * 8;
  if (i + 8 > (size_t)S_LEN * DMODEL) return;
  const float* p = x + i;
  float4 v0 = *reinterpret_cast<const float4*>(p);
  float4 v1 = *reinterpret_cast<const float4*>(p + 4);
  float vv[8] = {v0.x, v0.y, v0.z, v0.w, v1.x, v1.y, v1.z, v1.w};
  bf16x8 sh, sl;
#pragma unroll
  for (int t = 0; t < 8; t++) { short a, b; split2r(vv[t], a, b); sh[t] = a; sl[t] = b; }
  *reinterpret_cast<bf16x8*>(xh + i) = sh;
  *reinterpret_cast<bf16x8*>(xl + i) = sl;
}

// ---------------- transpose+convert: W (Kd,N) f32 -> Wt (N,Kd) bf16
__global__ __launch_bounds__(256) void transpose_cvt(const float* __restrict__ W,
                                                     short* __restrict__ Wt,
                                                     int Kd, int N) {
  __shared__ float tile[64][65];
  int tx = threadIdx.x;
  int n0 = blockIdx.x * 64;
  int k0 = blockIdx.y * 64;
#pragma unroll
  for (int i = 0; i < 4; i++) {
    int idx = tx + i * 256;
    int r = idx >> 4, c4 = (idx & 15) * 4;
    float4 v = *reinterpret_cast<const float4*>(W + (size_t)(k0 + r) * N + n0 + c4);
    tile[r][c4 + 0] = v.x;
    tile[r][c4 + 1] = v.y;
    tile[r][c4 + 2] = v.z;
    tile[r][c4 + 3] = v.w;
  }
  __syncthreads();
#pragma unroll
  for (int i = 0; i < 4; i++) {
    int idx = tx + i * 256;
    int rn = idx >> 4, c4 = (idx & 15) * 4;
    short4v o;
#pragma unroll
    for (int j = 0; j < 4; j++) o[j] = f2bf(tile[c4 + j][rn]);
    *reinterpret_cast<short4v*>(Wt + (size_t)(n0 + rn) * Kd + k0 + c4) = o;
  }
}

// ---------------- transpose+split: W (Kd,N) f32 -> hi/lo bf16 planes (N,Kd)
__global__ __launch_bounds__(256) void transpose_split(const float* __restrict__ W,
                                                       short* __restrict__ Wth,
                                                       short* __restrict__ Wtl,
                                                       int Kd, int N) {
  __shared__ float tile[64][65];
  int tx = threadIdx.x;
  int n0 = blockIdx.x * 64;
  int k0 = blockIdx.y * 64;
#pragma unroll
  for (int i = 0; i < 4; i++) {
    int idx = tx + i * 256;
    int r = idx >> 4, c4 = (idx & 15) * 4;
    float4 v = *reinterpret_cast<const float4*>(W + (size_t)(k0 + r) * N + n0 + c4);
    tile[r][c4 + 0] = v.x;
    tile[r][c4 + 1] = v.y;
    tile[r][c4 + 2] = v.z;
    tile[r][c4 + 3] = v.w;
  }
  __syncthreads();
#pragma unroll
  for (int i = 0; i < 4; i++) {
    int idx = tx + i * 256;
    int rn = idx >> 4, c4 = (idx & 15) * 4;
    short4v oh, ol;
#pragma unroll
    for (int j = 0; j < 4; j++) {
      short a, b;
      split2r(tile[c4 + j][rn], a, b);
      oh[j] = a; ol[j] = b;
    }
    size_t wi = (size_t)(n0 + rn) * Kd + k0 + c4;
    *reinterpret_cast<short4v*>(Wth + wi) = oh;
    *reinterpret_cast<short4v*>(Wtl + wi) = ol;
  }
}

// ---------------- gemm_hp2bt: C planes = A planes[M,Kd] * B^T planes[N,Kd]
// 64x128 tile (grid doubled -> 4 blocks/CU), acc[2][4]. Numerics = R13 (bitwise).
__global__ __launch_bounds__(256, 4) void gemm_hp2bt(const short* __restrict__ Ath,
                                                     const short* __restrict__ Atl,
                                                     const short* __restrict__ Bth,
                                                     const short* __restrict__ Btl,
                                                     short* __restrict__ Ch,
                                                     short* __restrict__ Cl,
                                                     int M, int N, int Kd) {
  __shared__ alignas(16) short Ah[64 * 40];
  __shared__ alignas(16) short Alo[64 * 40];
  __shared__ alignas(16) short Bh[128 * 40];
  __shared__ alignas(16) short Bl[128 * 40];
  int tid = threadIdx.x;
  int lane = tid & 63, wave = tid >> 6;
  int l15 = lane & 15, l4 = lane >> 4;
  int m0 = blockIdx.x * 64, n0 = blockIdx.y * 128;
  int wm = (wave >> 1) * 32, wn = (wave & 1) * 64;
  f32x4 zf = {0.f, 0.f, 0.f, 0.f};
  f32x4 acc[2][4];
#pragma unroll
  for (int i = 0; i < 2; i++)
#pragma unroll
    for (int j = 0; j < 4; j++) acc[i][j] = zf;

  for (int k0 = 0; k0 < Kd; k0 += 32) {
    // A tile 64x32 per plane: 256 threads x 1 vec8
    {
      int r = tid >> 2, c8 = (tid & 3) * 8;
      size_t ai = (size_t)(m0 + r) * Kd + k0 + c8;
      *reinterpret_cast<bf16x8*>(&Ah[r * 40 + c8]) =
          *reinterpret_cast<const bf16x8*>(Ath + ai);
      *reinterpret_cast<bf16x8*>(&Alo[r * 40 + c8]) =
          *reinterpret_cast<const bf16x8*>(Atl + ai);
    }
    // B tile 128x32 per plane: 2 vec8 per thread
#pragma unroll
    for (int c = 0; c < 2; c++) {
      int idx = tid + c * 256;
      int r = idx >> 2, c8 = (idx & 3) * 8;
      size_t bi = (size_t)(n0 + r) * Kd + k0 + c8;
      *reinterpret_cast<bf16x8*>(&Bh[r * 40 + c8]) =
          *reinterpret_cast<const bf16x8*>(Bth + bi);
      *reinterpret_cast<bf16x8*>(&Bl[r * 40 + c8]) =
          *reinterpret_cast<const bf16x8*>(Btl + bi);
    }
    __syncthreads();
    bf16x8 ah[2], al[2], bh4[4], bl4[4];
#pragma unroll
    for (int mf = 0; mf < 2; mf++) {
      int ar = (wm + mf * 16 + l15) * 40 + l4 * 8;
      ah[mf] = *reinterpret_cast<const bf16x8*>(&Ah[ar]);
      al[mf] = *reinterpret_cast<const bf16x8*>(&Alo[ar]);
    }
#pragma unroll
    for (int nf = 0; nf < 4; nf++) {
      int br = (wn + nf * 16 + l15) * 40 + l4 * 8;
      bh4[nf] = *reinterpret_cast<const bf16x8*>(&Bh[br]);
      bl4[nf] = *reinterpret_cast<const bf16x8*>(&Bl[br]);
    }
#pragma unroll
    for (int mf = 0; mf < 2; mf++)
#pragma unroll
      for (int nf = 0; nf < 4; nf++)
        acc[mf][nf] = mfma16(ah[mf], bh4[nf],
                      mfma16(al[mf], bh4[nf],
                      mfma16(ah[mf], bl4[nf], acc[mf][nf])));
    __syncthreads();
  }
  int rbase = m0 + wm + (l4 << 2);
  int cbase = n0 + wn + l15;
#pragma unroll
  for (int mf = 0; mf < 2; mf++)
#pragma unroll
    for (int nf = 0; nf < 4; nf++)
#pragma unroll
      for (int r = 0; r < 4; r++) {
        int row = rbase + mf * 16 + r;
        int col = cbase + nf * 16;
        if (row < M && col < N) {
          size_t ci = (size_t)row * N + col;
          short h, l;
          split2r(acc[mf][nf][r], h, l);
          Ch[ci] = h;
          Cl[ci] = l;
        }
      }
}

// ---------------- gemm_bt: plain bf16 GEMM, 64x128 tile, B^T (N,Kd) bf16
template <int A_F32, int STORE_BF16>
__global__ __launch_bounds__(256, 4) void gemm_bt(const void* __restrict__ Av,
                                                  const short* __restrict__ Bt,
                                                  void* __restrict__ Cv,
                                                  int M, int N, int Kd) {
  __shared__ alignas(16) short Al[64 * 72];
  __shared__ alignas(16) short Bl[128 * 72];
  int tid = threadIdx.x;
  int lane = tid & 63, wave = tid >> 6;
  int l15 = lane & 15, l4 = lane >> 4;
  int m0 = blockIdx.x * 64, n0 = blockIdx.y * 128;
  int wm = (wave >> 1) * 32, wn = (wave & 1) * 64;
  f32x4 zf = {0.f, 0.f, 0.f, 0.f};
  f32x4 acc[2][4];
#pragma unroll
  for (int i = 0; i < 2; i++)
#pragma unroll
    for (int j = 0; j < 4; j++) acc[i][j] = zf;

  for (int k0 = 0; k0 < Kd; k0 += 64) {
    // A tile 64x64: 2 vec8 per thread
#pragma unroll
    for (int c = 0; c < 2; c++) {
      int idx = tid + c * 256;
      int r = idx >> 3, k8 = (idx & 7) * 8;
      bf16x8 a;
      if constexpr (A_F32 != 0) {
        const float* Ap = (const float*)Av + (size_t)(m0 + r) * Kd + k0 + k8;
        float4 v0 = *reinterpret_cast<const float4*>(Ap);
        float4 v1 = *reinterpret_cast<const float4*>(Ap + 4);
        a[0] = f2bf(v0.x); a[1] = f2bf(v0.y); a[2] = f2bf(v0.z); a[3] = f2bf(v0.w);
        a[4] = f2bf(v1.x); a[5] = f2bf(v1.y); a[6] = f2bf(v1.z); a[7] = f2bf(v1.w);
      } else {
        a = *reinterpret_cast<const bf16x8*>((const short*)Av + (size_t)(m0 + r) * Kd + k0 + k8);
      }
      *reinterpret_cast<bf16x8*>(&Al[r * 72 + k8]) = a;
    }
    // B tile 128x64: 4 vec8 per thread
#pragma unroll
    for (int c = 0; c < 4; c++) {
      int idx = tid + c * 256;
      int r = idx >> 3, k8 = (idx & 7) * 8;
      *reinterpret_cast<bf16x8*>(&Bl[r * 72 + k8]) =
          *reinterpret_cast<const bf16x8*>(Bt + (size_t)(n0 + r) * Kd + k0 + k8);
    }
    __syncthreads();
    bf16x8 af[2][2], bfr[4][2];
#pragma unroll
    for (int mf = 0; mf < 2; mf++)
#pragma unroll
      for (int ks = 0; ks < 2; ks++)
        af[mf][ks] = *reinterpret_cast<const bf16x8*>(
            &Al[(wm + mf * 16 + l15) * 72 + ks * 32 + l4 * 8]);
#pragma unroll
    for (int nf = 0; nf < 4; nf++)
#pragma unroll
      for (int ks = 0; ks < 2; ks++)
        bfr[nf][ks] = *reinterpret_cast<const bf16x8*>(
            &Bl[(wn + nf * 16 + l15) * 72 + ks * 32 + l4 * 8]);
#pragma unroll
    for (int ks = 0; ks < 2; ks++)
#pragma unroll
      for (int mf = 0; mf < 2; mf++)
#pragma unroll
        for (int nf = 0; nf < 4; nf++)
          acc[mf][nf] = mfma16(af[mf][ks], bfr[nf][ks], acc[mf][nf]);
    __syncthreads();
  }
  int rbase = m0 + wm + (l4 << 2);
  int cbase = n0 + wn + l15;
#pragma unroll
  for (int mf = 0; mf < 2; mf++)
#pragma unroll
    for (int nf = 0; nf < 4; nf++)
#pragma unroll
      for (int r = 0; r < 4; r++) {
        int row = rbase + mf * 16 + r;
        int col = cbase + nf * 16;
        if (row < M && col < N) {
          size_t ci = (size_t)row * N + col;
          float v = acc[mf][nf][r];
          if constexpr (STORE_BF16 != 0)
            ((short*)Cv)[ci] = f2bf(v);
          else
            ((float*)Cv)[ci] = v;
        }
      }
}

// ---------------- RoPE in-place on split planes (s, NH*128)
template <int NH>
__global__ __launch_bounds__(256) void rope_planes(short* __restrict__ bh,
                                                   short* __restrict__ bl,
                                                   const float* __restrict__ cosb,
                                                   const float* __restrict__ sinb,
                                                   const int* __restrict__ pos) {
  int idx = blockIdx.x * 256 + threadIdx.x;
  if (idx >= S_LEN * NH * 64) return;
  int d = idx & 63;
  int h = (idx >> 6) % NH;
  int s = idx / (64 * NH);
  int p = pos[s];
  if (p < 0) p = 0;
  if (p >= S_LEN) p = S_LEN - 1;
  size_t base = ((size_t)s * NH + h) * 128 + d;
  float lo = bf2f(bh[base]) + bf2f(bl[base]);
  float hi = bf2f(bh[base + 64]) + bf2f(bl[base + 64]);
  float c0 = cosb[p * 128 + d], s0 = sinb[p * 128 + d];
  float c1 = cosb[p * 128 + d + 64], s1 = sinb[p * 128 + d + 64];
  float o0 = lo * c0 - hi * s0;
  float o1 = hi * c1 + lo * s1;
  short a, b;
  split2r(o0, a, b);
  bh[base] = a; bl[base] = b;
  split2r(o1, a, b);
  bh[base + 64] = a; bl[base + 64] = b;
}

// ---------------- V transpose: (s, g, d) -> (g, d, s) bf16
__global__ __launch_bounds__(128) void vtrans_k(const short* __restrict__ v,
                                                short* __restrict__ vT) {
  int g = blockIdx.y;
  int s0 = blockIdx.x * 8;
  int d = threadIdx.x;
  if (s0 + 7 >= S_LEN || g >= NHKV || d >= HDIM) return;
  const size_t vSz = (size_t)S_LEN * KVDIM;
  bf16x8 vals;
#pragma unroll
  for (int i = 0; i < 8; i++)
    vals[i] = v[climp((size_t)(s0 + i) * KVDIM + g * HDIM + d, vSz, 1)];
  *reinterpret_cast<bf16x8*>(vT + climp(((size_t)g * HDIM + d) * S_LEN + s0,
                                        (size_t)NHKV * HDIM * S_LEN, 8)) = vals;
}

// ---------------- attn_fwd3: FUSED, QBLK=64 (wave owns 16 rows). grid (NHQ, 32).
// Remap qt = z<16 ? z : 47-z -> per-CU 4-block work sets sum to 132 iters (const).
__global__ __launch_bounds__(256, 4) void attn_fwd3(const short* __restrict__ qhp,
                                                    const short* __restrict__ qlp,
                                                    const short* __restrict__ khp,
                                                    const short* __restrict__ klp,
                                                    const short* __restrict__ vT,
                                                    short* __restrict__ ob,
                                                    float* __restrict__ mbuf,
                                                    float* __restrict__ lbuf) {
  int h = blockIdx.x;
  int z = blockIdx.y;
  int qt = (z < 16) ? z : (47 - z);
  int g = h >> 2;
  int q0 = qt * 64;
  int tid = threadIdx.x, lane = tid & 63, wave = tid >> 6;
  int l15 = lane & 15, l4 = lane >> 4;
  __shared__ alignas(16) short Kh[32 * 136];
  __shared__ alignas(16) short Kl2[32 * 136];
  __shared__ alignas(16) short Vl[128 * 40];
  __shared__ alignas(16) short Pl[4][16 * 40];
  const size_t qSz = (size_t)S_LEN * DMODEL;
  const size_t kSz = (size_t)S_LEN * KVDIM;
  const size_t vtSz = (size_t)NHKV * HDIM * S_LEN;

  int qrow_base = q0 + wave * 16;
  bf16x8 qh[4], ql[4];
#pragma unroll
  for (int ks = 0; ks < 4; ks++) {
    size_t qi = climp((size_t)(qrow_base + l15) * DMODEL + h * HDIM + ks * 32 + l4 * 8,
                      qSz, 8);
    qh[ks] = *reinterpret_cast<const bf16x8*>(qhp + qi);
    ql[ks] = *reinterpret_cast<const bf16x8*>(qlp + qi);
  }

  f32x4 zf = {0.f, 0.f, 0.f, 0.f};
  f32x4 accO[8];
  float mrow[4], lrow[4];
#pragma unroll
  for (int nfo = 0; nfo < 8; nfo++) accO[nfo] = zf;
#pragma unroll
  for (int r = 0; r < 4; r++) { mrow[r] = -1e30f; lrow[r] = 0.f; }
  int wqmax = qrow_base + 15;
  int nkt = qt * 2 + 2;
  const float scale = 0.08838834764831845f;

  for (int kt = 0; kt < nkt; kt++) {
    int k0 = kt * 32;
#pragma unroll
    for (int c = 0; c < 2; c++) {
      int idx = tid + c * 256;
      int r = idx >> 4, c8 = (idx & 15) * 8;
      size_t ki = climp((size_t)(k0 + r) * KVDIM + g * HDIM + c8, kSz, 8);
      *reinterpret_cast<bf16x8*>(&Kh[r * 136 + c8]) =
          *reinterpret_cast<const bf16x8*>(khp + ki);
      *reinterpret_cast<bf16x8*>(&Kl2[r * 136 + c8]) =
          *reinterpret_cast<const bf16x8*>(klp + ki);
    }
#pragma unroll
    for (int c = 0; c < 2; c++) {
      int idx = tid + c * 256;
      int r = idx >> 2, c8 = idx & 3;
      *reinterpret_cast<bf16x8*>(&Vl[r * 40 + c8 * 8]) =
          *reinterpret_cast<const bf16x8*>(
              vT + climp(((size_t)g * HDIM + r) * S_LEN + k0 + c8 * 8, vtSz, 8));
    }
    __syncthreads();
    if (k0 <= wqmax) {
      f32x4 sf[2] = {zf, zf};
#pragma unroll
      for (int ks = 0; ks < 4; ks++)
#pragma unroll
        for (int nf = 0; nf < 2; nf++) {
          int kr = (nf * 16 + l15) * 136 + ks * 32 + l4 * 8;
          bf16x8 bh = *reinterpret_cast<const bf16x8*>(&Kh[kr]);
          bf16x8 bl = *reinterpret_cast<const bf16x8*>(&Kl2[kr]);
          sf[nf] = mfma16(qh[ks], bh,
                   mfma16(ql[ks], bh,
                   mfma16(qh[ks], bl, sf[nf])));
        }
      float p[2][4];
#pragma unroll
      for (int r = 0; r < 4; r++) {
        int qg = qrow_base + (l4 << 2) + r;
        float v0 = sf[0][r] * scale;
        float v1 = sf[1][r] * scale;
        if (k0 + l15 > qg) v0 = -1e9f;
        if (k0 + 16 + l15 > qg) v1 = -1e9f;
        float mx = fmaxf(v0, v1);
        mx = fmaxf(mx, __shfl_xor(mx, 1));
        mx = fmaxf(mx, __shfl_xor(mx, 2));
        mx = fmaxf(mx, __shfl_xor(mx, 4));
        mx = fmaxf(mx, __shfl_xor(mx, 8));
        float mnew = fmaxf(mrow[r], mx);
        float alpha = __expf(mrow[r] - mnew);
        float p0 = __expf(v0 - mnew);
        float p1 = __expf(v1 - mnew);
        float rs = p0 + p1;
        rs += __shfl_xor(rs, 1);
        rs += __shfl_xor(rs, 2);
        rs += __shfl_xor(rs, 4);
        rs += __shfl_xor(rs, 8);
        lrow[r] = lrow[r] * alpha + rs;
        mrow[r] = mnew;
#pragma unroll
        for (int nfo = 0; nfo < 8; nfo++) accO[nfo][r] *= alpha;
        p[0][r] = p0;
        p[1][r] = p1;
      }
#pragma unroll
      for (int nf = 0; nf < 2; nf++)
#pragma unroll
        for (int r = 0; r < 4; r++)
          Pl[wave][((l4 << 2) + r) * 40 + nf * 16 + l15] = f2bf(p[nf][r]);
      bf16x8 pa = *reinterpret_cast<const bf16x8*>(&Pl[wave][l15 * 40 + l4 * 8]);
#pragma unroll
      for (int nfo = 0; nfo < 8; nfo++) {
        bf16x8 bv = *reinterpret_cast<const bf16x8*>(&Vl[(nfo * 16 + l15) * 40 + l4 * 8]);
        accO[nfo] = mfma16(pa, bv, accO[nfo]);
      }
    }
    __syncthreads();
  }
  float inv[4];
#pragma unroll
  for (int r = 0; r < 4; r++) inv[r] = 1.0f / lrow[r];
#pragma unroll
  for (int nfo = 0; nfo < 8; nfo++)
#pragma unroll
    for (int r = 0; r < 4; r++) {
      int row = qrow_base + (l4 << 2) + r;
      int col = h * HDIM + nfo * 16 + l15;
      if (row < S_LEN && col < DMODEL)
        ob[(size_t)row * DMODEL + col] = f2bf(accO[nfo][r] * inv[r]);
    }
  if (l15 == 0) {
#pragma unroll
    for (int r = 0; r < 4; r++) {
      int row = qrow_base + (l4 << 2) + r;
      if (row < S_LEN) {
        mbuf[(size_t)h * S_LEN + row] = mrow[r];
        lbuf[(size_t)h * S_LEN + row] = lrow[r];
      }
    }
  }
}

// ---------------- attn_hh2: column sums, KBLK=64 (wave owns 16 keys). grid (NHQ, 32).
__global__ __launch_bounds__(256, 4) void attn_hh2(const short* __restrict__ qhp,
                                                   const short* __restrict__ qlp,
                                                   const short* __restrict__ khp,
                                                   const short* __restrict__ klp,
                                                   const float* __restrict__ mbuf,
                                                   const float* __restrict__ lbuf,
                                                   float* __restrict__ hh_h) {
  int h = blockIdx.x;
  int z = blockIdx.y;
  int kt = (z < 16) ? z : (47 - z);
  int g = h >> 2;
  int key0 = kt * 64;
  int tid = threadIdx.x, lane = tid & 63, wave = tid >> 6;
  int l15 = lane & 15, l4 = lane >> 4;
  __shared__ alignas(16) short Qh[32 * 136];
  __shared__ alignas(16) short Ql[32 * 136];
  const size_t qSz = (size_t)S_LEN * DMODEL;
  const size_t kSz = (size_t)S_LEN * KVDIM;
  const size_t mlSz = (size_t)NHQ * S_LEN;
  const float scale = 0.08838834764831845f;
  f32x4 zf = {0.f, 0.f, 0.f, 0.f};

  int keymin = key0 + wave * 16;
  bf16x8 akh[4], akl[4];
#pragma unroll
  for (int ks = 0; ks < 4; ks++) {
    size_t ki = climp((size_t)(keymin + l15) * KVDIM + g * HDIM + ks * 32 + l4 * 8,
                      kSz, 8);
    akh[ks] = *reinterpret_cast<const bf16x8*>(khp + ki);
    akl[ks] = *reinterpret_cast<const bf16x8*>(klp + ki);
  }

  double acc[4];
#pragma unroll
  for (int r = 0; r < 4; r++) acc[r] = 0.0;

  for (int q0 = key0; q0 < S_LEN; q0 += 32) {
#pragma unroll
    for (int c = 0; c < 2; c++) {
      int idx = tid + c * 256;
      int r = idx >> 4, c8 = (idx & 15) * 8;
      size_t qi = climp((size_t)(q0 + r) * DMODEL + h * HDIM + c8, qSz, 8);
      *reinterpret_cast<bf16x8*>(&Qh[r * 136 + c8]) =
          *reinterpret_cast<const bf16x8*>(qhp + qi);
      *reinterpret_cast<bf16x8*>(&Ql[r * 136 + c8]) =
          *reinterpret_cast<const bf16x8*>(qlp + qi);
    }
    __syncthreads();
    if (q0 + 31 >= keymin) {
      f32x4 sf[2] = {zf, zf};
#pragma unroll
      for (int ks = 0; ks < 4; ks++)
#pragma unroll
        for (int nf = 0; nf < 2; nf++) {
          int qr = (nf * 16 + l15) * 136 + ks * 32 + l4 * 8;
          bf16x8 bqh = *reinterpret_cast<const bf16x8*>(&Qh[qr]);
          bf16x8 bql = *reinterpret_cast<const bf16x8*>(&Ql[qr]);
          sf[nf] = mfma16(akh[ks], bqh,
                   mfma16(akh[ks], bql,
                   mfma16(akl[ks], bqh, sf[nf])));
        }
#pragma unroll
      for (int nf = 0; nf < 2; nf++) {
        int q = q0 + nf * 16 + l15;
        float mq = mbuf[climp((size_t)h * S_LEN + q, mlSz, 1)];
        float rl = 1.0f / lbuf[climp((size_t)h * S_LEN + q, mlSz, 1)];
#pragma unroll
        for (int r = 0; r < 4; r++) {
          int key = keymin + (l4 << 2) + r;
          if (q >= key && q < S_LEN)
            acc[r] += (double)(__expf(sf[nf][r] * scale - mq) * rl);
        }
      }
    }
    __syncthreads();
  }
#pragma unroll
  for (int r = 0; r < 4; r++) {
    double v = acc[r];
    v += __shfl_xor(v, 1);
    v += __shfl_xor(v, 2);
    v += __shfl_xor(v, 4);
    v += __shfl_xor(v, 8);
    int key = keymin + (l4 << 2) + r;
    if (l15 == 0 && key < S_LEN)
      hh_h[(size_t)h * S_LEN + key] = (float)v;
  }
}

// ---------------- top-k + gather (k reconstructed from planes)
__global__ __launch_bounds__(512) void topk_gather(const float* __restrict__ hh_h,
                                                   const short* __restrict__ khp,
                                                   const short* __restrict__ klp,
                                                   const short* __restrict__ vb,
                                                   float* __restrict__ out_k,
                                                   float* __restrict__ out_v,
                                                   float* __restrict__ out_hh) {
  int g = blockIdx.x, t = threadIdx.x;
  __shared__ float hhg[2048];
  __shared__ float sv[2048];
  __shared__ int si[2048];
  __shared__ int st[128];
  __shared__ int keep[NKEEP];
  const size_t hhSz = (size_t)NHQ * S_LEN;
  const size_t kvSz = (size_t)S_LEN * KVDIM;
#pragma unroll
  for (int i = 0; i < 4; i++) {
    int idx = t + i * 512;
    float s = 0.25f * (hh_h[climp((size_t)(4 * g + 0) * 2048 + idx, hhSz, 1)] +
                       hh_h[climp((size_t)(4 * g + 1) * 2048 + idx, hhSz, 1)] +
                       hh_h[climp((size_t)(4 * g + 2) * 2048 + idx, hhSz, 1)] +
                       hh_h[climp((size_t)(4 * g + 3) * 2048 + idx, hhSz, 1)]);
    hhg[idx] = s;
    sv[idx] = (idx < SEL_N) ? s : -1e30f;
    si[idx] = idx;
  }
  __syncthreads();
  for (int k = 2; k <= 2048; k <<= 1) {
    for (int j = k >> 1; j > 0; j >>= 1) {
#pragma unroll
      for (int pass = 0; pass < 4; pass++) {
        int i = t + pass * 512;
        int ixj = i ^ j;
        if (ixj > i) {
          bool up = ((i & k) == 0);
          float a = sv[i], b = sv[ixj];
          int ia = si[i], ib = si[ixj];
          bool before = (a > b) || (a == b && ia < ib);
          bool doswap = up ? !before : before;
          if (doswap) { sv[i] = b; sv[ixj] = a; si[i] = ib; si[ixj] = ia; }
        }
      }
      __syncthreads();
    }
  }
  if (t < 128) st[t] = si[t];
  __syncthreads();
  for (int k = 2; k <= 128; k <<= 1) {
    for (int j = k >> 1; j > 0; j >>= 1) {
      if (t < 128) {
        int i = t, ixj = i ^ j;
        if (ixj > i) {
          bool up = ((i & k) == 0);
          int a = st[i], b = st[ixj];
          bool doswap = up ? (a > b) : (a < b);
          if (doswap) { st[i] = b; st[ixj] = a; }
        }
      }
      __syncthreads();
    }
  }
  // All 640 keep[] entries initialized by all 512 threads (R1-R6 bug fix).
  for (int i = t; i < NKEEP; i += 512)
    keep[i] = (i < 128) ? st[i] : (SEL_N + (i - 128));
  __syncthreads();
  for (int i = 0; i < 160; i++) {
    int idx = t + i * 512;
    int jj = idx >> 7, d = idx & 127;
    int src = (jj < NKEEP) ? keep[jj] : 0;
    if (src < 0) src = 0;
    if (src >= S_LEN) src = S_LEN - 1;
    size_t oi = ((size_t)g * NKEEP + jj) * HDIM + d;
    if (jj < NKEEP) {
      size_t ki = climp((size_t)src * KVDIM + g * HDIM + d, kvSz, 1);
      out_k[oi] = bf2f(khp[ki]) + bf2f(klp[ki]);
      out_v[oi] = bf2f(vb[ki]);
    }
  }
  for (int i = t; i < NKEEP; i += 512) {
    int src = keep[i];
    if (src < 0) src = 0;
    if (src >= 2048) src = 2047;
    out_hh[(size_t)g * NKEEP + i] = hhg[src];
  }
}

extern "C" void kernel_launch(void* const* d_in, const int* in_sizes, int n_in,
                              void* d_out, int out_size, void* d_ws, size_t ws_size,
                              hipStream_t stream) {
  const float* x = (const float*)d_in[0];
  const float* Wq = (const float*)d_in[1];
  const float* Wk = (const float*)d_in[2];
  const float* Wv = (const float*)d_in[3];
  const float* Wo = (const float*)d_in[4];
  const float* cosb = (const float*)d_in[5];
  const float* sinb = (const float*)d_in[6];
  const int* pos = (const int*)d_in[7];

  char* ws = (char*)d_ws;
  size_t off = 0;
  auto alloc = [&](size_t bytes) {
    void* p = ws + off;
    off += (bytes + 255) & ~(size_t)255;
    return p;
  };
  short* Rg = (short*)alloc((size_t)64 * 1024 * 1024);          // 64 MB
  short* qh = (short*)alloc((size_t)S_LEN * DMODEL * 2);        // 16 MB
  short* ql = (short*)alloc((size_t)S_LEN * DMODEL * 2);        // 16 MB
  short* kh = (short*)alloc((size_t)S_LEN * KVDIM * 2);         // 4 MB
  short* kl = (short*)alloc((size_t)S_LEN * KVDIM * 2);         // 4 MB
  short* vbuf = (short*)alloc((size_t)S_LEN * KVDIM * 2);       // 4 MB
  short* vT = (short*)alloc((size_t)NHKV * HDIM * S_LEN * 2);   // 4 MB
  short* obuf = (short*)alloc((size_t)S_LEN * DMODEL * 2);      // 16 MB
  float* mbuf = (float*)alloc((size_t)NHQ * S_LEN * 4);
  float* lbuf = (float*)alloc((size_t)NHQ * S_LEN * 4);
  float* hh_h = (float*)alloc((size_t)NHQ * S_LEN * 4);
  if (off > ws_size) return;

  short* WqTh = Rg;
  short* WqTl = Rg + (size_t)16777216;   // +32 MB
  short* WkTh = Rg;
  short* WkTl = Rg + (size_t)4194304;    // +8 MB
  short* WvT  = Rg + (size_t)8388608;    // +16 MB
  short* WoT  = Rg + (size_t)12582912;   // +24 MB

  float* out = (float*)d_out;
  float* out_k = out + (size_t)S_LEN * DMODEL;
  float* out_v = out_k + (size_t)NHKV * NKEEP * HDIM;
  float* out_hh = out_v + (size_t)NHKV * NKEEP * HDIM;

  // x planes live in the `out` chunk of d_out (dead until O-projection writes it)
  short* xh = (short*)out;
  short* xl = xh + (size_t)S_LEN * DMODEL;

  split_x<<<(S_LEN * DMODEL / 8) / 256, 256, 0, stream>>>(x, xh, xl);
  transpose_split<<<dim3(64, 64), 256, 0, stream>>>(Wq, WqTh, WqTl, DMODEL, DMODEL);
  gemm_hp2bt<<<dim3(32, 32), 256, 0, stream>>>(xh, xl, WqTh, WqTl, qh, ql, S_LEN, DMODEL, DMODEL);
  transpose_split<<<dim3(16, 64), 256, 0, stream>>>(Wk, WkTh, WkTl, DMODEL, KVDIM);
  gemm_hp2bt<<<dim3(32, 8), 256, 0, stream>>>(xh, xl, WkTh, WkTl, kh, kl, S_LEN, KVDIM, DMODEL);
  transpose_cvt<<<dim3(16, 64), 256, 0, stream>>>(Wv, WvT, DMODEL, KVDIM);
  gemm_bt<0, 1><<<dim3(32, 8), 256, 0, stream>>>(xh, WvT, vbuf, S_LEN, KVDIM, DMODEL);
  transpose_cvt<<<dim3(64, 64), 256, 0, stream>>>(Wo, WoT, DMODEL, DMODEL);
  rope_planes<32><<<(S_LEN * 32 * 64) / 256, 256, 0, stream>>>(qh, ql, cosb, sinb, pos);
  rope_planes<8><<<(S_LEN * 8 * 64) / 256, 256, 0, stream>>>(kh, kl, cosb, sinb, pos);
  vtrans_k<<<dim3(S_LEN / 8, NHKV), 128, 0, stream>>>(vbuf, vT);
  attn_fwd3<<<dim3(NHQ, 32), 256, 0, stream>>>(qh, ql, kh, kl, vT, obuf, mbuf, lbuf);
  attn_hh2<<<dim3(NHQ, 32), 256, 0, stream>>>(qh, ql, kh, kl, mbuf, lbuf, hh_h);
  gemm_bt<0, 0><<<dim3(32, 32), 256, 0, stream>>>(obuf, WoT, out, S_LEN, DMODEL, DMODEL);
  topk_gather<<<NHKV, 512, 0, stream>>>(hh_h, kh, kl, vbuf, out_k, out_v, out_hh);
}

// Round 15
// 980.373 us; speedup vs baseline: 2.5857x; 1.0667x over previous
//
#include <hip/hip_runtime.h>
#include <cstdint>
#include <cstddef>

typedef __attribute__((ext_vector_type(8))) short bf16x8;
typedef __attribute__((ext_vector_type(4))) short short4v;
typedef __attribute__((ext_vector_type(4))) float f32x4;

#define S_LEN 2048
#define DMODEL 4096
#define NHQ 32
#define NHKV 8
#define HDIM 128
#define KVDIM 1024
#define NKEEP 640
#define SEL_N 1536

__device__ __forceinline__ short f2bf(float f) {
  unsigned u = __float_as_uint(f);
  u += 0x7fffu + ((u >> 16) & 1u);
  return (short)(u >> 16);
}
__device__ __forceinline__ float bf2f(short s) {
  return __uint_as_float(((unsigned)(unsigned short)s) << 16);
}
// split-2, round-to-nearest hi plane: h = rne16(x), l = rne16(x - h). err <= 2^-17|x|
__device__ __forceinline__ void split2r(float x, short& h, short& l) {
  short hh = f2bf(x);
  float r = x - bf2f(hh);
  h = hh;
  l = f2bf(r);
}
__device__ __forceinline__ f32x4 mfma16(bf16x8 a, bf16x8 b, f32x4 c) {
  return __builtin_amdgcn_mfma_f32_16x16x32_bf16(a, b, c, 0, 0, 0);
}
__device__ __forceinline__ size_t climp(size_t i, size_t sz, size_t w) {
  size_t hi = sz - w;
  return i <= hi ? i : hi;
}

// ---------------- split_x: x f32 -> hi/lo bf16 planes
__global__ __launch_bounds__(256) void split_x(const float* __restrict__ x,
                                               short* __restrict__ xh,
                                               short* __restrict__ xl) {
  size_t i = ((size_t)blockIdx.x * 256 + threadIdx.x) * 8;
  if (i + 8 > (size_t)S_LEN * DMODEL) return;
  const float* p = x + i;
  float4 v0 = *reinterpret_cast<const float4*>(p);
  float4 v1 = *reinterpret_cast<const float4*>(p + 4);
  float vv[8] = {v0.x, v0.y, v0.z, v0.w, v1.x, v1.y, v1.z, v1.w};
  bf16x8 sh, sl;
#pragma unroll
  for (int t = 0; t < 8; t++) { short a, b; split2r(vv[t], a, b); sh[t] = a; sl[t] = b; }
  *reinterpret_cast<bf16x8*>(xh + i) = sh;
  *reinterpret_cast<bf16x8*>(xl + i) = sl;
}

// ---------------- transpose+convert: W (Kd,N) f32 -> Wt (N,Kd) bf16
__global__ __launch_bounds__(256) void transpose_cvt(const float* __restrict__ W,
                                                     short* __restrict__ Wt,
                                                     int Kd, int N) {
  __shared__ float tile[64][65];
  int tx = threadIdx.x;
  int n0 = blockIdx.x * 64;
  int k0 = blockIdx.y * 64;
#pragma unroll
  for (int i = 0; i < 4; i++) {
    int idx = tx + i * 256;
    int r = idx >> 4, c4 = (idx & 15) * 4;
    float4 v = *reinterpret_cast<const float4*>(W + (size_t)(k0 + r) * N + n0 + c4);
    tile[r][c4 + 0] = v.x;
    tile[r][c4 + 1] = v.y;
    tile[r][c4 + 2] = v.z;
    tile[r][c4 + 3] = v.w;
  }
  __syncthreads();
#pragma unroll
  for (int i = 0; i < 4; i++) {
    int idx = tx + i * 256;
    int rn = idx >> 4, c4 = (idx & 15) * 4;
    short4v o;
#pragma unroll
    for (int j = 0; j < 4; j++) o[j] = f2bf(tile[c4 + j][rn]);
    *reinterpret_cast<short4v*>(Wt + (size_t)(n0 + rn) * Kd + k0 + c4) = o;
  }
}

// ---------------- transpose+split: W (Kd,N) f32 -> hi/lo bf16 planes (N,Kd)
__global__ __launch_bounds__(256) void transpose_split(const float* __restrict__ W,
                                                       short* __restrict__ Wth,
                                                       short* __restrict__ Wtl,
                                                       int Kd, int N) {
  __shared__ float tile[64][65];
  int tx = threadIdx.x;
  int n0 = blockIdx.x * 64;
  int k0 = blockIdx.y * 64;
#pragma unroll
  for (int i = 0; i < 4; i++) {
    int idx = tx + i * 256;
    int r = idx >> 4, c4 = (idx & 15) * 4;
    float4 v = *reinterpret_cast<const float4*>(W + (size_t)(k0 + r) * N + n0 + c4);
    tile[r][c4 + 0] = v.x;
    tile[r][c4 + 1] = v.y;
    tile[r][c4 + 2] = v.z;
    tile[r][c4 + 3] = v.w;
  }
  __syncthreads();
#pragma unroll
  for (int i = 0; i < 4; i++) {
    int idx = tx + i * 256;
    int rn = idx >> 4, c4 = (idx & 15) * 4;
    short4v oh, ol;
#pragma unroll
    for (int j = 0; j < 4; j++) {
      short a, b;
      split2r(tile[c4 + j][rn], a, b);
      oh[j] = a; ol[j] = b;
    }
    size_t wi = (size_t)(n0 + rn) * Kd + k0 + c4;
    *reinterpret_cast<short4v*>(Wth + wi) = oh;
    *reinterpret_cast<short4v*>(Wtl + wi) = ol;
  }
}

// ---------------- gemm_hp2bt<BM>: C planes = A planes[M,Kd] * B^T planes[N,Kd]
// BM=128: max-reuse config (Q-proj; weights don't L3-fit).
// BM=64: 2x grid (K-proj; weights L3-fit so extra re-reads are absorbed).
template <int BM>
__global__ __launch_bounds__(256, (BM == 128) ? 3 : 4)
void gemm_hp2bt(const short* __restrict__ Ath,
                const short* __restrict__ Atl,
                const short* __restrict__ Bth,
                const short* __restrict__ Btl,
                short* __restrict__ Ch,
                short* __restrict__ Cl,
                int M, int N, int Kd) {
  constexpr int MF = BM / 32;
  __shared__ alignas(16) short Ah[BM * 40];
  __shared__ alignas(16) short Alo[BM * 40];
  __shared__ alignas(16) short Bh[128 * 40];
  __shared__ alignas(16) short Bl[128 * 40];
  int tid = threadIdx.x;
  int lane = tid & 63, wave = tid >> 6;
  int l15 = lane & 15, l4 = lane >> 4;
  int m0 = blockIdx.x * BM, n0 = blockIdx.y * 128;
  int wm = (wave >> 1) * (BM / 2), wn = (wave & 1) * 64;
  f32x4 zf = {0.f, 0.f, 0.f, 0.f};
  f32x4 acc[MF][4];
#pragma unroll
  for (int i = 0; i < MF; i++)
#pragma unroll
    for (int j = 0; j < 4; j++) acc[i][j] = zf;

  for (int k0 = 0; k0 < Kd; k0 += 32) {
#pragma unroll
    for (int c = 0; c < BM / 64; c++) {
      int idx = tid + c * 256;
      int r = idx >> 2, c8 = (idx & 3) * 8;
      size_t ai = (size_t)(m0 + r) * Kd + k0 + c8;
      *reinterpret_cast<bf16x8*>(&Ah[r * 40 + c8]) =
          *reinterpret_cast<const bf16x8*>(Ath + ai);
      *reinterpret_cast<bf16x8*>(&Alo[r * 40 + c8]) =
          *reinterpret_cast<const bf16x8*>(Atl + ai);
    }
#pragma unroll
    for (int c = 0; c < 2; c++) {
      int idx = tid + c * 256;
      int r = idx >> 2, c8 = (idx & 3) * 8;
      size_t bi = (size_t)(n0 + r) * Kd + k0 + c8;
      *reinterpret_cast<bf16x8*>(&Bh[r * 40 + c8]) =
          *reinterpret_cast<const bf16x8*>(Bth + bi);
      *reinterpret_cast<bf16x8*>(&Bl[r * 40 + c8]) =
          *reinterpret_cast<const bf16x8*>(Btl + bi);
    }
    __syncthreads();
    bf16x8 ah[MF], al[MF], bh4[4], bl4[4];
#pragma unroll
    for (int mf = 0; mf < MF; mf++) {
      int ar = (wm + mf * 16 + l15) * 40 + l4 * 8;
      ah[mf] = *reinterpret_cast<const bf16x8*>(&Ah[ar]);
      al[mf] = *reinterpret_cast<const bf16x8*>(&Alo[ar]);
    }
#pragma unroll
    for (int nf = 0; nf < 4; nf++) {
      int br = (wn + nf * 16 + l15) * 40 + l4 * 8;
      bh4[nf] = *reinterpret_cast<const bf16x8*>(&Bh[br]);
      bl4[nf] = *reinterpret_cast<const bf16x8*>(&Bl[br]);
    }
#pragma unroll
    for (int mf = 0; mf < MF; mf++)
#pragma unroll
      for (int nf = 0; nf < 4; nf++)
        acc[mf][nf] = mfma16(ah[mf], bh4[nf],
                      mfma16(al[mf], bh4[nf],
                      mfma16(ah[mf], bl4[nf], acc[mf][nf])));
    __syncthreads();
  }
  int rbase = m0 + wm + (l4 << 2);
  int cbase = n0 + wn + l15;
#pragma unroll
  for (int mf = 0; mf < MF; mf++)
#pragma unroll
    for (int nf = 0; nf < 4; nf++)
#pragma unroll
      for (int r = 0; r < 4; r++) {
        int row = rbase + mf * 16 + r;
        int col = cbase + nf * 16;
        if (row < M && col < N) {
          size_t ci = (size_t)row * N + col;
          short h, l;
          split2r(acc[mf][nf][r], h, l);
          Ch[ci] = h;
          Cl[ci] = l;
        }
      }
}

// ---------------- gemm_bt<BM>: plain bf16 GEMM with B^T (N,Kd) bf16 input
template <int BM, int A_F32, int STORE_BF16>
__global__ __launch_bounds__(256, (BM == 128) ? 3 : 4)
void gemm_bt(const void* __restrict__ Av,
             const short* __restrict__ Bt,
             void* __restrict__ Cv,
             int M, int N, int Kd) {
  constexpr int MF = BM / 32;
  __shared__ alignas(16) short Al[BM * 72];
  __shared__ alignas(16) short Bl[128 * 72];
  int tid = threadIdx.x;
  int lane = tid & 63, wave = tid >> 6;
  int l15 = lane & 15, l4 = lane >> 4;
  int m0 = blockIdx.x * BM, n0 = blockIdx.y * 128;
  int wm = (wave >> 1) * (BM / 2), wn = (wave & 1) * 64;
  f32x4 zf = {0.f, 0.f, 0.f, 0.f};
  f32x4 acc[MF][4];
#pragma unroll
  for (int i = 0; i < MF; i++)
#pragma unroll
    for (int j = 0; j < 4; j++) acc[i][j] = zf;

  for (int k0 = 0; k0 < Kd; k0 += 64) {
#pragma unroll
    for (int c = 0; c < BM / 32; c++) {
      int idx = tid + c * 256;
      int r = idx >> 3, k8 = (idx & 7) * 8;
      bf16x8 a;
      if constexpr (A_F32 != 0) {
        const float* Ap = (const float*)Av + (size_t)(m0 + r) * Kd + k0 + k8;
        float4 v0 = *reinterpret_cast<const float4*>(Ap);
        float4 v1 = *reinterpret_cast<const float4*>(Ap + 4);
        a[0] = f2bf(v0.x); a[1] = f2bf(v0.y); a[2] = f2bf(v0.z); a[3] = f2bf(v0.w);
        a[4] = f2bf(v1.x); a[5] = f2bf(v1.y); a[6] = f2bf(v1.z); a[7] = f2bf(v1.w);
      } else {
        a = *reinterpret_cast<const bf16x8*>((const short*)Av + (size_t)(m0 + r) * Kd + k0 + k8);
      }
      *reinterpret_cast<bf16x8*>(&Al[r * 72 + k8]) = a;
    }
#pragma unroll
    for (int c = 0; c < 4; c++) {
      int idx = tid + c * 256;
      int r = idx >> 3, k8 = (idx & 7) * 8;
      *reinterpret_cast<bf16x8*>(&Bl[r * 72 + k8]) =
          *reinterpret_cast<const bf16x8*>(Bt + (size_t)(n0 + r) * Kd + k0 + k8);
    }
    __syncthreads();
    bf16x8 af[MF][2], bfr[4][2];
#pragma unroll
    for (int mf = 0; mf < MF; mf++)
#pragma unroll
      for (int ks = 0; ks < 2; ks++)
        af[mf][ks] = *reinterpret_cast<const bf16x8*>(
            &Al[(wm + mf * 16 + l15) * 72 + ks * 32 + l4 * 8]);
#pragma unroll
    for (int nf = 0; nf < 4; nf++)
#pragma unroll
      for (int ks = 0; ks < 2; ks++)
        bfr[nf][ks] = *reinterpret_cast<const bf16x8*>(
            &Bl[(wn + nf * 16 + l15) * 72 + ks * 32 + l4 * 8]);
#pragma unroll
    for (int ks = 0; ks < 2; ks++)
#pragma unroll
      for (int mf = 0; mf < MF; mf++)
#pragma unroll
        for (int nf = 0; nf < 4; nf++)
          acc[mf][nf] = mfma16(af[mf][ks], bfr[nf][ks], acc[mf][nf]);
    __syncthreads();
  }
  int rbase = m0 + wm + (l4 << 2);
  int cbase = n0 + wn + l15;
#pragma unroll
  for (int mf = 0; mf < MF; mf++)
#pragma unroll
    for (int nf = 0; nf < 4; nf++)
#pragma unroll
      for (int r = 0; r < 4; r++) {
        int row = rbase + mf * 16 + r;
        int col = cbase + nf * 16;
        if (row < M && col < N) {
          size_t ci = (size_t)row * N + col;
          float v = acc[mf][nf][r];
          if constexpr (STORE_BF16 != 0)
            ((short*)Cv)[ci] = f2bf(v);
          else
            ((float*)Cv)[ci] = v;
        }
      }
}

// ---------------- RoPE in-place on split planes (s, NH*128)
template <int NH>
__global__ __launch_bounds__(256) void rope_planes(short* __restrict__ bh,
                                                   short* __restrict__ bl,
                                                   const float* __restrict__ cosb,
                                                   const float* __restrict__ sinb,
                                                   const int* __restrict__ pos) {
  int idx = blockIdx.x * 256 + threadIdx.x;
  if (idx >= S_LEN * NH * 64) return;
  int d = idx & 63;
  int h = (idx >> 6) % NH;
  int s = idx / (64 * NH);
  int p = pos[s];
  if (p < 0) p = 0;
  if (p >= S_LEN) p = S_LEN - 1;
  size_t base = ((size_t)s * NH + h) * 128 + d;
  float lo = bf2f(bh[base]) + bf2f(bl[base]);
  float hi = bf2f(bh[base + 64]) + bf2f(bl[base + 64]);
  float c0 = cosb[p * 128 + d], s0 = sinb[p * 128 + d];
  float c1 = cosb[p * 128 + d + 64], s1 = sinb[p * 128 + d + 64];
  float o0 = lo * c0 - hi * s0;
  float o1 = hi * c1 + lo * s1;
  short a, b;
  split2r(o0, a, b);
  bh[base] = a; bl[base] = b;
  split2r(o1, a, b);
  bh[base + 64] = a; bl[base + 64] = b;
}

// ---------------- V transpose: (s, g, d) -> (g, d, s) bf16
__global__ __launch_bounds__(128) void vtrans_k(const short* __restrict__ v,
                                                short* __restrict__ vT) {
  int g = blockIdx.y;
  int s0 = blockIdx.x * 8;
  int d = threadIdx.x;
  if (s0 + 7 >= S_LEN || g >= NHKV || d >= HDIM) return;
  const size_t vSz = (size_t)S_LEN * KVDIM;
  bf16x8 vals;
#pragma unroll
  for (int i = 0; i < 8; i++)
    vals[i] = v[climp((size_t)(s0 + i) * KVDIM + g * HDIM + d, vSz, 1)];
  *reinterpret_cast<bf16x8*>(vT + climp(((size_t)g * HDIM + d) * S_LEN + s0,
                                        (size_t)NHKV * HDIM * S_LEN, 8)) = vals;
}

// ---------------- attn_fwd3: FUSED, QBLK=64 (wave owns 16 rows). grid (NHQ, 32).
__global__ __launch_bounds__(256, 4) void attn_fwd3(const short* __restrict__ qhp,
                                                    const short* __restrict__ qlp,
                                                    const short* __restrict__ khp,
                                                    const short* __restrict__ klp,
                                                    const short* __restrict__ vT,
                                                    short* __restrict__ ob,
                                                    float* __restrict__ mbuf,
                                                    float* __restrict__ lbuf) {
  int h = blockIdx.x;
  int z = blockIdx.y;
  int qt = (z < 16) ? z : (47 - z);
  int g = h >> 2;
  int q0 = qt * 64;
  int tid = threadIdx.x, lane = tid & 63, wave = tid >> 6;
  int l15 = lane & 15, l4 = lane >> 4;
  __shared__ alignas(16) short Kh[32 * 136];
  __shared__ alignas(16) short Kl2[32 * 136];
  __shared__ alignas(16) short Vl[128 * 40];
  __shared__ alignas(16) short Pl[4][16 * 40];
  const size_t qSz = (size_t)S_LEN * DMODEL;
  const size_t kSz = (size_t)S_LEN * KVDIM;
  const size_t vtSz = (size_t)NHKV * HDIM * S_LEN;

  int qrow_base = q0 + wave * 16;
  bf16x8 qh[4], ql[4];
#pragma unroll
  for (int ks = 0; ks < 4; ks++) {
    size_t qi = climp((size_t)(qrow_base + l15) * DMODEL + h * HDIM + ks * 32 + l4 * 8,
                      qSz, 8);
    qh[ks] = *reinterpret_cast<const bf16x8*>(qhp + qi);
    ql[ks] = *reinterpret_cast<const bf16x8*>(qlp + qi);
  }

  f32x4 zf = {0.f, 0.f, 0.f, 0.f};
  f32x4 accO[8];
  float mrow[4], lrow[4];
#pragma unroll
  for (int nfo = 0; nfo < 8; nfo++) accO[nfo] = zf;
#pragma unroll
  for (int r = 0; r < 4; r++) { mrow[r] = -1e30f; lrow[r] = 0.f; }
  int wqmax = qrow_base + 15;
  int nkt = qt * 2 + 2;
  const float scale = 0.08838834764831845f;

  for (int kt = 0; kt < nkt; kt++) {
    int k0 = kt * 32;
#pragma unroll
    for (int c = 0; c < 2; c++) {
      int idx = tid + c * 256;
      int r = idx >> 4, c8 = (idx & 15) * 8;
      size_t ki = climp((size_t)(k0 + r) * KVDIM + g * HDIM + c8, kSz, 8);
      *reinterpret_cast<bf16x8*>(&Kh[r * 136 + c8]) =
          *reinterpret_cast<const bf16x8*>(khp + ki);
      *reinterpret_cast<bf16x8*>(&Kl2[r * 136 + c8]) =
          *reinterpret_cast<const bf16x8*>(klp + ki);
    }
#pragma unroll
    for (int c = 0; c < 2; c++) {
      int idx = tid + c * 256;
      int r = idx >> 2, c8 = idx & 3;
      *reinterpret_cast<bf16x8*>(&Vl[r * 40 + c8 * 8]) =
          *reinterpret_cast<const bf16x8*>(
              vT + climp(((size_t)g * HDIM + r) * S_LEN + k0 + c8 * 8, vtSz, 8));
    }
    __syncthreads();
    if (k0 <= wqmax) {
      f32x4 sf[2] = {zf, zf};
#pragma unroll
      for (int ks = 0; ks < 4; ks++)
#pragma unroll
        for (int nf = 0; nf < 2; nf++) {
          int kr = (nf * 16 + l15) * 136 + ks * 32 + l4 * 8;
          bf16x8 bh = *reinterpret_cast<const bf16x8*>(&Kh[kr]);
          bf16x8 bl = *reinterpret_cast<const bf16x8*>(&Kl2[kr]);
          sf[nf] = mfma16(qh[ks], bh,
                   mfma16(ql[ks], bh,
                   mfma16(qh[ks], bl, sf[nf])));
        }
      float p[2][4];
#pragma unroll
      for (int r = 0; r < 4; r++) {
        int qg = qrow_base + (l4 << 2) + r;
        float v0 = sf[0][r] * scale;
        float v1 = sf[1][r] * scale;
        if (k0 + l15 > qg) v0 = -1e9f;
        if (k0 + 16 + l15 > qg) v1 = -1e9f;
        float mx = fmaxf(v0, v1);
        mx = fmaxf(mx, __shfl_xor(mx, 1));
        mx = fmaxf(mx, __shfl_xor(mx, 2));
        mx = fmaxf(mx, __shfl_xor(mx, 4));
        mx = fmaxf(mx, __shfl_xor(mx, 8));
        float mnew = fmaxf(mrow[r], mx);
        float alpha = __expf(mrow[r] - mnew);
        float p0 = __expf(v0 - mnew);
        float p1 = __expf(v1 - mnew);
        float rs = p0 + p1;
        rs += __shfl_xor(rs, 1);
        rs += __shfl_xor(rs, 2);
        rs += __shfl_xor(rs, 4);
        rs += __shfl_xor(rs, 8);
        lrow[r] = lrow[r] * alpha + rs;
        mrow[r] = mnew;
#pragma unroll
        for (int nfo = 0; nfo < 8; nfo++) accO[nfo][r] *= alpha;
        p[0][r] = p0;
        p[1][r] = p1;
      }
#pragma unroll
      for (int nf = 0; nf < 2; nf++)
#pragma unroll
        for (int r = 0; r < 4; r++)
          Pl[wave][((l4 << 2) + r) * 40 + nf * 16 + l15] = f2bf(p[nf][r]);
      bf16x8 pa = *reinterpret_cast<const bf16x8*>(&Pl[wave][l15 * 40 + l4 * 8]);
#pragma unroll
      for (int nfo = 0; nfo < 8; nfo++) {
        bf16x8 bv = *reinterpret_cast<const bf16x8*>(&Vl[(nfo * 16 + l15) * 40 + l4 * 8]);
        accO[nfo] = mfma16(pa, bv, accO[nfo]);
      }
    }
    __syncthreads();
  }
  float inv[4];
#pragma unroll
  for (int r = 0; r < 4; r++) inv[r] = 1.0f / lrow[r];
#pragma unroll
  for (int nfo = 0; nfo < 8; nfo++)
#pragma unroll
    for (int r = 0; r < 4; r++) {
      int row = qrow_base + (l4 << 2) + r;
      int col = h * HDIM + nfo * 16 + l15;
      if (row < S_LEN && col < DMODEL)
        ob[(size_t)row * DMODEL + col] = f2bf(accO[nfo][r] * inv[r]);
    }
  if (l15 == 0) {
#pragma unroll
    for (int r = 0; r < 4; r++) {
      int row = qrow_base + (l4 << 2) + r;
      if (row < S_LEN) {
        mbuf[(size_t)h * S_LEN + row] = mrow[r];
        lbuf[(size_t)h * S_LEN + row] = lrow[r];
      }
    }
  }
}

// ---------------- attn_hh2: column sums, KBLK=64 (wave owns 16 keys). grid (NHQ, 32).
__global__ __launch_bounds__(256, 4) void attn_hh2(const short* __restrict__ qhp,
                                                   const short* __restrict__ qlp,
                                                   const short* __restrict__ khp,
                                                   const short* __restrict__ klp,
                                                   const float* __restrict__ mbuf,
                                                   const float* __restrict__ lbuf,
                                                   float* __restrict__ hh_h) {
  int h = blockIdx.x;
  int z = blockIdx.y;
  int kt = (z < 16) ? z : (47 - z);
  int g = h >> 2;
  int key0 = kt * 64;
  int tid = threadIdx.x, lane = tid & 63, wave = tid >> 6;
  int l15 = lane & 15, l4 = lane >> 4;
  __shared__ alignas(16) short Qh[32 * 136];
  __shared__ alignas(16) short Ql[32 * 136];
  const size_t qSz = (size_t)S_LEN * DMODEL;
  const size_t kSz = (size_t)S_LEN * KVDIM;
  const size_t mlSz = (size_t)NHQ * S_LEN;
  const float scale = 0.08838834764831845f;
  f32x4 zf = {0.f, 0.f, 0.f, 0.f};

  int keymin = key0 + wave * 16;
  bf16x8 akh[4], akl[4];
#pragma unroll
  for (int ks = 0; ks < 4; ks++) {
    size_t ki = climp((size_t)(keymin + l15) * KVDIM + g * HDIM + ks * 32 + l4 * 8,
                      kSz, 8);
    akh[ks] = *reinterpret_cast<const bf16x8*>(khp + ki);
    akl[ks] = *reinterpret_cast<const bf16x8*>(klp + ki);
  }

  double acc[4];
#pragma unroll
  for (int r = 0; r < 4; r++) acc[r] = 0.0;

  for (int q0 = key0; q0 < S_LEN; q0 += 32) {
#pragma unroll
    for (int c = 0; c < 2; c++) {
      int idx = tid + c * 256;
      int r = idx >> 4, c8 = (idx & 15) * 8;
      size_t qi = climp((size_t)(q0 + r) * DMODEL + h * HDIM + c8, qSz, 8);
      *reinterpret_cast<bf16x8*>(&Qh[r * 136 + c8]) =
          *reinterpret_cast<const bf16x8*>(qhp + qi);
      *reinterpret_cast<bf16x8*>(&Ql[r * 136 + c8]) =
          *reinterpret_cast<const bf16x8*>(qlp + qi);
    }
    __syncthreads();
    if (q0 + 31 >= keymin) {
      f32x4 sf[2] = {zf, zf};
#pragma unroll
      for (int ks = 0; ks < 4; ks++)
#pragma unroll
        for (int nf = 0; nf < 2; nf++) {
          int qr = (nf * 16 + l15) * 136 + ks * 32 + l4 * 8;
          bf16x8 bqh = *reinterpret_cast<const bf16x8*>(&Qh[qr]);
          bf16x8 bql = *reinterpret_cast<const bf16x8*>(&Ql[qr]);
          sf[nf] = mfma16(akh[ks], bqh,
                   mfma16(akh[ks], bql,
                   mfma16(akl[ks], bqh, sf[nf])));
        }
#pragma unroll
      for (int nf = 0; nf < 2; nf++) {
        int q = q0 + nf * 16 + l15;
        float mq = mbuf[climp((size_t)h * S_LEN + q, mlSz, 1)];
        float rl = 1.0f / lbuf[climp((size_t)h * S_LEN + q, mlSz, 1)];
#pragma unroll
        for (int r = 0; r < 4; r++) {
          int key = keymin + (l4 << 2) + r;
          if (q >= key && q < S_LEN)
            acc[r] += (double)(__expf(sf[nf][r] * scale - mq) * rl);
        }
      }
    }
    __syncthreads();
  }
#pragma unroll
  for (int r = 0; r < 4; r++) {
    double v = acc[r];
    v += __shfl_xor(v, 1);
    v += __shfl_xor(v, 2);
    v += __shfl_xor(v, 4);
    v += __shfl_xor(v, 8);
    int key = keymin + (l4 << 2) + r;
    if (l15 == 0 && key < S_LEN)
      hh_h[(size_t)h * S_LEN + key] = (float)v;
  }
}

// ---------------- top-k + gather (k reconstructed from planes)
__global__ __launch_bounds__(512) void topk_gather(const float* __restrict__ hh_h,
                                                   const short* __restrict__ khp,
                                                   const short* __restrict__ klp,
                                                   const short* __restrict__ vb,
                                                   float* __restrict__ out_k,
                                                   float* __restrict__ out_v,
                                                   float* __restrict__ out_hh) {
  int g = blockIdx.x, t = threadIdx.x;
  __shared__ float hhg[2048];
  __shared__ float sv[2048];
  __shared__ int si[2048];
  __shared__ int st[128];
  __shared__ int keep[NKEEP];
  const size_t hhSz = (size_t)NHQ * S_LEN;
  const size_t kvSz = (size_t)S_LEN * KVDIM;
#pragma unroll
  for (int i = 0; i < 4; i++) {
    int idx = t + i * 512;
    float s = 0.25f * (hh_h[climp((size_t)(4 * g + 0) * 2048 + idx, hhSz, 1)] +
                       hh_h[climp((size_t)(4 * g + 1) * 2048 + idx, hhSz, 1)] +
                       hh_h[climp((size_t)(4 * g + 2) * 2048 + idx, hhSz, 1)] +
                       hh_h[climp((size_t)(4 * g + 3) * 2048 + idx, hhSz, 1)]);
    hhg[idx] = s;
    sv[idx] = (idx < SEL_N) ? s : -1e30f;
    si[idx] = idx;
  }
  __syncthreads();
  for (int k = 2; k <= 2048; k <<= 1) {
    for (int j = k >> 1; j > 0; j >>= 1) {
#pragma unroll
      for (int pass = 0; pass < 4; pass++) {
        int i = t + pass * 512;
        int ixj = i ^ j;
        if (ixj > i) {
          bool up = ((i & k) == 0);
          float a = sv[i], b = sv[ixj];
          int ia = si[i], ib = si[ixj];
          bool before = (a > b) || (a == b && ia < ib);
          bool doswap = up ? !before : before;
          if (doswap) { sv[i] = b; sv[ixj] = a; si[i] = ib; si[ixj] = ia; }
        }
      }
      __syncthreads();
    }
  }
  if (t < 128) st[t] = si[t];
  __syncthreads();
  for (int k = 2; k <= 128; k <<= 1) {
    for (int j = k >> 1; j > 0; j >>= 1) {
      if (t < 128) {
        int i = t, ixj = i ^ j;
        if (ixj > i) {
          bool up = ((i & k) == 0);
          int a = st[i], b = st[ixj];
          bool doswap = up ? (a > b) : (a < b);
          if (doswap) { st[i] = b; st[ixj] = a; }
        }
      }
      __syncthreads();
    }
  }
  // All 640 keep[] entries initialized by all 512 threads (R1-R6 bug fix).
  for (int i = t; i < NKEEP; i += 512)
    keep[i] = (i < 128) ? st[i] : (SEL_N + (i - 128));
  __syncthreads();
  for (int i = 0; i < 160; i++) {
    int idx = t + i * 512;
    int jj = idx >> 7, d = idx & 127;
    int src = (jj < NKEEP) ? keep[jj] : 0;
    if (src < 0) src = 0;
    if (src >= S_LEN) src = S_LEN - 1;
    size_t oi = ((size_t)g * NKEEP + jj) * HDIM + d;
    if (jj < NKEEP) {
      size_t ki = climp((size_t)src * KVDIM + g * HDIM + d, kvSz, 1);
      out_k[oi] = bf2f(khp[ki]) + bf2f(klp[ki]);
      out_v[oi] = bf2f(vb[ki]);
    }
  }
  for (int i = t; i < NKEEP; i += 512) {
    int src = keep[i];
    if (src < 0) src = 0;
    if (src >= 2048) src = 2047;
    out_hh[(size_t)g * NKEEP + i] = hhg[src];
  }
}

extern "C" void kernel_launch(void* const* d_in, const int* in_sizes, int n_in,
                              void* d_out, int out_size, void* d_ws, size_t ws_size,
                              hipStream_t stream) {
  const float* x = (const float*)d_in[0];
  const float* Wq = (const float*)d_in[1];
  const float* Wk = (const float*)d_in[2];
  const float* Wv = (const float*)d_in[3];
  const float* Wo = (const float*)d_in[4];
  const float* cosb = (const float*)d_in[5];
  const float* sinb = (const float*)d_in[6];
  const int* pos = (const int*)d_in[7];

  char* ws = (char*)d_ws;
  size_t off = 0;
  auto alloc = [&](size_t bytes) {
    void* p = ws + off;
    off += (bytes + 255) & ~(size_t)255;
    return p;
  };
  short* Rg = (short*)alloc((size_t)64 * 1024 * 1024);          // 64 MB
  short* qh = (short*)alloc((size_t)S_LEN * DMODEL * 2);        // 16 MB
  short* ql = (short*)alloc((size_t)S_LEN * DMODEL * 2);        // 16 MB
  short* kh = (short*)alloc((size_t)S_LEN * KVDIM * 2);         // 4 MB
  short* kl = (short*)alloc((size_t)S_LEN * KVDIM * 2);         // 4 MB
  short* vbuf = (short*)alloc((size_t)S_LEN * KVDIM * 2);       // 4 MB
  short* vT = (short*)alloc((size_t)NHKV * HDIM * S_LEN * 2);   // 4 MB
  short* obuf = (short*)alloc((size_t)S_LEN * DMODEL * 2);      // 16 MB
  float* mbuf = (float*)alloc((size_t)NHQ * S_LEN * 4);
  float* lbuf = (float*)alloc((size_t)NHQ * S_LEN * 4);
  float* hh_h = (float*)alloc((size_t)NHQ * S_LEN * 4);
  if (off > ws_size) return;

  short* WqTh = Rg;
  short* WqTl = Rg + (size_t)16777216;   // +32 MB
  short* WkTh = Rg;
  short* WkTl = Rg + (size_t)4194304;    // +8 MB
  short* WvT  = Rg + (size_t)8388608;    // +16 MB
  short* WoT  = Rg + (size_t)12582912;   // +24 MB

  float* out = (float*)d_out;
  float* out_k = out + (size_t)S_LEN * DMODEL;
  float* out_v = out_k + (size_t)NHKV * NKEEP * HDIM;
  float* out_hh = out_v + (size_t)NHKV * NKEEP * HDIM;

  // x planes live in the `out` chunk of d_out (dead until O-projection writes it)
  short* xh = (short*)out;
  short* xl = xh + (size_t)S_LEN * DMODEL;

  split_x<<<(S_LEN * DMODEL / 8) / 256, 256, 0, stream>>>(x, xh, xl);
  transpose_split<<<dim3(64, 64), 256, 0, stream>>>(Wq, WqTh, WqTl, DMODEL, DMODEL);
  // Q-proj: BM=128 (weights don't cache-fit -> maximize reuse)
  gemm_hp2bt<128><<<dim3(16, 32), 256, 0, stream>>>(xh, xl, WqTh, WqTl, qh, ql, S_LEN, DMODEL, DMODEL);
  transpose_split<<<dim3(16, 64), 256, 0, stream>>>(Wk, WkTh, WkTl, DMODEL, KVDIM);
  // K-proj: BM=64 (weights L3-fit -> doubled grid wins)
  gemm_hp2bt<64><<<dim3(32, 8), 256, 0, stream>>>(xh, xl, WkTh, WkTl, kh, kl, S_LEN, KVDIM, DMODEL);
  transpose_cvt<<<dim3(16, 64), 256, 0, stream>>>(Wv, WvT, DMODEL, KVDIM);
  gemm_bt<64, 0, 1><<<dim3(32, 8), 256, 0, stream>>>(xh, WvT, vbuf, S_LEN, KVDIM, DMODEL);
  transpose_cvt<<<dim3(64, 64), 256, 0, stream>>>(Wo, WoT, DMODEL, DMODEL);
  rope_planes<32><<<(S_LEN * 32 * 64) / 256, 256, 0, stream>>>(qh, ql, cosb, sinb, pos);
  rope_planes<8><<<(S_LEN * 8 * 64) / 256, 256, 0, stream>>>(kh, kl, cosb, sinb, pos);
  vtrans_k<<<dim3(S_LEN / 8, NHKV), 128, 0, stream>>>(vbuf, vT);
  attn_fwd3<<<dim3(NHQ, 32), 256, 0, stream>>>(qh, ql, kh, kl, vT, obuf, mbuf, lbuf);
  attn_hh2<<<dim3(NHQ, 32), 256, 0, stream>>>(qh, ql, kh, kl, mbuf, lbuf, hh_h);
  // O-proj: BM=128 (Wo doesn't cache-fit)
  gemm_bt<128, 0, 0><<<dim3(16, 32), 256, 0, stream>>>(obuf, WoT, out, S_LEN, DMODEL, DMODEL);
  topk_gather<<<NHKV, 512, 0, stream>>>(hh_h, kh, kl, vbuf, out_k, out_v, out_hh);
}

// Round 16
// 874.359 us; speedup vs baseline: 2.8992x; 1.1212x over previous
//
#include <hip/hip_runtime.h>
#include <cstdint>
#include <cstddef>

typedef __attribute__((ext_vector_type(8))) short bf16x8;
typedef __attribute__((ext_vector_type(4))) short short4v;
typedef __attribute__((ext_vector_type(4))) float f32x4;

#define S_LEN 2048
#define DMODEL 4096
#define NHQ 32
#define NHKV 8
#define HDIM 128
#define KVDIM 1024
#define NKEEP 640
#define SEL_N 1536

__device__ __forceinline__ short f2bf(float f) {
  unsigned u = __float_as_uint(f);
  u += 0x7fffu + ((u >> 16) & 1u);
  return (short)(u >> 16);
}
__device__ __forceinline__ float bf2f(short s) {
  return __uint_as_float(((unsigned)(unsigned short)s) << 16);
}
// split-2, round-to-nearest hi plane: h = rne16(x), l = rne16(x - h). err <= 2^-17|x|
__device__ __forceinline__ void split2r(float x, short& h, short& l) {
  short hh = f2bf(x);
  float r = x - bf2f(hh);
  h = hh;
  l = f2bf(r);
}
__device__ __forceinline__ f32x4 mfma16(bf16x8 a, bf16x8 b, f32x4 c) {
  return __builtin_amdgcn_mfma_f32_16x16x32_bf16(a, b, c, 0, 0, 0);
}
__device__ __forceinline__ size_t climp(size_t i, size_t sz, size_t w) {
  size_t hi = sz - w;
  return i <= hi ? i : hi;
}

// ---------------- split_x: x f32 -> hi/lo bf16 planes
__global__ __launch_bounds__(256) void split_x(const float* __restrict__ x,
                                               short* __restrict__ xh,
                                               short* __restrict__ xl) {
  size_t i = ((size_t)blockIdx.x * 256 + threadIdx.x) * 8;
  if (i + 8 > (size_t)S_LEN * DMODEL) return;
  const float* p = x + i;
  float4 v0 = *reinterpret_cast<const float4*>(p);
  float4 v1 = *reinterpret_cast<const float4*>(p + 4);
  float vv[8] = {v0.x, v0.y, v0.z, v0.w, v1.x, v1.y, v1.z, v1.w};
  bf16x8 sh, sl;
#pragma unroll
  for (int t = 0; t < 8; t++) { short a, b; split2r(vv[t], a, b); sh[t] = a; sl[t] = b; }
  *reinterpret_cast<bf16x8*>(xh + i) = sh;
  *reinterpret_cast<bf16x8*>(xl + i) = sl;
}

// ---------------- transpose+convert: W (Kd,N) f32 -> Wt (N,Kd) bf16
__global__ __launch_bounds__(256) void transpose_cvt(const float* __restrict__ W,
                                                     short* __restrict__ Wt,
                                                     int Kd, int N) {
  __shared__ float tile[64][65];
  int tx = threadIdx.x;
  int n0 = blockIdx.x * 64;
  int k0 = blockIdx.y * 64;
#pragma unroll
  for (int i = 0; i < 4; i++) {
    int idx = tx + i * 256;
    int r = idx >> 4, c4 = (idx & 15) * 4;
    float4 v = *reinterpret_cast<const float4*>(W + (size_t)(k0 + r) * N + n0 + c4);
    tile[r][c4 + 0] = v.x;
    tile[r][c4 + 1] = v.y;
    tile[r][c4 + 2] = v.z;
    tile[r][c4 + 3] = v.w;
  }
  __syncthreads();
#pragma unroll
  for (int i = 0; i < 4; i++) {
    int idx = tx + i * 256;
    int rn = idx >> 4, c4 = (idx & 15) * 4;
    short4v o;
#pragma unroll
    for (int j = 0; j < 4; j++) o[j] = f2bf(tile[c4 + j][rn]);
    *reinterpret_cast<short4v*>(Wt + (size_t)(n0 + rn) * Kd + k0 + c4) = o;
  }
}

// ---------------- transpose+split: W (Kd,N) f32 -> hi/lo bf16 planes (N,Kd)
__global__ __launch_bounds__(256) void transpose_split(const float* __restrict__ W,
                                                       short* __restrict__ Wth,
                                                       short* __restrict__ Wtl,
                                                       int Kd, int N) {
  __shared__ float tile[64][65];
  int tx = threadIdx.x;
  int n0 = blockIdx.x * 64;
  int k0 = blockIdx.y * 64;
#pragma unroll
  for (int i = 0; i < 4; i++) {
    int idx = tx + i * 256;
    int r = idx >> 4, c4 = (idx & 15) * 4;
    float4 v = *reinterpret_cast<const float4*>(W + (size_t)(k0 + r) * N + n0 + c4);
    tile[r][c4 + 0] = v.x;
    tile[r][c4 + 1] = v.y;
    tile[r][c4 + 2] = v.z;
    tile[r][c4 + 3] = v.w;
  }
  __syncthreads();
#pragma unroll
  for (int i = 0; i < 4; i++) {
    int idx = tx + i * 256;
    int rn = idx >> 4, c4 = (idx & 15) * 4;
    short4v oh, ol;
#pragma unroll
    for (int j = 0; j < 4; j++) {
      short a, b;
      split2r(tile[c4 + j][rn], a, b);
      oh[j] = a; ol[j] = b;
    }
    size_t wi = (size_t)(n0 + rn) * Kd + k0 + c4;
    *reinterpret_cast<short4v*>(Wth + wi) = oh;
    *reinterpret_cast<short4v*>(Wtl + wi) = ol;
  }
}

// ---------------- gemm_hp2bt<BM>: C planes = A planes[M,Kd] * B^T planes[N,Kd]
template <int BM>
__global__ __launch_bounds__(256, (BM == 128) ? 3 : 4)
void gemm_hp2bt(const short* __restrict__ Ath,
                const short* __restrict__ Atl,
                const short* __restrict__ Bth,
                const short* __restrict__ Btl,
                short* __restrict__ Ch,
                short* __restrict__ Cl,
                int M, int N, int Kd) {
  constexpr int MF = BM / 32;
  __shared__ alignas(16) short Ah[BM * 40];
  __shared__ alignas(16) short Alo[BM * 40];
  __shared__ alignas(16) short Bh[128 * 40];
  __shared__ alignas(16) short Bl[128 * 40];
  int tid = threadIdx.x;
  int lane = tid & 63, wave = tid >> 6;
  int l15 = lane & 15, l4 = lane >> 4;
  int m0 = blockIdx.x * BM, n0 = blockIdx.y * 128;
  int wm = (wave >> 1) * (BM / 2), wn = (wave & 1) * 64;
  f32x4 zf = {0.f, 0.f, 0.f, 0.f};
  f32x4 acc[MF][4];
#pragma unroll
  for (int i = 0; i < MF; i++)
#pragma unroll
    for (int j = 0; j < 4; j++) acc[i][j] = zf;

  for (int k0 = 0; k0 < Kd; k0 += 32) {
#pragma unroll
    for (int c = 0; c < BM / 64; c++) {
      int idx = tid + c * 256;
      int r = idx >> 2, c8 = (idx & 3) * 8;
      size_t ai = (size_t)(m0 + r) * Kd + k0 + c8;
      *reinterpret_cast<bf16x8*>(&Ah[r * 40 + c8]) =
          *reinterpret_cast<const bf16x8*>(Ath + ai);
      *reinterpret_cast<bf16x8*>(&Alo[r * 40 + c8]) =
          *reinterpret_cast<const bf16x8*>(Atl + ai);
    }
#pragma unroll
    for (int c = 0; c < 2; c++) {
      int idx = tid + c * 256;
      int r = idx >> 2, c8 = (idx & 3) * 8;
      size_t bi = (size_t)(n0 + r) * Kd + k0 + c8;
      *reinterpret_cast<bf16x8*>(&Bh[r * 40 + c8]) =
          *reinterpret_cast<const bf16x8*>(Bth + bi);
      *reinterpret_cast<bf16x8*>(&Bl[r * 40 + c8]) =
          *reinterpret_cast<const bf16x8*>(Btl + bi);
    }
    __syncthreads();
    bf16x8 ah[MF], al[MF], bh4[4], bl4[4];
#pragma unroll
    for (int mf = 0; mf < MF; mf++) {
      int ar = (wm + mf * 16 + l15) * 40 + l4 * 8;
      ah[mf] = *reinterpret_cast<const bf16x8*>(&Ah[ar]);
      al[mf] = *reinterpret_cast<const bf16x8*>(&Alo[ar]);
    }
#pragma unroll
    for (int nf = 0; nf < 4; nf++) {
      int br = (wn + nf * 16 + l15) * 40 + l4 * 8;
      bh4[nf] = *reinterpret_cast<const bf16x8*>(&Bh[br]);
      bl4[nf] = *reinterpret_cast<const bf16x8*>(&Bl[br]);
    }
#pragma unroll
    for (int mf = 0; mf < MF; mf++)
#pragma unroll
      for (int nf = 0; nf < 4; nf++)
        acc[mf][nf] = mfma16(ah[mf], bh4[nf],
                      mfma16(al[mf], bh4[nf],
                      mfma16(ah[mf], bl4[nf], acc[mf][nf])));
    __syncthreads();
  }
  int rbase = m0 + wm + (l4 << 2);
  int cbase = n0 + wn + l15;
#pragma unroll
  for (int mf = 0; mf < MF; mf++)
#pragma unroll
    for (int nf = 0; nf < 4; nf++)
#pragma unroll
      for (int r = 0; r < 4; r++) {
        int row = rbase + mf * 16 + r;
        int col = cbase + nf * 16;
        if (row < M && col < N) {
          size_t ci = (size_t)row * N + col;
          short h, l;
          split2r(acc[mf][nf][r], h, l);
          Ch[ci] = h;
          Cl[ci] = l;
        }
      }
}

// ---------------- gemm_bt<BM>: plain bf16 GEMM with B^T (N,Kd) bf16 input
template <int BM, int A_F32, int STORE_BF16>
__global__ __launch_bounds__(256, (BM == 128) ? 3 : 4)
void gemm_bt(const void* __restrict__ Av,
             const short* __restrict__ Bt,
             void* __restrict__ Cv,
             int M, int N, int Kd) {
  constexpr int MF = BM / 32;
  __shared__ alignas(16) short Al[BM * 72];
  __shared__ alignas(16) short Bl[128 * 72];
  int tid = threadIdx.x;
  int lane = tid & 63, wave = tid >> 6;
  int l15 = lane & 15, l4 = lane >> 4;
  int m0 = blockIdx.x * BM, n0 = blockIdx.y * 128;
  int wm = (wave >> 1) * (BM / 2), wn = (wave & 1) * 64;
  f32x4 zf = {0.f, 0.f, 0.f, 0.f};
  f32x4 acc[MF][4];
#pragma unroll
  for (int i = 0; i < MF; i++)
#pragma unroll
    for (int j = 0; j < 4; j++) acc[i][j] = zf;

  for (int k0 = 0; k0 < Kd; k0 += 64) {
#pragma unroll
    for (int c = 0; c < BM / 32; c++) {
      int idx = tid + c * 256;
      int r = idx >> 3, k8 = (idx & 7) * 8;
      bf16x8 a;
      if constexpr (A_F32 != 0) {
        const float* Ap = (const float*)Av + (size_t)(m0 + r) * Kd + k0 + k8;
        float4 v0 = *reinterpret_cast<const float4*>(Ap);
        float4 v1 = *reinterpret_cast<const float4*>(Ap + 4);
        a[0] = f2bf(v0.x); a[1] = f2bf(v0.y); a[2] = f2bf(v0.z); a[3] = f2bf(v0.w);
        a[4] = f2bf(v1.x); a[5] = f2bf(v1.y); a[6] = f2bf(v1.z); a[7] = f2bf(v1.w);
      } else {
        a = *reinterpret_cast<const bf16x8*>((const short*)Av + (size_t)(m0 + r) * Kd + k0 + k8);
      }
      *reinterpret_cast<bf16x8*>(&Al[r * 72 + k8]) = a;
    }
#pragma unroll
    for (int c = 0; c < 4; c++) {
      int idx = tid + c * 256;
      int r = idx >> 3, k8 = (idx & 7) * 8;
      *reinterpret_cast<bf16x8*>(&Bl[r * 72 + k8]) =
          *reinterpret_cast<const bf16x8*>(Bt + (size_t)(n0 + r) * Kd + k0 + k8);
    }
    __syncthreads();
    bf16x8 af[MF][2], bfr[4][2];
#pragma unroll
    for (int mf = 0; mf < MF; mf++)
#pragma unroll
      for (int ks = 0; ks < 2; ks++)
        af[mf][ks] = *reinterpret_cast<const bf16x8*>(
            &Al[(wm + mf * 16 + l15) * 72 + ks * 32 + l4 * 8]);
#pragma unroll
    for (int nf = 0; nf < 4; nf++)
#pragma unroll
      for (int ks = 0; ks < 2; ks++)
        bfr[nf][ks] = *reinterpret_cast<const bf16x8*>(
            &Bl[(wn + nf * 16 + l15) * 72 + ks * 32 + l4 * 8]);
#pragma unroll
    for (int ks = 0; ks < 2; ks++)
#pragma unroll
      for (int mf = 0; mf < MF; mf++)
#pragma unroll
        for (int nf = 0; nf < 4; nf++)
          acc[mf][nf] = mfma16(af[mf][ks], bfr[nf][ks], acc[mf][nf]);
    __syncthreads();
  }
  int rbase = m0 + wm + (l4 << 2);
  int cbase = n0 + wn + l15;
#pragma unroll
  for (int mf = 0; mf < MF; mf++)
#pragma unroll
    for (int nf = 0; nf < 4; nf++)
#pragma unroll
      for (int r = 0; r < 4; r++) {
        int row = rbase + mf * 16 + r;
        int col = cbase + nf * 16;
        if (row < M && col < N) {
          size_t ci = (size_t)row * N + col;
          float v = acc[mf][nf][r];
          if constexpr (STORE_BF16 != 0)
            ((short*)Cv)[ci] = f2bf(v);
          else
            ((float*)Cv)[ci] = v;
        }
      }
}

// ---------------- RoPE in-place on split planes (s, NH*128)
template <int NH>
__global__ __launch_bounds__(256) void rope_planes(short* __restrict__ bh,
                                                   short* __restrict__ bl,
                                                   const float* __restrict__ cosb,
                                                   const float* __restrict__ sinb,
                                                   const int* __restrict__ pos) {
  int idx = blockIdx.x * 256 + threadIdx.x;
  if (idx >= S_LEN * NH * 64) return;
  int d = idx & 63;
  int h = (idx >> 6) % NH;
  int s = idx / (64 * NH);
  int p = pos[s];
  if (p < 0) p = 0;
  if (p >= S_LEN) p = S_LEN - 1;
  size_t base = ((size_t)s * NH + h) * 128 + d;
  float lo = bf2f(bh[base]) + bf2f(bl[base]);
  float hi = bf2f(bh[base + 64]) + bf2f(bl[base + 64]);
  float c0 = cosb[p * 128 + d], s0 = sinb[p * 128 + d];
  float c1 = cosb[p * 128 + d + 64], s1 = sinb[p * 128 + d + 64];
  float o0 = lo * c0 - hi * s0;
  float o1 = hi * c1 + lo * s1;
  short a, b;
  split2r(o0, a, b);
  bh[base] = a; bl[base] = b;
  split2r(o1, a, b);
  bh[base + 64] = a; bl[base + 64] = b;
}

// ---------------- V transpose: (s, g, d) -> (g, d, s) bf16
__global__ __launch_bounds__(128) void vtrans_k(const short* __restrict__ v,
                                                short* __restrict__ vT) {
  int g = blockIdx.y;
  int s0 = blockIdx.x * 8;
  int d = threadIdx.x;
  if (s0 + 7 >= S_LEN || g >= NHKV || d >= HDIM) return;
  const size_t vSz = (size_t)S_LEN * KVDIM;
  bf16x8 vals;
#pragma unroll
  for (int i = 0; i < 8; i++)
    vals[i] = v[climp((size_t)(s0 + i) * KVDIM + g * HDIM + d, vSz, 1)];
  *reinterpret_cast<bf16x8*>(vT + climp(((size_t)g * HDIM + d) * S_LEN + s0,
                                        (size_t)NHKV * HDIM * S_LEN, 8)) = vals;
}

// ---------------- attn_fwd3: FUSED, QBLK=64, K-TILE=64 (halved iteration count).
__global__ __launch_bounds__(256, 2) void attn_fwd3(const short* __restrict__ qhp,
                                                    const short* __restrict__ qlp,
                                                    const short* __restrict__ khp,
                                                    const short* __restrict__ klp,
                                                    const short* __restrict__ vT,
                                                    short* __restrict__ ob,
                                                    float* __restrict__ mbuf,
                                                    float* __restrict__ lbuf) {
  int h = blockIdx.x;
  int z = blockIdx.y;
  int qt = (z < 16) ? z : (47 - z);
  int g = h >> 2;
  int q0 = qt * 64;
  int tid = threadIdx.x, lane = tid & 63, wave = tid >> 6;
  int l15 = lane & 15, l4 = lane >> 4;
  __shared__ alignas(16) short Kh[64 * 136];
  __shared__ alignas(16) short Kl2[64 * 136];
  __shared__ alignas(16) short Vl[128 * 72];
  __shared__ alignas(16) short Pl[4][16 * 72];
  const size_t qSz = (size_t)S_LEN * DMODEL;
  const size_t kSz = (size_t)S_LEN * KVDIM;
  const size_t vtSz = (size_t)NHKV * HDIM * S_LEN;

  int qrow_base = q0 + wave * 16;
  bf16x8 qh[4], ql[4];
#pragma unroll
  for (int ks = 0; ks < 4; ks++) {
    size_t qi = climp((size_t)(qrow_base + l15) * DMODEL + h * HDIM + ks * 32 + l4 * 8,
                      qSz, 8);
    qh[ks] = *reinterpret_cast<const bf16x8*>(qhp + qi);
    ql[ks] = *reinterpret_cast<const bf16x8*>(qlp + qi);
  }

  f32x4 zf = {0.f, 0.f, 0.f, 0.f};
  f32x4 accO[8];
  float mrow[4], lrow[4];
#pragma unroll
  for (int nfo = 0; nfo < 8; nfo++) accO[nfo] = zf;
#pragma unroll
  for (int r = 0; r < 4; r++) { mrow[r] = -1e30f; lrow[r] = 0.f; }
  int nkt = qt + 1;  // 64-key tiles
  const float scale = 0.08838834764831845f;

  for (int kt = 0; kt < nkt; kt++) {
    int k0 = kt * 64;
    // stage K 64x128, two planes (4 vec8/thread each)
#pragma unroll
    for (int c = 0; c < 4; c++) {
      int idx = tid + c * 256;
      int r = idx >> 4, c8 = (idx & 15) * 8;
      size_t ki = climp((size_t)(k0 + r) * KVDIM + g * HDIM + c8, kSz, 8);
      *reinterpret_cast<bf16x8*>(&Kh[r * 136 + c8]) =
          *reinterpret_cast<const bf16x8*>(khp + ki);
      *reinterpret_cast<bf16x8*>(&Kl2[r * 136 + c8]) =
          *reinterpret_cast<const bf16x8*>(klp + ki);
    }
    // stage V^T 128d x 64s (4 vec8/thread)
#pragma unroll
    for (int c = 0; c < 4; c++) {
      int idx = tid + c * 256;
      int r = idx >> 3, c8 = (idx & 7) * 8;
      *reinterpret_cast<bf16x8*>(&Vl[r * 72 + c8]) =
          *reinterpret_cast<const bf16x8*>(
              vT + climp(((size_t)g * HDIM + r) * S_LEN + k0 + c8, vtSz, 8));
    }
    __syncthreads();
    {
      f32x4 sf[4] = {zf, zf, zf, zf};
#pragma unroll
      for (int ks = 0; ks < 4; ks++)
#pragma unroll
        for (int nf = 0; nf < 4; nf++) {
          int kr = (nf * 16 + l15) * 136 + ks * 32 + l4 * 8;
          bf16x8 bh = *reinterpret_cast<const bf16x8*>(&Kh[kr]);
          bf16x8 bl = *reinterpret_cast<const bf16x8*>(&Kl2[kr]);
          sf[nf] = mfma16(qh[ks], bh,
                   mfma16(ql[ks], bh,
                   mfma16(qh[ks], bl, sf[nf])));
        }
      float p[4][4];
#pragma unroll
      for (int r = 0; r < 4; r++) {
        int qg = qrow_base + (l4 << 2) + r;
        float v[4];
#pragma unroll
        for (int nf = 0; nf < 4; nf++) {
          v[nf] = sf[nf][r] * scale;
          if (k0 + nf * 16 + l15 > qg) v[nf] = -1e9f;
        }
        float mx = fmaxf(fmaxf(v[0], v[1]), fmaxf(v[2], v[3]));
        mx = fmaxf(mx, __shfl_xor(mx, 1));
        mx = fmaxf(mx, __shfl_xor(mx, 2));
        mx = fmaxf(mx, __shfl_xor(mx, 4));
        mx = fmaxf(mx, __shfl_xor(mx, 8));
        float mnew = fmaxf(mrow[r], mx);
        float alpha = __expf(mrow[r] - mnew);
        float p0 = __expf(v[0] - mnew);
        float p1 = __expf(v[1] - mnew);
        float p2 = __expf(v[2] - mnew);
        float p3 = __expf(v[3] - mnew);
        float rs = (p0 + p1) + (p2 + p3);
        rs += __shfl_xor(rs, 1);
        rs += __shfl_xor(rs, 2);
        rs += __shfl_xor(rs, 4);
        rs += __shfl_xor(rs, 8);
        lrow[r] = lrow[r] * alpha + rs;
        mrow[r] = mnew;
#pragma unroll
        for (int nfo = 0; nfo < 8; nfo++) accO[nfo][r] *= alpha;
        p[0][r] = p0; p[1][r] = p1; p[2][r] = p2; p[3][r] = p3;
      }
#pragma unroll
      for (int nf = 0; nf < 4; nf++)
#pragma unroll
        for (int r = 0; r < 4; r++)
          Pl[wave][((l4 << 2) + r) * 72 + nf * 16 + l15] = f2bf(p[nf][r]);
      bf16x8 pa[2];
      pa[0] = *reinterpret_cast<const bf16x8*>(&Pl[wave][l15 * 72 + l4 * 8]);
      pa[1] = *reinterpret_cast<const bf16x8*>(&Pl[wave][l15 * 72 + 32 + l4 * 8]);
#pragma unroll
      for (int nfo = 0; nfo < 8; nfo++) {
        bf16x8 bv0 = *reinterpret_cast<const bf16x8*>(&Vl[(nfo * 16 + l15) * 72 + l4 * 8]);
        bf16x8 bv1 = *reinterpret_cast<const bf16x8*>(&Vl[(nfo * 16 + l15) * 72 + 32 + l4 * 8]);
        accO[nfo] = mfma16(pa[1], bv1, mfma16(pa[0], bv0, accO[nfo]));
      }
    }
    __syncthreads();
  }
  float inv[4];
#pragma unroll
  for (int r = 0; r < 4; r++) inv[r] = 1.0f / lrow[r];
#pragma unroll
  for (int nfo = 0; nfo < 8; nfo++)
#pragma unroll
    for (int r = 0; r < 4; r++) {
      int row = qrow_base + (l4 << 2) + r;
      int col = h * HDIM + nfo * 16 + l15;
      if (row < S_LEN && col < DMODEL)
        ob[(size_t)row * DMODEL + col] = f2bf(accO[nfo][r] * inv[r]);
    }
  if (l15 == 0) {
#pragma unroll
    for (int r = 0; r < 4; r++) {
      int row = qrow_base + (l4 << 2) + r;
      if (row < S_LEN) {
        mbuf[(size_t)h * S_LEN + row] = mrow[r];
        lbuf[(size_t)h * S_LEN + row] = lrow[r];
      }
    }
  }
}

// ---------------- attn_hh2: column sums, KBLK=64, Q-TILE=64 (halved iterations).
__global__ __launch_bounds__(256, 4) void attn_hh2(const short* __restrict__ qhp,
                                                   const short* __restrict__ qlp,
                                                   const short* __restrict__ khp,
                                                   const short* __restrict__ klp,
                                                   const float* __restrict__ mbuf,
                                                   const float* __restrict__ lbuf,
                                                   float* __restrict__ hh_h) {
  int h = blockIdx.x;
  int z = blockIdx.y;
  int kt = (z < 16) ? z : (47 - z);
  int g = h >> 2;
  int key0 = kt * 64;
  int tid = threadIdx.x, lane = tid & 63, wave = tid >> 6;
  int l15 = lane & 15, l4 = lane >> 4;
  __shared__ alignas(16) short Qh[64 * 136];
  __shared__ alignas(16) short Ql[64 * 136];
  const size_t qSz = (size_t)S_LEN * DMODEL;
  const size_t kSz = (size_t)S_LEN * KVDIM;
  const size_t mlSz = (size_t)NHQ * S_LEN;
  const float scale = 0.08838834764831845f;
  f32x4 zf = {0.f, 0.f, 0.f, 0.f};

  int keymin = key0 + wave * 16;
  bf16x8 akh[4], akl[4];
#pragma unroll
  for (int ks = 0; ks < 4; ks++) {
    size_t ki = climp((size_t)(keymin + l15) * KVDIM + g * HDIM + ks * 32 + l4 * 8,
                      kSz, 8);
    akh[ks] = *reinterpret_cast<const bf16x8*>(khp + ki);
    akl[ks] = *reinterpret_cast<const bf16x8*>(klp + ki);
  }

  double acc[4];
#pragma unroll
  for (int r = 0; r < 4; r++) acc[r] = 0.0;

  for (int q0 = key0; q0 < S_LEN; q0 += 64) {
    // stage Q 64x128, two planes (4 vec8/thread each)
#pragma unroll
    for (int c = 0; c < 4; c++) {
      int idx = tid + c * 256;
      int r = idx >> 4, c8 = (idx & 15) * 8;
      size_t qi = climp((size_t)(q0 + r) * DMODEL + h * HDIM + c8, qSz, 8);
      *reinterpret_cast<bf16x8*>(&Qh[r * 136 + c8]) =
          *reinterpret_cast<const bf16x8*>(qhp + qi);
      *reinterpret_cast<bf16x8*>(&Ql[r * 136 + c8]) =
          *reinterpret_cast<const bf16x8*>(qlp + qi);
    }
    __syncthreads();
    if (q0 + 63 >= keymin) {
      f32x4 sf[4] = {zf, zf, zf, zf};
#pragma unroll
      for (int ks = 0; ks < 4; ks++)
#pragma unroll
        for (int nf = 0; nf < 4; nf++) {
          int qr = (nf * 16 + l15) * 136 + ks * 32 + l4 * 8;
          bf16x8 bqh = *reinterpret_cast<const bf16x8*>(&Qh[qr]);
          bf16x8 bql = *reinterpret_cast<const bf16x8*>(&Ql[qr]);
          sf[nf] = mfma16(akh[ks], bqh,
                   mfma16(akh[ks], bql,
                   mfma16(akl[ks], bqh, sf[nf])));
        }
#pragma unroll
      for (int nf = 0; nf < 4; nf++) {
        int q = q0 + nf * 16 + l15;
        float mq = mbuf[climp((size_t)h * S_LEN + q, mlSz, 1)];
        float rl = 1.0f / lbuf[climp((size_t)h * S_LEN + q, mlSz, 1)];
#pragma unroll
        for (int r = 0; r < 4; r++) {
          int key = keymin + (l4 << 2) + r;
          if (q >= key && q < S_LEN)
            acc[r] += (double)(__expf(sf[nf][r] * scale - mq) * rl);
        }
      }
    }
    __syncthreads();
  }
#pragma unroll
  for (int r = 0; r < 4; r++) {
    double v = acc[r];
    v += __shfl_xor(v, 1);
    v += __shfl_xor(v, 2);
    v += __shfl_xor(v, 4);
    v += __shfl_xor(v, 8);
    int key = keymin + (l4 << 2) + r;
    if (l15 == 0 && key < S_LEN)
      hh_h[(size_t)h * S_LEN + key] = (float)v;
  }
}

// ---------------- top-k + gather (k reconstructed from planes)
__global__ __launch_bounds__(512) void topk_gather(const float* __restrict__ hh_h,
                                                   const short* __restrict__ khp,
                                                   const short* __restrict__ klp,
                                                   const short* __restrict__ vb,
                                                   float* __restrict__ out_k,
                                                   float* __restrict__ out_v,
                                                   float* __restrict__ out_hh) {
  int g = blockIdx.x, t = threadIdx.x;
  __shared__ float hhg[2048];
  __shared__ float sv[2048];
  __shared__ int si[2048];
  __shared__ int st[128];
  __shared__ int keep[NKEEP];
  const size_t hhSz = (size_t)NHQ * S_LEN;
  const size_t kvSz = (size_t)S_LEN * KVDIM;
#pragma unroll
  for (int i = 0; i < 4; i++) {
    int idx = t + i * 512;
    float s = 0.25f * (hh_h[climp((size_t)(4 * g + 0) * 2048 + idx, hhSz, 1)] +
                       hh_h[climp((size_t)(4 * g + 1) * 2048 + idx, hhSz, 1)] +
                       hh_h[climp((size_t)(4 * g + 2) * 2048 + idx, hhSz, 1)] +
                       hh_h[climp((size_t)(4 * g + 3) * 2048 + idx, hhSz, 1)]);
    hhg[idx] = s;
    sv[idx] = (idx < SEL_N) ? s : -1e30f;
    si[idx] = idx;
  }
  __syncthreads();
  for (int k = 2; k <= 2048; k <<= 1) {
    for (int j = k >> 1; j > 0; j >>= 1) {
#pragma unroll
      for (int pass = 0; pass < 4; pass++) {
        int i = t + pass * 512;
        int ixj = i ^ j;
        if (ixj > i) {
          bool up = ((i & k) == 0);
          float a = sv[i], b = sv[ixj];
          int ia = si[i], ib = si[ixj];
          bool before = (a > b) || (a == b && ia < ib);
          bool doswap = up ? !before : before;
          if (doswap) { sv[i] = b; sv[ixj] = a; si[i] = ib; si[ixj] = ia; }
        }
      }
      __syncthreads();
    }
  }
  if (t < 128) st[t] = si[t];
  __syncthreads();
  for (int k = 2; k <= 128; k <<= 1) {
    for (int j = k >> 1; j > 0; j >>= 1) {
      if (t < 128) {
        int i = t, ixj = i ^ j;
        if (ixj > i) {
          bool up = ((i & k) == 0);
          int a = st[i], b = st[ixj];
          bool doswap = up ? (a > b) : (a < b);
          if (doswap) { st[i] = b; st[ixj] = a; }
        }
      }
      __syncthreads();
    }
  }
  // All 640 keep[] entries initialized by all 512 threads (R1-R6 bug fix).
  for (int i = t; i < NKEEP; i += 512)
    keep[i] = (i < 128) ? st[i] : (SEL_N + (i - 128));
  __syncthreads();
  for (int i = 0; i < 160; i++) {
    int idx = t + i * 512;
    int jj = idx >> 7, d = idx & 127;
    int src = (jj < NKEEP) ? keep[jj] : 0;
    if (src < 0) src = 0;
    if (src >= S_LEN) src = S_LEN - 1;
    size_t oi = ((size_t)g * NKEEP + jj) * HDIM + d;
    if (jj < NKEEP) {
      size_t ki = climp((size_t)src * KVDIM + g * HDIM + d, kvSz, 1);
      out_k[oi] = bf2f(khp[ki]) + bf2f(klp[ki]);
      out_v[oi] = bf2f(vb[ki]);
    }
  }
  for (int i = t; i < NKEEP; i += 512) {
    int src = keep[i];
    if (src < 0) src = 0;
    if (src >= 2048) src = 2047;
    out_hh[(size_t)g * NKEEP + i] = hhg[src];
  }
}

extern "C" void kernel_launch(void* const* d_in, const int* in_sizes, int n_in,
                              void* d_out, int out_size, void* d_ws, size_t ws_size,
                              hipStream_t stream) {
  const float* x = (const float*)d_in[0];
  const float* Wq = (const float*)d_in[1];
  const float* Wk = (const float*)d_in[2];
  const float* Wv = (const float*)d_in[3];
  const float* Wo = (const float*)d_in[4];
  const float* cosb = (const float*)d_in[5];
  const float* sinb = (const float*)d_in[6];
  const int* pos = (const int*)d_in[7];

  char* ws = (char*)d_ws;
  size_t off = 0;
  auto alloc = [&](size_t bytes) {
    void* p = ws + off;
    off += (bytes + 255) & ~(size_t)255;
    return p;
  };
  short* Rg = (short*)alloc((size_t)64 * 1024 * 1024);          // 64 MB
  short* qh = (short*)alloc((size_t)S_LEN * DMODEL * 2);        // 16 MB
  short* ql = (short*)alloc((size_t)S_LEN * DMODEL * 2);        // 16 MB
  short* kh = (short*)alloc((size_t)S_LEN * KVDIM * 2);         // 4 MB
  short* kl = (short*)alloc((size_t)S_LEN * KVDIM * 2);         // 4 MB
  short* vbuf = (short*)alloc((size_t)S_LEN * KVDIM * 2);       // 4 MB
  short* vT = (short*)alloc((size_t)NHKV * HDIM * S_LEN * 2);   // 4 MB
  short* obuf = (short*)alloc((size_t)S_LEN * DMODEL * 2);      // 16 MB
  float* mbuf = (float*)alloc((size_t)NHQ * S_LEN * 4);
  float* lbuf = (float*)alloc((size_t)NHQ * S_LEN * 4);
  float* hh_h = (float*)alloc((size_t)NHQ * S_LEN * 4);
  if (off > ws_size) return;

  short* WqTh = Rg;
  short* WqTl = Rg + (size_t)16777216;   // +32 MB
  short* WkTh = Rg;
  short* WkTl = Rg + (size_t)4194304;    // +8 MB
  short* WvT  = Rg + (size_t)8388608;    // +16 MB
  short* WoT  = Rg + (size_t)12582912;   // +24 MB

  float* out = (float*)d_out;
  float* out_k = out + (size_t)S_LEN * DMODEL;
  float* out_v = out_k + (size_t)NHKV * NKEEP * HDIM;
  float* out_hh = out_v + (size_t)NHKV * NKEEP * HDIM;

  // x planes live in the `out` chunk of d_out (dead until O-projection writes it)
  short* xh = (short*)out;
  short* xl = xh + (size_t)S_LEN * DMODEL;

  split_x<<<(S_LEN * DMODEL / 8) / 256, 256, 0, stream>>>(x, xh, xl);
  transpose_split<<<dim3(64, 64), 256, 0, stream>>>(Wq, WqTh, WqTl, DMODEL, DMODEL);
  gemm_hp2bt<128><<<dim3(16, 32), 256, 0, stream>>>(xh, xl, WqTh, WqTl, qh, ql, S_LEN, DMODEL, DMODEL);
  transpose_split<<<dim3(16, 64), 256, 0, stream>>>(Wk, WkTh, WkTl, DMODEL, KVDIM);
  gemm_hp2bt<64><<<dim3(32, 8), 256, 0, stream>>>(xh, xl, WkTh, WkTl, kh, kl, S_LEN, KVDIM, DMODEL);
  transpose_cvt<<<dim3(16, 64), 256, 0, stream>>>(Wv, WvT, DMODEL, KVDIM);
  gemm_bt<64, 0, 1><<<dim3(32, 8), 256, 0, stream>>>(xh, WvT, vbuf, S_LEN, KVDIM, DMODEL);
  transpose_cvt<<<dim3(64, 64), 256, 0, stream>>>(Wo, WoT, DMODEL, DMODEL);
  rope_planes<32><<<(S_LEN * 32 * 64) / 256, 256, 0, stream>>>(qh, ql, cosb, sinb, pos);
  rope_planes<8><<<(S_LEN * 8 * 64) / 256, 256, 0, stream>>>(kh, kl, cosb, sinb, pos);
  vtrans_k<<<dim3(S_LEN / 8, NHKV), 128, 0, stream>>>(vbuf, vT);
  attn_fwd3<<<dim3(NHQ, 32), 256, 0, stream>>>(qh, ql, kh, kl, vT, obuf, mbuf, lbuf);
  attn_hh2<<<dim3(NHQ, 32), 256, 0, stream>>>(qh, ql, kh, kl, mbuf, lbuf, hh_h);
  gemm_bt<128, 0, 0><<<dim3(16, 32), 256, 0, stream>>>(obuf, WoT, out, S_LEN, DMODEL, DMODEL);
  topk_gather<<<NHKV, 512, 0, stream>>>(hh_h, kh, kl, vbuf, out_k, out_v, out_hh);
}

// Round 17
// 869.684 us; speedup vs baseline: 2.9148x; 1.0054x over previous
//
#include <hip/hip_runtime.h>
#include <cstdint>
#include <cstddef>

typedef __attribute__((ext_vector_type(8))) short bf16x8;
typedef __attribute__((ext_vector_type(4))) short short4v;
typedef __attribute__((ext_vector_type(4))) float f32x4;

#define S_LEN 2048
#define DMODEL 4096
#define NHQ 32
#define NHKV 8
#define HDIM 128
#define KVDIM 1024
#define NKEEP 640
#define SEL_N 1536

__device__ __forceinline__ short f2bf(float f) {
  unsigned u = __float_as_uint(f);
  u += 0x7fffu + ((u >> 16) & 1u);
  return (short)(u >> 16);
}
__device__ __forceinline__ float bf2f(short s) {
  return __uint_as_float(((unsigned)(unsigned short)s) << 16);
}
// split-2, round-to-nearest hi plane: h = rne16(x), l = rne16(x - h). err <= 2^-17|x|
__device__ __forceinline__ void split2r(float x, short& h, short& l) {
  short hh = f2bf(x);
  float r = x - bf2f(hh);
  h = hh;
  l = f2bf(r);
}
__device__ __forceinline__ f32x4 mfma16(bf16x8 a, bf16x8 b, f32x4 c) {
  return __builtin_amdgcn_mfma_f32_16x16x32_bf16(a, b, c, 0, 0, 0);
}
__device__ __forceinline__ size_t climp(size_t i, size_t sz, size_t w) {
  size_t hi = sz - w;
  return i <= hi ? i : hi;
}

// ---------------- split_x: x f32 -> hi/lo bf16 planes
__global__ __launch_bounds__(256) void split_x(const float* __restrict__ x,
                                               short* __restrict__ xh,
                                               short* __restrict__ xl) {
  size_t i = ((size_t)blockIdx.x * 256 + threadIdx.x) * 8;
  if (i + 8 > (size_t)S_LEN * DMODEL) return;
  const float* p = x + i;
  float4 v0 = *reinterpret_cast<const float4*>(p);
  float4 v1 = *reinterpret_cast<const float4*>(p + 4);
  float vv[8] = {v0.x, v0.y, v0.z, v0.w, v1.x, v1.y, v1.z, v1.w};
  bf16x8 sh, sl;
#pragma unroll
  for (int t = 0; t < 8; t++) { short a, b; split2r(vv[t], a, b); sh[t] = a; sl[t] = b; }
  *reinterpret_cast<bf16x8*>(xh + i) = sh;
  *reinterpret_cast<bf16x8*>(xl + i) = sl;
}

// ---------------- transpose+convert: W (Kd,N) f32 -> Wt (N,Kd) bf16
__global__ __launch_bounds__(256) void transpose_cvt(const float* __restrict__ W,
                                                     short* __restrict__ Wt,
                                                     int Kd, int N) {
  __shared__ float tile[64][65];
  int tx = threadIdx.x;
  int n0 = blockIdx.x * 64;
  int k0 = blockIdx.y * 64;
#pragma unroll
  for (int i = 0; i < 4; i++) {
    int idx = tx + i * 256;
    int r = idx >> 4, c4 = (idx & 15) * 4;
    float4 v = *reinterpret_cast<const float4*>(W + (size_t)(k0 + r) * N + n0 + c4);
    tile[r][c4 + 0] = v.x;
    tile[r][c4 + 1] = v.y;
    tile[r][c4 + 2] = v.z;
    tile[r][c4 + 3] = v.w;
  }
  __syncthreads();
#pragma unroll
  for (int i = 0; i < 4; i++) {
    int idx = tx + i * 256;
    int rn = idx >> 4, c4 = (idx & 15) * 4;
    short4v o;
#pragma unroll
    for (int j = 0; j < 4; j++) o[j] = f2bf(tile[c4 + j][rn]);
    *reinterpret_cast<short4v*>(Wt + (size_t)(n0 + rn) * Kd + k0 + c4) = o;
  }
}

// ---------------- transpose+split: W (Kd,N) f32 -> hi/lo bf16 planes (N,Kd)
__global__ __launch_bounds__(256) void transpose_split(const float* __restrict__ W,
                                                       short* __restrict__ Wth,
                                                       short* __restrict__ Wtl,
                                                       int Kd, int N) {
  __shared__ float tile[64][65];
  int tx = threadIdx.x;
  int n0 = blockIdx.x * 64;
  int k0 = blockIdx.y * 64;
#pragma unroll
  for (int i = 0; i < 4; i++) {
    int idx = tx + i * 256;
    int r = idx >> 4, c4 = (idx & 15) * 4;
    float4 v = *reinterpret_cast<const float4*>(W + (size_t)(k0 + r) * N + n0 + c4);
    tile[r][c4 + 0] = v.x;
    tile[r][c4 + 1] = v.y;
    tile[r][c4 + 2] = v.z;
    tile[r][c4 + 3] = v.w;
  }
  __syncthreads();
#pragma unroll
  for (int i = 0; i < 4; i++) {
    int idx = tx + i * 256;
    int rn = idx >> 4, c4 = (idx & 15) * 4;
    short4v oh, ol;
#pragma unroll
    for (int j = 0; j < 4; j++) {
      short a, b;
      split2r(tile[c4 + j][rn], a, b);
      oh[j] = a; ol[j] = b;
    }
    size_t wi = (size_t)(n0 + rn) * Kd + k0 + c4;
    *reinterpret_cast<short4v*>(Wth + wi) = oh;
    *reinterpret_cast<short4v*>(Wtl + wi) = ol;
  }
}

// ---------------- gemm_hp2bt<BM>: C planes = A planes[M,Kd] * B^T planes[N,Kd]
template <int BM>
__global__ __launch_bounds__(256, (BM == 128) ? 3 : 4)
void gemm_hp2bt(const short* __restrict__ Ath,
                const short* __restrict__ Atl,
                const short* __restrict__ Bth,
                const short* __restrict__ Btl,
                short* __restrict__ Ch,
                short* __restrict__ Cl,
                int M, int N, int Kd) {
  constexpr int MF = BM / 32;
  __shared__ alignas(16) short Ah[BM * 40];
  __shared__ alignas(16) short Alo[BM * 40];
  __shared__ alignas(16) short Bh[128 * 40];
  __shared__ alignas(16) short Bl[128 * 40];
  int tid = threadIdx.x;
  int lane = tid & 63, wave = tid >> 6;
  int l15 = lane & 15, l4 = lane >> 4;
  int m0 = blockIdx.x * BM, n0 = blockIdx.y * 128;
  int wm = (wave >> 1) * (BM / 2), wn = (wave & 1) * 64;
  f32x4 zf = {0.f, 0.f, 0.f, 0.f};
  f32x4 acc[MF][4];
#pragma unroll
  for (int i = 0; i < MF; i++)
#pragma unroll
    for (int j = 0; j < 4; j++) acc[i][j] = zf;

  for (int k0 = 0; k0 < Kd; k0 += 32) {
#pragma unroll
    for (int c = 0; c < BM / 64; c++) {
      int idx = tid + c * 256;
      int r = idx >> 2, c8 = (idx & 3) * 8;
      size_t ai = (size_t)(m0 + r) * Kd + k0 + c8;
      *reinterpret_cast<bf16x8*>(&Ah[r * 40 + c8]) =
          *reinterpret_cast<const bf16x8*>(Ath + ai);
      *reinterpret_cast<bf16x8*>(&Alo[r * 40 + c8]) =
          *reinterpret_cast<const bf16x8*>(Atl + ai);
    }
#pragma unroll
    for (int c = 0; c < 2; c++) {
      int idx = tid + c * 256;
      int r = idx >> 2, c8 = (idx & 3) * 8;
      size_t bi = (size_t)(n0 + r) * Kd + k0 + c8;
      *reinterpret_cast<bf16x8*>(&Bh[r * 40 + c8]) =
          *reinterpret_cast<const bf16x8*>(Bth + bi);
      *reinterpret_cast<bf16x8*>(&Bl[r * 40 + c8]) =
          *reinterpret_cast<const bf16x8*>(Btl + bi);
    }
    __syncthreads();
    bf16x8 ah[MF], al[MF], bh4[4], bl4[4];
#pragma unroll
    for (int mf = 0; mf < MF; mf++) {
      int ar = (wm + mf * 16 + l15) * 40 + l4 * 8;
      ah[mf] = *reinterpret_cast<const bf16x8*>(&Ah[ar]);
      al[mf] = *reinterpret_cast<const bf16x8*>(&Alo[ar]);
    }
#pragma unroll
    for (int nf = 0; nf < 4; nf++) {
      int br = (wn + nf * 16 + l15) * 40 + l4 * 8;
      bh4[nf] = *reinterpret_cast<const bf16x8*>(&Bh[br]);
      bl4[nf] = *reinterpret_cast<const bf16x8*>(&Bl[br]);
    }
#pragma unroll
    for (int mf = 0; mf < MF; mf++)
#pragma unroll
      for (int nf = 0; nf < 4; nf++)
        acc[mf][nf] = mfma16(ah[mf], bh4[nf],
                      mfma16(al[mf], bh4[nf],
                      mfma16(ah[mf], bl4[nf], acc[mf][nf])));
    __syncthreads();
  }
  int rbase = m0 + wm + (l4 << 2);
  int cbase = n0 + wn + l15;
#pragma unroll
  for (int mf = 0; mf < MF; mf++)
#pragma unroll
    for (int nf = 0; nf < 4; nf++)
#pragma unroll
      for (int r = 0; r < 4; r++) {
        int row = rbase + mf * 16 + r;
        int col = cbase + nf * 16;
        if (row < M && col < N) {
          size_t ci = (size_t)row * N + col;
          short h, l;
          split2r(acc[mf][nf][r], h, l);
          Ch[ci] = h;
          Cl[ci] = l;
        }
      }
}

// ---------------- gemm_bt<BM>: plain bf16 GEMM with B^T (N,Kd) bf16 input
template <int BM, int A_F32, int STORE_BF16>
__global__ __launch_bounds__(256, (BM == 128) ? 3 : 4)
void gemm_bt(const void* __restrict__ Av,
             const short* __restrict__ Bt,
             void* __restrict__ Cv,
             int M, int N, int Kd) {
  constexpr int MF = BM / 32;
  __shared__ alignas(16) short Al[BM * 72];
  __shared__ alignas(16) short Bl[128 * 72];
  int tid = threadIdx.x;
  int lane = tid & 63, wave = tid >> 6;
  int l15 = lane & 15, l4 = lane >> 4;
  int m0 = blockIdx.x * BM, n0 = blockIdx.y * 128;
  int wm = (wave >> 1) * (BM / 2), wn = (wave & 1) * 64;
  f32x4 zf = {0.f, 0.f, 0.f, 0.f};
  f32x4 acc[MF][4];
#pragma unroll
  for (int i = 0; i < MF; i++)
#pragma unroll
    for (int j = 0; j < 4; j++) acc[i][j] = zf;

  for (int k0 = 0; k0 < Kd; k0 += 64) {
#pragma unroll
    for (int c = 0; c < BM / 32; c++) {
      int idx = tid + c * 256;
      int r = idx >> 3, k8 = (idx & 7) * 8;
      bf16x8 a;
      if constexpr (A_F32 != 0) {
        const float* Ap = (const float*)Av + (size_t)(m0 + r) * Kd + k0 + k8;
        float4 v0 = *reinterpret_cast<const float4*>(Ap);
        float4 v1 = *reinterpret_cast<const float4*>(Ap + 4);
        a[0] = f2bf(v0.x); a[1] = f2bf(v0.y); a[2] = f2bf(v0.z); a[3] = f2bf(v0.w);
        a[4] = f2bf(v1.x); a[5] = f2bf(v1.y); a[6] = f2bf(v1.z); a[7] = f2bf(v1.w);
      } else {
        a = *reinterpret_cast<const bf16x8*>((const short*)Av + (size_t)(m0 + r) * Kd + k0 + k8);
      }
      *reinterpret_cast<bf16x8*>(&Al[r * 72 + k8]) = a;
    }
#pragma unroll
    for (int c = 0; c < 4; c++) {
      int idx = tid + c * 256;
      int r = idx >> 3, k8 = (idx & 7) * 8;
      *reinterpret_cast<bf16x8*>(&Bl[r * 72 + k8]) =
          *reinterpret_cast<const bf16x8*>(Bt + (size_t)(n0 + r) * Kd + k0 + k8);
    }
    __syncthreads();
    bf16x8 af[MF][2], bfr[4][2];
#pragma unroll
    for (int mf = 0; mf < MF; mf++)
#pragma unroll
      for (int ks = 0; ks < 2; ks++)
        af[mf][ks] = *reinterpret_cast<const bf16x8*>(
            &Al[(wm + mf * 16 + l15) * 72 + ks * 32 + l4 * 8]);
#pragma unroll
    for (int nf = 0; nf < 4; nf++)
#pragma unroll
      for (int ks = 0; ks < 2; ks++)
        bfr[nf][ks] = *reinterpret_cast<const bf16x8*>(
            &Bl[(wn + nf * 16 + l15) * 72 + ks * 32 + l4 * 8]);
#pragma unroll
    for (int ks = 0; ks < 2; ks++)
#pragma unroll
      for (int mf = 0; mf < MF; mf++)
#pragma unroll
        for (int nf = 0; nf < 4; nf++)
          acc[mf][nf] = mfma16(af[mf][ks], bfr[nf][ks], acc[mf][nf]);
    __syncthreads();
  }
  int rbase = m0 + wm + (l4 << 2);
  int cbase = n0 + wn + l15;
#pragma unroll
  for (int mf = 0; mf < MF; mf++)
#pragma unroll
    for (int nf = 0; nf < 4; nf++)
#pragma unroll
      for (int r = 0; r < 4; r++) {
        int row = rbase + mf * 16 + r;
        int col = cbase + nf * 16;
        if (row < M && col < N) {
          size_t ci = (size_t)row * N + col;
          float v = acc[mf][nf][r];
          if constexpr (STORE_BF16 != 0)
            ((short*)Cv)[ci] = f2bf(v);
          else
            ((float*)Cv)[ci] = v;
        }
      }
}

// ---------------- RoPE in-place on split planes (s, NH*128)
template <int NH>
__global__ __launch_bounds__(256) void rope_planes(short* __restrict__ bh,
                                                   short* __restrict__ bl,
                                                   const float* __restrict__ cosb,
                                                   const float* __restrict__ sinb,
                                                   const int* __restrict__ pos) {
  int idx = blockIdx.x * 256 + threadIdx.x;
  if (idx >= S_LEN * NH * 64) return;
  int d = idx & 63;
  int h = (idx >> 6) % NH;
  int s = idx / (64 * NH);
  int p = pos[s];
  if (p < 0) p = 0;
  if (p >= S_LEN) p = S_LEN - 1;
  size_t base = ((size_t)s * NH + h) * 128 + d;
  float lo = bf2f(bh[base]) + bf2f(bl[base]);
  float hi = bf2f(bh[base + 64]) + bf2f(bl[base + 64]);
  float c0 = cosb[p * 128 + d], s0 = sinb[p * 128 + d];
  float c1 = cosb[p * 128 + d + 64], s1 = sinb[p * 128 + d + 64];
  float o0 = lo * c0 - hi * s0;
  float o1 = hi * c1 + lo * s1;
  short a, b;
  split2r(o0, a, b);
  bh[base] = a; bl[base] = b;
  split2r(o1, a, b);
  bh[base + 64] = a; bl[base + 64] = b;
}

// ---------------- V transpose: (s, g, d) -> (g, d, s) bf16
__global__ __launch_bounds__(128) void vtrans_k(const short* __restrict__ v,
                                                short* __restrict__ vT) {
  int g = blockIdx.y;
  int s0 = blockIdx.x * 8;
  int d = threadIdx.x;
  if (s0 + 7 >= S_LEN || g >= NHKV || d >= HDIM) return;
  const size_t vSz = (size_t)S_LEN * KVDIM;
  bf16x8 vals;
#pragma unroll
  for (int i = 0; i < 8; i++)
    vals[i] = v[climp((size_t)(s0 + i) * KVDIM + g * HDIM + d, vSz, 1)];
  *reinterpret_cast<bf16x8*>(vT + climp(((size_t)g * HDIM + d) * S_LEN + s0,
                                        (size_t)NHKV * HDIM * S_LEN, 8)) = vals;
}

// ---------------- attn_fwd3: FUSED, QBLK=64, K-TILE=64.
// NOTE: lbuf now stores 1/l (the inv used for O) -- hh2 consumes it directly.
__global__ __launch_bounds__(256, 2) void attn_fwd3(const short* __restrict__ qhp,
                                                    const short* __restrict__ qlp,
                                                    const short* __restrict__ khp,
                                                    const short* __restrict__ klp,
                                                    const short* __restrict__ vT,
                                                    short* __restrict__ ob,
                                                    float* __restrict__ mbuf,
                                                    float* __restrict__ lbuf) {
  int h = blockIdx.x;
  int z = blockIdx.y;
  int qt = (z < 16) ? z : (47 - z);
  int g = h >> 2;
  int q0 = qt * 64;
  int tid = threadIdx.x, lane = tid & 63, wave = tid >> 6;
  int l15 = lane & 15, l4 = lane >> 4;
  __shared__ alignas(16) short Kh[64 * 136];
  __shared__ alignas(16) short Kl2[64 * 136];
  __shared__ alignas(16) short Vl[128 * 72];
  __shared__ alignas(16) short Pl[4][16 * 72];
  const size_t qSz = (size_t)S_LEN * DMODEL;
  const size_t kSz = (size_t)S_LEN * KVDIM;
  const size_t vtSz = (size_t)NHKV * HDIM * S_LEN;

  int qrow_base = q0 + wave * 16;
  bf16x8 qh[4], ql[4];
#pragma unroll
  for (int ks = 0; ks < 4; ks++) {
    size_t qi = climp((size_t)(qrow_base + l15) * DMODEL + h * HDIM + ks * 32 + l4 * 8,
                      qSz, 8);
    qh[ks] = *reinterpret_cast<const bf16x8*>(qhp + qi);
    ql[ks] = *reinterpret_cast<const bf16x8*>(qlp + qi);
  }

  f32x4 zf = {0.f, 0.f, 0.f, 0.f};
  f32x4 accO[8];
  float mrow[4], lrow[4];
#pragma unroll
  for (int nfo = 0; nfo < 8; nfo++) accO[nfo] = zf;
#pragma unroll
  for (int r = 0; r < 4; r++) { mrow[r] = -1e30f; lrow[r] = 0.f; }
  int nkt = qt + 1;  // 64-key tiles
  const float scale = 0.08838834764831845f;

  for (int kt = 0; kt < nkt; kt++) {
    int k0 = kt * 64;
#pragma unroll
    for (int c = 0; c < 4; c++) {
      int idx = tid + c * 256;
      int r = idx >> 4, c8 = (idx & 15) * 8;
      size_t ki = climp((size_t)(k0 + r) * KVDIM + g * HDIM + c8, kSz, 8);
      *reinterpret_cast<bf16x8*>(&Kh[r * 136 + c8]) =
          *reinterpret_cast<const bf16x8*>(khp + ki);
      *reinterpret_cast<bf16x8*>(&Kl2[r * 136 + c8]) =
          *reinterpret_cast<const bf16x8*>(klp + ki);
    }
#pragma unroll
    for (int c = 0; c < 4; c++) {
      int idx = tid + c * 256;
      int r = idx >> 3, c8 = (idx & 7) * 8;
      *reinterpret_cast<bf16x8*>(&Vl[r * 72 + c8]) =
          *reinterpret_cast<const bf16x8*>(
              vT + climp(((size_t)g * HDIM + r) * S_LEN + k0 + c8, vtSz, 8));
    }
    __syncthreads();
    {
      f32x4 sf[4] = {zf, zf, zf, zf};
#pragma unroll
      for (int ks = 0; ks < 4; ks++)
#pragma unroll
        for (int nf = 0; nf < 4; nf++) {
          int kr = (nf * 16 + l15) * 136 + ks * 32 + l4 * 8;
          bf16x8 bh = *reinterpret_cast<const bf16x8*>(&Kh[kr]);
          bf16x8 bl = *reinterpret_cast<const bf16x8*>(&Kl2[kr]);
          sf[nf] = mfma16(qh[ks], bh,
                   mfma16(ql[ks], bh,
                   mfma16(qh[ks], bl, sf[nf])));
        }
      float p[4][4];
#pragma unroll
      for (int r = 0; r < 4; r++) {
        int qg = qrow_base + (l4 << 2) + r;
        float v[4];
#pragma unroll
        for (int nf = 0; nf < 4; nf++) {
          v[nf] = sf[nf][r] * scale;
          if (k0 + nf * 16 + l15 > qg) v[nf] = -1e9f;
        }
        float mx = fmaxf(fmaxf(v[0], v[1]), fmaxf(v[2], v[3]));
        mx = fmaxf(mx, __shfl_xor(mx, 1));
        mx = fmaxf(mx, __shfl_xor(mx, 2));
        mx = fmaxf(mx, __shfl_xor(mx, 4));
        mx = fmaxf(mx, __shfl_xor(mx, 8));
        float mnew = fmaxf(mrow[r], mx);
        float alpha = __expf(mrow[r] - mnew);
        float p0 = __expf(v[0] - mnew);
        float p1 = __expf(v[1] - mnew);
        float p2 = __expf(v[2] - mnew);
        float p3 = __expf(v[3] - mnew);
        float rs = (p0 + p1) + (p2 + p3);
        rs += __shfl_xor(rs, 1);
        rs += __shfl_xor(rs, 2);
        rs += __shfl_xor(rs, 4);
        rs += __shfl_xor(rs, 8);
        lrow[r] = lrow[r] * alpha + rs;
        mrow[r] = mnew;
#pragma unroll
        for (int nfo = 0; nfo < 8; nfo++) accO[nfo][r] *= alpha;
        p[0][r] = p0; p[1][r] = p1; p[2][r] = p2; p[3][r] = p3;
      }
#pragma unroll
      for (int nf = 0; nf < 4; nf++)
#pragma unroll
        for (int r = 0; r < 4; r++)
          Pl[wave][((l4 << 2) + r) * 72 + nf * 16 + l15] = f2bf(p[nf][r]);
      bf16x8 pa[2];
      pa[0] = *reinterpret_cast<const bf16x8*>(&Pl[wave][l15 * 72 + l4 * 8]);
      pa[1] = *reinterpret_cast<const bf16x8*>(&Pl[wave][l15 * 72 + 32 + l4 * 8]);
#pragma unroll
      for (int nfo = 0; nfo < 8; nfo++) {
        bf16x8 bv0 = *reinterpret_cast<const bf16x8*>(&Vl[(nfo * 16 + l15) * 72 + l4 * 8]);
        bf16x8 bv1 = *reinterpret_cast<const bf16x8*>(&Vl[(nfo * 16 + l15) * 72 + 32 + l4 * 8]);
        accO[nfo] = mfma16(pa[1], bv1, mfma16(pa[0], bv0, accO[nfo]));
      }
    }
    __syncthreads();
  }
  float inv[4];
#pragma unroll
  for (int r = 0; r < 4; r++) inv[r] = 1.0f / lrow[r];
#pragma unroll
  for (int nfo = 0; nfo < 8; nfo++)
#pragma unroll
    for (int r = 0; r < 4; r++) {
      int row = qrow_base + (l4 << 2) + r;
      int col = h * HDIM + nfo * 16 + l15;
      if (row < S_LEN && col < DMODEL)
        ob[(size_t)row * DMODEL + col] = f2bf(accO[nfo][r] * inv[r]);
    }
  if (l15 == 0) {
#pragma unroll
    for (int r = 0; r < 4; r++) {
      int row = qrow_base + (l4 << 2) + r;
      if (row < S_LEN) {
        mbuf[(size_t)h * S_LEN + row] = mrow[r];
        lbuf[(size_t)h * S_LEN + row] = inv[r];  // store 1/l (same division as O path)
      }
    }
  }
}

// ---------------- attn_hh2: column sums, KBLK=64, Q-TILE=64.
// f32 column accumulator (R3-f32 == R6-f64 ordering proved sufficiency);
// lbuf already holds 1/l -> no per-iteration reciprocal.
__global__ __launch_bounds__(256, 4) void attn_hh2(const short* __restrict__ qhp,
                                                   const short* __restrict__ qlp,
                                                   const short* __restrict__ khp,
                                                   const short* __restrict__ klp,
                                                   const float* __restrict__ mbuf,
                                                   const float* __restrict__ lbuf,
                                                   float* __restrict__ hh_h) {
  int h = blockIdx.x;
  int z = blockIdx.y;
  int kt = (z < 16) ? z : (47 - z);
  int g = h >> 2;
  int key0 = kt * 64;
  int tid = threadIdx.x, lane = tid & 63, wave = tid >> 6;
  int l15 = lane & 15, l4 = lane >> 4;
  __shared__ alignas(16) short Qh[64 * 136];
  __shared__ alignas(16) short Ql[64 * 136];
  const size_t qSz = (size_t)S_LEN * DMODEL;
  const size_t kSz = (size_t)S_LEN * KVDIM;
  const size_t mlSz = (size_t)NHQ * S_LEN;
  const float scale = 0.08838834764831845f;
  f32x4 zf = {0.f, 0.f, 0.f, 0.f};

  int keymin = key0 + wave * 16;
  bf16x8 akh[4], akl[4];
#pragma unroll
  for (int ks = 0; ks < 4; ks++) {
    size_t ki = climp((size_t)(keymin + l15) * KVDIM + g * HDIM + ks * 32 + l4 * 8,
                      kSz, 8);
    akh[ks] = *reinterpret_cast<const bf16x8*>(khp + ki);
    akl[ks] = *reinterpret_cast<const bf16x8*>(klp + ki);
  }

  float acc[4] = {0.f, 0.f, 0.f, 0.f};

  for (int q0 = key0; q0 < S_LEN; q0 += 64) {
#pragma unroll
    for (int c = 0; c < 4; c++) {
      int idx = tid + c * 256;
      int r = idx >> 4, c8 = (idx & 15) * 8;
      size_t qi = climp((size_t)(q0 + r) * DMODEL + h * HDIM + c8, qSz, 8);
      *reinterpret_cast<bf16x8*>(&Qh[r * 136 + c8]) =
          *reinterpret_cast<const bf16x8*>(qhp + qi);
      *reinterpret_cast<bf16x8*>(&Ql[r * 136 + c8]) =
          *reinterpret_cast<const bf16x8*>(qlp + qi);
    }
    __syncthreads();
    if (q0 + 63 >= keymin) {
      f32x4 sf[4] = {zf, zf, zf, zf};
#pragma unroll
      for (int ks = 0; ks < 4; ks++)
#pragma unroll
        for (int nf = 0; nf < 4; nf++) {
          int qr = (nf * 16 + l15) * 136 + ks * 32 + l4 * 8;
          bf16x8 bqh = *reinterpret_cast<const bf16x8*>(&Qh[qr]);
          bf16x8 bql = *reinterpret_cast<const bf16x8*>(&Ql[qr]);
          sf[nf] = mfma16(akh[ks], bqh,
                   mfma16(akh[ks], bql,
                   mfma16(akl[ks], bqh, sf[nf])));
        }
#pragma unroll
      for (int nf = 0; nf < 4; nf++) {
        int q = q0 + nf * 16 + l15;
        float mq = mbuf[climp((size_t)h * S_LEN + q, mlSz, 1)];
        float rl = lbuf[climp((size_t)h * S_LEN + q, mlSz, 1)];  // already 1/l
#pragma unroll
        for (int r = 0; r < 4; r++) {
          int key = keymin + (l4 << 2) + r;
          if (q >= key && q < S_LEN)
            acc[r] += __expf(sf[nf][r] * scale - mq) * rl;
        }
      }
    }
    __syncthreads();
  }
#pragma unroll
  for (int r = 0; r < 4; r++) {
    float v = acc[r];
    v += __shfl_xor(v, 1);
    v += __shfl_xor(v, 2);
    v += __shfl_xor(v, 4);
    v += __shfl_xor(v, 8);
    int key = keymin + (l4 << 2) + r;
    if (l15 == 0 && key < S_LEN)
      hh_h[(size_t)h * S_LEN + key] = v;
  }
}

// ---------------- top-k + gather (k reconstructed from planes)
__global__ __launch_bounds__(512) void topk_gather(const float* __restrict__ hh_h,
                                                   const short* __restrict__ khp,
                                                   const short* __restrict__ klp,
                                                   const short* __restrict__ vb,
                                                   float* __restrict__ out_k,
                                                   float* __restrict__ out_v,
                                                   float* __restrict__ out_hh) {
  int g = blockIdx.x, t = threadIdx.x;
  __shared__ float hhg[2048];
  __shared__ float sv[2048];
  __shared__ int si[2048];
  __shared__ int st[128];
  __shared__ int keep[NKEEP];
  const size_t hhSz = (size_t)NHQ * S_LEN;
  const size_t kvSz = (size_t)S_LEN * KVDIM;
#pragma unroll
  for (int i = 0; i < 4; i++) {
    int idx = t + i * 512;
    float s = 0.25f * (hh_h[climp((size_t)(4 * g + 0) * 2048 + idx, hhSz, 1)] +
                       hh_h[climp((size_t)(4 * g + 1) * 2048 + idx, hhSz, 1)] +
                       hh_h[climp((size_t)(4 * g + 2) * 2048 + idx, hhSz, 1)] +
                       hh_h[climp((size_t)(4 * g + 3) * 2048 + idx, hhSz, 1)]);
    hhg[idx] = s;
    sv[idx] = (idx < SEL_N) ? s : -1e30f;
    si[idx] = idx;
  }
  __syncthreads();
  for (int k = 2; k <= 2048; k <<= 1) {
    for (int j = k >> 1; j > 0; j >>= 1) {
#pragma unroll
      for (int pass = 0; pass < 4; pass++) {
        int i = t + pass * 512;
        int ixj = i ^ j;
        if (ixj > i) {
          bool up = ((i & k) == 0);
          float a = sv[i], b = sv[ixj];
          int ia = si[i], ib = si[ixj];
          bool before = (a > b) || (a == b && ia < ib);
          bool doswap = up ? !before : before;
          if (doswap) { sv[i] = b; sv[ixj] = a; si[i] = ib; si[ixj] = ia; }
        }
      }
      __syncthreads();
    }
  }
  if (t < 128) st[t] = si[t];
  __syncthreads();
  for (int k = 2; k <= 128; k <<= 1) {
    for (int j = k >> 1; j > 0; j >>= 1) {
      if (t < 128) {
        int i = t, ixj = i ^ j;
        if (ixj > i) {
          bool up = ((i & k) == 0);
          int a = st[i], b = st[ixj];
          bool doswap = up ? (a > b) : (a < b);
          if (doswap) { st[i] = b; st[ixj] = a; }
        }
      }
      __syncthreads();
    }
  }
  // All 640 keep[] entries initialized by all 512 threads (R1-R6 bug fix).
  for (int i = t; i < NKEEP; i += 512)
    keep[i] = (i < 128) ? st[i] : (SEL_N + (i - 128));
  __syncthreads();
  for (int i = 0; i < 160; i++) {
    int idx = t + i * 512;
    int jj = idx >> 7, d = idx & 127;
    int src = (jj < NKEEP) ? keep[jj] : 0;
    if (src < 0) src = 0;
    if (src >= S_LEN) src = S_LEN - 1;
    size_t oi = ((size_t)g * NKEEP + jj) * HDIM + d;
    if (jj < NKEEP) {
      size_t ki = climp((size_t)src * KVDIM + g * HDIM + d, kvSz, 1);
      out_k[oi] = bf2f(khp[ki]) + bf2f(klp[ki]);
      out_v[oi] = bf2f(vb[ki]);
    }
  }
  for (int i = t; i < NKEEP; i += 512) {
    int src = keep[i];
    if (src < 0) src = 0;
    if (src >= 2048) src = 2047;
    out_hh[(size_t)g * NKEEP + i] = hhg[src];
  }
}

extern "C" void kernel_launch(void* const* d_in, const int* in_sizes, int n_in,
                              void* d_out, int out_size, void* d_ws, size_t ws_size,
                              hipStream_t stream) {
  const float* x = (const float*)d_in[0];
  const float* Wq = (const float*)d_in[1];
  const float* Wk = (const float*)d_in[2];
  const float* Wv = (const float*)d_in[3];
  const float* Wo = (const float*)d_in[4];
  const float* cosb = (const float*)d_in[5];
  const float* sinb = (const float*)d_in[6];
  const int* pos = (const int*)d_in[7];

  char* ws = (char*)d_ws;
  size_t off = 0;
  auto alloc = [&](size_t bytes) {
    void* p = ws + off;
    off += (bytes + 255) & ~(size_t)255;
    return p;
  };
  short* Rg = (short*)alloc((size_t)64 * 1024 * 1024);          // 64 MB
  short* qh = (short*)alloc((size_t)S_LEN * DMODEL * 2);        // 16 MB
  short* ql = (short*)alloc((size_t)S_LEN * DMODEL * 2);        // 16 MB
  short* kh = (short*)alloc((size_t)S_LEN * KVDIM * 2);         // 4 MB
  short* kl = (short*)alloc((size_t)S_LEN * KVDIM * 2);         // 4 MB
  short* vbuf = (short*)alloc((size_t)S_LEN * KVDIM * 2);       // 4 MB
  short* vT = (short*)alloc((size_t)NHKV * HDIM * S_LEN * 2);   // 4 MB
  short* obuf = (short*)alloc((size_t)S_LEN * DMODEL * 2);      // 16 MB
  float* mbuf = (float*)alloc((size_t)NHQ * S_LEN * 4);
  float* lbuf = (float*)alloc((size_t)NHQ * S_LEN * 4);
  float* hh_h = (float*)alloc((size_t)NHQ * S_LEN * 4);
  if (off > ws_size) return;

  short* WqTh = Rg;
  short* WqTl = Rg + (size_t)16777216;   // +32 MB
  short* WkTh = Rg;
  short* WkTl = Rg + (size_t)4194304;    // +8 MB
  short* WvT  = Rg + (size_t)8388608;    // +16 MB
  short* WoT  = Rg + (size_t)12582912;   // +24 MB

  float* out = (float*)d_out;
  float* out_k = out + (size_t)S_LEN * DMODEL;
  float* out_v = out_k + (size_t)NHKV * NKEEP * HDIM;
  float* out_hh = out_v + (size_t)NHKV * NKEEP * HDIM;

  // x planes live in the `out` chunk of d_out (dead until O-projection writes it)
  short* xh = (short*)out;
  short* xl = xh + (size_t)S_LEN * DMODEL;

  split_x<<<(S_LEN * DMODEL / 8) / 256, 256, 0, stream>>>(x, xh, xl);
  transpose_split<<<dim3(64, 64), 256, 0, stream>>>(Wq, WqTh, WqTl, DMODEL, DMODEL);
  gemm_hp2bt<128><<<dim3(16, 32), 256, 0, stream>>>(xh, xl, WqTh, WqTl, qh, ql, S_LEN, DMODEL, DMODEL);
  transpose_split<<<dim3(16, 64), 256, 0, stream>>>(Wk, WkTh, WkTl, DMODEL, KVDIM);
  gemm_hp2bt<64><<<dim3(32, 8), 256, 0, stream>>>(xh, xl, WkTh, WkTl, kh, kl, S_LEN, KVDIM, DMODEL);
  transpose_cvt<<<dim3(16, 64), 256, 0, stream>>>(Wv, WvT, DMODEL, KVDIM);
  gemm_bt<64, 0, 1><<<dim3(32, 8), 256, 0, stream>>>(xh, WvT, vbuf, S_LEN, KVDIM, DMODEL);
  transpose_cvt<<<dim3(64, 64), 256, 0, stream>>>(Wo, WoT, DMODEL, DMODEL);
  rope_planes<32><<<(S_LEN * 32 * 64) / 256, 256, 0, stream>>>(qh, ql, cosb, sinb, pos);
  rope_planes<8><<<(S_LEN * 8 * 64) / 256, 256, 0, stream>>>(kh, kl, cosb, sinb, pos);
  vtrans_k<<<dim3(S_LEN / 8, NHKV), 128, 0, stream>>>(vbuf, vT);
  attn_fwd3<<<dim3(NHQ, 32), 256, 0, stream>>>(qh, ql, kh, kl, vT, obuf, mbuf, lbuf);
  attn_hh2<<<dim3(NHQ, 32), 256, 0, stream>>>(qh, ql, kh, kl, mbuf, lbuf, hh_h);
  gemm_bt<128, 0, 0><<<dim3(16, 32), 256, 0, stream>>>(obuf, WoT, out, S_LEN, DMODEL, DMODEL);
  topk_gather<<<NHKV, 512, 0, stream>>>(hh_h, kh, kl, vbuf, out_k, out_v, out_hh);
}

// Round 18
// 854.011 us; speedup vs baseline: 2.9683x; 1.0184x over previous
//
#include <hip/hip_runtime.h>
#include <cstdint>
#include <cstddef>

typedef __attribute__((ext_vector_type(8))) short bf16x8;
typedef __attribute__((ext_vector_type(4))) short short4v;
typedef __attribute__((ext_vector_type(4))) float f32x4;

#define S_LEN 2048
#define DMODEL 4096
#define NHQ 32
#define NHKV 8
#define HDIM 128
#define KVDIM 1024
#define NKEEP 640
#define SEL_N 1536

__device__ __forceinline__ short f2bf(float f) {
  unsigned u = __float_as_uint(f);
  u += 0x7fffu + ((u >> 16) & 1u);
  return (short)(u >> 16);
}
__device__ __forceinline__ float bf2f(short s) {
  return __uint_as_float(((unsigned)(unsigned short)s) << 16);
}
// split-2, round-to-nearest hi plane: h = rne16(x), l = rne16(x - h). err <= 2^-17|x|
__device__ __forceinline__ void split2r(float x, short& h, short& l) {
  short hh = f2bf(x);
  float r = x - bf2f(hh);
  h = hh;
  l = f2bf(r);
}
__device__ __forceinline__ f32x4 mfma16(bf16x8 a, bf16x8 b, f32x4 c) {
  return __builtin_amdgcn_mfma_f32_16x16x32_bf16(a, b, c, 0, 0, 0);
}
__device__ __forceinline__ size_t climp(size_t i, size_t sz, size_t w) {
  size_t hi = sz - w;
  return i <= hi ? i : hi;
}

// ---------------- prep: fused split_x + Wq/Wk transpose_split + Wv/Wo transpose_cvt
// block ranges: [0,4096) split_x | [4096,8192) Wq | [8192,9216) Wk
//               [9216,10240) Wv | [10240,14336) Wo
__global__ __launch_bounds__(256) void prep(const float* __restrict__ x,
                                            short* __restrict__ xh,
                                            short* __restrict__ xl,
                                            const float* __restrict__ Wq,
                                            short* __restrict__ WqTh,
                                            short* __restrict__ WqTl,
                                            const float* __restrict__ Wk,
                                            short* __restrict__ WkTh,
                                            short* __restrict__ WkTl,
                                            const float* __restrict__ Wv,
                                            short* __restrict__ WvT,
                                            const float* __restrict__ Wo,
                                            short* __restrict__ WoT) {
  __shared__ float tile[64][65];
  int b = blockIdx.x;
  if (b < 4096) {
    // ---- split_x (identical to former split_x kernel)
    size_t i = ((size_t)b * 256 + threadIdx.x) * 8;
    if (i + 8 > (size_t)S_LEN * DMODEL) return;
    const float* p = x + i;
    float4 v0 = *reinterpret_cast<const float4*>(p);
    float4 v1 = *reinterpret_cast<const float4*>(p + 4);
    float vv[8] = {v0.x, v0.y, v0.z, v0.w, v1.x, v1.y, v1.z, v1.w};
    bf16x8 sh, sl;
#pragma unroll
    for (int t = 0; t < 8; t++) { short a2, b2; split2r(vv[t], a2, b2); sh[t] = a2; sl[t] = b2; }
    *reinterpret_cast<bf16x8*>(xh + i) = sh;
    *reinterpret_cast<bf16x8*>(xl + i) = sl;
    return;
  }
  b -= 4096;
  const float* W;
  short* Th;
  short* Tl;
  int N, bx, by, split;
  if (b < 4096) {
    W = Wq; Th = WqTh; Tl = WqTl; N = 4096; split = 1; bx = b & 63; by = b >> 6;
  } else if (b < 5120) {
    b -= 4096; W = Wk; Th = WkTh; Tl = WkTl; N = 1024; split = 1; bx = b & 15; by = b >> 4;
  } else if (b < 6144) {
    b -= 5120; W = Wv; Th = WvT; Tl = nullptr; N = 1024; split = 0; bx = b & 15; by = b >> 4;
  } else {
    b -= 6144; W = Wo; Th = WoT; Tl = nullptr; N = 4096; split = 0; bx = b & 63; by = b >> 6;
  }
  int tx = threadIdx.x;
  int n0 = bx * 64;
  int k0 = by * 64;
#pragma unroll
  for (int i = 0; i < 4; i++) {
    int idx = tx + i * 256;
    int r = idx >> 4, c4 = (idx & 15) * 4;
    float4 v = *reinterpret_cast<const float4*>(W + (size_t)(k0 + r) * N + n0 + c4);
    tile[r][c4 + 0] = v.x;
    tile[r][c4 + 1] = v.y;
    tile[r][c4 + 2] = v.z;
    tile[r][c4 + 3] = v.w;
  }
  __syncthreads();
#pragma unroll
  for (int i = 0; i < 4; i++) {
    int idx = tx + i * 256;
    int rn = idx >> 4, c4 = (idx & 15) * 4;
    size_t wi = (size_t)(n0 + rn) * DMODEL + k0 + c4;  // output row stride = Kd = 4096
    if (split) {
      short4v oh, ol;
#pragma unroll
      for (int j = 0; j < 4; j++) {
        short a2, b2;
        split2r(tile[c4 + j][rn], a2, b2);
        oh[j] = a2; ol[j] = b2;
      }
      *reinterpret_cast<short4v*>(Th + wi) = oh;
      *reinterpret_cast<short4v*>(Tl + wi) = ol;
    } else {
      short4v o;
#pragma unroll
      for (int j = 0; j < 4; j++) o[j] = f2bf(tile[c4 + j][rn]);
      *reinterpret_cast<short4v*>(Th + wi) = o;
    }
  }
}

// ---------------- gemm_hp2bt<BM>: C planes = A planes[M,Kd] * B^T planes[N,Kd]
template <int BM>
__global__ __launch_bounds__(256, (BM == 128) ? 3 : 4)
void gemm_hp2bt(const short* __restrict__ Ath,
                const short* __restrict__ Atl,
                const short* __restrict__ Bth,
                const short* __restrict__ Btl,
                short* __restrict__ Ch,
                short* __restrict__ Cl,
                int M, int N, int Kd) {
  constexpr int MF = BM / 32;
  __shared__ alignas(16) short Ah[BM * 40];
  __shared__ alignas(16) short Alo[BM * 40];
  __shared__ alignas(16) short Bh[128 * 40];
  __shared__ alignas(16) short Bl[128 * 40];
  int tid = threadIdx.x;
  int lane = tid & 63, wave = tid >> 6;
  int l15 = lane & 15, l4 = lane >> 4;
  int m0 = blockIdx.x * BM, n0 = blockIdx.y * 128;
  int wm = (wave >> 1) * (BM / 2), wn = (wave & 1) * 64;
  f32x4 zf = {0.f, 0.f, 0.f, 0.f};
  f32x4 acc[MF][4];
#pragma unroll
  for (int i = 0; i < MF; i++)
#pragma unroll
    for (int j = 0; j < 4; j++) acc[i][j] = zf;

  for (int k0 = 0; k0 < Kd; k0 += 32) {
#pragma unroll
    for (int c = 0; c < BM / 64; c++) {
      int idx = tid + c * 256;
      int r = idx >> 2, c8 = (idx & 3) * 8;
      size_t ai = (size_t)(m0 + r) * Kd + k0 + c8;
      *reinterpret_cast<bf16x8*>(&Ah[r * 40 + c8]) =
          *reinterpret_cast<const bf16x8*>(Ath + ai);
      *reinterpret_cast<bf16x8*>(&Alo[r * 40 + c8]) =
          *reinterpret_cast<const bf16x8*>(Atl + ai);
    }
#pragma unroll
    for (int c = 0; c < 2; c++) {
      int idx = tid + c * 256;
      int r = idx >> 2, c8 = (idx & 3) * 8;
      size_t bi = (size_t)(n0 + r) * Kd + k0 + c8;
      *reinterpret_cast<bf16x8*>(&Bh[r * 40 + c8]) =
          *reinterpret_cast<const bf16x8*>(Bth + bi);
      *reinterpret_cast<bf16x8*>(&Bl[r * 40 + c8]) =
          *reinterpret_cast<const bf16x8*>(Btl + bi);
    }
    __syncthreads();
    bf16x8 ah[MF], al[MF], bh4[4], bl4[4];
#pragma unroll
    for (int mf = 0; mf < MF; mf++) {
      int ar = (wm + mf * 16 + l15) * 40 + l4 * 8;
      ah[mf] = *reinterpret_cast<const bf16x8*>(&Ah[ar]);
      al[mf] = *reinterpret_cast<const bf16x8*>(&Alo[ar]);
    }
#pragma unroll
    for (int nf = 0; nf < 4; nf++) {
      int br = (wn + nf * 16 + l15) * 40 + l4 * 8;
      bh4[nf] = *reinterpret_cast<const bf16x8*>(&Bh[br]);
      bl4[nf] = *reinterpret_cast<const bf16x8*>(&Bl[br]);
    }
#pragma unroll
    for (int mf = 0; mf < MF; mf++)
#pragma unroll
      for (int nf = 0; nf < 4; nf++)
        acc[mf][nf] = mfma16(ah[mf], bh4[nf],
                      mfma16(al[mf], bh4[nf],
                      mfma16(ah[mf], bl4[nf], acc[mf][nf])));
    __syncthreads();
  }
  int rbase = m0 + wm + (l4 << 2);
  int cbase = n0 + wn + l15;
#pragma unroll
  for (int mf = 0; mf < MF; mf++)
#pragma unroll
    for (int nf = 0; nf < 4; nf++)
#pragma unroll
      for (int r = 0; r < 4; r++) {
        int row = rbase + mf * 16 + r;
        int col = cbase + nf * 16;
        if (row < M && col < N) {
          size_t ci = (size_t)row * N + col;
          short h, l;
          split2r(acc[mf][nf][r], h, l);
          Ch[ci] = h;
          Cl[ci] = l;
        }
      }
}

// ---------------- gemm_bt<BM>: plain bf16 GEMM with B^T (N,Kd) bf16 input
template <int BM, int A_F32, int STORE_BF16>
__global__ __launch_bounds__(256, (BM == 128) ? 3 : 4)
void gemm_bt(const void* __restrict__ Av,
             const short* __restrict__ Bt,
             void* __restrict__ Cv,
             int M, int N, int Kd) {
  constexpr int MF = BM / 32;
  __shared__ alignas(16) short Al[BM * 72];
  __shared__ alignas(16) short Bl[128 * 72];
  int tid = threadIdx.x;
  int lane = tid & 63, wave = tid >> 6;
  int l15 = lane & 15, l4 = lane >> 4;
  int m0 = blockIdx.x * BM, n0 = blockIdx.y * 128;
  int wm = (wave >> 1) * (BM / 2), wn = (wave & 1) * 64;
  f32x4 zf = {0.f, 0.f, 0.f, 0.f};
  f32x4 acc[MF][4];
#pragma unroll
  for (int i = 0; i < MF; i++)
#pragma unroll
    for (int j = 0; j < 4; j++) acc[i][j] = zf;

  for (int k0 = 0; k0 < Kd; k0 += 64) {
#pragma unroll
    for (int c = 0; c < BM / 32; c++) {
      int idx = tid + c * 256;
      int r = idx >> 3, k8 = (idx & 7) * 8;
      bf16x8 a;
      if constexpr (A_F32 != 0) {
        const float* Ap = (const float*)Av + (size_t)(m0 + r) * Kd + k0 + k8;
        float4 v0 = *reinterpret_cast<const float4*>(Ap);
        float4 v1 = *reinterpret_cast<const float4*>(Ap + 4);
        a[0] = f2bf(v0.x); a[1] = f2bf(v0.y); a[2] = f2bf(v0.z); a[3] = f2bf(v0.w);
        a[4] = f2bf(v1.x); a[5] = f2bf(v1.y); a[6] = f2bf(v1.z); a[7] = f2bf(v1.w);
      } else {
        a = *reinterpret_cast<const bf16x8*>((const short*)Av + (size_t)(m0 + r) * Kd + k0 + k8);
      }
      *reinterpret_cast<bf16x8*>(&Al[r * 72 + k8]) = a;
    }
#pragma unroll
    for (int c = 0; c < 4; c++) {
      int idx = tid + c * 256;
      int r = idx >> 3, k8 = (idx & 7) * 8;
      *reinterpret_cast<bf16x8*>(&Bl[r * 72 + k8]) =
          *reinterpret_cast<const bf16x8*>(Bt + (size_t)(n0 + r) * Kd + k0 + k8);
    }
    __syncthreads();
    bf16x8 af[MF][2], bfr[4][2];
#pragma unroll
    for (int mf = 0; mf < MF; mf++)
#pragma unroll
      for (int ks = 0; ks < 2; ks++)
        af[mf][ks] = *reinterpret_cast<const bf16x8*>(
            &Al[(wm + mf * 16 + l15) * 72 + ks * 32 + l4 * 8]);
#pragma unroll
    for (int nf = 0; nf < 4; nf++)
#pragma unroll
      for (int ks = 0; ks < 2; ks++)
        bfr[nf][ks] = *reinterpret_cast<const bf16x8*>(
            &Bl[(wn + nf * 16 + l15) * 72 + ks * 32 + l4 * 8]);
#pragma unroll
    for (int ks = 0; ks < 2; ks++)
#pragma unroll
      for (int mf = 0; mf < MF; mf++)
#pragma unroll
        for (int nf = 0; nf < 4; nf++)
          acc[mf][nf] = mfma16(af[mf][ks], bfr[nf][ks], acc[mf][nf]);
    __syncthreads();
  }
  int rbase = m0 + wm + (l4 << 2);
  int cbase = n0 + wn + l15;
#pragma unroll
  for (int mf = 0; mf < MF; mf++)
#pragma unroll
    for (int nf = 0; nf < 4; nf++)
#pragma unroll
      for (int r = 0; r < 4; r++) {
        int row = rbase + mf * 16 + r;
        int col = cbase + nf * 16;
        if (row < M && col < N) {
          size_t ci = (size_t)row * N + col;
          float v = acc[mf][nf][r];
          if constexpr (STORE_BF16 != 0)
            ((short*)Cv)[ci] = f2bf(v);
          else
            ((float*)Cv)[ci] = v;
        }
      }
}

// ---------------- post: fused rope(q planes) + rope(k planes) + vtrans
// block ranges: [0,16384) rope q | [16384,20480) rope k | [20480,21504) vtrans
__global__ __launch_bounds__(256) void post(short* __restrict__ qh,
                                            short* __restrict__ ql,
                                            short* __restrict__ kh,
                                            short* __restrict__ kl,
                                            const float* __restrict__ cosb,
                                            const float* __restrict__ sinb,
                                            const int* __restrict__ pos,
                                            const short* __restrict__ vbuf,
                                            short* __restrict__ vT) {
  int b = blockIdx.x;
  if (b < 20480) {
    short* bh;
    short* bl;
    int d, h, s;
    if (b < 16384) {  // q: NH=32
      int idx = b * 256 + threadIdx.x;
      bh = qh; bl = ql;
      d = idx & 63;
      h = (idx >> 6) & 31;
      s = idx >> 11;
      size_t base = ((size_t)s * 32 + h) * 128 + d;
      float lo = bf2f(bh[base]) + bf2f(bl[base]);
      float hi = bf2f(bh[base + 64]) + bf2f(bl[base + 64]);
      int p = pos[s];
      if (p < 0) p = 0;
      if (p >= S_LEN) p = S_LEN - 1;
      float c0 = cosb[p * 128 + d], s0 = sinb[p * 128 + d];
      float c1 = cosb[p * 128 + d + 64], s1 = sinb[p * 128 + d + 64];
      float o0 = lo * c0 - hi * s0;
      float o1 = hi * c1 + lo * s1;
      short a2, b2;
      split2r(o0, a2, b2);
      bh[base] = a2; bl[base] = b2;
      split2r(o1, a2, b2);
      bh[base + 64] = a2; bl[base + 64] = b2;
    } else {  // k: NH=8
      int idx = (b - 16384) * 256 + threadIdx.x;
      bh = kh; bl = kl;
      d = idx & 63;
      h = (idx >> 6) & 7;
      s = idx >> 9;
      size_t base = ((size_t)s * 8 + h) * 128 + d;
      float lo = bf2f(bh[base]) + bf2f(bl[base]);
      float hi = bf2f(bh[base + 64]) + bf2f(bl[base + 64]);
      int p = pos[s];
      if (p < 0) p = 0;
      if (p >= S_LEN) p = S_LEN - 1;
      float c0 = cosb[p * 128 + d], s0 = sinb[p * 128 + d];
      float c1 = cosb[p * 128 + d + 64], s1 = sinb[p * 128 + d + 64];
      float o0 = lo * c0 - hi * s0;
      float o1 = hi * c1 + lo * s1;
      short a2, b2;
      split2r(o0, a2, b2);
      bh[base] = a2; bl[base] = b2;
      split2r(o1, a2, b2);
      bh[base + 64] = a2; bl[base + 64] = b2;
    }
    return;
  }
  // ---- vtrans: (s, g, d) -> (g, d, s) bf16
  int w = (b - 20480) * 256 + threadIdx.x;  // [0, 262144)
  int d = w & 127;
  int sblk = (w >> 7) & 255;
  int g = w >> 15;
  int s0 = sblk * 8;
  const size_t vSz = (size_t)S_LEN * KVDIM;
  bf16x8 vals;
#pragma unroll
  for (int i = 0; i < 8; i++)
    vals[i] = vbuf[climp((size_t)(s0 + i) * KVDIM + g * HDIM + d, vSz, 1)];
  *reinterpret_cast<bf16x8*>(vT + climp(((size_t)g * HDIM + d) * S_LEN + s0,
                                        (size_t)NHKV * HDIM * S_LEN, 8)) = vals;
}

// ---------------- attn_fwd3: FUSED, QBLK=64, K-TILE=64. lbuf stores 1/l.
__global__ __launch_bounds__(256, 2) void attn_fwd3(const short* __restrict__ qhp,
                                                    const short* __restrict__ qlp,
                                                    const short* __restrict__ khp,
                                                    const short* __restrict__ klp,
                                                    const short* __restrict__ vT,
                                                    short* __restrict__ ob,
                                                    float* __restrict__ mbuf,
                                                    float* __restrict__ lbuf) {
  int h = blockIdx.x;
  int z = blockIdx.y;
  int qt = (z < 16) ? z : (47 - z);
  int g = h >> 2;
  int q0 = qt * 64;
  int tid = threadIdx.x, lane = tid & 63, wave = tid >> 6;
  int l15 = lane & 15, l4 = lane >> 4;
  __shared__ alignas(16) short Kh[64 * 136];
  __shared__ alignas(16) short Kl2[64 * 136];
  __shared__ alignas(16) short Vl[128 * 72];
  __shared__ alignas(16) short Pl[4][16 * 72];
  const size_t qSz = (size_t)S_LEN * DMODEL;
  const size_t kSz = (size_t)S_LEN * KVDIM;
  const size_t vtSz = (size_t)NHKV * HDIM * S_LEN;

  int qrow_base = q0 + wave * 16;
  bf16x8 qh[4], ql[4];
#pragma unroll
  for (int ks = 0; ks < 4; ks++) {
    size_t qi = climp((size_t)(qrow_base + l15) * DMODEL + h * HDIM + ks * 32 + l4 * 8,
                      qSz, 8);
    qh[ks] = *reinterpret_cast<const bf16x8*>(qhp + qi);
    ql[ks] = *reinterpret_cast<const bf16x8*>(qlp + qi);
  }

  f32x4 zf = {0.f, 0.f, 0.f, 0.f};
  f32x4 accO[8];
  float mrow[4], lrow[4];
#pragma unroll
  for (int nfo = 0; nfo < 8; nfo++) accO[nfo] = zf;
#pragma unroll
  for (int r = 0; r < 4; r++) { mrow[r] = -1e30f; lrow[r] = 0.f; }
  int nkt = qt + 1;
  const float scale = 0.08838834764831845f;

  for (int kt = 0; kt < nkt; kt++) {
    int k0 = kt * 64;
#pragma unroll
    for (int c = 0; c < 4; c++) {
      int idx = tid + c * 256;
      int r = idx >> 4, c8 = (idx & 15) * 8;
      size_t ki = climp((size_t)(k0 + r) * KVDIM + g * HDIM + c8, kSz, 8);
      *reinterpret_cast<bf16x8*>(&Kh[r * 136 + c8]) =
          *reinterpret_cast<const bf16x8*>(khp + ki);
      *reinterpret_cast<bf16x8*>(&Kl2[r * 136 + c8]) =
          *reinterpret_cast<const bf16x8*>(klp + ki);
    }
#pragma unroll
    for (int c = 0; c < 4; c++) {
      int idx = tid + c * 256;
      int r = idx >> 3, c8 = (idx & 7) * 8;
      *reinterpret_cast<bf16x8*>(&Vl[r * 72 + c8]) =
          *reinterpret_cast<const bf16x8*>(
              vT + climp(((size_t)g * HDIM + r) * S_LEN + k0 + c8, vtSz, 8));
    }
    __syncthreads();
    {
      f32x4 sf[4] = {zf, zf, zf, zf};
#pragma unroll
      for (int ks = 0; ks < 4; ks++)
#pragma unroll
        for (int nf = 0; nf < 4; nf++) {
          int kr = (nf * 16 + l15) * 136 + ks * 32 + l4 * 8;
          bf16x8 bh = *reinterpret_cast<const bf16x8*>(&Kh[kr]);
          bf16x8 bl = *reinterpret_cast<const bf16x8*>(&Kl2[kr]);
          sf[nf] = mfma16(qh[ks], bh,
                   mfma16(ql[ks], bh,
                   mfma16(qh[ks], bl, sf[nf])));
        }
      float p[4][4];
#pragma unroll
      for (int r = 0; r < 4; r++) {
        int qg = qrow_base + (l4 << 2) + r;
        float v[4];
#pragma unroll
        for (int nf = 0; nf < 4; nf++) {
          v[nf] = sf[nf][r] * scale;
          if (k0 + nf * 16 + l15 > qg) v[nf] = -1e9f;
        }
        float mx = fmaxf(fmaxf(v[0], v[1]), fmaxf(v[2], v[3]));
        mx = fmaxf(mx, __shfl_xor(mx, 1));
        mx = fmaxf(mx, __shfl_xor(mx, 2));
        mx = fmaxf(mx, __shfl_xor(mx, 4));
        mx = fmaxf(mx, __shfl_xor(mx, 8));
        float mnew = fmaxf(mrow[r], mx);
        float alpha = __expf(mrow[r] - mnew);
        float p0 = __expf(v[0] - mnew);
        float p1 = __expf(v[1] - mnew);
        float p2 = __expf(v[2] - mnew);
        float p3 = __expf(v[3] - mnew);
        float rs = (p0 + p1) + (p2 + p3);
        rs += __shfl_xor(rs, 1);
        rs += __shfl_xor(rs, 2);
        rs += __shfl_xor(rs, 4);
        rs += __shfl_xor(rs, 8);
        lrow[r] = lrow[r] * alpha + rs;
        mrow[r] = mnew;
#pragma unroll
        for (int nfo = 0; nfo < 8; nfo++) accO[nfo][r] *= alpha;
        p[0][r] = p0; p[1][r] = p1; p[2][r] = p2; p[3][r] = p3;
      }
#pragma unroll
      for (int nf = 0; nf < 4; nf++)
#pragma unroll
        for (int r = 0; r < 4; r++)
          Pl[wave][((l4 << 2) + r) * 72 + nf * 16 + l15] = f2bf(p[nf][r]);
      bf16x8 pa[2];
      pa[0] = *reinterpret_cast<const bf16x8*>(&Pl[wave][l15 * 72 + l4 * 8]);
      pa[1] = *reinterpret_cast<const bf16x8*>(&Pl[wave][l15 * 72 + 32 + l4 * 8]);
#pragma unroll
      for (int nfo = 0; nfo < 8; nfo++) {
        bf16x8 bv0 = *reinterpret_cast<const bf16x8*>(&Vl[(nfo * 16 + l15) * 72 + l4 * 8]);
        bf16x8 bv1 = *reinterpret_cast<const bf16x8*>(&Vl[(nfo * 16 + l15) * 72 + 32 + l4 * 8]);
        accO[nfo] = mfma16(pa[1], bv1, mfma16(pa[0], bv0, accO[nfo]));
      }
    }
    __syncthreads();
  }
  float inv[4];
#pragma unroll
  for (int r = 0; r < 4; r++) inv[r] = 1.0f / lrow[r];
#pragma unroll
  for (int nfo = 0; nfo < 8; nfo++)
#pragma unroll
    for (int r = 0; r < 4; r++) {
      int row = qrow_base + (l4 << 2) + r;
      int col = h * HDIM + nfo * 16 + l15;
      if (row < S_LEN && col < DMODEL)
        ob[(size_t)row * DMODEL + col] = f2bf(accO[nfo][r] * inv[r]);
    }
  if (l15 == 0) {
#pragma unroll
    for (int r = 0; r < 4; r++) {
      int row = qrow_base + (l4 << 2) + r;
      if (row < S_LEN) {
        mbuf[(size_t)h * S_LEN + row] = mrow[r];
        lbuf[(size_t)h * S_LEN + row] = inv[r];
      }
    }
  }
}

// ---------------- attn_hh2: column sums, KBLK=64, Q-TILE=64, f32 col-acc.
__global__ __launch_bounds__(256, 4) void attn_hh2(const short* __restrict__ qhp,
                                                   const short* __restrict__ qlp,
                                                   const short* __restrict__ khp,
                                                   const short* __restrict__ klp,
                                                   const float* __restrict__ mbuf,
                                                   const float* __restrict__ lbuf,
                                                   float* __restrict__ hh_h) {
  int h = blockIdx.x;
  int z = blockIdx.y;
  int kt = (z < 16) ? z : (47 - z);
  int g = h >> 2;
  int key0 = kt * 64;
  int tid = threadIdx.x, lane = tid & 63, wave = tid >> 6;
  int l15 = lane & 15, l4 = lane >> 4;
  __shared__ alignas(16) short Qh[64 * 136];
  __shared__ alignas(16) short Ql[64 * 136];
  const size_t qSz = (size_t)S_LEN * DMODEL;
  const size_t kSz = (size_t)S_LEN * KVDIM;
  const size_t mlSz = (size_t)NHQ * S_LEN;
  const float scale = 0.08838834764831845f;
  f32x4 zf = {0.f, 0.f, 0.f, 0.f};

  int keymin = key0 + wave * 16;
  bf16x8 akh[4], akl[4];
#pragma unroll
  for (int ks = 0; ks < 4; ks++) {
    size_t ki = climp((size_t)(keymin + l15) * KVDIM + g * HDIM + ks * 32 + l4 * 8,
                      kSz, 8);
    akh[ks] = *reinterpret_cast<const bf16x8*>(khp + ki);
    akl[ks] = *reinterpret_cast<const bf16x8*>(klp + ki);
  }

  float acc[4] = {0.f, 0.f, 0.f, 0.f};

  for (int q0 = key0; q0 < S_LEN; q0 += 64) {
#pragma unroll
    for (int c = 0; c < 4; c++) {
      int idx = tid + c * 256;
      int r = idx >> 4, c8 = (idx & 15) * 8;
      size_t qi = climp((size_t)(q0 + r) * DMODEL + h * HDIM + c8, qSz, 8);
      *reinterpret_cast<bf16x8*>(&Qh[r * 136 + c8]) =
          *reinterpret_cast<const bf16x8*>(qhp + qi);
      *reinterpret_cast<bf16x8*>(&Ql[r * 136 + c8]) =
          *reinterpret_cast<const bf16x8*>(qlp + qi);
    }
    __syncthreads();
    if (q0 + 63 >= keymin) {
      f32x4 sf[4] = {zf, zf, zf, zf};
#pragma unroll
      for (int ks = 0; ks < 4; ks++)
#pragma unroll
        for (int nf = 0; nf < 4; nf++) {
          int qr = (nf * 16 + l15) * 136 + ks * 32 + l4 * 8;
          bf16x8 bqh = *reinterpret_cast<const bf16x8*>(&Qh[qr]);
          bf16x8 bql = *reinterpret_cast<const bf16x8*>(&Ql[qr]);
          sf[nf] = mfma16(akh[ks], bqh,
                   mfma16(akh[ks], bql,
                   mfma16(akl[ks], bqh, sf[nf])));
        }
#pragma unroll
      for (int nf = 0; nf < 4; nf++) {
        int q = q0 + nf * 16 + l15;
        float mq = mbuf[climp((size_t)h * S_LEN + q, mlSz, 1)];
        float rl = lbuf[climp((size_t)h * S_LEN + q, mlSz, 1)];  // already 1/l
#pragma unroll
        for (int r = 0; r < 4; r++) {
          int key = keymin + (l4 << 2) + r;
          if (q >= key && q < S_LEN)
            acc[r] += __expf(sf[nf][r] * scale - mq) * rl;
        }
      }
    }
    __syncthreads();
  }
#pragma unroll
  for (int r = 0; r < 4; r++) {
    float v = acc[r];
    v += __shfl_xor(v, 1);
    v += __shfl_xor(v, 2);
    v += __shfl_xor(v, 4);
    v += __shfl_xor(v, 8);
    int key = keymin + (l4 << 2) + r;
    if (l15 == 0 && key < S_LEN)
      hh_h[(size_t)h * S_LEN + key] = v;
  }
}

// ---------------- top-k + gather (k reconstructed from planes)
__global__ __launch_bounds__(512) void topk_gather(const float* __restrict__ hh_h,
                                                   const short* __restrict__ khp,
                                                   const short* __restrict__ klp,
                                                   const short* __restrict__ vb,
                                                   float* __restrict__ out_k,
                                                   float* __restrict__ out_v,
                                                   float* __restrict__ out_hh) {
  int g = blockIdx.x, t = threadIdx.x;
  __shared__ float hhg[2048];
  __shared__ float sv[2048];
  __shared__ int si[2048];
  __shared__ int st[128];
  __shared__ int keep[NKEEP];
  const size_t hhSz = (size_t)NHQ * S_LEN;
  const size_t kvSz = (size_t)S_LEN * KVDIM;
#pragma unroll
  for (int i = 0; i < 4; i++) {
    int idx = t + i * 512;
    float s = 0.25f * (hh_h[climp((size_t)(4 * g + 0) * 2048 + idx, hhSz, 1)] +
                       hh_h[climp((size_t)(4 * g + 1) * 2048 + idx, hhSz, 1)] +
                       hh_h[climp((size_t)(4 * g + 2) * 2048 + idx, hhSz, 1)] +
                       hh_h[climp((size_t)(4 * g + 3) * 2048 + idx, hhSz, 1)]);
    hhg[idx] = s;
    sv[idx] = (idx < SEL_N) ? s : -1e30f;
    si[idx] = idx;
  }
  __syncthreads();
  for (int k = 2; k <= 2048; k <<= 1) {
    for (int j = k >> 1; j > 0; j >>= 1) {
#pragma unroll
      for (int pass = 0; pass < 4; pass++) {
        int i = t + pass * 512;
        int ixj = i ^ j;
        if (ixj > i) {
          bool up = ((i & k) == 0);
          float a = sv[i], b = sv[ixj];
          int ia = si[i], ib = si[ixj];
          bool before = (a > b) || (a == b && ia < ib);
          bool doswap = up ? !before : before;
          if (doswap) { sv[i] = b; sv[ixj] = a; si[i] = ib; si[ixj] = ia; }
        }
      }
      __syncthreads();
    }
  }
  if (t < 128) st[t] = si[t];
  __syncthreads();
  for (int k = 2; k <= 128; k <<= 1) {
    for (int j = k >> 1; j > 0; j >>= 1) {
      if (t < 128) {
        int i = t, ixj = i ^ j;
        if (ixj > i) {
          bool up = ((i & k) == 0);
          int a = st[i], b = st[ixj];
          bool doswap = up ? (a > b) : (a < b);
          if (doswap) { st[i] = b; st[ixj] = a; }
        }
      }
      __syncthreads();
    }
  }
  // All 640 keep[] entries initialized by all 512 threads (R1-R6 bug fix).
  for (int i = t; i < NKEEP; i += 512)
    keep[i] = (i < 128) ? st[i] : (SEL_N + (i - 128));
  __syncthreads();
  for (int i = 0; i < 160; i++) {
    int idx = t + i * 512;
    int jj = idx >> 7, d = idx & 127;
    int src = (jj < NKEEP) ? keep[jj] : 0;
    if (src < 0) src = 0;
    if (src >= S_LEN) src = S_LEN - 1;
    size_t oi = ((size_t)g * NKEEP + jj) * HDIM + d;
    if (jj < NKEEP) {
      size_t ki = climp((size_t)src * KVDIM + g * HDIM + d, kvSz, 1);
      out_k[oi] = bf2f(khp[ki]) + bf2f(klp[ki]);
      out_v[oi] = bf2f(vb[ki]);
    }
  }
  for (int i = t; i < NKEEP; i += 512) {
    int src = keep[i];
    if (src < 0) src = 0;
    if (src >= 2048) src = 2047;
    out_hh[(size_t)g * NKEEP + i] = hhg[src];
  }
}

extern "C" void kernel_launch(void* const* d_in, const int* in_sizes, int n_in,
                              void* d_out, int out_size, void* d_ws, size_t ws_size,
                              hipStream_t stream) {
  const float* x = (const float*)d_in[0];
  const float* Wq = (const float*)d_in[1];
  const float* Wk = (const float*)d_in[2];
  const float* Wv = (const float*)d_in[3];
  const float* Wo = (const float*)d_in[4];
  const float* cosb = (const float*)d_in[5];
  const float* sinb = (const float*)d_in[6];
  const int* pos = (const int*)d_in[7];

  char* ws = (char*)d_ws;
  size_t off = 0;
  auto alloc = [&](size_t bytes) {
    void* p = ws + off;
    off += (bytes + 255) & ~(size_t)255;
    return p;
  };
  short* Rg = (short*)alloc((size_t)160 * 1024 * 1024 / 2 * 2);  // 160 MB? no -- see below
  // NOTE: layout identical to R17: 64MB shared weight region
  (void)Rg;
  off = 0;
  Rg = (short*)alloc((size_t)64 * 1024 * 1024);                 // 64 MB
  short* qh = (short*)alloc((size_t)S_LEN * DMODEL * 2);        // 16 MB
  short* ql = (short*)alloc((size_t)S_LEN * DMODEL * 2);        // 16 MB
  short* kh = (short*)alloc((size_t)S_LEN * KVDIM * 2);         // 4 MB
  short* kl = (short*)alloc((size_t)S_LEN * KVDIM * 2);         // 4 MB
  short* vbuf = (short*)alloc((size_t)S_LEN * KVDIM * 2);       // 4 MB
  short* vT = (short*)alloc((size_t)NHKV * HDIM * S_LEN * 2);   // 4 MB
  short* obuf = (short*)alloc((size_t)S_LEN * DMODEL * 2);      // 16 MB
  float* mbuf = (float*)alloc((size_t)NHQ * S_LEN * 4);
  float* lbuf = (float*)alloc((size_t)NHQ * S_LEN * 4);
  float* hh_h = (float*)alloc((size_t)NHQ * S_LEN * 4);
  if (off > ws_size) return;

  // Weight-transpose layout: all five outputs live simultaneously now
  //   WqTh 32MB @0 | WqTl 32MB @+32MB  -- reuses the same 64MB region as before,
  //   but WkT/WvT/WoT must not overlap WqT while prep runs: move them after obuf?
  // Budget check: 64 + 16+16+4+4+4+4+16 + ~0.1 = ~128 MB used; WkTh/l (16MB) +
  // WvT (8MB) + WoT (32MB) = 56MB more -> 184 MB total. R17 used ~128MB and
  // passed ws_size; 184MB is unverified. Instead: keep the proven 64MB region
  // by ordering prep so Wq transpose uses [0,64) and WkT/WvT/WoT ALSO need
  // space -> allocate the extra 56MB explicitly (guard protects us if short).
  short* WqTh = Rg;                       // 32 MB
  short* WqTl = Rg + (size_t)16777216;    // 32 MB
  short* WkTh = (short*)alloc((size_t)8 * 1024 * 1024);   // 8 MB
  short* WkTl = (short*)alloc((size_t)8 * 1024 * 1024);   // 8 MB
  short* WvT  = (short*)alloc((size_t)8 * 1024 * 1024);   // 8 MB
  short* WoT  = (short*)alloc((size_t)32 * 1024 * 1024);  // 32 MB
  if (off > ws_size) return;  // clean poison-fail diagnostic if ws too small

  float* out = (float*)d_out;
  float* out_k = out + (size_t)S_LEN * DMODEL;
  float* out_v = out_k + (size_t)NHKV * NKEEP * HDIM;
  float* out_hh = out_v + (size_t)NHKV * NKEEP * HDIM;

  // x planes live in the `out` chunk of d_out (dead until O-projection writes it)
  short* xh = (short*)out;
  short* xl = xh + (size_t)S_LEN * DMODEL;

  // fused prep: split_x + all 4 weight transposes (one launch)
  prep<<<14336, 256, 0, stream>>>(x, xh, xl, Wq, WqTh, WqTl, Wk, WkTh, WkTl,
                                  Wv, WvT, Wo, WoT);
  gemm_hp2bt<128><<<dim3(16, 32), 256, 0, stream>>>(xh, xl, WqTh, WqTl, qh, ql, S_LEN, DMODEL, DMODEL);
  gemm_hp2bt<64><<<dim3(32, 8), 256, 0, stream>>>(xh, xl, WkTh, WkTl, kh, kl, S_LEN, KVDIM, DMODEL);
  gemm_bt<64, 0, 1><<<dim3(32, 8), 256, 0, stream>>>(xh, WvT, vbuf, S_LEN, KVDIM, DMODEL);
  // fused post: rope(q) + rope(k) + vtrans (one launch)
  post<<<21504, 256, 0, stream>>>(qh, ql, kh, kl, cosb, sinb, pos, vbuf, vT);
  attn_fwd3<<<dim3(NHQ, 32), 256, 0, stream>>>(qh, ql, kh, kl, vT, obuf, mbuf, lbuf);
  attn_hh2<<<dim3(NHQ, 32), 256, 0, stream>>>(qh, ql, kh, kl, mbuf, lbuf, hh_h);
  gemm_bt<128, 0, 0><<<dim3(16, 32), 256, 0, stream>>>(obuf, WoT, out, S_LEN, DMODEL, DMODEL);
  topk_gather<<<NHKV, 512, 0, stream>>>(hh_h, kh, kl, vbuf, out_k, out_v, out_hh);
}